// Round 2
// baseline (866.149 us; speedup 1.0000x reference)
//
#include <hip/hip_runtime.h>
#include <hip/hip_bf16.h>

typedef __hip_bfloat16 bf16;

#define N_NODES 50000
#define N_EDGES 800000
#define NB 64

// param block offsets (floats)
#define P_W1 0
#define P_A1S 384
#define P_A1D 512
#define P_B1 640
#define P_W2 768
#define P_A2S 8960
#define P_A2D 9024
#define P_B2 9088
#define P_W3 9152
#define P_A3S 17344
#define P_A3D 17472
#define P_B3 17600
#define P_W4 17728
#define P_A4S 18112
#define P_A4D 18115
#define P_B4 18118
#define P_WC1 18121
#define P_BC1 20169
#define P_WC2 20201
#define P_BC2 20265
#define P_TOTAL 20267

__device__ __forceinline__ float wave_max(float v) {
#pragma unroll
    for (int o = 32; o >= 1; o >>= 1) v = fmaxf(v, __shfl_xor(v, o, 64));
    return v;
}
__device__ __forceinline__ float wave_sum(float v) {
#pragma unroll
    for (int o = 32; o >= 1; o >>= 1) v += __shfl_xor(v, o, 64);
    return v;
}

// runtime dtype helpers: flags[0]=float-inputs-are-bf16, flags[1]=ints-are-int64
__device__ __forceinline__ int ld_idx(const void* p, long long i, int is64) {
    return is64 ? (int)((const long long*)p)[i] : ((const int*)p)[i];
}
__device__ __forceinline__ void st_out(void* p, long long i, float v, int isbf) {
    if (isbf) ((bf16*)p)[i] = __float2bfloat16(v);
    else ((float*)p)[i] = v;
}

// ---------------- dtype detection ----------------
__global__ void k_detect(const unsigned short* xraw, const unsigned int* eraw,
                         int* flags) {
    if (threadIdx.x != 0 || blockIdx.x != 0) return;
    // x ~ N(0,1). If bf16: even uint16s are bf16 values -> (bits>>8)&0x7F in [58,65]
    // for |v| in [2^-10, 2^3]. If f32: even uint16s are mantissa-low words (uniform).
    int cnt = 0;
    for (int i = 0; i < 256; i++) {
        unsigned int hb = (xraw[2 * i] >> 8) & 0x7F;
        if (hb >= 58 && hb <= 65) cnt++;
    }
    flags[0] = (cnt >= 200) ? 1 : 0;
    // edge_index values < 2^31, nonneg. If int64: odd uint32 words (high words) are 0.
    int z = 0;
    for (int i = 0; i < 64; i++)
        if (eraw[2 * i + 1] == 0u) z++;
    flags[1] = (z >= 60) ? 1 : 0;
}

// ---------------- input/param convert to f32 ----------------
struct PTab {
    const void* src[20];
    int off[20];
    int n[20];
};

__global__ void k_cvt_params(PTab tab, const int* __restrict__ flags,
                             float* __restrict__ pblock) {
    int t = blockIdx.x;
    const void* s = tab.src[t];
    float* d = pblock + tab.off[t];
    int n = tab.n[t];
    int isbf = flags[0];
    for (int i = threadIdx.x; i < n; i += blockDim.x)
        d[i] = isbf ? __bfloat162float(((const bf16*)s)[i]) : ((const float*)s)[i];
}

__global__ void k_cvt_x(const void* __restrict__ x, const int* __restrict__ flags,
                        float* __restrict__ buf) {
    int i = blockIdx.x * blockDim.x + threadIdx.x;
    if (i < N_NODES * 3)
        buf[i] = flags[0] ? __bfloat162float(((const bf16*)x)[i]) : ((const float*)x)[i];
}

// ---------------- CSR build ----------------
__global__ void k_init_counts(int* __restrict__ counts) {
    int i = blockIdx.x * blockDim.x + threadIdx.x;
    if (i < N_NODES) counts[i] = 1;  // self loop
}

__global__ void k_count(const void* __restrict__ eidx, const int* __restrict__ flags,
                        int* __restrict__ counts) {
    int e = blockIdx.x * blockDim.x + threadIdx.x;
    if (e < N_EDGES) {
        int r = ld_idx(eidx, (long long)N_EDGES + e, flags[1]);
        atomicAdd(&counts[r], 1);
    }
}

#define SCAN_T 1024
__global__ void k_scan(const int* __restrict__ counts, int* __restrict__ off) {
    __shared__ int part[SCAN_T];
    int t = threadIdx.x;
    const int per = (N_NODES + SCAN_T - 1) / SCAN_T;
    int begin = t * per;
    int finish = min(begin + per, N_NODES);
    int loc = 0;
    for (int i = begin; i < finish; i++) loc += counts[i];
    part[t] = loc;
    __syncthreads();
    for (int o = 1; o < SCAN_T; o <<= 1) {
        int add = (t >= o) ? part[t - o] : 0;
        __syncthreads();
        part[t] += add;
        __syncthreads();
    }
    int run = part[t] - loc;  // exclusive base
    for (int i = begin; i < finish; i++) { run += counts[i]; off[i + 1] = run; }
    if (t == 0) off[0] = 0;
}

__global__ void k_selfloop(const int* __restrict__ off, int* __restrict__ csr_send,
                           int* __restrict__ cursor) {
    int i = blockIdx.x * blockDim.x + threadIdx.x;
    if (i < N_NODES) { csr_send[off[i]] = i; cursor[i] = 1; }
}

__global__ void k_fill(const void* __restrict__ eidx, const int* __restrict__ flags,
                       const int* __restrict__ off, int* __restrict__ cursor,
                       int* __restrict__ csr_send) {
    int e = blockIdx.x * blockDim.x + threadIdx.x;
    if (e < N_EDGES) {
        int s = ld_idx(eidx, e, flags[1]);
        int r = ld_idx(eidx, (long long)N_EDGES + e, flags[1]);
        int p = atomicAdd(&cursor[r], 1);
        csr_send[off[r] + p] = s;
    }
}

// ---------------- fused linear + attention coefficients ----------------
// one wave per node; 4 nodes per 256-thread block
template <int DIN, int DOUT>
__global__ void k_gemm(const float* __restrict__ in, const float* __restrict__ W,
                       const float* __restrict__ asrc, const float* __restrict__ adst,
                       float* __restrict__ h, float* __restrict__ es, float* __restrict__ ed) {
    int wid = threadIdx.x >> 6, lane = threadIdx.x & 63;
    int node = blockIdx.x * 4 + wid;
    __shared__ float srow[4][DIN];
    if (node < N_NODES) {
        const float* inrow = in + (size_t)node * DIN;
        for (int k = lane; k < DIN; k += 64) srow[wid][k] = inrow[k];
    }
    __syncthreads();
    if (node >= N_NODES) return;

    const int c0 = lane, c1 = lane + 64;
    float acc0 = 0.f, acc1 = 0.f;
#pragma unroll 4
    for (int k = 0; k < DIN; k++) {
        float xv = srow[wid][k];
        const float* wrow = W + k * DOUT;
        if (c0 < DOUT) acc0 = fmaf(xv, wrow[c0], acc0);
        if (DOUT > 64) acc1 = fmaf(xv, wrow[c1], acc1);
    }
    float* hrow = h + (size_t)node * DOUT;
    float e_s = 0.f, e_d = 0.f;
    if (c0 < DOUT) {
        hrow[c0] = acc0;
        e_s = fmaf(acc0, asrc[c0], e_s);
        e_d = fmaf(acc0, adst[c0], e_d);
    }
    if (DOUT > 64) {
        hrow[c1] = acc1;
        e_s = fmaf(acc1, asrc[c1], e_s);
        e_d = fmaf(acc1, adst[c1], e_d);
    }
    e_s = wave_sum(e_s);
    e_d = wave_sum(e_d);
    if (lane == 0) { es[node] = e_s; ed[node] = e_d; }
}

// ---------------- attention softmax + aggregate (wave per node, online softmax) ----
template <int DOUT, bool RELU_OUT>
__global__ void k_aggr(const float* __restrict__ h, const float* __restrict__ es,
                       const float* __restrict__ ed, const float* __restrict__ bias,
                       const int* __restrict__ off, const int* __restrict__ csr_send,
                       float* __restrict__ out, void* __restrict__ out_dev,
                       long long out_off, const int* __restrict__ flags) {
    int wid = threadIdx.x >> 6, lane = threadIdx.x & 63;
    int node = blockIdx.x * 4 + wid;
    if (node >= N_NODES) return;
    int start = off[node], end = off[node + 1];
    float edi = ed[node];

    float M = -1e30f, S = 0.f, acc0 = 0.f, acc1 = 0.f;
    for (int base = start; base < end; base += 64) {
        int j = base + lane;
        bool valid = j < end;
        int src = valid ? csr_send[j] : 0;
        float e = -1e30f;
        if (valid) {
            float v = es[src] + edi;
            e = (v >= 0.f) ? v : 0.2f * v;
        }
        float cmax = wave_max(e);
        float newM = fmaxf(M, cmax);
        float r = __expf(M - newM);
        float p = valid ? __expf(e - newM) : 0.f;
        S = S * r + wave_sum(p);
        acc0 *= r;
        acc1 *= r;
        int cnt = min(64, end - base);
        for (int j2 = 0; j2 < cnt; j2++) {
            float pj = __shfl(p, j2, 64);
            int sj = __shfl(src, j2, 64);
            const float* row = h + (size_t)sj * DOUT;
            if (lane < DOUT) acc0 = fmaf(pj, row[lane], acc0);
            if (DOUT > 64) acc1 = fmaf(pj, row[lane + 64], acc1);
        }
        M = newM;
    }
    float inv = 1.f / S;
    int isbf = flags[0];
    if (lane < DOUT) {
        float v = acc0 * inv + bias[lane];
        if (RELU_OUT) v = fmaxf(v, 0.f);
        out[(size_t)node * DOUT + lane] = v;
        if (out_dev) st_out(out_dev, out_off + (long long)node * DOUT + lane, v, isbf);
    }
    if (DOUT > 64) {
        float v = acc1 * inv + bias[lane + 64];
        if (RELU_OUT) v = fmaxf(v, 0.f);
        out[(size_t)node * DOUT + lane + 64] = v;
        if (out_dev) st_out(out_dev, out_off + (long long)node * DOUT + lane + 64, v, isbf);
    }
}

// ---------------- per-graph mean pooling ----------------
__global__ void k_pool(const float* __restrict__ latent, const void* __restrict__ batch,
                       const int* __restrict__ flags, float* __restrict__ pooled) {
    int b = blockIdx.x;
    int t = threadIdx.x;  // 64 threads, lane == latent channel
    int is64 = flags[1];
    int lo = 0, hi = N_NODES;
    while (lo < hi) { int mid = (lo + hi) >> 1; if (ld_idx(batch, mid, is64) < b) lo = mid + 1; else hi = mid; }
    int start = lo;
    lo = 0; hi = N_NODES;
    while (lo < hi) { int mid = (lo + hi) >> 1; if (ld_idx(batch, mid, is64) < b + 1) lo = mid + 1; else hi = mid; }
    int end = lo;
    float s = 0.f;
    for (int n = start; n < end; n++) s += latent[(size_t)n * 64 + t];
    float cnt = (float)(end - start);
    pooled[b * 64 + t] = s / fmaxf(cnt, 1.f);
}

// ---------------- classifier head ----------------
__global__ void k_cls(const float* __restrict__ pooled, const float* __restrict__ pb,
                      void* __restrict__ out_dev, long long out_off,
                      const int* __restrict__ flags) {
    int b = threadIdx.x;  // 64 threads, one per graph
    const float* Wc1 = pb + P_WC1;
    const float* bc1 = pb + P_BC1;
    const float* Wc2 = pb + P_WC2;
    const float* bc2 = pb + P_BC2;
    float z[32];
#pragma unroll
    for (int k = 0; k < 32; k++) z[k] = bc1[k];
    for (int c = 0; c < 64; c++) {
        float pv = pooled[b * 64 + c];
#pragma unroll
        for (int k = 0; k < 32; k++) z[k] = fmaf(pv, Wc1[c * 32 + k], z[k]);
    }
#pragma unroll
    for (int k = 0; k < 32; k++) z[k] = fmaxf(z[k], 0.f);
    float n0 = bc2[0], n1 = bc2[1];
#pragma unroll
    for (int k = 0; k < 32; k++) {
        n0 = fmaf(z[k], Wc2[k * 2 + 0], n0);
        n1 = fmaf(z[k], Wc2[k * 2 + 1], n1);
    }
    int isbf = flags[0];
    st_out(out_dev, out_off + b * 2 + 0, n0, isbf);
    st_out(out_dev, out_off + b * 2 + 1, n1, isbf);
}

extern "C" void kernel_launch(void* const* d_in, const int* in_sizes, int n_in,
                              void* d_out, int out_size, void* d_ws, size_t ws_size,
                              hipStream_t stream) {
    const void* x    = d_in[0];
    const void* eidx = d_in[1];
    const void* batch= d_in[2];

    // workspace carve-up (256B aligned)
    char* w = (char*)d_ws;
    size_t o = 0;
    auto carve = [&](size_t bytes) { void* p = w + o; o = (o + bytes + 255) & ~(size_t)255; return p; };
    int* flags    = (int*)carve(8 * sizeof(int));
    int* off      = (int*)carve((N_NODES + 1) * sizeof(int));
    int* counts   = (int*)carve(N_NODES * sizeof(int));
    int* cursor   = (int*)carve(N_NODES * sizeof(int));
    int* csr_send = (int*)carve((size_t)(N_EDGES + N_NODES) * sizeof(int));
    float* pblock = (float*)carve(P_TOTAL * sizeof(float));
    float* buf0   = (float*)carve((size_t)N_NODES * 128 * sizeof(float));
    float* buf1   = (float*)carve((size_t)N_NODES * 128 * sizeof(float));
    float* es     = (float*)carve(N_NODES * sizeof(float));
    float* ed     = (float*)carve(N_NODES * sizeof(float));
    float* pooled = (float*)carve(NB * 64 * sizeof(float));

    int gN = (N_NODES + 255) / 256;
    int gE = (N_EDGES + 255) / 256;
    int gW = N_NODES / 4;  // 4 waves (nodes) per block

    // dtype detect
    k_detect<<<1, 64, 0, stream>>>((const unsigned short*)x, (const unsigned int*)eidx, flags);

    // params -> f32 block
    PTab tab;
    const int pn[20]  = {384,128,128,128, 8192,64,64,64, 8192,128,128,128, 384,3,3,3, 2048,32,64,2};
    const int pof[20] = {P_W1,P_A1S,P_A1D,P_B1, P_W2,P_A2S,P_A2D,P_B2, P_W3,P_A3S,P_A3D,P_B3,
                         P_W4,P_A4S,P_A4D,P_B4, P_WC1,P_BC1,P_WC2,P_BC2};
    for (int i = 0; i < 20; i++) { tab.src[i] = d_in[3 + i]; tab.off[i] = pof[i]; tab.n[i] = pn[i]; }
    k_cvt_params<<<20, 256, 0, stream>>>(tab, flags, pblock);

    // CSR build
    k_init_counts<<<gN, 256, 0, stream>>>(counts);
    k_count<<<gE, 256, 0, stream>>>(eidx, flags, counts);
    k_scan<<<1, SCAN_T, 0, stream>>>(counts, off);
    k_selfloop<<<gN, 256, 0, stream>>>(off, csr_send, cursor);
    k_fill<<<gE, 256, 0, stream>>>(eidx, flags, off, cursor, csr_send);

    // x -> f32
    k_cvt_x<<<(N_NODES * 3 + 255) / 256, 256, 0, stream>>>(x, flags, buf0);

    // output element offsets
    const long long OFF_RECON = 0, OFF_LATENT = 150000, OFF_NOISE = 3350000;

    // conv1: [N,3] -> [N,128], relu
    k_gemm<3, 128><<<gW, 256, 0, stream>>>(buf0, pblock + P_W1, pblock + P_A1S, pblock + P_A1D, buf1, es, ed);
    k_aggr<128, true><<<gW, 256, 0, stream>>>(buf1, es, ed, pblock + P_B1, off, csr_send, buf0, nullptr, 0, flags);

    // conv2: [N,128] -> [N,64] (latent)
    k_gemm<128, 64><<<gW, 256, 0, stream>>>(buf0, pblock + P_W2, pblock + P_A2S, pblock + P_A2D, buf1, es, ed);
    k_aggr<64, false><<<gW, 256, 0, stream>>>(buf1, es, ed, pblock + P_B2, off, csr_send, buf0, d_out, OFF_LATENT, flags);

    // pooling + classifier from f32 latent (buf0)
    k_pool<<<NB, 64, 0, stream>>>(buf0, batch, flags, pooled);
    k_cls<<<1, 64, 0, stream>>>(pooled, pblock, d_out, OFF_NOISE, flags);

    // conv3: [N,64] -> [N,128], relu
    k_gemm<64, 128><<<gW, 256, 0, stream>>>(buf0, pblock + P_W3, pblock + P_A3S, pblock + P_A3D, buf1, es, ed);
    k_aggr<128, true><<<gW, 256, 0, stream>>>(buf1, es, ed, pblock + P_B3, off, csr_send, buf0, nullptr, 0, flags);

    // conv4: [N,128] -> [N,3] (reconstructed)
    k_gemm<128, 3><<<gW, 256, 0, stream>>>(buf0, pblock + P_W4, pblock + P_A4S, pblock + P_A4D, buf1, es, ed);
    k_aggr<3, false><<<gW, 256, 0, stream>>>(buf1, es, ed, pblock + P_B4, off, csr_send, buf0, d_out, OFF_RECON, flags);
}

// Round 3
// 680.680 us; speedup vs baseline: 1.2725x; 1.2725x over previous
//
#include <hip/hip_runtime.h>
#include <hip/hip_bf16.h>

typedef __hip_bfloat16 bf16;

#define N_NODES 50000
#define N_EDGES 800000
#define NB 64

// param block offsets (floats)
#define P_W1 0
#define P_A1S 384
#define P_A1D 512
#define P_B1 640
#define P_W2 768
#define P_A2S 8960
#define P_A2D 9024
#define P_B2 9088
#define P_W3 9152
#define P_A3S 17344
#define P_A3D 17472
#define P_B3 17600
#define P_W4 17728
#define P_A4S 18112
#define P_A4D 18115
#define P_B4 18118
#define P_WC1 18121
#define P_BC1 20169
#define P_WC2 20201
#define P_BC2 20265
#define P_TOTAL 20267

__device__ __forceinline__ float wave_max(float v) {
#pragma unroll
    for (int o = 32; o >= 1; o >>= 1) v = fmaxf(v, __shfl_xor(v, o, 64));
    return v;
}
__device__ __forceinline__ float wave_sum(float v) {
#pragma unroll
    for (int o = 32; o >= 1; o >>= 1) v += __shfl_xor(v, o, 64);
    return v;
}

// runtime dtype helpers: flags[0]=float-inputs-are-bf16, flags[1]=ints-are-int64
__device__ __forceinline__ int ld_idx(const void* p, long long i, int is64) {
    return is64 ? (int)((const long long*)p)[i] : ((const int*)p)[i];
}
__device__ __forceinline__ void st_out(void* p, long long i, float v, int isbf) {
    if (isbf) ((bf16*)p)[i] = __float2bfloat16(v);
    else ((float*)p)[i] = v;
}

// ---------------- dtype detection ----------------
__global__ void k_detect(const unsigned short* xraw, const unsigned int* eraw,
                         int* flags) {
    if (threadIdx.x != 0 || blockIdx.x != 0) return;
    int cnt = 0;
    for (int i = 0; i < 256; i++) {
        unsigned int hb = (xraw[2 * i] >> 8) & 0x7F;
        if (hb >= 58 && hb <= 65) cnt++;
    }
    flags[0] = (cnt >= 200) ? 1 : 0;
    int z = 0;
    for (int i = 0; i < 64; i++)
        if (eraw[2 * i + 1] == 0u) z++;
    flags[1] = (z >= 60) ? 1 : 0;
}

// ---------------- input/param convert to f32 ----------------
struct PTab {
    const void* src[20];
    int off[20];
    int n[20];
};

__global__ void k_cvt_params(PTab tab, const int* __restrict__ flags,
                             float* __restrict__ pblock) {
    int t = blockIdx.x;
    const void* s = tab.src[t];
    float* d = pblock + tab.off[t];
    int n = tab.n[t];
    int isbf = flags[0];
    for (int i = threadIdx.x; i < n; i += blockDim.x)
        d[i] = isbf ? __bfloat162float(((const bf16*)s)[i]) : ((const float*)s)[i];
}

__global__ void k_cvt_x(const void* __restrict__ x, const int* __restrict__ flags,
                        float* __restrict__ buf) {
    int i = blockIdx.x * blockDim.x + threadIdx.x;
    if (i < N_NODES * 3)
        buf[i] = flags[0] ? __bfloat162float(((const bf16*)x)[i]) : ((const float*)x)[i];
}

// ---------------- CSR build ----------------
__global__ void k_init_counts(int* __restrict__ counts) {
    int i = blockIdx.x * blockDim.x + threadIdx.x;
    if (i < N_NODES) counts[i] = 1;  // self loop
}

__global__ void k_count(const void* __restrict__ eidx, const int* __restrict__ flags,
                        int* __restrict__ counts) {
    int e = blockIdx.x * blockDim.x + threadIdx.x;
    if (e < N_EDGES) {
        int r = ld_idx(eidx, (long long)N_EDGES + e, flags[1]);
        atomicAdd(&counts[r], 1);
    }
}

#define SCAN_T 1024
__global__ void k_scan(const int* __restrict__ counts, int* __restrict__ off) {
    __shared__ int part[SCAN_T];
    int t = threadIdx.x;
    const int per = (N_NODES + SCAN_T - 1) / SCAN_T;
    int begin = t * per;
    int finish = min(begin + per, N_NODES);
    int loc = 0;
    for (int i = begin; i < finish; i++) loc += counts[i];
    part[t] = loc;
    __syncthreads();
    for (int o = 1; o < SCAN_T; o <<= 1) {
        int add = (t >= o) ? part[t - o] : 0;
        __syncthreads();
        part[t] += add;
        __syncthreads();
    }
    int run = part[t] - loc;  // exclusive base
    for (int i = begin; i < finish; i++) { run += counts[i]; off[i + 1] = run; }
    if (t == 0) off[0] = 0;
}

__global__ void k_selfloop(const int* __restrict__ off, int* __restrict__ csr_send,
                           int* __restrict__ cursor) {
    int i = blockIdx.x * blockDim.x + threadIdx.x;
    if (i < N_NODES) { csr_send[off[i]] = i; cursor[i] = 1; }
}

__global__ void k_fill(const void* __restrict__ eidx, const int* __restrict__ flags,
                       const int* __restrict__ off, int* __restrict__ cursor,
                       int* __restrict__ csr_send) {
    int e = blockIdx.x * blockDim.x + threadIdx.x;
    if (e < N_EDGES) {
        int s = ld_idx(eidx, e, flags[1]);
        int r = ld_idx(eidx, (long long)N_EDGES + e, flags[1]);
        int p = atomicAdd(&cursor[r], 1);
        csr_send[off[r] + p] = s;
    }
}

// ---------------- fused linear + attention coefficients ----------------
template <int DIN, int DOUT>
__global__ void k_gemm(const float* __restrict__ in, const float* __restrict__ W,
                       const float* __restrict__ asrc, const float* __restrict__ adst,
                       float* __restrict__ h, float* __restrict__ es, float* __restrict__ ed) {
    int wid = threadIdx.x >> 6, lane = threadIdx.x & 63;
    int node = blockIdx.x * 4 + wid;
    __shared__ float srow[4][DIN];
    if (node < N_NODES) {
        const float* inrow = in + (size_t)node * DIN;
        for (int k = lane; k < DIN; k += 64) srow[wid][k] = inrow[k];
    }
    __syncthreads();
    if (node >= N_NODES) return;

    const int c0 = lane, c1 = lane + 64;
    float acc0 = 0.f, acc1 = 0.f;
#pragma unroll 4
    for (int k = 0; k < DIN; k++) {
        float xv = srow[wid][k];
        const float* wrow = W + k * DOUT;
        if (c0 < DOUT) acc0 = fmaf(xv, wrow[c0], acc0);
        if (DOUT > 64) acc1 = fmaf(xv, wrow[c1], acc1);
    }
    float* hrow = h + (size_t)node * DOUT;
    float e_s = 0.f, e_d = 0.f;
    if (c0 < DOUT) {
        hrow[c0] = acc0;
        e_s = fmaf(acc0, asrc[c0], e_s);
        e_d = fmaf(acc0, adst[c0], e_d);
    }
    if (DOUT > 64) {
        hrow[c1] = acc1;
        e_s = fmaf(acc1, asrc[c1], e_s);
        e_d = fmaf(acc1, adst[c1], e_d);
    }
    e_s = wave_sum(e_s);
    e_d = wave_sum(e_d);
    if (lane == 0) { es[node] = e_s; ed[node] = e_d; }
}

// ---------------- attention softmax + aggregate (wave per node, online softmax) ----
template <int DOUT, bool RELU_OUT>
__global__ void k_aggr(const float* __restrict__ h, const float* __restrict__ es,
                       const float* __restrict__ ed, const float* __restrict__ bias,
                       const int* __restrict__ off, const int* __restrict__ csr_send,
                       float* __restrict__ out, void* __restrict__ out_dev,
                       long long out_off, const int* __restrict__ flags) {
    int wid = threadIdx.x >> 6, lane = threadIdx.x & 63;
    int node = blockIdx.x * 4 + wid;
    if (node >= N_NODES) return;
    int start = off[node], end = off[node + 1];
    float edi = ed[node];

    float M = -1e30f, S = 0.f, acc0 = 0.f, acc1 = 0.f;
    for (int base = start; base < end; base += 64) {
        int j = base + lane;
        bool valid = j < end;
        int src = valid ? csr_send[j] : 0;
        float e = -1e30f;
        if (valid) {
            float v = es[src] + edi;
            e = (v >= 0.f) ? v : 0.2f * v;
        }
        float cmax = wave_max(e);
        float newM = fmaxf(M, cmax);
        float r = __expf(M - newM);
        float p = valid ? __expf(e - newM) : 0.f;
        S = S * r + wave_sum(p);
        acc0 *= r;
        acc1 *= r;
        int cnt = min(64, end - base);
        for (int j2 = 0; j2 < cnt; j2++) {
            float pj = __shfl(p, j2, 64);
            int sj = __shfl(src, j2, 64);
            const float* row = h + (size_t)sj * DOUT;
            if (lane < DOUT) acc0 = fmaf(pj, row[lane], acc0);
            if (DOUT > 64) acc1 = fmaf(pj, row[lane + 64], acc1);
        }
        M = newM;
    }
    float inv = 1.f / S;
    int isbf = flags[0];
    if (lane < DOUT) {
        float v = acc0 * inv + bias[lane];
        if (RELU_OUT) v = fmaxf(v, 0.f);
        out[(size_t)node * DOUT + lane] = v;
        if (out_dev) st_out(out_dev, out_off + (long long)node * DOUT + lane, v, isbf);
    }
    if (DOUT > 64) {
        float v = acc1 * inv + bias[lane + 64];
        if (RELU_OUT) v = fmaxf(v, 0.f);
        out[(size_t)node * DOUT + lane + 64] = v;
        if (out_dev) st_out(out_dev, out_off + (long long)node * DOUT + lane + 64, v, isbf);
    }
}

// ---------------- per-graph mean pooling: 1 block/graph, 16 waves ----------------
#define POOL_W 16
__global__ void k_pool(const float* __restrict__ latent, const void* __restrict__ batch,
                       const int* __restrict__ flags, float* __restrict__ pooled) {
    int b = blockIdx.x;
    int lane = threadIdx.x & 63;   // channel
    int wave = threadIdx.x >> 6;   // 0..15
    int is64 = flags[1];
    int lo = 0, hi = N_NODES;
    while (lo < hi) { int mid = (lo + hi) >> 1; if (ld_idx(batch, mid, is64) < b) lo = mid + 1; else hi = mid; }
    int start = lo;
    lo = 0; hi = N_NODES;
    while (lo < hi) { int mid = (lo + hi) >> 1; if (ld_idx(batch, mid, is64) < b + 1) lo = mid + 1; else hi = mid; }
    int end = lo;
    float s = 0.f;
    for (int n = start + wave; n < end; n += POOL_W) s += latent[(size_t)n * 64 + lane];
    __shared__ float red[POOL_W][64];
    red[wave][lane] = s;
    __syncthreads();
    if (wave == 0) {
        float t = s;
#pragma unroll
        for (int w2 = 1; w2 < POOL_W; w2++) t += red[w2][lane];
        float cnt = (float)(end - start);
        pooled[b * 64 + lane] = t / fmaxf(cnt, 1.f);
    }
}

// ---------------- classifier head ----------------
__global__ void k_cls(const float* __restrict__ pooled, const float* __restrict__ pb,
                      void* __restrict__ out_dev, long long out_off,
                      const int* __restrict__ flags) {
    int b = threadIdx.x;  // 64 threads, one per graph
    const float* Wc1 = pb + P_WC1;
    const float* bc1 = pb + P_BC1;
    const float* Wc2 = pb + P_WC2;
    const float* bc2 = pb + P_BC2;
    float z[32];
#pragma unroll
    for (int k = 0; k < 32; k++) z[k] = bc1[k];
    for (int c = 0; c < 64; c++) {
        float pv = pooled[b * 64 + c];
#pragma unroll
        for (int k = 0; k < 32; k++) z[k] = fmaf(pv, Wc1[c * 32 + k], z[k]);
    }
#pragma unroll
    for (int k = 0; k < 32; k++) z[k] = fmaxf(z[k], 0.f);
    float n0 = bc2[0], n1 = bc2[1];
#pragma unroll
    for (int k = 0; k < 32; k++) {
        n0 = fmaf(z[k], Wc2[k * 2 + 0], n0);
        n1 = fmaf(z[k], Wc2[k * 2 + 1], n1);
    }
    int isbf = flags[0];
    st_out(out_dev, out_off + b * 2 + 0, n0, isbf);
    st_out(out_dev, out_off + b * 2 + 1, n1, isbf);
}

extern "C" void kernel_launch(void* const* d_in, const int* in_sizes, int n_in,
                              void* d_out, int out_size, void* d_ws, size_t ws_size,
                              hipStream_t stream) {
    const void* x    = d_in[0];
    const void* eidx = d_in[1];
    const void* batch= d_in[2];

    // workspace carve-up (256B aligned)
    char* w = (char*)d_ws;
    size_t o = 0;
    auto carve = [&](size_t bytes) { void* p = w + o; o = (o + bytes + 255) & ~(size_t)255; return p; };
    int* flags    = (int*)carve(8 * sizeof(int));
    int* off      = (int*)carve((N_NODES + 1) * sizeof(int));
    int* counts   = (int*)carve(N_NODES * sizeof(int));
    int* cursor   = (int*)carve(N_NODES * sizeof(int));
    int* csr_send = (int*)carve((size_t)(N_EDGES + N_NODES) * sizeof(int));
    float* pblock = (float*)carve(P_TOTAL * sizeof(float));
    float* buf0   = (float*)carve((size_t)N_NODES * 128 * sizeof(float));
    float* buf1   = (float*)carve((size_t)N_NODES * 128 * sizeof(float));
    float* es     = (float*)carve(N_NODES * sizeof(float));
    float* ed     = (float*)carve(N_NODES * sizeof(float));
    float* pooled = (float*)carve(NB * 64 * sizeof(float));

    int gN = (N_NODES + 255) / 256;
    int gE = (N_EDGES + 255) / 256;
    int gW = N_NODES / 4;  // 4 waves (nodes) per block

    // dtype detect
    k_detect<<<1, 64, 0, stream>>>((const unsigned short*)x, (const unsigned int*)eidx, flags);

    // params -> f32 block
    PTab tab;
    const int pn[20]  = {384,128,128,128, 8192,64,64,64, 8192,128,128,128, 384,3,3,3, 2048,32,64,2};
    const int pof[20] = {P_W1,P_A1S,P_A1D,P_B1, P_W2,P_A2S,P_A2D,P_B2, P_W3,P_A3S,P_A3D,P_B3,
                         P_W4,P_A4S,P_A4D,P_B4, P_WC1,P_BC1,P_WC2,P_BC2};
    for (int i = 0; i < 20; i++) { tab.src[i] = d_in[3 + i]; tab.off[i] = pof[i]; tab.n[i] = pn[i]; }
    k_cvt_params<<<20, 256, 0, stream>>>(tab, flags, pblock);

    // CSR build
    k_init_counts<<<gN, 256, 0, stream>>>(counts);
    k_count<<<gE, 256, 0, stream>>>(eidx, flags, counts);
    k_scan<<<1, SCAN_T, 0, stream>>>(counts, off);
    k_selfloop<<<gN, 256, 0, stream>>>(off, csr_send, cursor);
    k_fill<<<gE, 256, 0, stream>>>(eidx, flags, off, cursor, csr_send);

    // x -> f32
    k_cvt_x<<<(N_NODES * 3 + 255) / 256, 256, 0, stream>>>(x, flags, buf0);

    // output element offsets
    const long long OFF_RECON = 0, OFF_LATENT = 150000, OFF_NOISE = 3350000;

    // conv1: [N,3] -> [N,128], relu
    k_gemm<3, 128><<<gW, 256, 0, stream>>>(buf0, pblock + P_W1, pblock + P_A1S, pblock + P_A1D, buf1, es, ed);
    k_aggr<128, true><<<gW, 256, 0, stream>>>(buf1, es, ed, pblock + P_B1, off, csr_send, buf0, nullptr, 0, flags);

    // conv2: [N,128] -> [N,64] (latent)
    k_gemm<128, 64><<<gW, 256, 0, stream>>>(buf0, pblock + P_W2, pblock + P_A2S, pblock + P_A2D, buf1, es, ed);
    k_aggr<64, false><<<gW, 256, 0, stream>>>(buf1, es, ed, pblock + P_B2, off, csr_send, buf0, d_out, OFF_LATENT, flags);

    // pooling + classifier from f32 latent (buf0)
    k_pool<<<NB, POOL_W * 64, 0, stream>>>(buf0, batch, flags, pooled);
    k_cls<<<1, 64, 0, stream>>>(pooled, pblock, d_out, OFF_NOISE, flags);

    // conv3: [N,64] -> [N,128], relu
    k_gemm<64, 128><<<gW, 256, 0, stream>>>(buf0, pblock + P_W3, pblock + P_A3S, pblock + P_A3D, buf1, es, ed);
    k_aggr<128, true><<<gW, 256, 0, stream>>>(buf1, es, ed, pblock + P_B3, off, csr_send, buf0, nullptr, 0, flags);

    // conv4: [N,128] -> [N,3] (reconstructed)
    k_gemm<128, 3><<<gW, 256, 0, stream>>>(buf0, pblock + P_W4, pblock + P_A4S, pblock + P_A4D, buf1, es, ed);
    k_aggr<3, false><<<gW, 256, 0, stream>>>(buf1, es, ed, pblock + P_B4, off, csr_send, buf0, d_out, OFF_RECON, flags);
}

// Round 4
// 624.654 us; speedup vs baseline: 1.3866x; 1.0897x over previous
//
#include <hip/hip_runtime.h>
#include <hip/hip_bf16.h>

typedef __hip_bfloat16 bf16;

#define N_NODES 50000
#define N_EDGES 800000
#define NB 64

// param block offsets (floats)
#define P_W1 0
#define P_A1S 384
#define P_A1D 512
#define P_B1 640
#define P_W2 768
#define P_A2S 8960
#define P_A2D 9024
#define P_B2 9088
#define P_W3 9152
#define P_A3S 17344
#define P_A3D 17472
#define P_B3 17600
#define P_W4 17728
#define P_A4S 18112
#define P_A4D 18115
#define P_B4 18118
#define P_WC1 18121
#define P_BC1 20169
#define P_WC2 20201
#define P_BC2 20265
#define P_TOTAL 20267

__device__ __forceinline__ float wave_max(float v) {
#pragma unroll
    for (int o = 32; o >= 1; o >>= 1) v = fmaxf(v, __shfl_xor(v, o, 64));
    return v;
}
__device__ __forceinline__ float wave_sum(float v) {
#pragma unroll
    for (int o = 32; o >= 1; o >>= 1) v += __shfl_xor(v, o, 64);
    return v;
}

// runtime dtype helpers: flags[0]=float-inputs-are-bf16, flags[1]=ints-are-int64
__device__ __forceinline__ int ld_idx(const void* p, long long i, int is64) {
    return is64 ? (int)((const long long*)p)[i] : ((const int*)p)[i];
}
__device__ __forceinline__ void st_out(void* p, long long i, float v, int isbf) {
    if (isbf) ((bf16*)p)[i] = __float2bfloat16(v);
    else ((float*)p)[i] = v;
}

// ---------------- dtype detection ----------------
__global__ void k_detect(const unsigned short* xraw, const unsigned int* eraw,
                         int* flags) {
    if (threadIdx.x != 0 || blockIdx.x != 0) return;
    int cnt = 0;
    for (int i = 0; i < 256; i++) {
        unsigned int hb = (xraw[2 * i] >> 8) & 0x7F;
        if (hb >= 58 && hb <= 65) cnt++;
    }
    flags[0] = (cnt >= 200) ? 1 : 0;
    int z = 0;
    for (int i = 0; i < 64; i++)
        if (eraw[2 * i + 1] == 0u) z++;
    flags[1] = (z >= 60) ? 1 : 0;
}

// ---------------- input/param convert to f32 ----------------
struct PTab {
    const void* src[20];
    int off[20];
    int n[20];
};

__global__ void k_cvt_params(PTab tab, const int* __restrict__ flags,
                             float* __restrict__ pblock) {
    int t = blockIdx.x;
    const void* s = tab.src[t];
    float* d = pblock + tab.off[t];
    int n = tab.n[t];
    int isbf = flags[0];
    for (int i = threadIdx.x; i < n; i += blockDim.x)
        d[i] = isbf ? __bfloat162float(((const bf16*)s)[i]) : ((const float*)s)[i];
}

__global__ void k_cvt_x(const void* __restrict__ x, const int* __restrict__ flags,
                        float* __restrict__ buf) {
    int i = blockIdx.x * blockDim.x + threadIdx.x;
    if (i < N_NODES * 3)
        buf[i] = flags[0] ? __bfloat162float(((const bf16*)x)[i]) : ((const float*)x)[i];
}

// ---------------- CSR build ----------------
__global__ void k_init_counts(int* __restrict__ counts) {
    int i = blockIdx.x * blockDim.x + threadIdx.x;
    if (i < N_NODES) counts[i] = 1;  // self loop
}

__global__ void k_count(const void* __restrict__ eidx, const int* __restrict__ flags,
                        int* __restrict__ counts) {
    int e = blockIdx.x * blockDim.x + threadIdx.x;
    if (e < N_EDGES) {
        int r = ld_idx(eidx, (long long)N_EDGES + e, flags[1]);
        atomicAdd(&counts[r], 1);
    }
}

#define SCAN_T 1024
__global__ void k_scan(const int* __restrict__ counts, int* __restrict__ off) {
    __shared__ int part[SCAN_T];
    int t = threadIdx.x;
    const int per = (N_NODES + SCAN_T - 1) / SCAN_T;
    int begin = t * per;
    int finish = min(begin + per, N_NODES);
    int loc = 0;
    for (int i = begin; i < finish; i++) loc += counts[i];
    part[t] = loc;
    __syncthreads();
    for (int o = 1; o < SCAN_T; o <<= 1) {
        int add = (t >= o) ? part[t - o] : 0;
        __syncthreads();
        part[t] += add;
        __syncthreads();
    }
    int run = part[t] - loc;  // exclusive base
    for (int i = begin; i < finish; i++) { run += counts[i]; off[i + 1] = run; }
    if (t == 0) off[0] = 0;
}

__global__ void k_selfloop(const int* __restrict__ off, int* __restrict__ csr_send,
                           int* __restrict__ cursor) {
    int i = blockIdx.x * blockDim.x + threadIdx.x;
    if (i < N_NODES) { csr_send[off[i]] = i; cursor[i] = 1; }
}

__global__ void k_fill(const void* __restrict__ eidx, const int* __restrict__ flags,
                       const int* __restrict__ off, int* __restrict__ cursor,
                       int* __restrict__ csr_send) {
    int e = blockIdx.x * blockDim.x + threadIdx.x;
    if (e < N_EDGES) {
        int s = ld_idx(eidx, e, flags[1]);
        int r = ld_idx(eidx, (long long)N_EDGES + e, flags[1]);
        int p = atomicAdd(&cursor[r], 1);
        csr_send[off[r] + p] = s;
    }
}

// ---------------- tiled linear + attention coefficients ----------------
// 256 threads = 64-node tile; thread t: node t&63, column group t>>6 (DOUT/4 cols).
// x tile in LDS (+1 pad, conflict-free); W read from global (L1/L2-hot broadcast);
// h written coalesced via LDS transpose tile; es/ed via 4-group LDS reduce.
template <int DIN, int DOUT>
__global__ __launch_bounds__(256) void k_gemm(
        const float* __restrict__ in, const float* __restrict__ W,
        const float* __restrict__ as_, const float* __restrict__ ad_,
        float* __restrict__ h, float* __restrict__ es, float* __restrict__ ed) {
    constexpr int NT = 64;
    constexpr int CPT = (DOUT >= 4) ? (DOUT / 4) : 1;
    constexpr int XW = DIN + 1, HW = DOUT + 1;
    constexpr int SXH = NT * (XW > HW ? XW : HW);
    __shared__ float sXH[SXH];
    __shared__ float sred[2][4][NT];

    const int t = threadIdx.x;
    const int node0 = blockIdx.x * NT;
    const int nvalid = min(NT, N_NODES - node0);

    // stage x tile
    const int xelems = nvalid * DIN;
    if (DIN % 4 == 0) {
        const float4* in4 = (const float4*)(in + (size_t)node0 * DIN);
        for (int i = t; i < xelems / 4; i += 256) {
            float4 v = in4[i];
            int e = i * 4, r = e / DIN, c = e - r * DIN;
            float* dst = &sXH[r * XW + c];
            dst[0] = v.x; dst[1] = v.y; dst[2] = v.z; dst[3] = v.w;
        }
    } else {
        for (int i = t; i < xelems; i += 256) {
            int r = i / DIN, c = i - r * DIN;
            sXH[r * XW + c] = in[(size_t)node0 * DIN + i];
        }
    }
    __syncthreads();

    const int ns = t & 63, g = t >> 6;
    const int col0 = g * CPT;
    float acc[CPT];
#pragma unroll
    for (int c = 0; c < CPT; c++) acc[c] = 0.f;

    if (col0 < DOUT) {
        for (int k = 0; k < DIN; k++) {
            float xv = sXH[ns * XW + k];
            const float* wr = W + k * DOUT + col0;
#pragma unroll
            for (int c = 0; c < CPT; c++) acc[c] = fmaf(xv, wr[c], acc[c]);
        }
    }
    // es/ed partials
    float e_s = 0.f, e_d = 0.f;
    if (col0 < DOUT) {
#pragma unroll
        for (int c = 0; c < CPT; c++) {
            e_s = fmaf(acc[c], as_[col0 + c], e_s);
            e_d = fmaf(acc[c], ad_[col0 + c], e_d);
        }
    }
    sred[0][g][ns] = e_s;
    sred[1][g][ns] = e_d;
    __syncthreads();  // all reads of x tile done; sred populated

    // stage h into LDS transpose tile (reuse sXH)
    if (col0 < DOUT) {
#pragma unroll
        for (int c = 0; c < CPT; c++) sXH[ns * HW + col0 + c] = acc[c];
    }
    if (g == 0 && ns < nvalid) {
        es[node0 + ns] = sred[0][0][ns] + sred[0][1][ns] + sred[0][2][ns] + sred[0][3][ns];
        ed[node0 + ns] = sred[1][0][ns] + sred[1][1][ns] + sred[1][2][ns] + sred[1][3][ns];
    }
    __syncthreads();

    // coalesced h write-out
    const int helems = nvalid * DOUT;
    if (DOUT % 4 == 0) {
        float4* h4 = (float4*)(h + (size_t)node0 * DOUT);
        for (int i = t; i < helems / 4; i += 256) {
            int e = i * 4, r = e / DOUT, c = e - r * DOUT;
            const float* sp = &sXH[r * HW + c];
            float4 v; v.x = sp[0]; v.y = sp[1]; v.z = sp[2]; v.w = sp[3];
            h4[i] = v;
        }
    } else {
        for (int i = t; i < helems; i += 256) {
            int r = i / DOUT, c = i - r * DOUT;
            h[(size_t)node0 * DOUT + i] = sXH[r * HW + c];
        }
    }
}

// ---------------- attention softmax + aggregate (wave per node, online softmax) ----
template <int DOUT, bool RELU_OUT>
__global__ void k_aggr(const float* __restrict__ h, const float* __restrict__ es,
                       const float* __restrict__ ed, const float* __restrict__ bias,
                       const int* __restrict__ off, const int* __restrict__ csr_send,
                       float* __restrict__ out, void* __restrict__ out_dev,
                       long long out_off, const int* __restrict__ flags) {
    int wid = threadIdx.x >> 6, lane = threadIdx.x & 63;
    int node = blockIdx.x * 4 + wid;
    if (node >= N_NODES) return;
    int start = off[node], end = off[node + 1];
    float edi = ed[node];

    float M = -1e30f, S = 0.f, acc0 = 0.f, acc1 = 0.f;
    for (int base = start; base < end; base += 64) {
        int j = base + lane;
        bool valid = j < end;
        int src = valid ? csr_send[j] : 0;
        float e = -1e30f;
        if (valid) {
            float v = es[src] + edi;
            e = (v >= 0.f) ? v : 0.2f * v;
        }
        float cmax = wave_max(e);
        float newM = fmaxf(M, cmax);
        float r = __expf(M - newM);
        float p = valid ? __expf(e - newM) : 0.f;
        S = S * r + wave_sum(p);
        acc0 *= r;
        acc1 *= r;
        int cnt = min(64, end - base);
        for (int j2 = 0; j2 < cnt; j2++) {
            float pj = __shfl(p, j2, 64);
            int sj = __shfl(src, j2, 64);
            const float* row = h + (size_t)sj * DOUT;
            if (lane < DOUT) acc0 = fmaf(pj, row[lane], acc0);
            if (DOUT > 64) acc1 = fmaf(pj, row[lane + 64], acc1);
        }
        M = newM;
    }
    float inv = 1.f / S;
    int isbf = flags[0];
    if (lane < DOUT) {
        float v = acc0 * inv + bias[lane];
        if (RELU_OUT) v = fmaxf(v, 0.f);
        out[(size_t)node * DOUT + lane] = v;
        if (out_dev) st_out(out_dev, out_off + (long long)node * DOUT + lane, v, isbf);
    }
    if (DOUT > 64) {
        float v = acc1 * inv + bias[lane + 64];
        if (RELU_OUT) v = fmaxf(v, 0.f);
        out[(size_t)node * DOUT + lane + 64] = v;
        if (out_dev) st_out(out_dev, out_off + (long long)node * DOUT + lane + 64, v, isbf);
    }
}

// ---------------- per-graph mean pooling: 1 block/graph, 16 waves ----------------
#define POOL_W 16
__global__ void k_pool(const float* __restrict__ latent, const void* __restrict__ batch,
                       const int* __restrict__ flags, float* __restrict__ pooled) {
    int b = blockIdx.x;
    int lane = threadIdx.x & 63;   // channel
    int wave = threadIdx.x >> 6;   // 0..15
    int is64 = flags[1];
    int lo = 0, hi = N_NODES;
    while (lo < hi) { int mid = (lo + hi) >> 1; if (ld_idx(batch, mid, is64) < b) lo = mid + 1; else hi = mid; }
    int start = lo;
    lo = 0; hi = N_NODES;
    while (lo < hi) { int mid = (lo + hi) >> 1; if (ld_idx(batch, mid, is64) < b + 1) lo = mid + 1; else hi = mid; }
    int end = lo;
    float s = 0.f;
    for (int n = start + wave; n < end; n += POOL_W) s += latent[(size_t)n * 64 + lane];
    __shared__ float red[POOL_W][64];
    red[wave][lane] = s;
    __syncthreads();
    if (wave == 0) {
        float t = s;
#pragma unroll
        for (int w2 = 1; w2 < POOL_W; w2++) t += red[w2][lane];
        float cnt = (float)(end - start);
        pooled[b * 64 + lane] = t / fmaxf(cnt, 1.f);
    }
}

// ---------------- classifier head ----------------
__global__ void k_cls(const float* __restrict__ pooled, const float* __restrict__ pb,
                      void* __restrict__ out_dev, long long out_off,
                      const int* __restrict__ flags) {
    int b = threadIdx.x;  // 64 threads, one per graph
    const float* Wc1 = pb + P_WC1;
    const float* bc1 = pb + P_BC1;
    const float* Wc2 = pb + P_WC2;
    const float* bc2 = pb + P_BC2;
    float z[32];
#pragma unroll
    for (int k = 0; k < 32; k++) z[k] = bc1[k];
    for (int c = 0; c < 64; c++) {
        float pv = pooled[b * 64 + c];
#pragma unroll
        for (int k = 0; k < 32; k++) z[k] = fmaf(pv, Wc1[c * 32 + k], z[k]);
    }
#pragma unroll
    for (int k = 0; k < 32; k++) z[k] = fmaxf(z[k], 0.f);
    float n0 = bc2[0], n1 = bc2[1];
#pragma unroll
    for (int k = 0; k < 32; k++) {
        n0 = fmaf(z[k], Wc2[k * 2 + 0], n0);
        n1 = fmaf(z[k], Wc2[k * 2 + 1], n1);
    }
    int isbf = flags[0];
    st_out(out_dev, out_off + b * 2 + 0, n0, isbf);
    st_out(out_dev, out_off + b * 2 + 1, n1, isbf);
}

extern "C" void kernel_launch(void* const* d_in, const int* in_sizes, int n_in,
                              void* d_out, int out_size, void* d_ws, size_t ws_size,
                              hipStream_t stream) {
    const void* x    = d_in[0];
    const void* eidx = d_in[1];
    const void* batch= d_in[2];

    // workspace carve-up (256B aligned)
    char* w = (char*)d_ws;
    size_t o = 0;
    auto carve = [&](size_t bytes) { void* p = w + o; o = (o + bytes + 255) & ~(size_t)255; return p; };
    int* flags    = (int*)carve(8 * sizeof(int));
    int* off      = (int*)carve((N_NODES + 1) * sizeof(int));
    int* counts   = (int*)carve(N_NODES * sizeof(int));
    int* cursor   = (int*)carve(N_NODES * sizeof(int));
    int* csr_send = (int*)carve((size_t)(N_EDGES + N_NODES) * sizeof(int));
    float* pblock = (float*)carve(P_TOTAL * sizeof(float));
    float* buf0   = (float*)carve((size_t)N_NODES * 128 * sizeof(float));
    float* buf1   = (float*)carve((size_t)N_NODES * 128 * sizeof(float));
    float* es     = (float*)carve(N_NODES * sizeof(float));
    float* ed     = (float*)carve(N_NODES * sizeof(float));
    float* pooled = (float*)carve(NB * 64 * sizeof(float));

    int gN = (N_NODES + 255) / 256;
    int gE = (N_EDGES + 255) / 256;
    int gW = N_NODES / 4;                 // k_aggr: 4 waves (nodes) per block
    int gT = (N_NODES + 63) / 64;         // k_gemm: 64-node tiles

    // dtype detect
    k_detect<<<1, 64, 0, stream>>>((const unsigned short*)x, (const unsigned int*)eidx, flags);

    // params -> f32 block
    PTab tab;
    const int pn[20]  = {384,128,128,128, 8192,64,64,64, 8192,128,128,128, 384,3,3,3, 2048,32,64,2};
    const int pof[20] = {P_W1,P_A1S,P_A1D,P_B1, P_W2,P_A2S,P_A2D,P_B2, P_W3,P_A3S,P_A3D,P_B3,
                         P_W4,P_A4S,P_A4D,P_B4, P_WC1,P_BC1,P_WC2,P_BC2};
    for (int i = 0; i < 20; i++) { tab.src[i] = d_in[3 + i]; tab.off[i] = pof[i]; tab.n[i] = pn[i]; }
    k_cvt_params<<<20, 256, 0, stream>>>(tab, flags, pblock);

    // CSR build
    k_init_counts<<<gN, 256, 0, stream>>>(counts);
    k_count<<<gE, 256, 0, stream>>>(eidx, flags, counts);
    k_scan<<<1, SCAN_T, 0, stream>>>(counts, off);
    k_selfloop<<<gN, 256, 0, stream>>>(off, csr_send, cursor);
    k_fill<<<gE, 256, 0, stream>>>(eidx, flags, off, cursor, csr_send);

    // x -> f32
    k_cvt_x<<<(N_NODES * 3 + 255) / 256, 256, 0, stream>>>(x, flags, buf0);

    // output element offsets
    const long long OFF_RECON = 0, OFF_LATENT = 150000, OFF_NOISE = 3350000;

    // conv1: [N,3] -> [N,128], relu
    k_gemm<3, 128><<<gT, 256, 0, stream>>>(buf0, pblock + P_W1, pblock + P_A1S, pblock + P_A1D, buf1, es, ed);
    k_aggr<128, true><<<gW, 256, 0, stream>>>(buf1, es, ed, pblock + P_B1, off, csr_send, buf0, nullptr, 0, flags);

    // conv2: [N,128] -> [N,64] (latent)
    k_gemm<128, 64><<<gT, 256, 0, stream>>>(buf0, pblock + P_W2, pblock + P_A2S, pblock + P_A2D, buf1, es, ed);
    k_aggr<64, false><<<gW, 256, 0, stream>>>(buf1, es, ed, pblock + P_B2, off, csr_send, buf0, d_out, OFF_LATENT, flags);

    // pooling + classifier from f32 latent (buf0)
    k_pool<<<NB, POOL_W * 64, 0, stream>>>(buf0, batch, flags, pooled);
    k_cls<<<1, 64, 0, stream>>>(pooled, pblock, d_out, OFF_NOISE, flags);

    // conv3: [N,64] -> [N,128], relu
    k_gemm<64, 128><<<gT, 256, 0, stream>>>(buf0, pblock + P_W3, pblock + P_A3S, pblock + P_A3D, buf1, es, ed);
    k_aggr<128, true><<<gW, 256, 0, stream>>>(buf1, es, ed, pblock + P_B3, off, csr_send, buf0, nullptr, 0, flags);

    // conv4: [N,128] -> [N,3] (reconstructed)
    k_gemm<128, 3><<<gT, 256, 0, stream>>>(buf0, pblock + P_W4, pblock + P_A4S, pblock + P_A4D, buf1, es, ed);
    k_aggr<3, false><<<gW, 256, 0, stream>>>(buf1, es, ed, pblock + P_B4, off, csr_send, buf0, d_out, OFF_RECON, flags);
}

// Round 5
// 548.430 us; speedup vs baseline: 1.5793x; 1.1390x over previous
//
#include <hip/hip_runtime.h>
#include <hip/hip_bf16.h>

typedef __hip_bfloat16 bf16;

#define N_NODES 50000
#define N_EDGES 800000
#define NB 64
#define SCAN_BLK 256
#define SCAN_NBLK ((N_NODES + SCAN_BLK - 1) / SCAN_BLK)   // 196

// param block offsets (floats)
#define P_W1 0
#define P_A1S 384
#define P_A1D 512
#define P_B1 640
#define P_W2 768
#define P_A2S 8960
#define P_A2D 9024
#define P_B2 9088
#define P_W3 9152
#define P_A3S 17344
#define P_A3D 17472
#define P_B3 17600
#define P_W4 17728
#define P_A4S 18112
#define P_A4D 18115
#define P_B4 18118
#define P_WC1 18121
#define P_BC1 20169
#define P_WC2 20201
#define P_BC2 20265
#define P_TOTAL 20267

__device__ __forceinline__ float wave_max(float v) {
#pragma unroll
    for (int o = 32; o >= 1; o >>= 1) v = fmaxf(v, __shfl_xor(v, o, 64));
    return v;
}
__device__ __forceinline__ float wave_sum(float v) {
#pragma unroll
    for (int o = 32; o >= 1; o >>= 1) v += __shfl_xor(v, o, 64);
    return v;
}

// runtime dtype helpers: flags[0]=float-inputs-are-bf16, flags[1]=ints-are-int64
__device__ __forceinline__ int ld_idx(const void* p, long long i, int is64) {
    return is64 ? (int)((const long long*)p)[i] : ((const int*)p)[i];
}
__device__ __forceinline__ void st_out(void* p, long long i, float v, int isbf) {
    if (isbf) ((bf16*)p)[i] = __float2bfloat16(v);
    else ((float*)p)[i] = v;
}

// ---------------- dtype detection ----------------
__global__ void k_detect(const unsigned short* xraw, const unsigned int* eraw,
                         int* flags) {
    if (threadIdx.x != 0 || blockIdx.x != 0) return;
    int cnt = 0;
    for (int i = 0; i < 256; i++) {
        unsigned int hb = (xraw[2 * i] >> 8) & 0x7F;
        if (hb >= 58 && hb <= 65) cnt++;
    }
    flags[0] = (cnt >= 200) ? 1 : 0;
    int z = 0;
    for (int i = 0; i < 64; i++)
        if (eraw[2 * i + 1] == 0u) z++;
    flags[1] = (z >= 60) ? 1 : 0;
}

// ---------------- input/param convert to f32 ----------------
struct PTab {
    const void* src[20];
    int off[20];
    int n[20];
};

__global__ void k_cvt_params(PTab tab, const int* __restrict__ flags,
                             float* __restrict__ pblock) {
    int t = blockIdx.x;
    const void* s = tab.src[t];
    float* d = pblock + tab.off[t];
    int n = tab.n[t];
    int isbf = flags[0];
    for (int i = threadIdx.x; i < n; i += blockDim.x)
        d[i] = isbf ? __bfloat162float(((const bf16*)s)[i]) : ((const float*)s)[i];
}

__global__ void k_cvt_x(const void* __restrict__ x, const int* __restrict__ flags,
                        float* __restrict__ buf) {
    int i = blockIdx.x * blockDim.x + threadIdx.x;
    if (i < N_NODES * 3)
        buf[i] = flags[0] ? __bfloat162float(((const bf16*)x)[i]) : ((const float*)x)[i];
}

// ---------------- CSR build ----------------
__global__ void k_init_counts(int* __restrict__ counts) {
    int i = blockIdx.x * blockDim.x + threadIdx.x;
    if (i < N_NODES) counts[i] = 1;  // self loop
}

__global__ void k_count(const void* __restrict__ eidx, const int* __restrict__ flags,
                        int* __restrict__ counts) {
    int e = blockIdx.x * blockDim.x + threadIdx.x;
    if (e < N_EDGES) {
        int r = ld_idx(eidx, (long long)N_EDGES + e, flags[1]);
        atomicAdd(&counts[r], 1);
    }
}

// ---------------- 3-phase parallel scan: off[i+1] = inclusive prefix of counts ----
__global__ void k_scan_a(const int* __restrict__ counts, int* __restrict__ off,
                         int* __restrict__ bsum) {
    __shared__ int s[SCAN_BLK];
    int t = threadIdx.x;
    int i = blockIdx.x * SCAN_BLK + t;
    int v = (i < N_NODES) ? counts[i] : 0;
    s[t] = v;
    __syncthreads();
#pragma unroll
    for (int o = 1; o < SCAN_BLK; o <<= 1) {
        int add = (t >= o) ? s[t - o] : 0;
        __syncthreads();
        s[t] += add;
        __syncthreads();
    }
    if (i < N_NODES) off[i + 1] = s[t];
    if (t == SCAN_BLK - 1) bsum[blockIdx.x] = s[t];
}

__global__ void k_scan_b(int* __restrict__ bsum, int* __restrict__ bbase) {
    __shared__ int s[SCAN_BLK];
    int t = threadIdx.x;
    s[t] = (t < SCAN_NBLK) ? bsum[t] : 0;
    __syncthreads();
#pragma unroll
    for (int o = 1; o < SCAN_BLK; o <<= 1) {
        int add = (t >= o) ? s[t - o] : 0;
        __syncthreads();
        s[t] += add;
        __syncthreads();
    }
    if (t < SCAN_NBLK) bbase[t] = s[t] - ((t < SCAN_NBLK) ? bsum[t] : 0);  // exclusive
}

__global__ void k_scan_c(int* __restrict__ off, const int* __restrict__ bbase) {
    int t = threadIdx.x;
    int i = blockIdx.x * SCAN_BLK + t;
    if (i < N_NODES) off[i + 1] += bbase[blockIdx.x];
    if (i == 0) off[0] = 0;
}

__global__ void k_selfloop(const int* __restrict__ off, int* __restrict__ csr_send,
                           int* __restrict__ cursor) {
    int i = blockIdx.x * blockDim.x + threadIdx.x;
    if (i < N_NODES) { csr_send[off[i]] = i; cursor[i] = 1; }
}

__global__ void k_fill(const void* __restrict__ eidx, const int* __restrict__ flags,
                       const int* __restrict__ off, int* __restrict__ cursor,
                       int* __restrict__ csr_send) {
    int e = blockIdx.x * blockDim.x + threadIdx.x;
    if (e < N_EDGES) {
        int s = ld_idx(eidx, e, flags[1]);
        int r = ld_idx(eidx, (long long)N_EDGES + e, flags[1]);
        int p = atomicAdd(&cursor[r], 1);
        csr_send[off[r] + p] = s;
    }
}

// ---------------- tiled linear + attention coefficients ----------------
// 256 threads = 64-node tile; thread t: node t&63, column group t>>6 (DOUT/4 cols).
template <int DIN, int DOUT>
__global__ __launch_bounds__(256) void k_gemm(
        const float* __restrict__ in, const float* __restrict__ W,
        const float* __restrict__ as_, const float* __restrict__ ad_,
        float* __restrict__ h, float* __restrict__ es, float* __restrict__ ed) {
    constexpr int NT = 64;
    constexpr int CPT = (DOUT >= 4) ? (DOUT / 4) : 1;
    constexpr int XW = DIN + 1, HW = DOUT + 1;
    constexpr int SXH = NT * (XW > HW ? XW : HW);
    __shared__ float sXH[SXH];
    __shared__ float sred[2][4][NT];

    const int t = threadIdx.x;
    const int node0 = blockIdx.x * NT;
    const int nvalid = min(NT, N_NODES - node0);

    // stage x tile
    const int xelems = nvalid * DIN;
    if (DIN % 4 == 0) {
        const float4* in4 = (const float4*)(in + (size_t)node0 * DIN);
        for (int i = t; i < xelems / 4; i += 256) {
            float4 v = in4[i];
            int e = i * 4, r = e / DIN, c = e - r * DIN;
            float* dst = &sXH[r * XW + c];
            dst[0] = v.x; dst[1] = v.y; dst[2] = v.z; dst[3] = v.w;
        }
    } else {
        for (int i = t; i < xelems; i += 256) {
            int r = i / DIN, c = i - r * DIN;
            sXH[r * XW + c] = in[(size_t)node0 * DIN + i];
        }
    }
    __syncthreads();

    const int ns = t & 63, g = t >> 6;
    const int col0 = g * CPT;
    float acc[CPT];
#pragma unroll
    for (int c = 0; c < CPT; c++) acc[c] = 0.f;

    if (col0 < DOUT) {
        for (int k = 0; k < DIN; k++) {
            float xv = sXH[ns * XW + k];
            const float* wr = W + k * DOUT + col0;
#pragma unroll
            for (int c = 0; c < CPT; c++) acc[c] = fmaf(xv, wr[c], acc[c]);
        }
    }
    // es/ed partials
    float e_s = 0.f, e_d = 0.f;
    if (col0 < DOUT) {
#pragma unroll
        for (int c = 0; c < CPT; c++) {
            e_s = fmaf(acc[c], as_[col0 + c], e_s);
            e_d = fmaf(acc[c], ad_[col0 + c], e_d);
        }
    }
    sred[0][g][ns] = e_s;
    sred[1][g][ns] = e_d;
    __syncthreads();  // all reads of x tile done; sred populated

    // stage h into LDS transpose tile (reuse sXH)
    if (col0 < DOUT) {
#pragma unroll
        for (int c = 0; c < CPT; c++) sXH[ns * HW + col0 + c] = acc[c];
    }
    if (g == 0 && ns < nvalid) {
        es[node0 + ns] = sred[0][0][ns] + sred[0][1][ns] + sred[0][2][ns] + sred[0][3][ns];
        ed[node0 + ns] = sred[1][0][ns] + sred[1][1][ns] + sred[1][2][ns] + sred[1][3][ns];
    }
    __syncthreads();

    // coalesced h write-out
    const int helems = nvalid * DOUT;
    if (DOUT % 4 == 0) {
        float4* h4 = (float4*)(h + (size_t)node0 * DOUT);
        for (int i = t; i < helems / 4; i += 256) {
            int e = i * 4, r = e / DOUT, c = e - r * DOUT;
            const float* sp = &sXH[r * HW + c];
            float4 v; v.x = sp[0]; v.y = sp[1]; v.z = sp[2]; v.w = sp[3];
            h4[i] = v;
        }
    } else {
        for (int i = t; i < helems; i += 256) {
            int r = i / DOUT, c = i - r * DOUT;
            h[(size_t)node0 * DOUT + i] = sXH[r * HW + c];
        }
    }
}

// ---------------- attention softmax + aggregate (wave per node, online softmax) ----
template <int DOUT, bool RELU_OUT>
__global__ void k_aggr(const float* __restrict__ h, const float* __restrict__ es,
                       const float* __restrict__ ed, const float* __restrict__ bias,
                       const int* __restrict__ off, const int* __restrict__ csr_send,
                       float* __restrict__ out, void* __restrict__ out_dev,
                       long long out_off, const int* __restrict__ flags) {
    int wid = threadIdx.x >> 6, lane = threadIdx.x & 63;
    int node = blockIdx.x * 4 + wid;
    if (node >= N_NODES) return;
    int start = off[node], end = off[node + 1];
    float edi = ed[node];

    float M = -1e30f, S = 0.f, acc0 = 0.f, acc1 = 0.f;
    for (int base = start; base < end; base += 64) {
        int j = base + lane;
        bool valid = j < end;
        int src = valid ? csr_send[j] : 0;
        float e = -1e30f;
        if (valid) {
            float v = es[src] + edi;
            e = (v >= 0.f) ? v : 0.2f * v;
        }
        float cmax = wave_max(e);
        float newM = fmaxf(M, cmax);
        float r = __expf(M - newM);
        float p = valid ? __expf(e - newM) : 0.f;
        S = S * r + wave_sum(p);
        acc0 *= r;
        acc1 *= r;
        int cnt = min(64, end - base);
        for (int j2 = 0; j2 < cnt; j2++) {
            float pj = __shfl(p, j2, 64);
            int sj = __shfl(src, j2, 64);
            const float* row = h + (size_t)sj * DOUT;
            if (lane < DOUT) acc0 = fmaf(pj, row[lane], acc0);
            if (DOUT > 64) acc1 = fmaf(pj, row[lane + 64], acc1);
        }
        M = newM;
    }
    float inv = 1.f / S;
    int isbf = flags[0];
    if (lane < DOUT) {
        float v = acc0 * inv + bias[lane];
        if (RELU_OUT) v = fmaxf(v, 0.f);
        out[(size_t)node * DOUT + lane] = v;
        if (out_dev) st_out(out_dev, out_off + (long long)node * DOUT + lane, v, isbf);
    }
    if (DOUT > 64) {
        float v = acc1 * inv + bias[lane + 64];
        if (RELU_OUT) v = fmaxf(v, 0.f);
        out[(size_t)node * DOUT + lane + 64] = v;
        if (out_dev) st_out(out_dev, out_off + (long long)node * DOUT + lane + 64, v, isbf);
    }
}

// ---------------- per-graph mean pooling: 1 block/graph, 16 waves ----------------
#define POOL_W 16
__global__ void k_pool(const float* __restrict__ latent, const void* __restrict__ batch,
                       const int* __restrict__ flags, float* __restrict__ pooled) {
    int b = blockIdx.x;
    int lane = threadIdx.x & 63;   // channel
    int wave = threadIdx.x >> 6;   // 0..15
    int is64 = flags[1];
    int lo = 0, hi = N_NODES;
    while (lo < hi) { int mid = (lo + hi) >> 1; if (ld_idx(batch, mid, is64) < b) lo = mid + 1; else hi = mid; }
    int start = lo;
    lo = 0; hi = N_NODES;
    while (lo < hi) { int mid = (lo + hi) >> 1; if (ld_idx(batch, mid, is64) < b + 1) lo = mid + 1; else hi = mid; }
    int end = lo;
    float s = 0.f;
    for (int n = start + wave; n < end; n += POOL_W) s += latent[(size_t)n * 64 + lane];
    __shared__ float red[POOL_W][64];
    red[wave][lane] = s;
    __syncthreads();
    if (wave == 0) {
        float t = s;
#pragma unroll
        for (int w2 = 1; w2 < POOL_W; w2++) t += red[w2][lane];
        float cnt = (float)(end - start);
        pooled[b * 64 + lane] = t / fmaxf(cnt, 1.f);
    }
}

// ---------------- classifier head ----------------
__global__ void k_cls(const float* __restrict__ pooled, const float* __restrict__ pb,
                      void* __restrict__ out_dev, long long out_off,
                      const int* __restrict__ flags) {
    int b = threadIdx.x;  // 64 threads, one per graph
    const float* Wc1 = pb + P_WC1;
    const float* bc1 = pb + P_BC1;
    const float* Wc2 = pb + P_WC2;
    const float* bc2 = pb + P_BC2;
    float z[32];
#pragma unroll
    for (int k = 0; k < 32; k++) z[k] = bc1[k];
    for (int c = 0; c < 64; c++) {
        float pv = pooled[b * 64 + c];
#pragma unroll
        for (int k = 0; k < 32; k++) z[k] = fmaf(pv, Wc1[c * 32 + k], z[k]);
    }
#pragma unroll
    for (int k = 0; k < 32; k++) z[k] = fmaxf(z[k], 0.f);
    float n0 = bc2[0], n1 = bc2[1];
#pragma unroll
    for (int k = 0; k < 32; k++) {
        n0 = fmaf(z[k], Wc2[k * 2 + 0], n0);
        n1 = fmaf(z[k], Wc2[k * 2 + 1], n1);
    }
    int isbf = flags[0];
    st_out(out_dev, out_off + b * 2 + 0, n0, isbf);
    st_out(out_dev, out_off + b * 2 + 1, n1, isbf);
}

extern "C" void kernel_launch(void* const* d_in, const int* in_sizes, int n_in,
                              void* d_out, int out_size, void* d_ws, size_t ws_size,
                              hipStream_t stream) {
    const void* x    = d_in[0];
    const void* eidx = d_in[1];
    const void* batch= d_in[2];

    // workspace carve-up (256B aligned)
    char* w = (char*)d_ws;
    size_t o = 0;
    auto carve = [&](size_t bytes) { void* p = w + o; o = (o + bytes + 255) & ~(size_t)255; return p; };
    int* flags    = (int*)carve(8 * sizeof(int));
    int* off      = (int*)carve((N_NODES + 1) * sizeof(int));
    int* counts   = (int*)carve(N_NODES * sizeof(int));
    int* cursor   = (int*)carve(N_NODES * sizeof(int));
    int* bsum     = (int*)carve(SCAN_NBLK * sizeof(int));
    int* bbase    = (int*)carve(SCAN_NBLK * sizeof(int));
    int* csr_send = (int*)carve((size_t)(N_EDGES + N_NODES) * sizeof(int));
    float* pblock = (float*)carve(P_TOTAL * sizeof(float));
    float* buf0   = (float*)carve((size_t)N_NODES * 128 * sizeof(float));
    float* buf1   = (float*)carve((size_t)N_NODES * 128 * sizeof(float));
    float* es     = (float*)carve(N_NODES * sizeof(float));
    float* ed     = (float*)carve(N_NODES * sizeof(float));
    float* pooled = (float*)carve(NB * 64 * sizeof(float));

    int gN = (N_NODES + 255) / 256;
    int gE = (N_EDGES + 255) / 256;
    int gW = N_NODES / 4;                 // k_aggr: 4 waves (nodes) per block
    int gT = (N_NODES + 63) / 64;         // k_gemm: 64-node tiles

    // dtype detect
    k_detect<<<1, 64, 0, stream>>>((const unsigned short*)x, (const unsigned int*)eidx, flags);

    // params -> f32 block
    PTab tab;
    const int pn[20]  = {384,128,128,128, 8192,64,64,64, 8192,128,128,128, 384,3,3,3, 2048,32,64,2};
    const int pof[20] = {P_W1,P_A1S,P_A1D,P_B1, P_W2,P_A2S,P_A2D,P_B2, P_W3,P_A3S,P_A3D,P_B3,
                         P_W4,P_A4S,P_A4D,P_B4, P_WC1,P_BC1,P_WC2,P_BC2};
    for (int i = 0; i < 20; i++) { tab.src[i] = d_in[3 + i]; tab.off[i] = pof[i]; tab.n[i] = pn[i]; }
    k_cvt_params<<<20, 256, 0, stream>>>(tab, flags, pblock);

    // CSR build
    k_init_counts<<<gN, 256, 0, stream>>>(counts);
    k_count<<<gE, 256, 0, stream>>>(eidx, flags, counts);
    k_scan_a<<<SCAN_NBLK, SCAN_BLK, 0, stream>>>(counts, off, bsum);
    k_scan_b<<<1, SCAN_BLK, 0, stream>>>(bsum, bbase);
    k_scan_c<<<SCAN_NBLK, SCAN_BLK, 0, stream>>>(off, bbase);
    k_selfloop<<<gN, 256, 0, stream>>>(off, csr_send, cursor);
    k_fill<<<gE, 256, 0, stream>>>(eidx, flags, off, cursor, csr_send);

    // x -> f32
    k_cvt_x<<<(N_NODES * 3 + 255) / 256, 256, 0, stream>>>(x, flags, buf0);

    // output element offsets
    const long long OFF_RECON = 0, OFF_LATENT = 150000, OFF_NOISE = 3350000;

    // conv1: [N,3] -> [N,128], relu
    k_gemm<3, 128><<<gT, 256, 0, stream>>>(buf0, pblock + P_W1, pblock + P_A1S, pblock + P_A1D, buf1, es, ed);
    k_aggr<128, true><<<gW, 256, 0, stream>>>(buf1, es, ed, pblock + P_B1, off, csr_send, buf0, nullptr, 0, flags);

    // conv2: [N,128] -> [N,64] (latent)
    k_gemm<128, 64><<<gT, 256, 0, stream>>>(buf0, pblock + P_W2, pblock + P_A2S, pblock + P_A2D, buf1, es, ed);
    k_aggr<64, false><<<gW, 256, 0, stream>>>(buf1, es, ed, pblock + P_B2, off, csr_send, buf0, d_out, OFF_LATENT, flags);

    // pooling + classifier from f32 latent (buf0)
    k_pool<<<NB, POOL_W * 64, 0, stream>>>(buf0, batch, flags, pooled);
    k_cls<<<1, 64, 0, stream>>>(pooled, pblock, d_out, OFF_NOISE, flags);

    // conv3: [N,64] -> [N,128], relu
    k_gemm<64, 128><<<gT, 256, 0, stream>>>(buf0, pblock + P_W3, pblock + P_A3S, pblock + P_A3D, buf1, es, ed);
    k_aggr<128, true><<<gW, 256, 0, stream>>>(buf1, es, ed, pblock + P_B3, off, csr_send, buf0, nullptr, 0, flags);

    // conv4: [N,128] -> [N,3] (reconstructed)
    k_gemm<128, 3><<<gT, 256, 0, stream>>>(buf0, pblock + P_W4, pblock + P_A4S, pblock + P_A4D, buf1, es, ed);
    k_aggr<3, false><<<gW, 256, 0, stream>>>(buf1, es, ed, pblock + P_B4, off, csr_send, buf0, d_out, OFF_RECON, flags);
}

// Round 6
// 532.657 us; speedup vs baseline: 1.6261x; 1.0296x over previous
//
#include <hip/hip_runtime.h>
#include <hip/hip_bf16.h>

typedef __hip_bfloat16 bf16;

#define N_NODES 50000
#define N_EDGES 800000
#define NB 64
#define SCAN_BLK 256
#define SCAN_NBLK ((N_NODES + SCAN_BLK - 1) / SCAN_BLK)   // 196

// param block offsets (floats)
#define P_W1 0
#define P_A1S 384
#define P_A1D 512
#define P_B1 640
#define P_W2 768
#define P_A2S 8960
#define P_A2D 9024
#define P_B2 9088
#define P_W3 9152
#define P_A3S 17344
#define P_A3D 17472
#define P_B3 17600
#define P_W4 17728
#define P_A4S 18112
#define P_A4D 18115
#define P_B4 18118
#define P_WC1 18121
#define P_BC1 20169
#define P_WC2 20201
#define P_BC2 20265
#define P_TOTAL 20267

__device__ __forceinline__ float wave_max(float v) {
#pragma unroll
    for (int o = 32; o >= 1; o >>= 1) v = fmaxf(v, __shfl_xor(v, o, 64));
    return v;
}
__device__ __forceinline__ float wave_sum(float v) {
#pragma unroll
    for (int o = 32; o >= 1; o >>= 1) v += __shfl_xor(v, o, 64);
    return v;
}

// runtime dtype helpers: flags[0]=float-inputs-are-bf16, flags[1]=ints-are-int64
__device__ __forceinline__ int ld_idx(const void* p, long long i, int is64) {
    return is64 ? (int)((const long long*)p)[i] : ((const int*)p)[i];
}
__device__ __forceinline__ void st_out(void* p, long long i, float v, int isbf) {
    if (isbf) ((bf16*)p)[i] = __float2bfloat16(v);
    else ((float*)p)[i] = v;
}

// ---------------- dtype detection ----------------
__global__ void k_detect(const unsigned short* xraw, const unsigned int* eraw,
                         int* flags) {
    if (threadIdx.x != 0 || blockIdx.x != 0) return;
    int cnt = 0;
    for (int i = 0; i < 256; i++) {
        unsigned int hb = (xraw[2 * i] >> 8) & 0x7F;
        if (hb >= 58 && hb <= 65) cnt++;
    }
    flags[0] = (cnt >= 200) ? 1 : 0;
    int z = 0;
    for (int i = 0; i < 64; i++)
        if (eraw[2 * i + 1] == 0u) z++;
    flags[1] = (z >= 60) ? 1 : 0;
}

// ---------------- input/param convert to f32 ----------------
struct PTab {
    const void* src[20];
    int off[20];
    int n[20];
};

__global__ void k_cvt_params(PTab tab, const int* __restrict__ flags,
                             float* __restrict__ pblock) {
    int t = blockIdx.x;
    const void* s = tab.src[t];
    float* d = pblock + tab.off[t];
    int n = tab.n[t];
    int isbf = flags[0];
    for (int i = threadIdx.x; i < n; i += blockDim.x)
        d[i] = isbf ? __bfloat162float(((const bf16*)s)[i]) : ((const float*)s)[i];
}

__global__ void k_cvt_x(const void* __restrict__ x, const int* __restrict__ flags,
                        float* __restrict__ buf) {
    int i = blockIdx.x * blockDim.x + threadIdx.x;
    if (i < N_NODES * 3)
        buf[i] = flags[0] ? __bfloat162float(((const bf16*)x)[i]) : ((const float*)x)[i];
}

// ---------------- CSR build ----------------
__global__ void k_init_counts(int* __restrict__ counts) {
    int i = blockIdx.x * blockDim.x + threadIdx.x;
    if (i < N_NODES) counts[i] = 1;  // self loop
}

__global__ void k_count(const void* __restrict__ eidx, const int* __restrict__ flags,
                        int* __restrict__ counts) {
    int e = blockIdx.x * blockDim.x + threadIdx.x;
    if (e < N_EDGES) {
        int r = ld_idx(eidx, (long long)N_EDGES + e, flags[1]);
        atomicAdd(&counts[r], 1);
    }
}

// ---------------- 3-phase parallel scan ----------------
__global__ void k_scan_a(const int* __restrict__ counts, int* __restrict__ off,
                         int* __restrict__ bsum) {
    __shared__ int s[SCAN_BLK];
    int t = threadIdx.x;
    int i = blockIdx.x * SCAN_BLK + t;
    int v = (i < N_NODES) ? counts[i] : 0;
    s[t] = v;
    __syncthreads();
#pragma unroll
    for (int o = 1; o < SCAN_BLK; o <<= 1) {
        int add = (t >= o) ? s[t - o] : 0;
        __syncthreads();
        s[t] += add;
        __syncthreads();
    }
    if (i < N_NODES) off[i + 1] = s[t];
    if (t == SCAN_BLK - 1) bsum[blockIdx.x] = s[t];
}

__global__ void k_scan_b(int* __restrict__ bsum, int* __restrict__ bbase) {
    __shared__ int s[SCAN_BLK];
    int t = threadIdx.x;
    s[t] = (t < SCAN_NBLK) ? bsum[t] : 0;
    __syncthreads();
#pragma unroll
    for (int o = 1; o < SCAN_BLK; o <<= 1) {
        int add = (t >= o) ? s[t - o] : 0;
        __syncthreads();
        s[t] += add;
        __syncthreads();
    }
    if (t < SCAN_NBLK) bbase[t] = s[t] - bsum[t];  // exclusive
}

__global__ void k_scan_c(int* __restrict__ off, const int* __restrict__ bbase) {
    int t = threadIdx.x;
    int i = blockIdx.x * SCAN_BLK + t;
    if (i < N_NODES) off[i + 1] += bbase[blockIdx.x];
    if (i == 0) off[0] = 0;
}

__global__ void k_selfloop(const int* __restrict__ off, int* __restrict__ csr_send,
                           int* __restrict__ cursor) {
    int i = blockIdx.x * blockDim.x + threadIdx.x;
    if (i < N_NODES) { csr_send[off[i]] = i; cursor[i] = 1; }
}

__global__ void k_fill(const void* __restrict__ eidx, const int* __restrict__ flags,
                       const int* __restrict__ off, int* __restrict__ cursor,
                       int* __restrict__ csr_send) {
    int e = blockIdx.x * blockDim.x + threadIdx.x;
    if (e < N_EDGES) {
        int s = ld_idx(eidx, e, flags[1]);
        int r = ld_idx(eidx, (long long)N_EDGES + e, flags[1]);
        int p = atomicAdd(&cursor[r], 1);
        csr_send[off[r] + p] = s;
    }
}

// ---------------- tiled linear + attention coefficients ----------------
template <int DIN, int DOUT>
__global__ __launch_bounds__(256) void k_gemm(
        const float* __restrict__ in, const float* __restrict__ W,
        const float* __restrict__ as_, const float* __restrict__ ad_,
        float* __restrict__ h, float* __restrict__ es, float* __restrict__ ed) {
    constexpr int NT = 64;
    constexpr int CPT = (DOUT >= 4) ? (DOUT / 4) : 1;
    constexpr int XW = DIN + 1, HW = DOUT + 1;
    constexpr int SXH = NT * (XW > HW ? XW : HW);
    __shared__ float sXH[SXH];
    __shared__ float sred[2][4][NT];

    const int t = threadIdx.x;
    const int node0 = blockIdx.x * NT;
    const int nvalid = min(NT, N_NODES - node0);

    const int xelems = nvalid * DIN;
    if (DIN % 4 == 0) {
        const float4* in4 = (const float4*)(in + (size_t)node0 * DIN);
        for (int i = t; i < xelems / 4; i += 256) {
            float4 v = in4[i];
            int e = i * 4, r = e / DIN, c = e - r * DIN;
            float* dst = &sXH[r * XW + c];
            dst[0] = v.x; dst[1] = v.y; dst[2] = v.z; dst[3] = v.w;
        }
    } else {
        for (int i = t; i < xelems; i += 256) {
            int r = i / DIN, c = i - r * DIN;
            sXH[r * XW + c] = in[(size_t)node0 * DIN + i];
        }
    }
    __syncthreads();

    const int ns = t & 63, g = t >> 6;
    const int col0 = g * CPT;
    float acc[CPT];
#pragma unroll
    for (int c = 0; c < CPT; c++) acc[c] = 0.f;

    if (col0 < DOUT) {
        for (int k = 0; k < DIN; k++) {
            float xv = sXH[ns * XW + k];
            const float* wr = W + k * DOUT + col0;
#pragma unroll
            for (int c = 0; c < CPT; c++) acc[c] = fmaf(xv, wr[c], acc[c]);
        }
    }
    float e_s = 0.f, e_d = 0.f;
    if (col0 < DOUT) {
#pragma unroll
        for (int c = 0; c < CPT; c++) {
            e_s = fmaf(acc[c], as_[col0 + c], e_s);
            e_d = fmaf(acc[c], ad_[col0 + c], e_d);
        }
    }
    sred[0][g][ns] = e_s;
    sred[1][g][ns] = e_d;
    __syncthreads();

    if (col0 < DOUT) {
#pragma unroll
        for (int c = 0; c < CPT; c++) sXH[ns * HW + col0 + c] = acc[c];
    }
    if (g == 0 && ns < nvalid) {
        es[node0 + ns] = sred[0][0][ns] + sred[0][1][ns] + sred[0][2][ns] + sred[0][3][ns];
        ed[node0 + ns] = sred[1][0][ns] + sred[1][1][ns] + sred[1][2][ns] + sred[1][3][ns];
    }
    __syncthreads();

    const int helems = nvalid * DOUT;
    if (DOUT % 4 == 0) {
        float4* h4 = (float4*)(h + (size_t)node0 * DOUT);
        for (int i = t; i < helems / 4; i += 256) {
            int e = i * 4, r = e / DOUT, c = e - r * DOUT;
            const float* sp = &sXH[r * HW + c];
            float4 v; v.x = sp[0]; v.y = sp[1]; v.z = sp[2]; v.w = sp[3];
            h4[i] = v;
        }
    } else {
        for (int i = t; i < helems; i += 256) {
            int r = i / DOUT, c = i - r * DOUT;
            h[(size_t)node0 * DOUT + i] = sXH[r * HW + c];
        }
    }
}

// ---------------- phase A: per-node softmax -> normalized alpha per CSR slot ----
__global__ __launch_bounds__(256) void k_alpha(
        const float* __restrict__ es, const float* __restrict__ ed,
        const int* __restrict__ off, const int* __restrict__ csr_send,
        float* __restrict__ alpha) {
    int wid = threadIdx.x >> 6, lane = threadIdx.x & 63;
    int node = blockIdx.x * 4 + wid;
    if (node >= N_NODES) return;
    int start = off[node], end = off[node + 1];
    float edi = ed[node];
    float M = -1e30f, S = 0.f;
    for (int base = start; base < end; base += 64) {
        int j = base + lane;
        bool valid = j < end;
        int src = valid ? csr_send[j] : 0;
        float e = -1e30f;
        if (valid) {
            float v = es[src] + edi;
            e = (v >= 0.f) ? v : 0.2f * v;
        }
        float cmax = wave_max(e);
        float newM = fmaxf(M, cmax);
        float p = valid ? __expf(e - newM) : 0.f;
        S = S * __expf(M - newM) + wave_sum(p);
        if (valid) alpha[j] = e;
        M = newM;
    }
    float inv = 1.f / S;
    for (int base = start; base < end; base += 64) {
        int j = base + lane;
        if (j < end) alpha[j] = __expf(alpha[j] - M) * inv;
    }
}

// ---------------- phase B: weighted sum, DOUT=128 (float2 per lane, 4 chains) ----
template <bool RELU_OUT>
__global__ __launch_bounds__(256) void k_wsum128(
        const float* __restrict__ h, const float* __restrict__ alpha,
        const float* __restrict__ bias, const int* __restrict__ off,
        const int* __restrict__ csr_send, float* __restrict__ out) {
    int wid = threadIdx.x >> 6, lane = threadIdx.x & 63;
    int node = blockIdx.x * 4 + wid;
    if (node >= N_NODES) return;
    int start = off[node], end = off[node + 1];
    float2 a0 = {0.f, 0.f}, a1 = {0.f, 0.f}, a2 = {0.f, 0.f}, a3 = {0.f, 0.f};
    for (int base = start; base < end; base += 64) {
        int j = base + lane;
        bool valid = j < end;
        int src = valid ? csr_send[j] : 0;
        float p = valid ? alpha[j] : 0.f;
        int cnt = min(64, end - base);
        int j2 = 0;
        for (; j2 + 4 <= cnt; j2 += 4) {
            float p0 = __shfl(p, j2 + 0, 64); int s0 = __shfl(src, j2 + 0, 64);
            float p1 = __shfl(p, j2 + 1, 64); int s1 = __shfl(src, j2 + 1, 64);
            float p2 = __shfl(p, j2 + 2, 64); int s2 = __shfl(src, j2 + 2, 64);
            float p3 = __shfl(p, j2 + 3, 64); int s3 = __shfl(src, j2 + 3, 64);
            float2 v0 = ((const float2*)(h + (size_t)s0 * 128))[lane];
            float2 v1 = ((const float2*)(h + (size_t)s1 * 128))[lane];
            float2 v2 = ((const float2*)(h + (size_t)s2 * 128))[lane];
            float2 v3 = ((const float2*)(h + (size_t)s3 * 128))[lane];
            a0.x = fmaf(p0, v0.x, a0.x); a0.y = fmaf(p0, v0.y, a0.y);
            a1.x = fmaf(p1, v1.x, a1.x); a1.y = fmaf(p1, v1.y, a1.y);
            a2.x = fmaf(p2, v2.x, a2.x); a2.y = fmaf(p2, v2.y, a2.y);
            a3.x = fmaf(p3, v3.x, a3.x); a3.y = fmaf(p3, v3.y, a3.y);
        }
        for (; j2 < cnt; j2++) {
            float pj = __shfl(p, j2, 64); int sj = __shfl(src, j2, 64);
            float2 v = ((const float2*)(h + (size_t)sj * 128))[lane];
            a0.x = fmaf(pj, v.x, a0.x); a0.y = fmaf(pj, v.y, a0.y);
        }
    }
    float2 r;
    r.x = ((a0.x + a1.x) + (a2.x + a3.x)) + bias[2 * lane];
    r.y = ((a0.y + a1.y) + (a2.y + a3.y)) + bias[2 * lane + 1];
    if (RELU_OUT) { r.x = fmaxf(r.x, 0.f); r.y = fmaxf(r.y, 0.f); }
    ((float2*)(out + (size_t)node * 128))[lane] = r;
}

// ---------------- phase B: weighted sum, DOUT=64 (scalar per lane, 4 chains) ----
__global__ __launch_bounds__(256) void k_wsum64(
        const float* __restrict__ h, const float* __restrict__ alpha,
        const float* __restrict__ bias, const int* __restrict__ off,
        const int* __restrict__ csr_send, float* __restrict__ out,
        void* __restrict__ out_dev, long long out_off, const int* __restrict__ flags) {
    int wid = threadIdx.x >> 6, lane = threadIdx.x & 63;
    int node = blockIdx.x * 4 + wid;
    if (node >= N_NODES) return;
    int start = off[node], end = off[node + 1];
    float a0 = 0.f, a1 = 0.f, a2 = 0.f, a3 = 0.f;
    for (int base = start; base < end; base += 64) {
        int j = base + lane;
        bool valid = j < end;
        int src = valid ? csr_send[j] : 0;
        float p = valid ? alpha[j] : 0.f;
        int cnt = min(64, end - base);
        int j2 = 0;
        for (; j2 + 4 <= cnt; j2 += 4) {
            float p0 = __shfl(p, j2 + 0, 64); int s0 = __shfl(src, j2 + 0, 64);
            float p1 = __shfl(p, j2 + 1, 64); int s1 = __shfl(src, j2 + 1, 64);
            float p2 = __shfl(p, j2 + 2, 64); int s2 = __shfl(src, j2 + 2, 64);
            float p3 = __shfl(p, j2 + 3, 64); int s3 = __shfl(src, j2 + 3, 64);
            a0 = fmaf(p0, h[(size_t)s0 * 64 + lane], a0);
            a1 = fmaf(p1, h[(size_t)s1 * 64 + lane], a1);
            a2 = fmaf(p2, h[(size_t)s2 * 64 + lane], a2);
            a3 = fmaf(p3, h[(size_t)s3 * 64 + lane], a3);
        }
        for (; j2 < cnt; j2++) {
            float pj = __shfl(p, j2, 64); int sj = __shfl(src, j2, 64);
            a0 = fmaf(pj, h[(size_t)sj * 64 + lane], a0);
        }
    }
    float r = ((a0 + a1) + (a2 + a3)) + bias[lane];
    out[(size_t)node * 64 + lane] = r;
    if (out_dev) st_out(out_dev, out_off + (long long)node * 64 + lane, r, flags[0]);
}

// ---------------- phase B: weighted sum, DOUT=3 (edge-parallel lanes) ----------
__global__ __launch_bounds__(256) void k_wsum3(
        const float* __restrict__ h, const float* __restrict__ alpha,
        const float* __restrict__ bias, const int* __restrict__ off,
        const int* __restrict__ csr_send,
        void* __restrict__ out_dev, long long out_off, const int* __restrict__ flags) {
    int wid = threadIdx.x >> 6, lane = threadIdx.x & 63;
    int node = blockIdx.x * 4 + wid;
    if (node >= N_NODES) return;
    int start = off[node], end = off[node + 1];
    float a0 = 0.f, a1 = 0.f, a2 = 0.f;
    for (int j = start + lane; j < end; j += 64) {
        float p = alpha[j];
        int s = csr_send[j];
        const float* row = h + (size_t)s * 3;
        a0 = fmaf(p, row[0], a0);
        a1 = fmaf(p, row[1], a1);
        a2 = fmaf(p, row[2], a2);
    }
    a0 = wave_sum(a0);
    a1 = wave_sum(a1);
    a2 = wave_sum(a2);
    if (lane < 3) {
        float v = (lane == 0 ? a0 : (lane == 1 ? a1 : a2)) + bias[lane];
        st_out(out_dev, out_off + (long long)node * 3 + lane, v, flags[0]);
    }
}

// ---------------- per-graph mean pooling: 1 block/graph, 16 waves ----------------
#define POOL_W 16
__global__ void k_pool(const float* __restrict__ latent, const void* __restrict__ batch,
                       const int* __restrict__ flags, float* __restrict__ pooled) {
    int b = blockIdx.x;
    int lane = threadIdx.x & 63;   // channel
    int wave = threadIdx.x >> 6;   // 0..15
    int is64 = flags[1];
    int lo = 0, hi = N_NODES;
    while (lo < hi) { int mid = (lo + hi) >> 1; if (ld_idx(batch, mid, is64) < b) lo = mid + 1; else hi = mid; }
    int start = lo;
    lo = 0; hi = N_NODES;
    while (lo < hi) { int mid = (lo + hi) >> 1; if (ld_idx(batch, mid, is64) < b + 1) lo = mid + 1; else hi = mid; }
    int end = lo;
    float s = 0.f;
    for (int n = start + wave; n < end; n += POOL_W) s += latent[(size_t)n * 64 + lane];
    __shared__ float red[POOL_W][64];
    red[wave][lane] = s;
    __syncthreads();
    if (wave == 0) {
        float t = s;
#pragma unroll
        for (int w2 = 1; w2 < POOL_W; w2++) t += red[w2][lane];
        float cnt = (float)(end - start);
        pooled[b * 64 + lane] = t / fmaxf(cnt, 1.f);
    }
}

// ---------------- classifier head ----------------
__global__ void k_cls(const float* __restrict__ pooled, const float* __restrict__ pb,
                      void* __restrict__ out_dev, long long out_off,
                      const int* __restrict__ flags) {
    int b = threadIdx.x;  // 64 threads, one per graph
    const float* Wc1 = pb + P_WC1;
    const float* bc1 = pb + P_BC1;
    const float* Wc2 = pb + P_WC2;
    const float* bc2 = pb + P_BC2;
    float z[32];
#pragma unroll
    for (int k = 0; k < 32; k++) z[k] = bc1[k];
    for (int c = 0; c < 64; c++) {
        float pv = pooled[b * 64 + c];
#pragma unroll
        for (int k = 0; k < 32; k++) z[k] = fmaf(pv, Wc1[c * 32 + k], z[k]);
    }
#pragma unroll
    for (int k = 0; k < 32; k++) z[k] = fmaxf(z[k], 0.f);
    float n0 = bc2[0], n1 = bc2[1];
#pragma unroll
    for (int k = 0; k < 32; k++) {
        n0 = fmaf(z[k], Wc2[k * 2 + 0], n0);
        n1 = fmaf(z[k], Wc2[k * 2 + 1], n1);
    }
    int isbf = flags[0];
    st_out(out_dev, out_off + b * 2 + 0, n0, isbf);
    st_out(out_dev, out_off + b * 2 + 1, n1, isbf);
}

extern "C" void kernel_launch(void* const* d_in, const int* in_sizes, int n_in,
                              void* d_out, int out_size, void* d_ws, size_t ws_size,
                              hipStream_t stream) {
    const void* x    = d_in[0];
    const void* eidx = d_in[1];
    const void* batch= d_in[2];

    // workspace carve-up (256B aligned)
    char* w = (char*)d_ws;
    size_t o = 0;
    auto carve = [&](size_t bytes) { void* p = w + o; o = (o + bytes + 255) & ~(size_t)255; return p; };
    int* flags    = (int*)carve(8 * sizeof(int));
    int* off      = (int*)carve((N_NODES + 1) * sizeof(int));
    int* counts   = (int*)carve(N_NODES * sizeof(int));
    int* cursor   = (int*)carve(N_NODES * sizeof(int));
    int* bsum     = (int*)carve(SCAN_NBLK * sizeof(int));
    int* bbase    = (int*)carve(SCAN_NBLK * sizeof(int));
    int* csr_send = (int*)carve((size_t)(N_EDGES + N_NODES) * sizeof(int));
    float* alpha  = (float*)carve((size_t)(N_EDGES + N_NODES) * sizeof(float));
    float* pblock = (float*)carve(P_TOTAL * sizeof(float));
    float* buf0   = (float*)carve((size_t)N_NODES * 128 * sizeof(float));
    float* buf1   = (float*)carve((size_t)N_NODES * 128 * sizeof(float));
    float* es     = (float*)carve(N_NODES * sizeof(float));
    float* ed     = (float*)carve(N_NODES * sizeof(float));
    float* pooled = (float*)carve(NB * 64 * sizeof(float));

    int gN = (N_NODES + 255) / 256;
    int gE = (N_EDGES + 255) / 256;
    int gW = N_NODES / 4;                 // wave-per-node kernels
    int gT = (N_NODES + 63) / 64;         // k_gemm: 64-node tiles

    // dtype detect
    k_detect<<<1, 64, 0, stream>>>((const unsigned short*)x, (const unsigned int*)eidx, flags);

    // params -> f32 block
    PTab tab;
    const int pn[20]  = {384,128,128,128, 8192,64,64,64, 8192,128,128,128, 384,3,3,3, 2048,32,64,2};
    const int pof[20] = {P_W1,P_A1S,P_A1D,P_B1, P_W2,P_A2S,P_A2D,P_B2, P_W3,P_A3S,P_A3D,P_B3,
                         P_W4,P_A4S,P_A4D,P_B4, P_WC1,P_BC1,P_WC2,P_BC2};
    for (int i = 0; i < 20; i++) { tab.src[i] = d_in[3 + i]; tab.off[i] = pof[i]; tab.n[i] = pn[i]; }
    k_cvt_params<<<20, 256, 0, stream>>>(tab, flags, pblock);

    // CSR build
    k_init_counts<<<gN, 256, 0, stream>>>(counts);
    k_count<<<gE, 256, 0, stream>>>(eidx, flags, counts);
    k_scan_a<<<SCAN_NBLK, SCAN_BLK, 0, stream>>>(counts, off, bsum);
    k_scan_b<<<1, SCAN_BLK, 0, stream>>>(bsum, bbase);
    k_scan_c<<<SCAN_NBLK, SCAN_BLK, 0, stream>>>(off, bbase);
    k_selfloop<<<gN, 256, 0, stream>>>(off, csr_send, cursor);
    k_fill<<<gE, 256, 0, stream>>>(eidx, flags, off, cursor, csr_send);

    // x -> f32
    k_cvt_x<<<(N_NODES * 3 + 255) / 256, 256, 0, stream>>>(x, flags, buf0);

    // output element offsets
    const long long OFF_RECON = 0, OFF_LATENT = 150000, OFF_NOISE = 3350000;

    // conv1: [N,3] -> [N,128], relu
    k_gemm<3, 128><<<gT, 256, 0, stream>>>(buf0, pblock + P_W1, pblock + P_A1S, pblock + P_A1D, buf1, es, ed);
    k_alpha<<<gW, 256, 0, stream>>>(es, ed, off, csr_send, alpha);
    k_wsum128<true><<<gW, 256, 0, stream>>>(buf1, alpha, pblock + P_B1, off, csr_send, buf0);

    // conv2: [N,128] -> [N,64] (latent)
    k_gemm<128, 64><<<gT, 256, 0, stream>>>(buf0, pblock + P_W2, pblock + P_A2S, pblock + P_A2D, buf1, es, ed);
    k_alpha<<<gW, 256, 0, stream>>>(es, ed, off, csr_send, alpha);
    k_wsum64<<<gW, 256, 0, stream>>>(buf1, alpha, pblock + P_B2, off, csr_send, buf0, d_out, OFF_LATENT, flags);

    // pooling + classifier from f32 latent (buf0)
    k_pool<<<NB, POOL_W * 64, 0, stream>>>(buf0, batch, flags, pooled);
    k_cls<<<1, 64, 0, stream>>>(pooled, pblock, d_out, OFF_NOISE, flags);

    // conv3: [N,64] -> [N,128], relu
    k_gemm<64, 128><<<gT, 256, 0, stream>>>(buf0, pblock + P_W3, pblock + P_A3S, pblock + P_A3D, buf1, es, ed);
    k_alpha<<<gW, 256, 0, stream>>>(es, ed, off, csr_send, alpha);
    k_wsum128<true><<<gW, 256, 0, stream>>>(buf1, alpha, pblock + P_B3, off, csr_send, buf0);

    // conv4: [N,128] -> [N,3] (reconstructed)
    k_gemm<128, 3><<<gT, 256, 0, stream>>>(buf0, pblock + P_W4, pblock + P_A4S, pblock + P_A4D, buf1, es, ed);
    k_alpha<<<gW, 256, 0, stream>>>(es, ed, off, csr_send, alpha);
    k_wsum3<<<gW, 256, 0, stream>>>(buf1, alpha, pblock + P_B4, off, csr_send, d_out, OFF_RECON, flags);
}

// Round 7
// 452.618 us; speedup vs baseline: 1.9136x; 1.1768x over previous
//
#include <hip/hip_runtime.h>
#include <hip/hip_bf16.h>

typedef __hip_bfloat16 bf16;

#define N_NODES 50000
#define N_EDGES 800000
#define NB 64
#define SCAN_BLK 256
#define SCAN_NBLK ((N_NODES + SCAN_BLK - 1) / SCAN_BLK)   // 196

// param block offsets (floats)
#define P_W1 0
#define P_A1S 384
#define P_A1D 512
#define P_B1 640
#define P_W2 768
#define P_A2S 8960
#define P_A2D 9024
#define P_B2 9088
#define P_W3 9152
#define P_A3S 17344
#define P_A3D 17472
#define P_B3 17600
#define P_W4 17728
#define P_A4S 18112
#define P_A4D 18115
#define P_B4 18118
#define P_WC1 18121
#define P_BC1 20169
#define P_WC2 20201
#define P_BC2 20265
#define P_TOTAL 20267

__device__ __forceinline__ float wave_max(float v) {
#pragma unroll
    for (int o = 32; o >= 1; o >>= 1) v = fmaxf(v, __shfl_xor(v, o, 64));
    return v;
}
__device__ __forceinline__ float wave_sum(float v) {
#pragma unroll
    for (int o = 32; o >= 1; o >>= 1) v += __shfl_xor(v, o, 64);
    return v;
}

// runtime dtype helpers: flags[0]=float-inputs-are-bf16, flags[1]=ints-are-int64
__device__ __forceinline__ int ld_idx(const void* p, long long i, int is64) {
    return is64 ? (int)((const long long*)p)[i] : ((const int*)p)[i];
}
__device__ __forceinline__ void st_out(void* p, long long i, float v, int isbf) {
    if (isbf) ((bf16*)p)[i] = __float2bfloat16(v);
    else ((float*)p)[i] = v;
}

// ---------------- dtype detection ----------------
__global__ void k_detect(const unsigned short* xraw, const unsigned int* eraw,
                         int* flags) {
    if (threadIdx.x != 0 || blockIdx.x != 0) return;
    int cnt = 0;
    for (int i = 0; i < 256; i++) {
        unsigned int hb = (xraw[2 * i] >> 8) & 0x7F;
        if (hb >= 58 && hb <= 65) cnt++;
    }
    flags[0] = (cnt >= 200) ? 1 : 0;
    int z = 0;
    for (int i = 0; i < 64; i++)
        if (eraw[2 * i + 1] == 0u) z++;
    flags[1] = (z >= 60) ? 1 : 0;
}

// ---------------- input/param convert to f32 ----------------
struct PTab {
    const void* src[20];
    int off[20];
    int n[20];
};

__global__ void k_cvt_params(PTab tab, const int* __restrict__ flags,
                             float* __restrict__ pblock) {
    int t = blockIdx.x;
    const void* s = tab.src[t];
    float* d = pblock + tab.off[t];
    int n = tab.n[t];
    int isbf = flags[0];
    for (int i = threadIdx.x; i < n; i += blockDim.x)
        d[i] = isbf ? __bfloat162float(((const bf16*)s)[i]) : ((const float*)s)[i];
}

__global__ void k_cvt_x(const void* __restrict__ x, const int* __restrict__ flags,
                        float* __restrict__ buf) {
    int i = blockIdx.x * blockDim.x + threadIdx.x;
    if (i < N_NODES * 3)
        buf[i] = flags[0] ? __bfloat162float(((const bf16*)x)[i]) : ((const float*)x)[i];
}

// ---------------- CSR build ----------------
__global__ void k_init_counts(int* __restrict__ counts) {
    int i = blockIdx.x * blockDim.x + threadIdx.x;
    if (i < N_NODES) counts[i] = 1;  // self loop
}

__global__ void k_count(const void* __restrict__ eidx, const int* __restrict__ flags,
                        int* __restrict__ counts) {
    int e = blockIdx.x * blockDim.x + threadIdx.x;
    if (e < N_EDGES) {
        int r = ld_idx(eidx, (long long)N_EDGES + e, flags[1]);
        atomicAdd(&counts[r], 1);
    }
}

// ---------------- 3-phase parallel scan ----------------
__global__ void k_scan_a(const int* __restrict__ counts, int* __restrict__ off,
                         int* __restrict__ bsum) {
    __shared__ int s[SCAN_BLK];
    int t = threadIdx.x;
    int i = blockIdx.x * SCAN_BLK + t;
    int v = (i < N_NODES) ? counts[i] : 0;
    s[t] = v;
    __syncthreads();
#pragma unroll
    for (int o = 1; o < SCAN_BLK; o <<= 1) {
        int add = (t >= o) ? s[t - o] : 0;
        __syncthreads();
        s[t] += add;
        __syncthreads();
    }
    if (i < N_NODES) off[i + 1] = s[t];
    if (t == SCAN_BLK - 1) bsum[blockIdx.x] = s[t];
}

__global__ void k_scan_b(int* __restrict__ bsum, int* __restrict__ bbase) {
    __shared__ int s[SCAN_BLK];
    int t = threadIdx.x;
    s[t] = (t < SCAN_NBLK) ? bsum[t] : 0;
    __syncthreads();
#pragma unroll
    for (int o = 1; o < SCAN_BLK; o <<= 1) {
        int add = (t >= o) ? s[t - o] : 0;
        __syncthreads();
        s[t] += add;
        __syncthreads();
    }
    if (t < SCAN_NBLK) bbase[t] = s[t] - bsum[t];  // exclusive
}

__global__ void k_scan_c(int* __restrict__ off, const int* __restrict__ bbase) {
    int t = threadIdx.x;
    int i = blockIdx.x * SCAN_BLK + t;
    if (i < N_NODES) off[i + 1] += bbase[blockIdx.x];
    if (i == 0) off[0] = 0;
}

__global__ void k_selfloop(const int* __restrict__ off, int* __restrict__ csr_send,
                           int* __restrict__ cursor) {
    int i = blockIdx.x * blockDim.x + threadIdx.x;
    if (i < N_NODES) { csr_send[off[i]] = i; cursor[i] = 1; }
}

__global__ void k_fill(const void* __restrict__ eidx, const int* __restrict__ flags,
                       const int* __restrict__ off, int* __restrict__ cursor,
                       int* __restrict__ csr_send) {
    int e = blockIdx.x * blockDim.x + threadIdx.x;
    if (e < N_EDGES) {
        int s = ld_idx(eidx, e, flags[1]);
        int r = ld_idx(eidx, (long long)N_EDGES + e, flags[1]);
        int p = atomicAdd(&cursor[r], 1);
        csr_send[off[r] + p] = s;
    }
}

// ---------------- register-tiled linear + attention coefficients ----------------
// DOUT>=64: thread (cg,ng) computes 4 nodes x 8 cols in registers.
//   Per k: 1 float4 x-read + 2 float4 W-reads from LDS -> 32 FMAs.
// DOUT==3: thread-per-node, W broadcast from LDS.
template <int DIN, int DOUT>
__global__ __launch_bounds__(256) void k_gemm(
        const float* __restrict__ in, const float* __restrict__ W,
        const float* __restrict__ as_, const float* __restrict__ ad_,
        float* __restrict__ h, float* __restrict__ es, float* __restrict__ ed) {
    constexpr int KC = (DIN < 32) ? DIN : 32;     // K-chunk
    constexpr int NCH = DIN / KC;                 // chunks
    constexpr int CG = (DOUT >= 64) ? (DOUT / 8) : 1;      // col groups
    constexpr int NT = (DOUT >= 64) ? ((256 / CG) * 4) : 256;  // nodes/block
    constexpr int NTP = NT + 4;                   // pad, keeps float4 alignment

    __shared__ float sX[KC][NTP];   // transposed x chunk
    __shared__ float sW[KC][DOUT];  // W chunk

    const int t = threadIdx.x;
    const int node0 = blockIdx.x * NT;
    const int nvalid = min(NT, N_NODES - node0);

    const int cg = t & (CG - 1);
    const int ng = t / CG;

    float acc[4][8] = {};  // DOUT==3 uses acc[0][0..2]

    for (int ch = 0; ch < NCH; ch++) {
        const int k0 = ch * KC;
        if (ch > 0) __syncthreads();  // previous chunk's reads done
        for (int i = t; i < nvalid * KC; i += 256) {
            int n = i / KC, k = i - n * KC;
            sX[k][n] = in[(size_t)(node0 + n) * DIN + k0 + k];
        }
        for (int i = t; i < KC * DOUT; i += 256) {
            int k = i / DOUT, c = i - k * DOUT;
            sW[k][c] = W[(size_t)(k0 + k) * DOUT + c];
        }
        __syncthreads();

        if constexpr (DOUT >= 64) {
#pragma unroll 4
            for (int k = 0; k < KC; k++) {
                float4 xv = *(const float4*)&sX[k][ng * 4];
                float4 w0 = *(const float4*)&sW[k][cg * 8];
                float4 w1 = *(const float4*)&sW[k][cg * 8 + 4];
                float xs[4] = {xv.x, xv.y, xv.z, xv.w};
                float ws[8] = {w0.x, w0.y, w0.z, w0.w, w1.x, w1.y, w1.z, w1.w};
#pragma unroll
                for (int j = 0; j < 4; j++)
#pragma unroll
                    for (int c = 0; c < 8; c++)
                        acc[j][c] = fmaf(xs[j], ws[c], acc[j][c]);
            }
        } else {
#pragma unroll 4
            for (int k = 0; k < KC; k++) {
                float xv = sX[k][t];
#pragma unroll
                for (int c = 0; c < DOUT; c++)
                    acc[0][c] = fmaf(xv, sW[k][c], acc[0][c]);
            }
        }
    }

    if constexpr (DOUT >= 64) {
        float asv[8], adv[8];
#pragma unroll
        for (int c = 0; c < 8; c++) {
            asv[c] = as_[cg * 8 + c];
            adv[c] = ad_[cg * 8 + c];
        }
#pragma unroll
        for (int j = 0; j < 4; j++) {
            int n = ng * 4 + j;
            float e_s = 0.f, e_d = 0.f;
#pragma unroll
            for (int c = 0; c < 8; c++) {
                e_s = fmaf(acc[j][c], asv[c], e_s);
                e_d = fmaf(acc[j][c], adv[c], e_d);
            }
#pragma unroll
            for (int m = 1; m < CG; m <<= 1) {
                e_s += __shfl_xor(e_s, m, 64);
                e_d += __shfl_xor(e_d, m, 64);
            }
            if (n < nvalid) {
                if (cg == 0) {
                    es[node0 + n] = e_s;
                    ed[node0 + n] = e_d;
                }
                float4 v0 = {acc[j][0], acc[j][1], acc[j][2], acc[j][3]};
                float4 v1 = {acc[j][4], acc[j][5], acc[j][6], acc[j][7]};
                *(float4*)&h[(size_t)(node0 + n) * DOUT + cg * 8] = v0;
                *(float4*)&h[(size_t)(node0 + n) * DOUT + cg * 8 + 4] = v1;
            }
        }
    } else {
        if (t < nvalid) {
            int node = node0 + t;
            float e_s = 0.f, e_d = 0.f;
#pragma unroll
            for (int c = 0; c < DOUT; c++) {
                e_s = fmaf(acc[0][c], as_[c], e_s);
                e_d = fmaf(acc[0][c], ad_[c], e_d);
            }
            es[node] = e_s;
            ed[node] = e_d;
#pragma unroll
            for (int c = 0; c < DOUT; c++) h[(size_t)node * DOUT + c] = acc[0][c];
        }
    }
}

// ---------------- phase A: per-node softmax -> normalized alpha per CSR slot ----
__global__ __launch_bounds__(256) void k_alpha(
        const float* __restrict__ es, const float* __restrict__ ed,
        const int* __restrict__ off, const int* __restrict__ csr_send,
        float* __restrict__ alpha) {
    int wid = threadIdx.x >> 6, lane = threadIdx.x & 63;
    int node = blockIdx.x * 4 + wid;
    if (node >= N_NODES) return;
    int start = off[node], end = off[node + 1];
    float edi = ed[node];
    float M = -1e30f, S = 0.f;
    for (int base = start; base < end; base += 64) {
        int j = base + lane;
        bool valid = j < end;
        int src = valid ? csr_send[j] : 0;
        float e = -1e30f;
        if (valid) {
            float v = es[src] + edi;
            e = (v >= 0.f) ? v : 0.2f * v;
        }
        float cmax = wave_max(e);
        float newM = fmaxf(M, cmax);
        float p = valid ? __expf(e - newM) : 0.f;
        S = S * __expf(M - newM) + wave_sum(p);
        if (valid) alpha[j] = e;
        M = newM;
    }
    float inv = 1.f / S;
    for (int base = start; base < end; base += 64) {
        int j = base + lane;
        if (j < end) alpha[j] = __expf(alpha[j] - M) * inv;
    }
}

// ---------------- phase B: weighted sum, DOUT=128 (float2 per lane, 4 chains) ----
template <bool RELU_OUT>
__global__ __launch_bounds__(256) void k_wsum128(
        const float* __restrict__ h, const float* __restrict__ alpha,
        const float* __restrict__ bias, const int* __restrict__ off,
        const int* __restrict__ csr_send, float* __restrict__ out) {
    int wid = threadIdx.x >> 6, lane = threadIdx.x & 63;
    int node = blockIdx.x * 4 + wid;
    if (node >= N_NODES) return;
    int start = off[node], end = off[node + 1];
    float2 a0 = {0.f, 0.f}, a1 = {0.f, 0.f}, a2 = {0.f, 0.f}, a3 = {0.f, 0.f};
    for (int base = start; base < end; base += 64) {
        int j = base + lane;
        bool valid = j < end;
        int src = valid ? csr_send[j] : 0;
        float p = valid ? alpha[j] : 0.f;
        int cnt = min(64, end - base);
        int j2 = 0;
        for (; j2 + 4 <= cnt; j2 += 4) {
            float p0 = __shfl(p, j2 + 0, 64); int s0 = __shfl(src, j2 + 0, 64);
            float p1 = __shfl(p, j2 + 1, 64); int s1 = __shfl(src, j2 + 1, 64);
            float p2 = __shfl(p, j2 + 2, 64); int s2 = __shfl(src, j2 + 2, 64);
            float p3 = __shfl(p, j2 + 3, 64); int s3 = __shfl(src, j2 + 3, 64);
            float2 v0 = ((const float2*)(h + (size_t)s0 * 128))[lane];
            float2 v1 = ((const float2*)(h + (size_t)s1 * 128))[lane];
            float2 v2 = ((const float2*)(h + (size_t)s2 * 128))[lane];
            float2 v3 = ((const float2*)(h + (size_t)s3 * 128))[lane];
            a0.x = fmaf(p0, v0.x, a0.x); a0.y = fmaf(p0, v0.y, a0.y);
            a1.x = fmaf(p1, v1.x, a1.x); a1.y = fmaf(p1, v1.y, a1.y);
            a2.x = fmaf(p2, v2.x, a2.x); a2.y = fmaf(p2, v2.y, a2.y);
            a3.x = fmaf(p3, v3.x, a3.x); a3.y = fmaf(p3, v3.y, a3.y);
        }
        for (; j2 < cnt; j2++) {
            float pj = __shfl(p, j2, 64); int sj = __shfl(src, j2, 64);
            float2 v = ((const float2*)(h + (size_t)sj * 128))[lane];
            a0.x = fmaf(pj, v.x, a0.x); a0.y = fmaf(pj, v.y, a0.y);
        }
    }
    float2 r;
    r.x = ((a0.x + a1.x) + (a2.x + a3.x)) + bias[2 * lane];
    r.y = ((a0.y + a1.y) + (a2.y + a3.y)) + bias[2 * lane + 1];
    if (RELU_OUT) { r.x = fmaxf(r.x, 0.f); r.y = fmaxf(r.y, 0.f); }
    ((float2*)(out + (size_t)node * 128))[lane] = r;
}

// ---------------- phase B: weighted sum, DOUT=64 (scalar per lane, 4 chains) ----
__global__ __launch_bounds__(256) void k_wsum64(
        const float* __restrict__ h, const float* __restrict__ alpha,
        const float* __restrict__ bias, const int* __restrict__ off,
        const int* __restrict__ csr_send, float* __restrict__ out,
        void* __restrict__ out_dev, long long out_off, const int* __restrict__ flags) {
    int wid = threadIdx.x >> 6, lane = threadIdx.x & 63;
    int node = blockIdx.x * 4 + wid;
    if (node >= N_NODES) return;
    int start = off[node], end = off[node + 1];
    float a0 = 0.f, a1 = 0.f, a2 = 0.f, a3 = 0.f;
    for (int base = start; base < end; base += 64) {
        int j = base + lane;
        bool valid = j < end;
        int src = valid ? csr_send[j] : 0;
        float p = valid ? alpha[j] : 0.f;
        int cnt = min(64, end - base);
        int j2 = 0;
        for (; j2 + 4 <= cnt; j2 += 4) {
            float p0 = __shfl(p, j2 + 0, 64); int s0 = __shfl(src, j2 + 0, 64);
            float p1 = __shfl(p, j2 + 1, 64); int s1 = __shfl(src, j2 + 1, 64);
            float p2 = __shfl(p, j2 + 2, 64); int s2 = __shfl(src, j2 + 2, 64);
            float p3 = __shfl(p, j2 + 3, 64); int s3 = __shfl(src, j2 + 3, 64);
            a0 = fmaf(p0, h[(size_t)s0 * 64 + lane], a0);
            a1 = fmaf(p1, h[(size_t)s1 * 64 + lane], a1);
            a2 = fmaf(p2, h[(size_t)s2 * 64 + lane], a2);
            a3 = fmaf(p3, h[(size_t)s3 * 64 + lane], a3);
        }
        for (; j2 < cnt; j2++) {
            float pj = __shfl(p, j2, 64); int sj = __shfl(src, j2, 64);
            a0 = fmaf(pj, h[(size_t)sj * 64 + lane], a0);
        }
    }
    float r = ((a0 + a1) + (a2 + a3)) + bias[lane];
    out[(size_t)node * 64 + lane] = r;
    if (out_dev) st_out(out_dev, out_off + (long long)node * 64 + lane, r, flags[0]);
}

// ---------------- phase B: weighted sum, DOUT=3 (edge-parallel lanes) ----------
__global__ __launch_bounds__(256) void k_wsum3(
        const float* __restrict__ h, const float* __restrict__ alpha,
        const float* __restrict__ bias, const int* __restrict__ off,
        const int* __restrict__ csr_send,
        void* __restrict__ out_dev, long long out_off, const int* __restrict__ flags) {
    int wid = threadIdx.x >> 6, lane = threadIdx.x & 63;
    int node = blockIdx.x * 4 + wid;
    if (node >= N_NODES) return;
    int start = off[node], end = off[node + 1];
    float a0 = 0.f, a1 = 0.f, a2 = 0.f;
    for (int j = start + lane; j < end; j += 64) {
        float p = alpha[j];
        int s = csr_send[j];
        const float* row = h + (size_t)s * 3;
        a0 = fmaf(p, row[0], a0);
        a1 = fmaf(p, row[1], a1);
        a2 = fmaf(p, row[2], a2);
    }
    a0 = wave_sum(a0);
    a1 = wave_sum(a1);
    a2 = wave_sum(a2);
    if (lane < 3) {
        float v = (lane == 0 ? a0 : (lane == 1 ? a1 : a2)) + bias[lane];
        st_out(out_dev, out_off + (long long)node * 3 + lane, v, flags[0]);
    }
}

// ---------------- per-graph mean pooling: 1 block/graph, 16 waves ----------------
#define POOL_W 16
__global__ void k_pool(const float* __restrict__ latent, const void* __restrict__ batch,
                       const int* __restrict__ flags, float* __restrict__ pooled) {
    int b = blockIdx.x;
    int lane = threadIdx.x & 63;   // channel
    int wave = threadIdx.x >> 6;   // 0..15
    int is64 = flags[1];
    int lo = 0, hi = N_NODES;
    while (lo < hi) { int mid = (lo + hi) >> 1; if (ld_idx(batch, mid, is64) < b) lo = mid + 1; else hi = mid; }
    int start = lo;
    lo = 0; hi = N_NODES;
    while (lo < hi) { int mid = (lo + hi) >> 1; if (ld_idx(batch, mid, is64) < b + 1) lo = mid + 1; else hi = mid; }
    int end = lo;
    float s = 0.f;
    for (int n = start + wave; n < end; n += POOL_W) s += latent[(size_t)n * 64 + lane];
    __shared__ float red[POOL_W][64];
    red[wave][lane] = s;
    __syncthreads();
    if (wave == 0) {
        float t = s;
#pragma unroll
        for (int w2 = 1; w2 < POOL_W; w2++) t += red[w2][lane];
        float cnt = (float)(end - start);
        pooled[b * 64 + lane] = t / fmaxf(cnt, 1.f);
    }
}

// ---------------- classifier head ----------------
__global__ void k_cls(const float* __restrict__ pooled, const float* __restrict__ pb,
                      void* __restrict__ out_dev, long long out_off,
                      const int* __restrict__ flags) {
    int b = threadIdx.x;  // 64 threads, one per graph
    const float* Wc1 = pb + P_WC1;
    const float* bc1 = pb + P_BC1;
    const float* Wc2 = pb + P_WC2;
    const float* bc2 = pb + P_BC2;
    float z[32];
#pragma unroll
    for (int k = 0; k < 32; k++) z[k] = bc1[k];
    for (int c = 0; c < 64; c++) {
        float pv = pooled[b * 64 + c];
#pragma unroll
        for (int k = 0; k < 32; k++) z[k] = fmaf(pv, Wc1[c * 32 + k], z[k]);
    }
#pragma unroll
    for (int k = 0; k < 32; k++) z[k] = fmaxf(z[k], 0.f);
    float n0 = bc2[0], n1 = bc2[1];
#pragma unroll
    for (int k = 0; k < 32; k++) {
        n0 = fmaf(z[k], Wc2[k * 2 + 0], n0);
        n1 = fmaf(z[k], Wc2[k * 2 + 1], n1);
    }
    int isbf = flags[0];
    st_out(out_dev, out_off + b * 2 + 0, n0, isbf);
    st_out(out_dev, out_off + b * 2 + 1, n1, isbf);
}

extern "C" void kernel_launch(void* const* d_in, const int* in_sizes, int n_in,
                              void* d_out, int out_size, void* d_ws, size_t ws_size,
                              hipStream_t stream) {
    const void* x    = d_in[0];
    const void* eidx = d_in[1];
    const void* batch= d_in[2];

    // workspace carve-up (256B aligned)
    char* w = (char*)d_ws;
    size_t o = 0;
    auto carve = [&](size_t bytes) { void* p = w + o; o = (o + bytes + 255) & ~(size_t)255; return p; };
    int* flags    = (int*)carve(8 * sizeof(int));
    int* off      = (int*)carve((N_NODES + 1) * sizeof(int));
    int* counts   = (int*)carve(N_NODES * sizeof(int));
    int* cursor   = (int*)carve(N_NODES * sizeof(int));
    int* bsum     = (int*)carve(SCAN_NBLK * sizeof(int));
    int* bbase    = (int*)carve(SCAN_NBLK * sizeof(int));
    int* csr_send = (int*)carve((size_t)(N_EDGES + N_NODES) * sizeof(int));
    float* alpha  = (float*)carve((size_t)(N_EDGES + N_NODES) * sizeof(float));
    float* pblock = (float*)carve(P_TOTAL * sizeof(float));
    float* buf0   = (float*)carve((size_t)N_NODES * 128 * sizeof(float));
    float* buf1   = (float*)carve((size_t)N_NODES * 128 * sizeof(float));
    float* es     = (float*)carve(N_NODES * sizeof(float));
    float* ed     = (float*)carve(N_NODES * sizeof(float));
    float* pooled = (float*)carve(NB * 64 * sizeof(float));

    int gN = (N_NODES + 255) / 256;
    int gE = (N_EDGES + 255) / 256;
    int gW = N_NODES / 4;                 // wave-per-node kernels

    // dtype detect
    k_detect<<<1, 64, 0, stream>>>((const unsigned short*)x, (const unsigned int*)eidx, flags);

    // params -> f32 block
    PTab tab;
    const int pn[20]  = {384,128,128,128, 8192,64,64,64, 8192,128,128,128, 384,3,3,3, 2048,32,64,2};
    const int pof[20] = {P_W1,P_A1S,P_A1D,P_B1, P_W2,P_A2S,P_A2D,P_B2, P_W3,P_A3S,P_A3D,P_B3,
                         P_W4,P_A4S,P_A4D,P_B4, P_WC1,P_BC1,P_WC2,P_BC2};
    for (int i = 0; i < 20; i++) { tab.src[i] = d_in[3 + i]; tab.off[i] = pof[i]; tab.n[i] = pn[i]; }
    k_cvt_params<<<20, 256, 0, stream>>>(tab, flags, pblock);

    // CSR build
    k_init_counts<<<gN, 256, 0, stream>>>(counts);
    k_count<<<gE, 256, 0, stream>>>(eidx, flags, counts);
    k_scan_a<<<SCAN_NBLK, SCAN_BLK, 0, stream>>>(counts, off, bsum);
    k_scan_b<<<1, SCAN_BLK, 0, stream>>>(bsum, bbase);
    k_scan_c<<<SCAN_NBLK, SCAN_BLK, 0, stream>>>(off, bbase);
    k_selfloop<<<gN, 256, 0, stream>>>(off, csr_send, cursor);
    k_fill<<<gE, 256, 0, stream>>>(eidx, flags, off, cursor, csr_send);

    // x -> f32
    k_cvt_x<<<(N_NODES * 3 + 255) / 256, 256, 0, stream>>>(x, flags, buf0);

    // output element offsets
    const long long OFF_RECON = 0, OFF_LATENT = 150000, OFF_NOISE = 3350000;

    // gemm grids: nodes/block = 64 (DOUT=128), 128 (DOUT=64), 256 (DOUT=3)
    int g64  = (N_NODES + 63) / 64;
    int g128 = (N_NODES + 127) / 128;
    int g256 = (N_NODES + 255) / 256;

    // conv1: [N,3] -> [N,128], relu
    k_gemm<3, 128><<<g64, 256, 0, stream>>>(buf0, pblock + P_W1, pblock + P_A1S, pblock + P_A1D, buf1, es, ed);
    k_alpha<<<gW, 256, 0, stream>>>(es, ed, off, csr_send, alpha);
    k_wsum128<true><<<gW, 256, 0, stream>>>(buf1, alpha, pblock + P_B1, off, csr_send, buf0);

    // conv2: [N,128] -> [N,64] (latent)
    k_gemm<128, 64><<<g128, 256, 0, stream>>>(buf0, pblock + P_W2, pblock + P_A2S, pblock + P_A2D, buf1, es, ed);
    k_alpha<<<gW, 256, 0, stream>>>(es, ed, off, csr_send, alpha);
    k_wsum64<<<gW, 256, 0, stream>>>(buf1, alpha, pblock + P_B2, off, csr_send, buf0, d_out, OFF_LATENT, flags);

    // pooling + classifier from f32 latent (buf0)
    k_pool<<<NB, POOL_W * 64, 0, stream>>>(buf0, batch, flags, pooled);
    k_cls<<<1, 64, 0, stream>>>(pooled, pblock, d_out, OFF_NOISE, flags);

    // conv3: [N,64] -> [N,128], relu
    k_gemm<64, 128><<<g64, 256, 0, stream>>>(buf0, pblock + P_W3, pblock + P_A3S, pblock + P_A3D, buf1, es, ed);
    k_alpha<<<gW, 256, 0, stream>>>(es, ed, off, csr_send, alpha);
    k_wsum128<true><<<gW, 256, 0, stream>>>(buf1, alpha, pblock + P_B3, off, csr_send, buf0);

    // conv4: [N,128] -> [N,3] (reconstructed)
    k_gemm<128, 3><<<g256, 256, 0, stream>>>(buf0, pblock + P_W4, pblock + P_A4S, pblock + P_A4D, buf1, es, ed);
    k_alpha<<<gW, 256, 0, stream>>>(es, ed, off, csr_send, alpha);
    k_wsum3<<<gW, 256, 0, stream>>>(buf1, alpha, pblock + P_B4, off, csr_send, d_out, OFF_RECON, flags);
}

// Round 8
// 377.364 us; speedup vs baseline: 2.2953x; 1.1994x over previous
//
#include <hip/hip_runtime.h>
#include <hip/hip_bf16.h>

typedef __hip_bfloat16 bf16;

#define N_NODES 50000
#define N_EDGES 800000
#define NB 64
#define SCAN_BLK 256
#define SCAN_NBLK ((N_NODES + SCAN_BLK - 1) / SCAN_BLK)   // 196

// param block offsets (floats)
#define P_W1 0
#define P_A1S 384
#define P_A1D 512
#define P_B1 640
#define P_W2 768
#define P_A2S 8960
#define P_A2D 9024
#define P_B2 9088
#define P_W3 9152
#define P_A3S 17344
#define P_A3D 17472
#define P_B3 17600
#define P_W4 17728
#define P_A4S 18112
#define P_A4D 18115
#define P_B4 18118
#define P_WC1 18121
#define P_BC1 20169
#define P_WC2 20201
#define P_BC2 20265
#define P_TOTAL 20267

__device__ __forceinline__ float wave_max(float v) {
#pragma unroll
    for (int o = 32; o >= 1; o >>= 1) v = fmaxf(v, __shfl_xor(v, o, 64));
    return v;
}
__device__ __forceinline__ float wave_sum(float v) {
#pragma unroll
    for (int o = 32; o >= 1; o >>= 1) v += __shfl_xor(v, o, 64);
    return v;
}

// bf16 pack/unpack (bit tricks, no cvt on unpack)
__device__ __forceinline__ unsigned int pk2(float a, float b) {
    bf16 x = __float2bfloat16(a);
    bf16 y = __float2bfloat16(b);
    unsigned short ux = *reinterpret_cast<unsigned short*>(&x);
    unsigned short uy = *reinterpret_cast<unsigned short*>(&y);
    return ((unsigned int)uy << 16) | ux;
}
__device__ __forceinline__ float bf_lo(unsigned int u) {
    unsigned int v = u << 16;
    return *reinterpret_cast<float*>(&v);
}
__device__ __forceinline__ float bf_hi(unsigned int u) {
    unsigned int v = u & 0xffff0000u;
    return *reinterpret_cast<float*>(&v);
}
__device__ __forceinline__ float bf_us(unsigned short u) {
    unsigned int v = ((unsigned int)u) << 16;
    return *reinterpret_cast<float*>(&v);
}

// runtime dtype helpers: flags[0]=float-inputs-are-bf16, flags[1]=ints-are-int64
__device__ __forceinline__ int ld_idx(const void* p, long long i, int is64) {
    return is64 ? (int)((const long long*)p)[i] : ((const int*)p)[i];
}
__device__ __forceinline__ void st_out(void* p, long long i, float v, int isbf) {
    if (isbf) ((bf16*)p)[i] = __float2bfloat16(v);
    else ((float*)p)[i] = v;
}

// ---------------- dtype detection ----------------
__global__ void k_detect(const unsigned short* xraw, const unsigned int* eraw,
                         int* flags) {
    if (threadIdx.x != 0 || blockIdx.x != 0) return;
    int cnt = 0;
    for (int i = 0; i < 256; i++) {
        unsigned int hb = (xraw[2 * i] >> 8) & 0x7F;
        if (hb >= 58 && hb <= 65) cnt++;
    }
    flags[0] = (cnt >= 200) ? 1 : 0;
    int z = 0;
    for (int i = 0; i < 64; i++)
        if (eraw[2 * i + 1] == 0u) z++;
    flags[1] = (z >= 60) ? 1 : 0;
}

// ---------------- input/param convert to f32 ----------------
struct PTab {
    const void* src[20];
    int off[20];
    int n[20];
};

__global__ void k_cvt_params(PTab tab, const int* __restrict__ flags,
                             float* __restrict__ pblock) {
    int t = blockIdx.x;
    const void* s = tab.src[t];
    float* d = pblock + tab.off[t];
    int n = tab.n[t];
    int isbf = flags[0];
    for (int i = threadIdx.x; i < n; i += blockDim.x)
        d[i] = isbf ? __bfloat162float(((const bf16*)s)[i]) : ((const float*)s)[i];
}

__global__ void k_cvt_x(const void* __restrict__ x, const int* __restrict__ flags,
                        float* __restrict__ buf) {
    int i = blockIdx.x * blockDim.x + threadIdx.x;
    if (i < N_NODES * 3)
        buf[i] = flags[0] ? __bfloat162float(((const bf16*)x)[i]) : ((const float*)x)[i];
}

// ---------------- CSR build ----------------
__global__ void k_init_counts(int* __restrict__ counts) {
    int i = blockIdx.x * blockDim.x + threadIdx.x;
    if (i < N_NODES) counts[i] = 1;  // self loop
}

__global__ void k_count(const void* __restrict__ eidx, const int* __restrict__ flags,
                        int* __restrict__ counts) {
    int e = blockIdx.x * blockDim.x + threadIdx.x;
    if (e < N_EDGES) {
        int r = ld_idx(eidx, (long long)N_EDGES + e, flags[1]);
        atomicAdd(&counts[r], 1);
    }
}

// ---------------- 3-phase parallel scan ----------------
__global__ void k_scan_a(const int* __restrict__ counts, int* __restrict__ off,
                         int* __restrict__ bsum) {
    __shared__ int s[SCAN_BLK];
    int t = threadIdx.x;
    int i = blockIdx.x * SCAN_BLK + t;
    int v = (i < N_NODES) ? counts[i] : 0;
    s[t] = v;
    __syncthreads();
#pragma unroll
    for (int o = 1; o < SCAN_BLK; o <<= 1) {
        int add = (t >= o) ? s[t - o] : 0;
        __syncthreads();
        s[t] += add;
        __syncthreads();
    }
    if (i < N_NODES) off[i + 1] = s[t];
    if (t == SCAN_BLK - 1) bsum[blockIdx.x] = s[t];
}

__global__ void k_scan_b(int* __restrict__ bsum, int* __restrict__ bbase) {
    __shared__ int s[SCAN_BLK];
    int t = threadIdx.x;
    s[t] = (t < SCAN_NBLK) ? bsum[t] : 0;
    __syncthreads();
#pragma unroll
    for (int o = 1; o < SCAN_BLK; o <<= 1) {
        int add = (t >= o) ? s[t - o] : 0;
        __syncthreads();
        s[t] += add;
        __syncthreads();
    }
    if (t < SCAN_NBLK) bbase[t] = s[t] - bsum[t];  // exclusive
}

__global__ void k_scan_c(int* __restrict__ off, const int* __restrict__ bbase) {
    int t = threadIdx.x;
    int i = blockIdx.x * SCAN_BLK + t;
    if (i < N_NODES) off[i + 1] += bbase[blockIdx.x];
    if (i == 0) off[0] = 0;
}

__global__ void k_selfloop(const int* __restrict__ off, int* __restrict__ csr_send,
                           int* __restrict__ cursor) {
    int i = blockIdx.x * blockDim.x + threadIdx.x;
    if (i < N_NODES) { csr_send[off[i]] = i; cursor[i] = 1; }
}

__global__ void k_fill(const void* __restrict__ eidx, const int* __restrict__ flags,
                       const int* __restrict__ off, int* __restrict__ cursor,
                       int* __restrict__ csr_send) {
    int e = blockIdx.x * blockDim.x + threadIdx.x;
    if (e < N_EDGES) {
        int s = ld_idx(eidx, e, flags[1]);
        int r = ld_idx(eidx, (long long)N_EDGES + e, flags[1]);
        int p = atomicAdd(&cursor[r], 1);
        csr_send[off[r] + p] = s;
    }
}

// ---------------- register-tiled linear + attention coefficients ----------------
// DOUT>=64: thread (cg,ng) computes 4 nodes x 8 cols in registers.
// HB16: h stored as packed bf16 (gather phase reads it); else f32.
template <int DIN, int DOUT, bool HB16>
__global__ __launch_bounds__(256) void k_gemm(
        const float* __restrict__ in, const float* __restrict__ W,
        const float* __restrict__ as_, const float* __restrict__ ad_,
        void* __restrict__ hout, float* __restrict__ es, float* __restrict__ ed) {
    constexpr int KC = (DIN < 32) ? DIN : 32;     // K-chunk
    constexpr int NCH = DIN / KC;                 // chunks
    constexpr int CG = (DOUT >= 64) ? (DOUT / 8) : 1;      // col groups
    constexpr int NT = (DOUT >= 64) ? ((256 / CG) * 4) : 256;  // nodes/block
    constexpr int NTP = NT + 4;                   // pad

    __shared__ float sX[KC][NTP];   // transposed x chunk
    __shared__ float sW[KC][DOUT];  // W chunk

    const int t = threadIdx.x;
    const int node0 = blockIdx.x * NT;
    const int nvalid = min(NT, N_NODES - node0);

    const int cg = t & (CG - 1);
    const int ng = t / CG;

    float acc[4][8] = {};

    for (int ch = 0; ch < NCH; ch++) {
        const int k0 = ch * KC;
        if (ch > 0) __syncthreads();
        for (int i = t; i < nvalid * KC; i += 256) {
            int n = i / KC, k = i - n * KC;
            sX[k][n] = in[(size_t)(node0 + n) * DIN + k0 + k];
        }
        for (int i = t; i < KC * DOUT; i += 256) {
            int k = i / DOUT, c = i - k * DOUT;
            sW[k][c] = W[(size_t)(k0 + k) * DOUT + c];
        }
        __syncthreads();

        if constexpr (DOUT >= 64) {
#pragma unroll 4
            for (int k = 0; k < KC; k++) {
                float4 xv = *(const float4*)&sX[k][ng * 4];
                float4 w0 = *(const float4*)&sW[k][cg * 8];
                float4 w1 = *(const float4*)&sW[k][cg * 8 + 4];
                float xs[4] = {xv.x, xv.y, xv.z, xv.w};
                float ws[8] = {w0.x, w0.y, w0.z, w0.w, w1.x, w1.y, w1.z, w1.w};
#pragma unroll
                for (int j = 0; j < 4; j++)
#pragma unroll
                    for (int c = 0; c < 8; c++)
                        acc[j][c] = fmaf(xs[j], ws[c], acc[j][c]);
            }
        } else {
#pragma unroll 4
            for (int k = 0; k < KC; k++) {
                float xv = sX[k][t];
#pragma unroll
                for (int c = 0; c < DOUT; c++)
                    acc[0][c] = fmaf(xv, sW[k][c], acc[0][c]);
            }
        }
    }

    if constexpr (DOUT >= 64) {
        float asv[8], adv[8];
#pragma unroll
        for (int c = 0; c < 8; c++) {
            asv[c] = as_[cg * 8 + c];
            adv[c] = ad_[cg * 8 + c];
        }
#pragma unroll
        for (int j = 0; j < 4; j++) {
            int n = ng * 4 + j;
            float e_s = 0.f, e_d = 0.f;
#pragma unroll
            for (int c = 0; c < 8; c++) {
                e_s = fmaf(acc[j][c], asv[c], e_s);
                e_d = fmaf(acc[j][c], adv[c], e_d);
            }
#pragma unroll
            for (int m = 1; m < CG; m <<= 1) {
                e_s += __shfl_xor(e_s, m, 64);
                e_d += __shfl_xor(e_d, m, 64);
            }
            if (n < nvalid) {
                if (cg == 0) {
                    es[node0 + n] = e_s;
                    ed[node0 + n] = e_d;
                }
                if constexpr (HB16) {
                    unsigned short* hb = (unsigned short*)hout;
                    uint4 u;
                    u.x = pk2(acc[j][0], acc[j][1]);
                    u.y = pk2(acc[j][2], acc[j][3]);
                    u.z = pk2(acc[j][4], acc[j][5]);
                    u.w = pk2(acc[j][6], acc[j][7]);
                    *(uint4*)&hb[(size_t)(node0 + n) * DOUT + cg * 8] = u;
                } else {
                    float* h = (float*)hout;
                    float4 v0 = {acc[j][0], acc[j][1], acc[j][2], acc[j][3]};
                    float4 v1 = {acc[j][4], acc[j][5], acc[j][6], acc[j][7]};
                    *(float4*)&h[(size_t)(node0 + n) * DOUT + cg * 8] = v0;
                    *(float4*)&h[(size_t)(node0 + n) * DOUT + cg * 8 + 4] = v1;
                }
            }
        }
    } else {
        if (t < nvalid) {
            int node = node0 + t;
            float e_s = 0.f, e_d = 0.f;
#pragma unroll
            for (int c = 0; c < DOUT; c++) {
                e_s = fmaf(acc[0][c], as_[c], e_s);
                e_d = fmaf(acc[0][c], ad_[c], e_d);
            }
            es[node] = e_s;
            ed[node] = e_d;
            float* h = (float*)hout;
#pragma unroll
            for (int c = 0; c < DOUT; c++) h[(size_t)node * DOUT + c] = acc[0][c];
        }
    }
}

// ---------------- fused softmax + weighted sum, DOUT=128, bf16 h ----------------
template <bool RELU_OUT>
__global__ __launch_bounds__(256) void k_wsum128f(
        const unsigned short* __restrict__ hb, const float* __restrict__ es,
        const float* __restrict__ ed, const float* __restrict__ bias,
        const int* __restrict__ off, const int* __restrict__ csr_send,
        float* __restrict__ out) {
    int wid = threadIdx.x >> 6, lane = threadIdx.x & 63;
    int node = blockIdx.x * 4 + wid;
    if (node >= N_NODES) return;
    int start = off[node], end = off[node + 1];
    float edi = ed[node];

    // pass A: online M, S (es gathers are L2-resident)
    float M = -1e30f, S = 0.f;
    for (int base = start; base < end; base += 64) {
        int j = base + lane;
        bool valid = j < end;
        int src = valid ? csr_send[j] : 0;
        float e = -1e30f;
        if (valid) {
            float v = es[src] + edi;
            e = (v >= 0.f) ? v : 0.2f * v;
        }
        float cmax = wave_max(e);
        float newM = fmaxf(M, cmax);
        float p = valid ? __expf(e - newM) : 0.f;
        S = S * __expf(M - newM) + wave_sum(p);
        M = newM;
    }
    float inv = 1.f / S;

    // pass B: gather bf16 rows
    float2 a0 = {0.f, 0.f}, a1 = {0.f, 0.f}, a2 = {0.f, 0.f}, a3 = {0.f, 0.f};
    for (int base = start; base < end; base += 64) {
        int j = base + lane;
        bool valid = j < end;
        int src = valid ? csr_send[j] : 0;
        float p = 0.f;
        if (valid) {
            float v = es[src] + edi;
            float e = (v >= 0.f) ? v : 0.2f * v;
            p = __expf(e - M) * inv;
        }
        int cnt = min(64, end - base);
        int j2 = 0;
        for (; j2 + 4 <= cnt; j2 += 4) {
            float p0 = __shfl(p, j2 + 0, 64); int s0 = __shfl(src, j2 + 0, 64);
            float p1 = __shfl(p, j2 + 1, 64); int s1 = __shfl(src, j2 + 1, 64);
            float p2 = __shfl(p, j2 + 2, 64); int s2 = __shfl(src, j2 + 2, 64);
            float p3 = __shfl(p, j2 + 3, 64); int s3 = __shfl(src, j2 + 3, 64);
            unsigned int u0 = ((const unsigned int*)(hb + (size_t)s0 * 128))[lane];
            unsigned int u1 = ((const unsigned int*)(hb + (size_t)s1 * 128))[lane];
            unsigned int u2 = ((const unsigned int*)(hb + (size_t)s2 * 128))[lane];
            unsigned int u3 = ((const unsigned int*)(hb + (size_t)s3 * 128))[lane];
            a0.x = fmaf(p0, bf_lo(u0), a0.x); a0.y = fmaf(p0, bf_hi(u0), a0.y);
            a1.x = fmaf(p1, bf_lo(u1), a1.x); a1.y = fmaf(p1, bf_hi(u1), a1.y);
            a2.x = fmaf(p2, bf_lo(u2), a2.x); a2.y = fmaf(p2, bf_hi(u2), a2.y);
            a3.x = fmaf(p3, bf_lo(u3), a3.x); a3.y = fmaf(p3, bf_hi(u3), a3.y);
        }
        for (; j2 < cnt; j2++) {
            float pj = __shfl(p, j2, 64); int sj = __shfl(src, j2, 64);
            unsigned int u = ((const unsigned int*)(hb + (size_t)sj * 128))[lane];
            a0.x = fmaf(pj, bf_lo(u), a0.x); a0.y = fmaf(pj, bf_hi(u), a0.y);
        }
    }
    float2 r;
    r.x = ((a0.x + a1.x) + (a2.x + a3.x)) + bias[2 * lane];
    r.y = ((a0.y + a1.y) + (a2.y + a3.y)) + bias[2 * lane + 1];
    if (RELU_OUT) { r.x = fmaxf(r.x, 0.f); r.y = fmaxf(r.y, 0.f); }
    ((float2*)(out + (size_t)node * 128))[lane] = r;
}

// ---------------- fused softmax + weighted sum, DOUT=64, bf16 h ----------------
__global__ __launch_bounds__(256) void k_wsum64f(
        const unsigned short* __restrict__ hb, const float* __restrict__ es,
        const float* __restrict__ ed, const float* __restrict__ bias,
        const int* __restrict__ off, const int* __restrict__ csr_send,
        float* __restrict__ out, void* __restrict__ out_dev, long long out_off,
        const int* __restrict__ flags) {
    int wid = threadIdx.x >> 6, lane = threadIdx.x & 63;
    int node = blockIdx.x * 4 + wid;
    if (node >= N_NODES) return;
    int start = off[node], end = off[node + 1];
    float edi = ed[node];

    float M = -1e30f, S = 0.f;
    for (int base = start; base < end; base += 64) {
        int j = base + lane;
        bool valid = j < end;
        int src = valid ? csr_send[j] : 0;
        float e = -1e30f;
        if (valid) {
            float v = es[src] + edi;
            e = (v >= 0.f) ? v : 0.2f * v;
        }
        float cmax = wave_max(e);
        float newM = fmaxf(M, cmax);
        float p = valid ? __expf(e - newM) : 0.f;
        S = S * __expf(M - newM) + wave_sum(p);
        M = newM;
    }
    float inv = 1.f / S;

    float a0 = 0.f, a1 = 0.f, a2 = 0.f, a3 = 0.f;
    for (int base = start; base < end; base += 64) {
        int j = base + lane;
        bool valid = j < end;
        int src = valid ? csr_send[j] : 0;
        float p = 0.f;
        if (valid) {
            float v = es[src] + edi;
            float e = (v >= 0.f) ? v : 0.2f * v;
            p = __expf(e - M) * inv;
        }
        int cnt = min(64, end - base);
        int j2 = 0;
        for (; j2 + 4 <= cnt; j2 += 4) {
            float p0 = __shfl(p, j2 + 0, 64); int s0 = __shfl(src, j2 + 0, 64);
            float p1 = __shfl(p, j2 + 1, 64); int s1 = __shfl(src, j2 + 1, 64);
            float p2 = __shfl(p, j2 + 2, 64); int s2 = __shfl(src, j2 + 2, 64);
            float p3 = __shfl(p, j2 + 3, 64); int s3 = __shfl(src, j2 + 3, 64);
            a0 = fmaf(p0, bf_us(hb[(size_t)s0 * 64 + lane]), a0);
            a1 = fmaf(p1, bf_us(hb[(size_t)s1 * 64 + lane]), a1);
            a2 = fmaf(p2, bf_us(hb[(size_t)s2 * 64 + lane]), a2);
            a3 = fmaf(p3, bf_us(hb[(size_t)s3 * 64 + lane]), a3);
        }
        for (; j2 < cnt; j2++) {
            float pj = __shfl(p, j2, 64); int sj = __shfl(src, j2, 64);
            a0 = fmaf(pj, bf_us(hb[(size_t)sj * 64 + lane]), a0);
        }
    }
    float r = ((a0 + a1) + (a2 + a3)) + bias[lane];
    out[(size_t)node * 64 + lane] = r;
    if (out_dev) st_out(out_dev, out_off + (long long)node * 64 + lane, r, flags[0]);
}

// ---------------- fused softmax + weighted sum, DOUT=3 (edge-parallel) ---------
__global__ __launch_bounds__(256) void k_wsum3f(
        const float* __restrict__ h, const float* __restrict__ es,
        const float* __restrict__ ed, const float* __restrict__ bias,
        const int* __restrict__ off, const int* __restrict__ csr_send,
        void* __restrict__ out_dev, long long out_off, const int* __restrict__ flags) {
    int wid = threadIdx.x >> 6, lane = threadIdx.x & 63;
    int node = blockIdx.x * 4 + wid;
    if (node >= N_NODES) return;
    int start = off[node], end = off[node + 1];
    float edi = ed[node];

    float M = -1e30f, S = 0.f;
    for (int base = start; base < end; base += 64) {
        int j = base + lane;
        bool valid = j < end;
        int src = valid ? csr_send[j] : 0;
        float e = -1e30f;
        if (valid) {
            float v = es[src] + edi;
            e = (v >= 0.f) ? v : 0.2f * v;
        }
        float cmax = wave_max(e);
        float newM = fmaxf(M, cmax);
        float p = valid ? __expf(e - newM) : 0.f;
        S = S * __expf(M - newM) + wave_sum(p);
        M = newM;
    }
    float inv = 1.f / S;

    float a0 = 0.f, a1 = 0.f, a2 = 0.f;
    for (int j = start + lane; j < end; j += 64) {
        int s = csr_send[j];
        float v = es[s] + edi;
        float e = (v >= 0.f) ? v : 0.2f * v;
        float p = __expf(e - M) * inv;
        const float* row = h + (size_t)s * 3;
        a0 = fmaf(p, row[0], a0);
        a1 = fmaf(p, row[1], a1);
        a2 = fmaf(p, row[2], a2);
    }
    a0 = wave_sum(a0);
    a1 = wave_sum(a1);
    a2 = wave_sum(a2);
    if (lane < 3) {
        float v = (lane == 0 ? a0 : (lane == 1 ? a1 : a2)) + bias[lane];
        st_out(out_dev, out_off + (long long)node * 3 + lane, v, flags[0]);
    }
}

// ---------------- per-graph mean pooling: 1 block/graph, 16 waves ----------------
#define POOL_W 16
__global__ void k_pool(const float* __restrict__ latent, const void* __restrict__ batch,
                       const int* __restrict__ flags, float* __restrict__ pooled) {
    int b = blockIdx.x;
    int lane = threadIdx.x & 63;   // channel
    int wave = threadIdx.x >> 6;   // 0..15
    int is64 = flags[1];
    int lo = 0, hi = N_NODES;
    while (lo < hi) { int mid = (lo + hi) >> 1; if (ld_idx(batch, mid, is64) < b) lo = mid + 1; else hi = mid; }
    int start = lo;
    lo = 0; hi = N_NODES;
    while (lo < hi) { int mid = (lo + hi) >> 1; if (ld_idx(batch, mid, is64) < b + 1) lo = mid + 1; else hi = mid; }
    int end = lo;
    float s = 0.f;
    for (int n = start + wave; n < end; n += POOL_W) s += latent[(size_t)n * 64 + lane];
    __shared__ float red[POOL_W][64];
    red[wave][lane] = s;
    __syncthreads();
    if (wave == 0) {
        float t = s;
#pragma unroll
        for (int w2 = 1; w2 < POOL_W; w2++) t += red[w2][lane];
        float cnt = (float)(end - start);
        pooled[b * 64 + lane] = t / fmaxf(cnt, 1.f);
    }
}

// ---------------- classifier head ----------------
__global__ void k_cls(const float* __restrict__ pooled, const float* __restrict__ pb,
                      void* __restrict__ out_dev, long long out_off,
                      const int* __restrict__ flags) {
    int b = threadIdx.x;  // 64 threads, one per graph
    const float* Wc1 = pb + P_WC1;
    const float* bc1 = pb + P_BC1;
    const float* Wc2 = pb + P_WC2;
    const float* bc2 = pb + P_BC2;
    float z[32];
#pragma unroll
    for (int k = 0; k < 32; k++) z[k] = bc1[k];
    for (int c = 0; c < 64; c++) {
        float pv = pooled[b * 64 + c];
#pragma unroll
        for (int k = 0; k < 32; k++) z[k] = fmaf(pv, Wc1[c * 32 + k], z[k]);
    }
#pragma unroll
    for (int k = 0; k < 32; k++) z[k] = fmaxf(z[k], 0.f);
    float n0 = bc2[0], n1 = bc2[1];
#pragma unroll
    for (int k = 0; k < 32; k++) {
        n0 = fmaf(z[k], Wc2[k * 2 + 0], n0);
        n1 = fmaf(z[k], Wc2[k * 2 + 1], n1);
    }
    int isbf = flags[0];
    st_out(out_dev, out_off + b * 2 + 0, n0, isbf);
    st_out(out_dev, out_off + b * 2 + 1, n1, isbf);
}

extern "C" void kernel_launch(void* const* d_in, const int* in_sizes, int n_in,
                              void* d_out, int out_size, void* d_ws, size_t ws_size,
                              hipStream_t stream) {
    const void* x    = d_in[0];
    const void* eidx = d_in[1];
    const void* batch= d_in[2];

    // workspace carve-up (256B aligned)
    char* w = (char*)d_ws;
    size_t o = 0;
    auto carve = [&](size_t bytes) { void* p = w + o; o = (o + bytes + 255) & ~(size_t)255; return p; };
    int* flags    = (int*)carve(8 * sizeof(int));
    int* off      = (int*)carve((N_NODES + 1) * sizeof(int));
    int* counts   = (int*)carve(N_NODES * sizeof(int));
    int* cursor   = (int*)carve(N_NODES * sizeof(int));
    int* bsum     = (int*)carve(SCAN_NBLK * sizeof(int));
    int* bbase    = (int*)carve(SCAN_NBLK * sizeof(int));
    int* csr_send = (int*)carve((size_t)(N_EDGES + N_NODES) * sizeof(int));
    float* pblock = (float*)carve(P_TOTAL * sizeof(float));
    float* buf0   = (float*)carve((size_t)N_NODES * 128 * sizeof(float));
    unsigned short* hb = (unsigned short*)carve((size_t)N_NODES * 128 * sizeof(unsigned short));
    float* h3     = (float*)carve((size_t)N_NODES * 3 * sizeof(float));
    float* es     = (float*)carve(N_NODES * sizeof(float));
    float* ed     = (float*)carve(N_NODES * sizeof(float));
    float* pooled = (float*)carve(NB * 64 * sizeof(float));

    int gN = (N_NODES + 255) / 256;
    int gE = (N_EDGES + 255) / 256;
    int gW = N_NODES / 4;                 // wave-per-node kernels

    // dtype detect
    k_detect<<<1, 64, 0, stream>>>((const unsigned short*)x, (const unsigned int*)eidx, flags);

    // params -> f32 block
    PTab tab;
    const int pn[20]  = {384,128,128,128, 8192,64,64,64, 8192,128,128,128, 384,3,3,3, 2048,32,64,2};
    const int pof[20] = {P_W1,P_A1S,P_A1D,P_B1, P_W2,P_A2S,P_A2D,P_B2, P_W3,P_A3S,P_A3D,P_B3,
                         P_W4,P_A4S,P_A4D,P_B4, P_WC1,P_BC1,P_WC2,P_BC2};
    for (int i = 0; i < 20; i++) { tab.src[i] = d_in[3 + i]; tab.off[i] = pof[i]; tab.n[i] = pn[i]; }
    k_cvt_params<<<20, 256, 0, stream>>>(tab, flags, pblock);

    // CSR build
    k_init_counts<<<gN, 256, 0, stream>>>(counts);
    k_count<<<gE, 256, 0, stream>>>(eidx, flags, counts);
    k_scan_a<<<SCAN_NBLK, SCAN_BLK, 0, stream>>>(counts, off, bsum);
    k_scan_b<<<1, SCAN_BLK, 0, stream>>>(bsum, bbase);
    k_scan_c<<<SCAN_NBLK, SCAN_BLK, 0, stream>>>(off, bbase);
    k_selfloop<<<gN, 256, 0, stream>>>(off, csr_send, cursor);
    k_fill<<<gE, 256, 0, stream>>>(eidx, flags, off, cursor, csr_send);

    // x -> f32
    k_cvt_x<<<(N_NODES * 3 + 255) / 256, 256, 0, stream>>>(x, flags, buf0);

    // output element offsets
    const long long OFF_RECON = 0, OFF_LATENT = 150000, OFF_NOISE = 3350000;

    // gemm grids: nodes/block = 64 (DOUT=128), 128 (DOUT=64), 256 (DOUT=3)
    int g64  = (N_NODES + 63) / 64;
    int g128 = (N_NODES + 127) / 128;
    int g256 = (N_NODES + 255) / 256;

    // conv1: [N,3] -> [N,128], relu
    k_gemm<3, 128, true><<<g64, 256, 0, stream>>>(buf0, pblock + P_W1, pblock + P_A1S, pblock + P_A1D, hb, es, ed);
    k_wsum128f<true><<<gW, 256, 0, stream>>>(hb, es, ed, pblock + P_B1, off, csr_send, buf0);

    // conv2: [N,128] -> [N,64] (latent)
    k_gemm<128, 64, true><<<g128, 256, 0, stream>>>(buf0, pblock + P_W2, pblock + P_A2S, pblock + P_A2D, hb, es, ed);
    k_wsum64f<<<gW, 256, 0, stream>>>(hb, es, ed, pblock + P_B2, off, csr_send, buf0, d_out, OFF_LATENT, flags);

    // pooling + classifier from f32 latent (buf0)
    k_pool<<<NB, POOL_W * 64, 0, stream>>>(buf0, batch, flags, pooled);
    k_cls<<<1, 64, 0, stream>>>(pooled, pblock, d_out, OFF_NOISE, flags);

    // conv3: [N,64] -> [N,128], relu
    k_gemm<64, 128, true><<<g64, 256, 0, stream>>>(buf0, pblock + P_W3, pblock + P_A3S, pblock + P_A3D, hb, es, ed);
    k_wsum128f<true><<<gW, 256, 0, stream>>>(hb, es, ed, pblock + P_B3, off, csr_send, buf0);

    // conv4: [N,128] -> [N,3] (reconstructed)
    k_gemm<128, 3, false><<<g256, 256, 0, stream>>>(buf0, pblock + P_W4, pblock + P_A4S, pblock + P_A4D, h3, es, ed);
    k_wsum3f<<<gW, 256, 0, stream>>>(h3, es, ed, pblock + P_B4, off, csr_send, d_out, OFF_RECON, flags);
}

// Round 9
// 370.613 us; speedup vs baseline: 2.3371x; 1.0182x over previous
//
#include <hip/hip_runtime.h>
#include <hip/hip_bf16.h>

typedef __hip_bfloat16 bf16;

#define N_NODES 50000
#define N_EDGES 800000
#define NB 64
#define SCAN_BLK 256
#define SCAN_NBLK ((N_NODES + SCAN_BLK - 1) / SCAN_BLK)   // 196

// k_fill pass partitioning
#define FILL_PASSES 8
#define FILL_BPP 256                                   // blocks per pass
#define FILL_RANGE ((N_NODES + FILL_PASSES - 1) / FILL_PASSES)  // 6250

// param block offsets (floats)
#define P_W1 0
#define P_A1S 384
#define P_A1D 512
#define P_B1 640
#define P_W2 768
#define P_A2S 8960
#define P_A2D 9024
#define P_B2 9088
#define P_W3 9152
#define P_A3S 17344
#define P_A3D 17472
#define P_B3 17600
#define P_W4 17728
#define P_A4S 18112
#define P_A4D 18115
#define P_B4 18118
#define P_WC1 18121
#define P_BC1 20169
#define P_WC2 20201
#define P_BC2 20265
#define P_TOTAL 20267

__device__ __forceinline__ float wave_max(float v) {
#pragma unroll
    for (int o = 32; o >= 1; o >>= 1) v = fmaxf(v, __shfl_xor(v, o, 64));
    return v;
}
__device__ __forceinline__ float wave_sum(float v) {
#pragma unroll
    for (int o = 32; o >= 1; o >>= 1) v += __shfl_xor(v, o, 64);
    return v;
}

// bf16 pack/unpack (bit tricks, no cvt on unpack)
__device__ __forceinline__ unsigned int pk2(float a, float b) {
    bf16 x = __float2bfloat16(a);
    bf16 y = __float2bfloat16(b);
    unsigned short ux = *reinterpret_cast<unsigned short*>(&x);
    unsigned short uy = *reinterpret_cast<unsigned short*>(&y);
    return ((unsigned int)uy << 16) | ux;
}
__device__ __forceinline__ float bf_lo(unsigned int u) {
    unsigned int v = u << 16;
    return *reinterpret_cast<float*>(&v);
}
__device__ __forceinline__ float bf_hi(unsigned int u) {
    unsigned int v = u & 0xffff0000u;
    return *reinterpret_cast<float*>(&v);
}
__device__ __forceinline__ float bf_us(unsigned short u) {
    unsigned int v = ((unsigned int)u) << 16;
    return *reinterpret_cast<float*>(&v);
}

// runtime dtype helpers: flags[0]=float-inputs-are-bf16, flags[1]=ints-are-int64
__device__ __forceinline__ int ld_idx(const void* p, long long i, int is64) {
    return is64 ? (int)((const long long*)p)[i] : ((const int*)p)[i];
}
__device__ __forceinline__ void st_out(void* p, long long i, float v, int isbf) {
    if (isbf) ((bf16*)p)[i] = __float2bfloat16(v);
    else ((float*)p)[i] = v;
}

// ---------------- dtype detection ----------------
__global__ void k_detect(const unsigned short* xraw, const unsigned int* eraw,
                         int* flags) {
    if (threadIdx.x != 0 || blockIdx.x != 0) return;
    int cnt = 0;
    for (int i = 0; i < 256; i++) {
        unsigned int hb = (xraw[2 * i] >> 8) & 0x7F;
        if (hb >= 58 && hb <= 65) cnt++;
    }
    flags[0] = (cnt >= 200) ? 1 : 0;
    int z = 0;
    for (int i = 0; i < 64; i++)
        if (eraw[2 * i + 1] == 0u) z++;
    flags[1] = (z >= 60) ? 1 : 0;
}

// ---------------- input/param convert to f32 ----------------
struct PTab {
    const void* src[20];
    int off[20];
    int n[20];
};

__global__ void k_cvt_params(PTab tab, const int* __restrict__ flags,
                             float* __restrict__ pblock) {
    int t = blockIdx.x;
    const void* s = tab.src[t];
    float* d = pblock + tab.off[t];
    int n = tab.n[t];
    int isbf = flags[0];
    for (int i = threadIdx.x; i < n; i += blockDim.x)
        d[i] = isbf ? __bfloat162float(((const bf16*)s)[i]) : ((const float*)s)[i];
}

__global__ void k_cvt_x(const void* __restrict__ x, const int* __restrict__ flags,
                        float* __restrict__ buf) {
    int i = blockIdx.x * blockDim.x + threadIdx.x;
    if (i < N_NODES * 3)
        buf[i] = flags[0] ? __bfloat162float(((const bf16*)x)[i]) : ((const float*)x)[i];
}

// ---------------- CSR build ----------------
__global__ void k_init_counts(int* __restrict__ counts) {
    int i = blockIdx.x * blockDim.x + threadIdx.x;
    if (i < N_NODES) counts[i] = 1;  // self loop
}

__global__ void k_count(const void* __restrict__ eidx, const int* __restrict__ flags,
                        int* __restrict__ counts) {
    int e = blockIdx.x * blockDim.x + threadIdx.x;
    if (e < N_EDGES) {
        int r = ld_idx(eidx, (long long)N_EDGES + e, flags[1]);
        atomicAdd(&counts[r], 1);
    }
}

// ---------------- 3-phase parallel scan ----------------
__global__ void k_scan_a(const int* __restrict__ counts, int* __restrict__ off,
                         int* __restrict__ bsum) {
    __shared__ int s[SCAN_BLK];
    int t = threadIdx.x;
    int i = blockIdx.x * SCAN_BLK + t;
    int v = (i < N_NODES) ? counts[i] : 0;
    s[t] = v;
    __syncthreads();
#pragma unroll
    for (int o = 1; o < SCAN_BLK; o <<= 1) {
        int add = (t >= o) ? s[t - o] : 0;
        __syncthreads();
        s[t] += add;
        __syncthreads();
    }
    if (i < N_NODES) off[i + 1] = s[t];
    if (t == SCAN_BLK - 1) bsum[blockIdx.x] = s[t];
}

__global__ void k_scan_b(int* __restrict__ bsum, int* __restrict__ bbase) {
    __shared__ int s[SCAN_BLK];
    int t = threadIdx.x;
    s[t] = (t < SCAN_NBLK) ? bsum[t] : 0;
    __syncthreads();
#pragma unroll
    for (int o = 1; o < SCAN_BLK; o <<= 1) {
        int add = (t >= o) ? s[t - o] : 0;
        __syncthreads();
        s[t] += add;
        __syncthreads();
    }
    if (t < SCAN_NBLK) bbase[t] = s[t] - bsum[t];  // exclusive
}

__global__ void k_scan_c(int* __restrict__ off, const int* __restrict__ bbase) {
    int t = threadIdx.x;
    int i = blockIdx.x * SCAN_BLK + t;
    if (i < N_NODES) off[i + 1] += bbase[blockIdx.x];
    if (i == 0) off[0] = 0;
}

__global__ void k_selfloop(const int* __restrict__ off, int* __restrict__ csr_send,
                           int* __restrict__ cursor) {
    int i = blockIdx.x * blockDim.x + threadIdx.x;
    if (i < N_NODES) { csr_send[off[i]] = i; cursor[i] = 1; }
}

// node-range-partitioned fill: pass p writes only nodes [p*RANGE,(p+1)*RANGE)
// -> write window ~425KB stays L2-resident, lines accumulate dirty bytes.
__global__ __launch_bounds__(256) void k_fill(
        const void* __restrict__ eidx, const int* __restrict__ flags,
        const int* __restrict__ off, int* __restrict__ cursor,
        int* __restrict__ csr_send) {
    const int pass = blockIdx.x / FILL_BPP;
    const int bid = blockIdx.x - pass * FILL_BPP;
    const int lo = pass * FILL_RANGE;
    const int hi = min(lo + FILL_RANGE, N_NODES);
    const int is64 = flags[1];
    for (int e = bid * 256 + threadIdx.x; e < N_EDGES; e += FILL_BPP * 256) {
        int r = ld_idx(eidx, (long long)N_EDGES + e, is64);
        if (r >= lo && r < hi) {
            int s = ld_idx(eidx, e, is64);
            int p = atomicAdd(&cursor[r], 1);
            csr_send[off[r] + p] = s;
        }
    }
}

// ---------------- register-tiled linear + attention coefficients ----------------
// DOUT>=64: thread (cg,ng) computes 4 nodes x 8 cols in registers.
// HB16: h stored as packed bf16; DOUT==3: f32, padded to stride 4.
template <int DIN, int DOUT, bool HB16>
__global__ __launch_bounds__(256) void k_gemm(
        const float* __restrict__ in, const float* __restrict__ W,
        const float* __restrict__ as_, const float* __restrict__ ad_,
        void* __restrict__ hout, float* __restrict__ es, float* __restrict__ ed) {
    constexpr int KC = (DIN < 32) ? DIN : 32;     // K-chunk
    constexpr int NCH = DIN / KC;                 // chunks
    constexpr int CG = (DOUT >= 64) ? (DOUT / 8) : 1;      // col groups
    constexpr int NT = (DOUT >= 64) ? ((256 / CG) * 4) : 256;  // nodes/block
    constexpr int NTP = NT + 4;                   // pad

    __shared__ float sX[KC][NTP];   // transposed x chunk
    __shared__ float sW[KC][DOUT];  // W chunk

    const int t = threadIdx.x;
    const int node0 = blockIdx.x * NT;
    const int nvalid = min(NT, N_NODES - node0);

    const int cg = t & (CG - 1);
    const int ng = t / CG;

    float acc[4][8] = {};

    for (int ch = 0; ch < NCH; ch++) {
        const int k0 = ch * KC;
        if (ch > 0) __syncthreads();
        for (int i = t; i < nvalid * KC; i += 256) {
            int n = i / KC, k = i - n * KC;
            sX[k][n] = in[(size_t)(node0 + n) * DIN + k0 + k];
        }
        for (int i = t; i < KC * DOUT; i += 256) {
            int k = i / DOUT, c = i - k * DOUT;
            sW[k][c] = W[(size_t)(k0 + k) * DOUT + c];
        }
        __syncthreads();

        if constexpr (DOUT >= 64) {
#pragma unroll 4
            for (int k = 0; k < KC; k++) {
                float4 xv = *(const float4*)&sX[k][ng * 4];
                float4 w0 = *(const float4*)&sW[k][cg * 8];
                float4 w1 = *(const float4*)&sW[k][cg * 8 + 4];
                float xs[4] = {xv.x, xv.y, xv.z, xv.w};
                float ws[8] = {w0.x, w0.y, w0.z, w0.w, w1.x, w1.y, w1.z, w1.w};
#pragma unroll
                for (int j = 0; j < 4; j++)
#pragma unroll
                    for (int c = 0; c < 8; c++)
                        acc[j][c] = fmaf(xs[j], ws[c], acc[j][c]);
            }
        } else {
#pragma unroll 4
            for (int k = 0; k < KC; k++) {
                float xv = sX[k][t];
#pragma unroll
                for (int c = 0; c < DOUT; c++)
                    acc[0][c] = fmaf(xv, sW[k][c], acc[0][c]);
            }
        }
    }

    if constexpr (DOUT >= 64) {
        float asv[8], adv[8];
#pragma unroll
        for (int c = 0; c < 8; c++) {
            asv[c] = as_[cg * 8 + c];
            adv[c] = ad_[cg * 8 + c];
        }
#pragma unroll
        for (int j = 0; j < 4; j++) {
            int n = ng * 4 + j;
            float e_s = 0.f, e_d = 0.f;
#pragma unroll
            for (int c = 0; c < 8; c++) {
                e_s = fmaf(acc[j][c], asv[c], e_s);
                e_d = fmaf(acc[j][c], adv[c], e_d);
            }
#pragma unroll
            for (int m = 1; m < CG; m <<= 1) {
                e_s += __shfl_xor(e_s, m, 64);
                e_d += __shfl_xor(e_d, m, 64);
            }
            if (n < nvalid) {
                if (cg == 0) {
                    es[node0 + n] = e_s;
                    ed[node0 + n] = e_d;
                }
                if constexpr (HB16) {
                    unsigned short* hb = (unsigned short*)hout;
                    uint4 u;
                    u.x = pk2(acc[j][0], acc[j][1]);
                    u.y = pk2(acc[j][2], acc[j][3]);
                    u.z = pk2(acc[j][4], acc[j][5]);
                    u.w = pk2(acc[j][6], acc[j][7]);
                    *(uint4*)&hb[(size_t)(node0 + n) * DOUT + cg * 8] = u;
                } else {
                    float* h = (float*)hout;
                    float4 v0 = {acc[j][0], acc[j][1], acc[j][2], acc[j][3]};
                    float4 v1 = {acc[j][4], acc[j][5], acc[j][6], acc[j][7]};
                    *(float4*)&h[(size_t)(node0 + n) * DOUT + cg * 8] = v0;
                    *(float4*)&h[(size_t)(node0 + n) * DOUT + cg * 8 + 4] = v1;
                }
            }
        }
    } else {
        if (t < nvalid) {
            int node = node0 + t;
            float e_s = 0.f, e_d = 0.f;
#pragma unroll
            for (int c = 0; c < DOUT; c++) {
                e_s = fmaf(acc[0][c], as_[c], e_s);
                e_d = fmaf(acc[0][c], ad_[c], e_d);
            }
            es[node] = e_s;
            ed[node] = e_d;
            float* h = (float*)hout;
            float4 v = {acc[0][0], acc[0][1], acc[0][2], 0.f};  // stride-4 padded
            *(float4*)&h[(size_t)node * 4] = v;
        }
    }
}

// ---------------- fused softmax + weighted sum, DOUT=128, bf16 h ----------------
template <bool RELU_OUT>
__global__ __launch_bounds__(256) void k_wsum128f(
        const unsigned short* __restrict__ hb, const float* __restrict__ es,
        const float* __restrict__ ed, const float* __restrict__ bias,
        const int* __restrict__ off, const int* __restrict__ csr_send,
        float* __restrict__ out) {
    int wid = threadIdx.x >> 6, lane = threadIdx.x & 63;
    int node = blockIdx.x * 4 + wid;
    if (node >= N_NODES) return;
    int start = off[node], end = off[node + 1];
    float edi = ed[node];

    // pass A: online M, S (es gathers are L2-resident)
    float M = -1e30f, S = 0.f;
    for (int base = start; base < end; base += 64) {
        int j = base + lane;
        bool valid = j < end;
        int src = valid ? csr_send[j] : 0;
        float e = -1e30f;
        if (valid) {
            float v = es[src] + edi;
            e = (v >= 0.f) ? v : 0.2f * v;
        }
        float cmax = wave_max(e);
        float newM = fmaxf(M, cmax);
        float p = valid ? __expf(e - newM) : 0.f;
        S = S * __expf(M - newM) + wave_sum(p);
        M = newM;
    }
    float inv = 1.f / S;

    // pass B: gather bf16 rows
    float2 a0 = {0.f, 0.f}, a1 = {0.f, 0.f}, a2 = {0.f, 0.f}, a3 = {0.f, 0.f};
    for (int base = start; base < end; base += 64) {
        int j = base + lane;
        bool valid = j < end;
        int src = valid ? csr_send[j] : 0;
        float p = 0.f;
        if (valid) {
            float v = es[src] + edi;
            float e = (v >= 0.f) ? v : 0.2f * v;
            p = __expf(e - M) * inv;
        }
        int cnt = min(64, end - base);
        int j2 = 0;
        for (; j2 + 4 <= cnt; j2 += 4) {
            float p0 = __shfl(p, j2 + 0, 64); int s0 = __shfl(src, j2 + 0, 64);
            float p1 = __shfl(p, j2 + 1, 64); int s1 = __shfl(src, j2 + 1, 64);
            float p2 = __shfl(p, j2 + 2, 64); int s2 = __shfl(src, j2 + 2, 64);
            float p3 = __shfl(p, j2 + 3, 64); int s3 = __shfl(src, j2 + 3, 64);
            unsigned int u0 = ((const unsigned int*)(hb + (size_t)s0 * 128))[lane];
            unsigned int u1 = ((const unsigned int*)(hb + (size_t)s1 * 128))[lane];
            unsigned int u2 = ((const unsigned int*)(hb + (size_t)s2 * 128))[lane];
            unsigned int u3 = ((const unsigned int*)(hb + (size_t)s3 * 128))[lane];
            a0.x = fmaf(p0, bf_lo(u0), a0.x); a0.y = fmaf(p0, bf_hi(u0), a0.y);
            a1.x = fmaf(p1, bf_lo(u1), a1.x); a1.y = fmaf(p1, bf_hi(u1), a1.y);
            a2.x = fmaf(p2, bf_lo(u2), a2.x); a2.y = fmaf(p2, bf_hi(u2), a2.y);
            a3.x = fmaf(p3, bf_lo(u3), a3.x); a3.y = fmaf(p3, bf_hi(u3), a3.y);
        }
        for (; j2 < cnt; j2++) {
            float pj = __shfl(p, j2, 64); int sj = __shfl(src, j2, 64);
            unsigned int u = ((const unsigned int*)(hb + (size_t)sj * 128))[lane];
            a0.x = fmaf(pj, bf_lo(u), a0.x); a0.y = fmaf(pj, bf_hi(u), a0.y);
        }
    }
    float2 r;
    r.x = ((a0.x + a1.x) + (a2.x + a3.x)) + bias[2 * lane];
    r.y = ((a0.y + a1.y) + (a2.y + a3.y)) + bias[2 * lane + 1];
    if (RELU_OUT) { r.x = fmaxf(r.x, 0.f); r.y = fmaxf(r.y, 0.f); }
    ((float2*)(out + (size_t)node * 128))[lane] = r;
}

// ---------------- fused softmax + weighted sum, DOUT=64, bf16 h ----------------
__global__ __launch_bounds__(256) void k_wsum64f(
        const unsigned short* __restrict__ hb, const float* __restrict__ es,
        const float* __restrict__ ed, const float* __restrict__ bias,
        const int* __restrict__ off, const int* __restrict__ csr_send,
        float* __restrict__ out, void* __restrict__ out_dev, long long out_off,
        const int* __restrict__ flags) {
    int wid = threadIdx.x >> 6, lane = threadIdx.x & 63;
    int node = blockIdx.x * 4 + wid;
    if (node >= N_NODES) return;
    int start = off[node], end = off[node + 1];
    float edi = ed[node];

    float M = -1e30f, S = 0.f;
    for (int base = start; base < end; base += 64) {
        int j = base + lane;
        bool valid = j < end;
        int src = valid ? csr_send[j] : 0;
        float e = -1e30f;
        if (valid) {
            float v = es[src] + edi;
            e = (v >= 0.f) ? v : 0.2f * v;
        }
        float cmax = wave_max(e);
        float newM = fmaxf(M, cmax);
        float p = valid ? __expf(e - newM) : 0.f;
        S = S * __expf(M - newM) + wave_sum(p);
        M = newM;
    }
    float inv = 1.f / S;

    float a0 = 0.f, a1 = 0.f, a2 = 0.f, a3 = 0.f;
    for (int base = start; base < end; base += 64) {
        int j = base + lane;
        bool valid = j < end;
        int src = valid ? csr_send[j] : 0;
        float p = 0.f;
        if (valid) {
            float v = es[src] + edi;
            float e = (v >= 0.f) ? v : 0.2f * v;
            p = __expf(e - M) * inv;
        }
        int cnt = min(64, end - base);
        int j2 = 0;
        for (; j2 + 4 <= cnt; j2 += 4) {
            float p0 = __shfl(p, j2 + 0, 64); int s0 = __shfl(src, j2 + 0, 64);
            float p1 = __shfl(p, j2 + 1, 64); int s1 = __shfl(src, j2 + 1, 64);
            float p2 = __shfl(p, j2 + 2, 64); int s2 = __shfl(src, j2 + 2, 64);
            float p3 = __shfl(p, j2 + 3, 64); int s3 = __shfl(src, j2 + 3, 64);
            a0 = fmaf(p0, bf_us(hb[(size_t)s0 * 64 + lane]), a0);
            a1 = fmaf(p1, bf_us(hb[(size_t)s1 * 64 + lane]), a1);
            a2 = fmaf(p2, bf_us(hb[(size_t)s2 * 64 + lane]), a2);
            a3 = fmaf(p3, bf_us(hb[(size_t)s3 * 64 + lane]), a3);
        }
        for (; j2 < cnt; j2++) {
            float pj = __shfl(p, j2, 64); int sj = __shfl(src, j2, 64);
            a0 = fmaf(pj, bf_us(hb[(size_t)sj * 64 + lane]), a0);
        }
    }
    float r = ((a0 + a1) + (a2 + a3)) + bias[lane];
    out[(size_t)node * 64 + lane] = r;
    if (out_dev) st_out(out_dev, out_off + (long long)node * 64 + lane, r, flags[0]);
}

// ---------------- fused softmax + weighted sum, DOUT=3 (edge-parallel) ---------
// h3 is stride-4 padded -> single aligned float4 gather per edge
__global__ __launch_bounds__(256) void k_wsum3f(
        const float* __restrict__ h, const float* __restrict__ es,
        const float* __restrict__ ed, const float* __restrict__ bias,
        const int* __restrict__ off, const int* __restrict__ csr_send,
        void* __restrict__ out_dev, long long out_off, const int* __restrict__ flags) {
    int wid = threadIdx.x >> 6, lane = threadIdx.x & 63;
    int node = blockIdx.x * 4 + wid;
    if (node >= N_NODES) return;
    int start = off[node], end = off[node + 1];
    float edi = ed[node];

    float M = -1e30f, S = 0.f;
    for (int base = start; base < end; base += 64) {
        int j = base + lane;
        bool valid = j < end;
        int src = valid ? csr_send[j] : 0;
        float e = -1e30f;
        if (valid) {
            float v = es[src] + edi;
            e = (v >= 0.f) ? v : 0.2f * v;
        }
        float cmax = wave_max(e);
        float newM = fmaxf(M, cmax);
        float p = valid ? __expf(e - newM) : 0.f;
        S = S * __expf(M - newM) + wave_sum(p);
        M = newM;
    }
    float inv = 1.f / S;

    float a0 = 0.f, a1 = 0.f, a2 = 0.f;
    for (int j = start + lane; j < end; j += 64) {
        int s = csr_send[j];
        float v = es[s] + edi;
        float e = (v >= 0.f) ? v : 0.2f * v;
        float p = __expf(e - M) * inv;
        float4 rv = *(const float4*)(h + (size_t)s * 4);
        a0 = fmaf(p, rv.x, a0);
        a1 = fmaf(p, rv.y, a1);
        a2 = fmaf(p, rv.z, a2);
    }
    a0 = wave_sum(a0);
    a1 = wave_sum(a1);
    a2 = wave_sum(a2);
    if (lane < 3) {
        float v = (lane == 0 ? a0 : (lane == 1 ? a1 : a2)) + bias[lane];
        st_out(out_dev, out_off + (long long)node * 3 + lane, v, flags[0]);
    }
}

// ---------------- per-graph mean pooling: 1 block/graph, 16 waves ----------------
#define POOL_W 16
__global__ void k_pool(const float* __restrict__ latent, const void* __restrict__ batch,
                       const int* __restrict__ flags, float* __restrict__ pooled) {
    int b = blockIdx.x;
    int lane = threadIdx.x & 63;   // channel
    int wave = threadIdx.x >> 6;   // 0..15
    int is64 = flags[1];
    int lo = 0, hi = N_NODES;
    while (lo < hi) { int mid = (lo + hi) >> 1; if (ld_idx(batch, mid, is64) < b) lo = mid + 1; else hi = mid; }
    int start = lo;
    lo = 0; hi = N_NODES;
    while (lo < hi) { int mid = (lo + hi) >> 1; if (ld_idx(batch, mid, is64) < b + 1) lo = mid + 1; else hi = mid; }
    int end = lo;
    float s = 0.f;
    for (int n = start + wave; n < end; n += POOL_W) s += latent[(size_t)n * 64 + lane];
    __shared__ float red[POOL_W][64];
    red[wave][lane] = s;
    __syncthreads();
    if (wave == 0) {
        float t = s;
#pragma unroll
        for (int w2 = 1; w2 < POOL_W; w2++) t += red[w2][lane];
        float cnt = (float)(end - start);
        pooled[b * 64 + lane] = t / fmaxf(cnt, 1.f);
    }
}

// ---------------- classifier head ----------------
__global__ void k_cls(const float* __restrict__ pooled, const float* __restrict__ pb,
                      void* __restrict__ out_dev, long long out_off,
                      const int* __restrict__ flags) {
    int b = threadIdx.x;  // 64 threads, one per graph
    const float* Wc1 = pb + P_WC1;
    const float* bc1 = pb + P_BC1;
    const float* Wc2 = pb + P_WC2;
    const float* bc2 = pb + P_BC2;
    float z[32];
#pragma unroll
    for (int k = 0; k < 32; k++) z[k] = bc1[k];
    for (int c = 0; c < 64; c++) {
        float pv = pooled[b * 64 + c];
#pragma unroll
        for (int k = 0; k < 32; k++) z[k] = fmaf(pv, Wc1[c * 32 + k], z[k]);
    }
#pragma unroll
    for (int k = 0; k < 32; k++) z[k] = fmaxf(z[k], 0.f);
    float n0 = bc2[0], n1 = bc2[1];
#pragma unroll
    for (int k = 0; k < 32; k++) {
        n0 = fmaf(z[k], Wc2[k * 2 + 0], n0);
        n1 = fmaf(z[k], Wc2[k * 2 + 1], n1);
    }
    int isbf = flags[0];
    st_out(out_dev, out_off + b * 2 + 0, n0, isbf);
    st_out(out_dev, out_off + b * 2 + 1, n1, isbf);
}

extern "C" void kernel_launch(void* const* d_in, const int* in_sizes, int n_in,
                              void* d_out, int out_size, void* d_ws, size_t ws_size,
                              hipStream_t stream) {
    const void* x    = d_in[0];
    const void* eidx = d_in[1];
    const void* batch= d_in[2];

    // workspace carve-up (256B aligned)
    char* w = (char*)d_ws;
    size_t o = 0;
    auto carve = [&](size_t bytes) { void* p = w + o; o = (o + bytes + 255) & ~(size_t)255; return p; };
    int* flags    = (int*)carve(8 * sizeof(int));
    int* off      = (int*)carve((N_NODES + 1) * sizeof(int));
    int* counts   = (int*)carve(N_NODES * sizeof(int));
    int* cursor   = (int*)carve(N_NODES * sizeof(int));
    int* bsum     = (int*)carve(SCAN_NBLK * sizeof(int));
    int* bbase    = (int*)carve(SCAN_NBLK * sizeof(int));
    int* csr_send = (int*)carve((size_t)(N_EDGES + N_NODES) * sizeof(int));
    float* pblock = (float*)carve(P_TOTAL * sizeof(float));
    float* buf0   = (float*)carve((size_t)N_NODES * 128 * sizeof(float));
    unsigned short* hb = (unsigned short*)carve((size_t)N_NODES * 128 * sizeof(unsigned short));
    float* h3     = (float*)carve((size_t)N_NODES * 4 * sizeof(float));
    float* es     = (float*)carve(N_NODES * sizeof(float));
    float* ed     = (float*)carve(N_NODES * sizeof(float));
    float* pooled = (float*)carve(NB * 64 * sizeof(float));

    int gN = (N_NODES + 255) / 256;
    int gE = (N_EDGES + 255) / 256;
    int gW = N_NODES / 4;                 // wave-per-node kernels

    // dtype detect
    k_detect<<<1, 64, 0, stream>>>((const unsigned short*)x, (const unsigned int*)eidx, flags);

    // params -> f32 block
    PTab tab;
    const int pn[20]  = {384,128,128,128, 8192,64,64,64, 8192,128,128,128, 384,3,3,3, 2048,32,64,2};
    const int pof[20] = {P_W1,P_A1S,P_A1D,P_B1, P_W2,P_A2S,P_A2D,P_B2, P_W3,P_A3S,P_A3D,P_B3,
                         P_W4,P_A4S,P_A4D,P_B4, P_WC1,P_BC1,P_WC2,P_BC2};
    for (int i = 0; i < 20; i++) { tab.src[i] = d_in[3 + i]; tab.off[i] = pof[i]; tab.n[i] = pn[i]; }
    k_cvt_params<<<20, 256, 0, stream>>>(tab, flags, pblock);

    // CSR build
    k_init_counts<<<gN, 256, 0, stream>>>(counts);
    k_count<<<gE, 256, 0, stream>>>(eidx, flags, counts);
    k_scan_a<<<SCAN_NBLK, SCAN_BLK, 0, stream>>>(counts, off, bsum);
    k_scan_b<<<1, SCAN_BLK, 0, stream>>>(bsum, bbase);
    k_scan_c<<<SCAN_NBLK, SCAN_BLK, 0, stream>>>(off, bbase);
    k_selfloop<<<gN, 256, 0, stream>>>(off, csr_send, cursor);
    k_fill<<<FILL_PASSES * FILL_BPP, 256, 0, stream>>>(eidx, flags, off, cursor, csr_send);

    // x -> f32
    k_cvt_x<<<(N_NODES * 3 + 255) / 256, 256, 0, stream>>>(x, flags, buf0);

    // output element offsets
    const long long OFF_RECON = 0, OFF_LATENT = 150000, OFF_NOISE = 3350000;

    // gemm grids: nodes/block = 64 (DOUT=128), 128 (DOUT=64), 256 (DOUT=3)
    int g64  = (N_NODES + 63) / 64;
    int g128 = (N_NODES + 127) / 128;
    int g256 = (N_NODES + 255) / 256;

    // conv1: [N,3] -> [N,128], relu
    k_gemm<3, 128, true><<<g64, 256, 0, stream>>>(buf0, pblock + P_W1, pblock + P_A1S, pblock + P_A1D, hb, es, ed);
    k_wsum128f<true><<<gW, 256, 0, stream>>>(hb, es, ed, pblock + P_B1, off, csr_send, buf0);

    // conv2: [N,128] -> [N,64] (latent)
    k_gemm<128, 64, true><<<g128, 256, 0, stream>>>(buf0, pblock + P_W2, pblock + P_A2S, pblock + P_A2D, hb, es, ed);
    k_wsum64f<<<gW, 256, 0, stream>>>(hb, es, ed, pblock + P_B2, off, csr_send, buf0, d_out, OFF_LATENT, flags);

    // pooling + classifier from f32 latent (buf0)
    k_pool<<<NB, POOL_W * 64, 0, stream>>>(buf0, batch, flags, pooled);
    k_cls<<<1, 64, 0, stream>>>(pooled, pblock, d_out, OFF_NOISE, flags);

    // conv3: [N,64] -> [N,128], relu
    k_gemm<64, 128, true><<<g64, 256, 0, stream>>>(buf0, pblock + P_W3, pblock + P_A3S, pblock + P_A3D, hb, es, ed);
    k_wsum128f<true><<<gW, 256, 0, stream>>>(hb, es, ed, pblock + P_B3, off, csr_send, buf0);

    // conv4: [N,128] -> [N,3] (reconstructed)
    k_gemm<128, 3, false><<<g256, 256, 0, stream>>>(buf0, pblock + P_W4, pblock + P_A4S, pblock + P_A4D, h3, es, ed);
    k_wsum3f<<<gW, 256, 0, stream>>>(h3, es, ed, pblock + P_B4, off, csr_send, d_out, OFF_RECON, flags);
}

// Round 10
// 354.174 us; speedup vs baseline: 2.4455x; 1.0464x over previous
//
#include <hip/hip_runtime.h>
#include <hip/hip_bf16.h>

typedef __hip_bfloat16 bf16;

#define N_NODES 50000
#define N_EDGES 800000
#define NB 64
#define SCAN_BLK 256
#define SCAN_NBLK ((N_NODES + SCAN_BLK - 1) / SCAN_BLK)   // 196

// k_fill pass partitioning
#define FILL_PASSES 8
#define FILL_BPP 256                                   // blocks per pass
#define FILL_RANGE ((N_NODES + FILL_PASSES - 1) / FILL_PASSES)  // 6250

// param block offsets (floats)
#define P_W1 0
#define P_A1S 384
#define P_A1D 512
#define P_B1 640
#define P_W2 768
#define P_A2S 8960
#define P_A2D 9024
#define P_B2 9088
#define P_W3 9152
#define P_A3S 17344
#define P_A3D 17472
#define P_B3 17600
#define P_W4 17728
#define P_A4S 18112
#define P_A4D 18115
#define P_B4 18118
#define P_WC1 18121
#define P_BC1 20169
#define P_WC2 20201
#define P_BC2 20265
#define P_TOTAL 20267

__device__ __forceinline__ float wave_max(float v) {
#pragma unroll
    for (int o = 32; o >= 1; o >>= 1) v = fmaxf(v, __shfl_xor(v, o, 64));
    return v;
}
__device__ __forceinline__ float wave_sum(float v) {
#pragma unroll
    for (int o = 32; o >= 1; o >>= 1) v += __shfl_xor(v, o, 64);
    return v;
}

// bf16 pack/unpack (bit tricks, no cvt on unpack)
__device__ __forceinline__ unsigned int pk2(float a, float b) {
    bf16 x = __float2bfloat16(a);
    bf16 y = __float2bfloat16(b);
    unsigned short ux = *reinterpret_cast<unsigned short*>(&x);
    unsigned short uy = *reinterpret_cast<unsigned short*>(&y);
    return ((unsigned int)uy << 16) | ux;
}
__device__ __forceinline__ float bf_lo(unsigned int u) {
    unsigned int v = u << 16;
    return *reinterpret_cast<float*>(&v);
}
__device__ __forceinline__ float bf_hi(unsigned int u) {
    unsigned int v = u & 0xffff0000u;
    return *reinterpret_cast<float*>(&v);
}

// runtime dtype helpers: flags[0]=float-inputs-are-bf16, flags[1]=ints-are-int64
__device__ __forceinline__ int ld_idx(const void* p, long long i, int is64) {
    return is64 ? (int)((const long long*)p)[i] : ((const int*)p)[i];
}
__device__ __forceinline__ void st_out(void* p, long long i, float v, int isbf) {
    if (isbf) ((bf16*)p)[i] = __float2bfloat16(v);
    else ((float*)p)[i] = v;
}

// ---------------- dtype detection ----------------
__global__ void k_detect(const unsigned short* xraw, const unsigned int* eraw,
                         int* flags) {
    if (threadIdx.x != 0 || blockIdx.x != 0) return;
    int cnt = 0;
    for (int i = 0; i < 256; i++) {
        unsigned int hb = (xraw[2 * i] >> 8) & 0x7F;
        if (hb >= 58 && hb <= 65) cnt++;
    }
    flags[0] = (cnt >= 200) ? 1 : 0;
    int z = 0;
    for (int i = 0; i < 64; i++)
        if (eraw[2 * i + 1] == 0u) z++;
    flags[1] = (z >= 60) ? 1 : 0;
}

// ---------------- input/param convert to f32 ----------------
struct PTab {
    const void* src[20];
    int off[20];
    int n[20];
};

__global__ void k_cvt_params(PTab tab, const int* __restrict__ flags,
                             float* __restrict__ pblock) {
    int t = blockIdx.x;
    const void* s = tab.src[t];
    float* d = pblock + tab.off[t];
    int n = tab.n[t];
    int isbf = flags[0];
    for (int i = threadIdx.x; i < n; i += blockDim.x)
        d[i] = isbf ? __bfloat162float(((const bf16*)s)[i]) : ((const float*)s)[i];
}

__global__ void k_cvt_x(const void* __restrict__ x, const int* __restrict__ flags,
                        float* __restrict__ buf) {
    int i = blockIdx.x * blockDim.x + threadIdx.x;
    if (i < N_NODES * 3)
        buf[i] = flags[0] ? __bfloat162float(((const bf16*)x)[i]) : ((const float*)x)[i];
}

// ---------------- CSR build ----------------
__global__ void k_init_counts(int* __restrict__ counts) {
    int i = blockIdx.x * blockDim.x + threadIdx.x;
    if (i < N_NODES) counts[i] = 1;  // self loop
}

__global__ void k_count(const void* __restrict__ eidx, const int* __restrict__ flags,
                        int* __restrict__ counts) {
    int e = blockIdx.x * blockDim.x + threadIdx.x;
    if (e < N_EDGES) {
        int r = ld_idx(eidx, (long long)N_EDGES + e, flags[1]);
        atomicAdd(&counts[r], 1);
    }
}

// ---------------- 3-phase parallel scan ----------------
__global__ void k_scan_a(const int* __restrict__ counts, int* __restrict__ off,
                         int* __restrict__ bsum) {
    __shared__ int s[SCAN_BLK];
    int t = threadIdx.x;
    int i = blockIdx.x * SCAN_BLK + t;
    int v = (i < N_NODES) ? counts[i] : 0;
    s[t] = v;
    __syncthreads();
#pragma unroll
    for (int o = 1; o < SCAN_BLK; o <<= 1) {
        int add = (t >= o) ? s[t - o] : 0;
        __syncthreads();
        s[t] += add;
        __syncthreads();
    }
    if (i < N_NODES) off[i + 1] = s[t];
    if (t == SCAN_BLK - 1) bsum[blockIdx.x] = s[t];
}

__global__ void k_scan_b(int* __restrict__ bsum, int* __restrict__ bbase) {
    __shared__ int s[SCAN_BLK];
    int t = threadIdx.x;
    s[t] = (t < SCAN_NBLK) ? bsum[t] : 0;
    __syncthreads();
#pragma unroll
    for (int o = 1; o < SCAN_BLK; o <<= 1) {
        int add = (t >= o) ? s[t - o] : 0;
        __syncthreads();
        s[t] += add;
        __syncthreads();
    }
    if (t < SCAN_NBLK) bbase[t] = s[t] - bsum[t];  // exclusive
}

__global__ void k_scan_c(int* __restrict__ off, const int* __restrict__ bbase) {
    int t = threadIdx.x;
    int i = blockIdx.x * SCAN_BLK + t;
    if (i < N_NODES) off[i + 1] += bbase[blockIdx.x];
    if (i == 0) off[0] = 0;
}

__global__ void k_selfloop(const int* __restrict__ off, int* __restrict__ csr_send,
                           int* __restrict__ cursor) {
    int i = blockIdx.x * blockDim.x + threadIdx.x;
    if (i < N_NODES) { csr_send[off[i]] = i; cursor[i] = 1; }
}

// node-range-partitioned fill: pass p writes only nodes [p*RANGE,(p+1)*RANGE)
__global__ __launch_bounds__(256) void k_fill(
        const void* __restrict__ eidx, const int* __restrict__ flags,
        const int* __restrict__ off, int* __restrict__ cursor,
        int* __restrict__ csr_send) {
    const int pass = blockIdx.x / FILL_BPP;
    const int bid = blockIdx.x - pass * FILL_BPP;
    const int lo = pass * FILL_RANGE;
    const int hi = min(lo + FILL_RANGE, N_NODES);
    const int is64 = flags[1];
    for (int e = bid * 256 + threadIdx.x; e < N_EDGES; e += FILL_BPP * 256) {
        int r = ld_idx(eidx, (long long)N_EDGES + e, is64);
        if (r >= lo && r < hi) {
            int s = ld_idx(eidx, e, is64);
            int p = atomicAdd(&cursor[r], 1);
            csr_send[off[r] + p] = s;
        }
    }
}

// ---------------- register-tiled linear + attention coefficients ----------------
template <int DIN, int DOUT, bool HB16>
__global__ __launch_bounds__(256) void k_gemm(
        const float* __restrict__ in, const float* __restrict__ W,
        const float* __restrict__ as_, const float* __restrict__ ad_,
        void* __restrict__ hout, float* __restrict__ es, float* __restrict__ ed) {
    constexpr int KC = (DIN < 32) ? DIN : 32;     // K-chunk
    constexpr int NCH = DIN / KC;                 // chunks
    constexpr int CG = (DOUT >= 64) ? (DOUT / 8) : 1;      // col groups
    constexpr int NT = (DOUT >= 64) ? ((256 / CG) * 4) : 256;  // nodes/block
    constexpr int NTP = NT + 4;                   // pad

    __shared__ float sX[KC][NTP];   // transposed x chunk
    __shared__ float sW[KC][DOUT];  // W chunk

    const int t = threadIdx.x;
    const int node0 = blockIdx.x * NT;
    const int nvalid = min(NT, N_NODES - node0);

    const int cg = t & (CG - 1);
    const int ng = t / CG;

    float acc[4][8] = {};

    for (int ch = 0; ch < NCH; ch++) {
        const int k0 = ch * KC;
        if (ch > 0) __syncthreads();
        for (int i = t; i < nvalid * KC; i += 256) {
            int n = i / KC, k = i - n * KC;
            sX[k][n] = in[(size_t)(node0 + n) * DIN + k0 + k];
        }
        for (int i = t; i < KC * DOUT; i += 256) {
            int k = i / DOUT, c = i - k * DOUT;
            sW[k][c] = W[(size_t)(k0 + k) * DOUT + c];
        }
        __syncthreads();

        if constexpr (DOUT >= 64) {
#pragma unroll 4
            for (int k = 0; k < KC; k++) {
                float4 xv = *(const float4*)&sX[k][ng * 4];
                float4 w0 = *(const float4*)&sW[k][cg * 8];
                float4 w1 = *(const float4*)&sW[k][cg * 8 + 4];
                float xs[4] = {xv.x, xv.y, xv.z, xv.w};
                float ws[8] = {w0.x, w0.y, w0.z, w0.w, w1.x, w1.y, w1.z, w1.w};
#pragma unroll
                for (int j = 0; j < 4; j++)
#pragma unroll
                    for (int c = 0; c < 8; c++)
                        acc[j][c] = fmaf(xs[j], ws[c], acc[j][c]);
            }
        } else {
#pragma unroll 4
            for (int k = 0; k < KC; k++) {
                float xv = sX[k][t];
#pragma unroll
                for (int c = 0; c < DOUT; c++)
                    acc[0][c] = fmaf(xv, sW[k][c], acc[0][c]);
            }
        }
    }

    if constexpr (DOUT >= 64) {
        float asv[8], adv[8];
#pragma unroll
        for (int c = 0; c < 8; c++) {
            asv[c] = as_[cg * 8 + c];
            adv[c] = ad_[cg * 8 + c];
        }
#pragma unroll
        for (int j = 0; j < 4; j++) {
            int n = ng * 4 + j;
            float e_s = 0.f, e_d = 0.f;
#pragma unroll
            for (int c = 0; c < 8; c++) {
                e_s = fmaf(acc[j][c], asv[c], e_s);
                e_d = fmaf(acc[j][c], adv[c], e_d);
            }
#pragma unroll
            for (int m = 1; m < CG; m <<= 1) {
                e_s += __shfl_xor(e_s, m, 64);
                e_d += __shfl_xor(e_d, m, 64);
            }
            if (n < nvalid) {
                if (cg == 0) {
                    es[node0 + n] = e_s;
                    ed[node0 + n] = e_d;
                }
                if constexpr (HB16) {
                    unsigned short* hb = (unsigned short*)hout;
                    uint4 u;
                    u.x = pk2(acc[j][0], acc[j][1]);
                    u.y = pk2(acc[j][2], acc[j][3]);
                    u.z = pk2(acc[j][4], acc[j][5]);
                    u.w = pk2(acc[j][6], acc[j][7]);
                    *(uint4*)&hb[(size_t)(node0 + n) * DOUT + cg * 8] = u;
                } else {
                    float* h = (float*)hout;
                    float4 v0 = {acc[j][0], acc[j][1], acc[j][2], acc[j][3]};
                    float4 v1 = {acc[j][4], acc[j][5], acc[j][6], acc[j][7]};
                    *(float4*)&h[(size_t)(node0 + n) * DOUT + cg * 8] = v0;
                    *(float4*)&h[(size_t)(node0 + n) * DOUT + cg * 8 + 4] = v1;
                }
            }
        }
    } else {
        if (t < nvalid) {
            int node = node0 + t;
            float e_s = 0.f, e_d = 0.f;
#pragma unroll
            for (int c = 0; c < DOUT; c++) {
                e_s = fmaf(acc[0][c], as_[c], e_s);
                e_d = fmaf(acc[0][c], ad_[c], e_d);
            }
            es[node] = e_s;
            ed[node] = e_d;
            float* h = (float*)hout;
            float4 v = {acc[0][0], acc[0][1], acc[0][2], 0.f};  // stride-4 padded
            *(float4*)&h[(size_t)node * 4] = v;
        }
    }
}

// ---------------- fused softmax + weighted sum, DOUT=128, bf16 h ----------------
// paired rows: half-wave 0 = even edges, half-wave 1 = odd edges; lane loads
// uint2 (4 bf16 cols); combine halves with one shfl_xor(32) at the end.
template <bool RELU_OUT>
__global__ __launch_bounds__(256) void k_wsum128f(
        const unsigned short* __restrict__ hb, const float* __restrict__ es,
        const float* __restrict__ ed, const float* __restrict__ bias,
        const int* __restrict__ off, const int* __restrict__ csr_send,
        float* __restrict__ out) {
    int wid = threadIdx.x >> 6, lane = threadIdx.x & 63;
    int node = blockIdx.x * 4 + wid;
    if (node >= N_NODES) return;
    int start = off[node], end = off[node + 1];
    float edi = ed[node];

    // pass A: online M,S; cache chunk-0 e/src in registers
    float e0 = -1e30f;
    int src0 = 0;
    float M = -1e30f, S = 0.f;
    for (int base = start; base < end; base += 64) {
        int j = base + lane;
        bool valid = j < end;
        int src = valid ? csr_send[j] : 0;
        float e = -1e30f;
        if (valid) {
            float v = es[src] + edi;
            e = (v >= 0.f) ? v : 0.2f * v;
        }
        if (base == start) { e0 = e; src0 = src; }
        float cmax = wave_max(e);
        float newM = fmaxf(M, cmax);
        float p = valid ? __expf(e - newM) : 0.f;
        S = S * __expf(M - newM) + wave_sum(p);
        M = newM;
    }
    float inv = 1.f / S;

    const int hf = lane >> 5;
    const int hl = lane & 31;
    float4 a0 = {0.f, 0.f, 0.f, 0.f}, a1 = {0.f, 0.f, 0.f, 0.f};

    for (int base = start; base < end; base += 64) {
        float p;
        int src;
        if (base == start) {
            p = __expf(e0 - M) * inv;  // 0 for invalid lanes (e0=-1e30)
            src = src0;
        } else {
            int j = base + lane;
            bool valid = j < end;
            src = valid ? csr_send[j] : 0;
            p = 0.f;
            if (valid) {
                float v = es[src] + edi;
                float e = (v >= 0.f) ? v : 0.2f * v;
                p = __expf(e - M) * inv;
            }
        }
        int cnt = min(64, end - base);
        int npr = (cnt + 1) >> 1;
        int j2 = 0;
        for (; j2 + 2 <= npr; j2 += 2) {
            int qA = 2 * j2 + hf, qB = qA + 2;
            float pA = __shfl(p, qA, 64); int sA = __shfl(src, qA, 64);
            float pB = __shfl(p, qB, 64); int sB = __shfl(src, qB, 64);
            uint2 uA = *((const uint2*)(hb + (size_t)sA * 128) + hl);
            uint2 uB = *((const uint2*)(hb + (size_t)sB * 128) + hl);
            a0.x = fmaf(pA, bf_lo(uA.x), a0.x); a0.y = fmaf(pA, bf_hi(uA.x), a0.y);
            a0.z = fmaf(pA, bf_lo(uA.y), a0.z); a0.w = fmaf(pA, bf_hi(uA.y), a0.w);
            a1.x = fmaf(pB, bf_lo(uB.x), a1.x); a1.y = fmaf(pB, bf_hi(uB.x), a1.y);
            a1.z = fmaf(pB, bf_lo(uB.y), a1.z); a1.w = fmaf(pB, bf_hi(uB.y), a1.w);
        }
        for (; j2 < npr; j2++) {
            int q = 2 * j2 + hf;
            float pq = __shfl(p, q, 64); int sq = __shfl(src, q, 64);
            uint2 u = *((const uint2*)(hb + (size_t)sq * 128) + hl);
            a0.x = fmaf(pq, bf_lo(u.x), a0.x); a0.y = fmaf(pq, bf_hi(u.x), a0.y);
            a0.z = fmaf(pq, bf_lo(u.y), a0.z); a0.w = fmaf(pq, bf_hi(u.y), a0.w);
        }
    }
    float4 r;
    r.x = a0.x + a1.x; r.y = a0.y + a1.y; r.z = a0.z + a1.z; r.w = a0.w + a1.w;
    r.x += __shfl_xor(r.x, 32, 64);
    r.y += __shfl_xor(r.y, 32, 64);
    r.z += __shfl_xor(r.z, 32, 64);
    r.w += __shfl_xor(r.w, 32, 64);
    if (hf == 0) {
        float4 b = ((const float4*)bias)[hl];
        r.x += b.x; r.y += b.y; r.z += b.z; r.w += b.w;
        if (RELU_OUT) {
            r.x = fmaxf(r.x, 0.f); r.y = fmaxf(r.y, 0.f);
            r.z = fmaxf(r.z, 0.f); r.w = fmaxf(r.w, 0.f);
        }
        ((float4*)(out + (size_t)node * 128))[hl] = r;
    }
}

// ---------------- fused softmax + weighted sum, DOUT=64, bf16 h ----------------
// quad rows: quarter-wave q = edges 4*j2+q; lane loads uint2 (4 bf16 cols);
// combine with shfl_xor(16) + shfl_xor(32).
__global__ __launch_bounds__(256) void k_wsum64f(
        const unsigned short* __restrict__ hb, const float* __restrict__ es,
        const float* __restrict__ ed, const float* __restrict__ bias,
        const int* __restrict__ off, const int* __restrict__ csr_send,
        float* __restrict__ out, void* __restrict__ out_dev, long long out_off,
        const int* __restrict__ flags) {
    int wid = threadIdx.x >> 6, lane = threadIdx.x & 63;
    int node = blockIdx.x * 4 + wid;
    if (node >= N_NODES) return;
    int start = off[node], end = off[node + 1];
    float edi = ed[node];

    float e0 = -1e30f;
    int src0 = 0;
    float M = -1e30f, S = 0.f;
    for (int base = start; base < end; base += 64) {
        int j = base + lane;
        bool valid = j < end;
        int src = valid ? csr_send[j] : 0;
        float e = -1e30f;
        if (valid) {
            float v = es[src] + edi;
            e = (v >= 0.f) ? v : 0.2f * v;
        }
        if (base == start) { e0 = e; src0 = src; }
        float cmax = wave_max(e);
        float newM = fmaxf(M, cmax);
        float p = valid ? __expf(e - newM) : 0.f;
        S = S * __expf(M - newM) + wave_sum(p);
        M = newM;
    }
    float inv = 1.f / S;

    const int qd = lane >> 4;
    const int ql = lane & 15;
    float4 a0 = {0.f, 0.f, 0.f, 0.f}, a1 = {0.f, 0.f, 0.f, 0.f};

    for (int base = start; base < end; base += 64) {
        float p;
        int src;
        if (base == start) {
            p = __expf(e0 - M) * inv;
            src = src0;
        } else {
            int j = base + lane;
            bool valid = j < end;
            src = valid ? csr_send[j] : 0;
            p = 0.f;
            if (valid) {
                float v = es[src] + edi;
                float e = (v >= 0.f) ? v : 0.2f * v;
                p = __expf(e - M) * inv;
            }
        }
        int cnt = min(64, end - base);
        int nq = (cnt + 3) >> 2;
        int j2 = 0;
        for (; j2 + 2 <= nq; j2 += 2) {
            int qA = 4 * j2 + qd, qB = qA + 4;
            float pA = __shfl(p, qA, 64); int sA = __shfl(src, qA, 64);
            float pB = __shfl(p, qB, 64); int sB = __shfl(src, qB, 64);
            uint2 uA = *((const uint2*)(hb + (size_t)sA * 64) + ql);
            uint2 uB = *((const uint2*)(hb + (size_t)sB * 64) + ql);
            a0.x = fmaf(pA, bf_lo(uA.x), a0.x); a0.y = fmaf(pA, bf_hi(uA.x), a0.y);
            a0.z = fmaf(pA, bf_lo(uA.y), a0.z); a0.w = fmaf(pA, bf_hi(uA.y), a0.w);
            a1.x = fmaf(pB, bf_lo(uB.x), a1.x); a1.y = fmaf(pB, bf_hi(uB.x), a1.y);
            a1.z = fmaf(pB, bf_lo(uB.y), a1.z); a1.w = fmaf(pB, bf_hi(uB.y), a1.w);
        }
        for (; j2 < nq; j2++) {
            int q = 4 * j2 + qd;
            float pq = __shfl(p, q, 64); int sq = __shfl(src, q, 64);
            uint2 u = *((const uint2*)(hb + (size_t)sq * 64) + ql);
            a0.x = fmaf(pq, bf_lo(u.x), a0.x); a0.y = fmaf(pq, bf_hi(u.x), a0.y);
            a0.z = fmaf(pq, bf_lo(u.y), a0.z); a0.w = fmaf(pq, bf_hi(u.y), a0.w);
        }
    }
    float4 r;
    r.x = a0.x + a1.x; r.y = a0.y + a1.y; r.z = a0.z + a1.z; r.w = a0.w + a1.w;
    r.x += __shfl_xor(r.x, 16, 64); r.y += __shfl_xor(r.y, 16, 64);
    r.z += __shfl_xor(r.z, 16, 64); r.w += __shfl_xor(r.w, 16, 64);
    r.x += __shfl_xor(r.x, 32, 64); r.y += __shfl_xor(r.y, 32, 64);
    r.z += __shfl_xor(r.z, 32, 64); r.w += __shfl_xor(r.w, 32, 64);
    if (qd == 0) {
        float4 b = ((const float4*)bias)[ql];
        r.x += b.x; r.y += b.y; r.z += b.z; r.w += b.w;
        ((float4*)(out + (size_t)node * 64))[ql] = r;
        if (out_dev) {
            int isbf = flags[0];
            long long o4 = out_off + (long long)node * 64 + 4 * ql;
            st_out(out_dev, o4 + 0, r.x, isbf);
            st_out(out_dev, o4 + 1, r.y, isbf);
            st_out(out_dev, o4 + 2, r.z, isbf);
            st_out(out_dev, o4 + 3, r.w, isbf);
        }
    }
}

// ---------------- fused softmax + weighted sum, DOUT=3 (edge-parallel) ---------
__global__ __launch_bounds__(256) void k_wsum3f(
        const float* __restrict__ h, const float* __restrict__ es,
        const float* __restrict__ ed, const float* __restrict__ bias,
        const int* __restrict__ off, const int* __restrict__ csr_send,
        void* __restrict__ out_dev, long long out_off, const int* __restrict__ flags) {
    int wid = threadIdx.x >> 6, lane = threadIdx.x & 63;
    int node = blockIdx.x * 4 + wid;
    if (node >= N_NODES) return;
    int start = off[node], end = off[node + 1];
    float edi = ed[node];

    float e0 = -1e30f;
    int src0 = 0;
    float M = -1e30f, S = 0.f;
    for (int base = start; base < end; base += 64) {
        int j = base + lane;
        bool valid = j < end;
        int src = valid ? csr_send[j] : 0;
        float e = -1e30f;
        if (valid) {
            float v = es[src] + edi;
            e = (v >= 0.f) ? v : 0.2f * v;
        }
        if (base == start) { e0 = e; src0 = src; }
        float cmax = wave_max(e);
        float newM = fmaxf(M, cmax);
        float p = valid ? __expf(e - newM) : 0.f;
        S = S * __expf(M - newM) + wave_sum(p);
        M = newM;
    }
    float inv = 1.f / S;

    float a0 = 0.f, a1 = 0.f, a2 = 0.f;
    bool first = true;
    for (int j = start + lane; j < end; j += 64) {
        int s;
        float e;
        if (first) { s = src0; e = e0; first = false; }
        else {
            s = csr_send[j];
            float v = es[s] + edi;
            e = (v >= 0.f) ? v : 0.2f * v;
        }
        float p = __expf(e - M) * inv;
        float4 rv = *(const float4*)(h + (size_t)s * 4);
        a0 = fmaf(p, rv.x, a0);
        a1 = fmaf(p, rv.y, a1);
        a2 = fmaf(p, rv.z, a2);
    }
    a0 = wave_sum(a0);
    a1 = wave_sum(a1);
    a2 = wave_sum(a2);
    if (lane < 3) {
        float v = (lane == 0 ? a0 : (lane == 1 ? a1 : a2)) + bias[lane];
        st_out(out_dev, out_off + (long long)node * 3 + lane, v, flags[0]);
    }
}

// ---------------- per-graph mean pooling: 1 block/graph, 16 waves ----------------
#define POOL_W 16
__global__ void k_pool(const float* __restrict__ latent, const void* __restrict__ batch,
                       const int* __restrict__ flags, float* __restrict__ pooled) {
    int b = blockIdx.x;
    int lane = threadIdx.x & 63;   // channel
    int wave = threadIdx.x >> 6;   // 0..15
    int is64 = flags[1];
    int lo = 0, hi = N_NODES;
    while (lo < hi) { int mid = (lo + hi) >> 1; if (ld_idx(batch, mid, is64) < b) lo = mid + 1; else hi = mid; }
    int start = lo;
    lo = 0; hi = N_NODES;
    while (lo < hi) { int mid = (lo + hi) >> 1; if (ld_idx(batch, mid, is64) < b + 1) lo = mid + 1; else hi = mid; }
    int end = lo;
    float s = 0.f;
    for (int n = start + wave; n < end; n += POOL_W) s += latent[(size_t)n * 64 + lane];
    __shared__ float red[POOL_W][64];
    red[wave][lane] = s;
    __syncthreads();
    if (wave == 0) {
        float t = s;
#pragma unroll
        for (int w2 = 1; w2 < POOL_W; w2++) t += red[w2][lane];
        float cnt = (float)(end - start);
        pooled[b * 64 + lane] = t / fmaxf(cnt, 1.f);
    }
}

// ---------------- classifier head ----------------
__global__ void k_cls(const float* __restrict__ pooled, const float* __restrict__ pb,
                      void* __restrict__ out_dev, long long out_off,
                      const int* __restrict__ flags) {
    int b = threadIdx.x;  // 64 threads, one per graph
    const float* Wc1 = pb + P_WC1;
    const float* bc1 = pb + P_BC1;
    const float* Wc2 = pb + P_WC2;
    const float* bc2 = pb + P_BC2;
    float z[32];
#pragma unroll
    for (int k = 0; k < 32; k++) z[k] = bc1[k];
    for (int c = 0; c < 64; c++) {
        float pv = pooled[b * 64 + c];
#pragma unroll
        for (int k = 0; k < 32; k++) z[k] = fmaf(pv, Wc1[c * 32 + k], z[k]);
    }
#pragma unroll
    for (int k = 0; k < 32; k++) z[k] = fmaxf(z[k], 0.f);
    float n0 = bc2[0], n1 = bc2[1];
#pragma unroll
    for (int k = 0; k < 32; k++) {
        n0 = fmaf(z[k], Wc2[k * 2 + 0], n0);
        n1 = fmaf(z[k], Wc2[k * 2 + 1], n1);
    }
    int isbf = flags[0];
    st_out(out_dev, out_off + b * 2 + 0, n0, isbf);
    st_out(out_dev, out_off + b * 2 + 1, n1, isbf);
}

extern "C" void kernel_launch(void* const* d_in, const int* in_sizes, int n_in,
                              void* d_out, int out_size, void* d_ws, size_t ws_size,
                              hipStream_t stream) {
    const void* x    = d_in[0];
    const void* eidx = d_in[1];
    const void* batch= d_in[2];

    // workspace carve-up (256B aligned)
    char* w = (char*)d_ws;
    size_t o = 0;
    auto carve = [&](size_t bytes) { void* p = w + o; o = (o + bytes + 255) & ~(size_t)255; return p; };
    int* flags    = (int*)carve(8 * sizeof(int));
    int* off      = (int*)carve((N_NODES + 1) * sizeof(int));
    int* counts   = (int*)carve(N_NODES * sizeof(int));
    int* cursor   = (int*)carve(N_NODES * sizeof(int));
    int* bsum     = (int*)carve(SCAN_NBLK * sizeof(int));
    int* bbase    = (int*)carve(SCAN_NBLK * sizeof(int));
    int* csr_send = (int*)carve((size_t)(N_EDGES + N_NODES) * sizeof(int));
    float* pblock = (float*)carve(P_TOTAL * sizeof(float));
    float* buf0   = (float*)carve((size_t)N_NODES * 128 * sizeof(float));
    unsigned short* hb = (unsigned short*)carve((size_t)N_NODES * 128 * sizeof(unsigned short));
    float* h3     = (float*)carve((size_t)N_NODES * 4 * sizeof(float));
    float* es     = (float*)carve(N_NODES * sizeof(float));
    float* ed     = (float*)carve(N_NODES * sizeof(float));
    float* pooled = (float*)carve(NB * 64 * sizeof(float));

    int gN = (N_NODES + 255) / 256;
    int gE = (N_EDGES + 255) / 256;
    int gW = N_NODES / 4;                 // wave-per-node kernels

    // dtype detect
    k_detect<<<1, 64, 0, stream>>>((const unsigned short*)x, (const unsigned int*)eidx, flags);

    // params -> f32 block
    PTab tab;
    const int pn[20]  = {384,128,128,128, 8192,64,64,64, 8192,128,128,128, 384,3,3,3, 2048,32,64,2};
    const int pof[20] = {P_W1,P_A1S,P_A1D,P_B1, P_W2,P_A2S,P_A2D,P_B2, P_W3,P_A3S,P_A3D,P_B3,
                         P_W4,P_A4S,P_A4D,P_B4, P_WC1,P_BC1,P_WC2,P_BC2};
    for (int i = 0; i < 20; i++) { tab.src[i] = d_in[3 + i]; tab.off[i] = pof[i]; tab.n[i] = pn[i]; }
    k_cvt_params<<<20, 256, 0, stream>>>(tab, flags, pblock);

    // CSR build
    k_init_counts<<<gN, 256, 0, stream>>>(counts);
    k_count<<<gE, 256, 0, stream>>>(eidx, flags, counts);
    k_scan_a<<<SCAN_NBLK, SCAN_BLK, 0, stream>>>(counts, off, bsum);
    k_scan_b<<<1, SCAN_BLK, 0, stream>>>(bsum, bbase);
    k_scan_c<<<SCAN_NBLK, SCAN_BLK, 0, stream>>>(off, bbase);
    k_selfloop<<<gN, 256, 0, stream>>>(off, csr_send, cursor);
    k_fill<<<FILL_PASSES * FILL_BPP, 256, 0, stream>>>(eidx, flags, off, cursor, csr_send);

    // x -> f32
    k_cvt_x<<<(N_NODES * 3 + 255) / 256, 256, 0, stream>>>(x, flags, buf0);

    // output element offsets
    const long long OFF_RECON = 0, OFF_LATENT = 150000, OFF_NOISE = 3350000;

    // gemm grids: nodes/block = 64 (DOUT=128), 128 (DOUT=64), 256 (DOUT=3)
    int g64  = (N_NODES + 63) / 64;
    int g128 = (N_NODES + 127) / 128;
    int g256 = (N_NODES + 255) / 256;

    // conv1: [N,3] -> [N,128], relu
    k_gemm<3, 128, true><<<g64, 256, 0, stream>>>(buf0, pblock + P_W1, pblock + P_A1S, pblock + P_A1D, hb, es, ed);
    k_wsum128f<true><<<gW, 256, 0, stream>>>(hb, es, ed, pblock + P_B1, off, csr_send, buf0);

    // conv2: [N,128] -> [N,64] (latent)
    k_gemm<128, 64, true><<<g128, 256, 0, stream>>>(buf0, pblock + P_W2, pblock + P_A2S, pblock + P_A2D, hb, es, ed);
    k_wsum64f<<<gW, 256, 0, stream>>>(hb, es, ed, pblock + P_B2, off, csr_send, buf0, d_out, OFF_LATENT, flags);

    // pooling + classifier from f32 latent (buf0)
    k_pool<<<NB, POOL_W * 64, 0, stream>>>(buf0, batch, flags, pooled);
    k_cls<<<1, 64, 0, stream>>>(pooled, pblock, d_out, OFF_NOISE, flags);

    // conv3: [N,64] -> [N,128], relu
    k_gemm<64, 128, true><<<g64, 256, 0, stream>>>(buf0, pblock + P_W3, pblock + P_A3S, pblock + P_A3D, hb, es, ed);
    k_wsum128f<true><<<gW, 256, 0, stream>>>(hb, es, ed, pblock + P_B3, off, csr_send, buf0);

    // conv4: [N,128] -> [N,3] (reconstructed)
    k_gemm<128, 3, false><<<g256, 256, 0, stream>>>(buf0, pblock + P_W4, pblock + P_A4S, pblock + P_A4D, h3, es, ed);
    k_wsum3f<<<gW, 256, 0, stream>>>(h3, es, ed, pblock + P_B4, off, csr_send, d_out, OFF_RECON, flags);
}

// Round 11
// 345.031 us; speedup vs baseline: 2.5104x; 1.0265x over previous
//
#include <hip/hip_runtime.h>
#include <hip/hip_bf16.h>

typedef __hip_bfloat16 bf16;

#define N_NODES 50000
#define N_EDGES 800000
#define NB 64
#define SCAN_BLK 256
#define SCAN_NBLK ((N_NODES + SCAN_BLK - 1) / SCAN_BLK)   // 196

// k_fill pass partitioning
#define FILL_PASSES 4
#define FILL_BPP 256                                   // blocks per pass
#define FILL_RANGE ((N_NODES + FILL_PASSES - 1) / FILL_PASSES)

// param block offsets (floats)
#define P_W1 0
#define P_A1S 384
#define P_A1D 512
#define P_B1 640
#define P_W2 768
#define P_A2S 8960
#define P_A2D 9024
#define P_B2 9088
#define P_W3 9152
#define P_A3S 17344
#define P_A3D 17472
#define P_B3 17600
#define P_W4 17728
#define P_A4S 18112
#define P_A4D 18115
#define P_B4 18118
#define P_WC1 18121
#define P_BC1 20169
#define P_WC2 20201
#define P_BC2 20265
#define P_TOTAL 20267

__device__ __forceinline__ float wave_sum(float v) {
#pragma unroll
    for (int o = 32; o >= 1; o >>= 1) v += __shfl_xor(v, o, 64);
    return v;
}

// bf16 pack/unpack (bit tricks, no cvt on unpack)
__device__ __forceinline__ unsigned int pk2(float a, float b) {
    bf16 x = __float2bfloat16(a);
    bf16 y = __float2bfloat16(b);
    unsigned short ux = *reinterpret_cast<unsigned short*>(&x);
    unsigned short uy = *reinterpret_cast<unsigned short*>(&y);
    return ((unsigned int)uy << 16) | ux;
}
__device__ __forceinline__ float bf_lo(unsigned int u) {
    unsigned int v = u << 16;
    return *reinterpret_cast<float*>(&v);
}
__device__ __forceinline__ float bf_hi(unsigned int u) {
    unsigned int v = u & 0xffff0000u;
    return *reinterpret_cast<float*>(&v);
}

// runtime dtype helpers: flags[0]=float-inputs-are-bf16, flags[1]=ints-are-int64
__device__ __forceinline__ int ld_idx(const void* p, long long i, int is64) {
    return is64 ? (int)((const long long*)p)[i] : ((const int*)p)[i];
}
__device__ __forceinline__ void st_out(void* p, long long i, float v, int isbf) {
    if (isbf) ((bf16*)p)[i] = __float2bfloat16(v);
    else ((float*)p)[i] = v;
}

// unnormalized attention weight: p = exp(leaky(es+ed)), clamped (clamp inactive
// for sane inputs; guards f32 overflow only)
__device__ __forceinline__ float attn_p(float esv, float edi) {
    float v = esv + edi;
    float e = (v >= 0.f) ? v : 0.2f * v;
    return __expf(fminf(e, 60.f));
}

// ---------------- counts init + dtype detection (merged) ----------------
__global__ void k_init_detect(int* __restrict__ counts,
                              const unsigned short* __restrict__ xraw,
                              const unsigned int* __restrict__ eraw,
                              int* __restrict__ flags) {
    int i = blockIdx.x * blockDim.x + threadIdx.x;
    if (i < N_NODES) counts[i] = 1;  // self loop
    if (i == 0) {
        int cnt = 0;
        for (int k = 0; k < 256; k++) {
            unsigned int hb = (xraw[2 * k] >> 8) & 0x7F;
            if (hb >= 58 && hb <= 65) cnt++;
        }
        flags[0] = (cnt >= 200) ? 1 : 0;
        int z = 0;
        for (int k = 0; k < 64; k++)
            if (eraw[2 * k + 1] == 0u) z++;
        flags[1] = (z >= 60) ? 1 : 0;
    }
}

// ---------------- input/param convert to f32 ----------------
struct PTab {
    const void* src[20];
    int off[20];
    int n[20];
};

__global__ void k_cvt_params(PTab tab, const int* __restrict__ flags,
                             float* __restrict__ pblock) {
    int t = blockIdx.x;
    const void* s = tab.src[t];
    float* d = pblock + tab.off[t];
    int n = tab.n[t];
    int isbf = flags[0];
    for (int i = threadIdx.x; i < n; i += blockDim.x)
        d[i] = isbf ? __bfloat162float(((const bf16*)s)[i]) : ((const float*)s)[i];
}

__global__ void k_cvt_x(const void* __restrict__ x, const int* __restrict__ flags,
                        float* __restrict__ buf) {
    int i = blockIdx.x * blockDim.x + threadIdx.x;
    if (i < N_NODES * 3)
        buf[i] = flags[0] ? __bfloat162float(((const bf16*)x)[i]) : ((const float*)x)[i];
}

// ---------------- CSR build ----------------
__global__ void k_count(const void* __restrict__ eidx, const int* __restrict__ flags,
                        int* __restrict__ counts) {
    int e = blockIdx.x * blockDim.x + threadIdx.x;
    if (e < N_EDGES) {
        int r = ld_idx(eidx, (long long)N_EDGES + e, flags[1]);
        atomicAdd(&counts[r], 1);
    }
}

__global__ void k_scan_a(const int* __restrict__ counts, int* __restrict__ off,
                         int* __restrict__ bsum) {
    __shared__ int s[SCAN_BLK];
    int t = threadIdx.x;
    int i = blockIdx.x * SCAN_BLK + t;
    int v = (i < N_NODES) ? counts[i] : 0;
    s[t] = v;
    __syncthreads();
#pragma unroll
    for (int o = 1; o < SCAN_BLK; o <<= 1) {
        int add = (t >= o) ? s[t - o] : 0;
        __syncthreads();
        s[t] += add;
        __syncthreads();
    }
    if (i < N_NODES) off[i + 1] = s[t];
    if (t == SCAN_BLK - 1) bsum[blockIdx.x] = s[t];
}

__global__ void k_scan_b(int* __restrict__ bsum, int* __restrict__ bbase) {
    __shared__ int s[SCAN_BLK];
    int t = threadIdx.x;
    s[t] = (t < SCAN_NBLK) ? bsum[t] : 0;
    __syncthreads();
#pragma unroll
    for (int o = 1; o < SCAN_BLK; o <<= 1) {
        int add = (t >= o) ? s[t - o] : 0;
        __syncthreads();
        s[t] += add;
        __syncthreads();
    }
    if (t < SCAN_NBLK) bbase[t] = s[t] - bsum[t];  // exclusive
}

__global__ void k_scan_c(int* __restrict__ off, const int* __restrict__ bbase) {
    int t = threadIdx.x;
    int i = blockIdx.x * SCAN_BLK + t;
    if (i < N_NODES) off[i + 1] += bbase[blockIdx.x];
    if (i == 0) off[0] = 0;
}

__global__ void k_selfloop(const int* __restrict__ off, int* __restrict__ csr_send,
                           int* __restrict__ cursor) {
    int i = blockIdx.x * blockDim.x + threadIdx.x;
    if (i < N_NODES) { csr_send[off[i]] = i; cursor[i] = 1; }
}

// node-range-partitioned fill: pass p writes only nodes [p*RANGE,(p+1)*RANGE)
__global__ __launch_bounds__(256) void k_fill(
        const void* __restrict__ eidx, const int* __restrict__ flags,
        const int* __restrict__ off, int* __restrict__ cursor,
        int* __restrict__ csr_send) {
    const int pass = blockIdx.x / FILL_BPP;
    const int bid = blockIdx.x - pass * FILL_BPP;
    const int lo = pass * FILL_RANGE;
    const int hi = min(lo + FILL_RANGE, N_NODES);
    const int is64 = flags[1];
    for (int e = bid * 256 + threadIdx.x; e < N_EDGES; e += FILL_BPP * 256) {
        int r = ld_idx(eidx, (long long)N_EDGES + e, is64);
        if (r >= lo && r < hi) {
            int s = ld_idx(eidx, e, is64);
            int p = atomicAdd(&cursor[r], 1);
            csr_send[off[r] + p] = s;
        }
    }
}

// ---------------- register-tiled linear + attention coefficients ----------------
template <int DIN, int DOUT, bool HB16>
__global__ __launch_bounds__(256) void k_gemm(
        const float* __restrict__ in, const float* __restrict__ W,
        const float* __restrict__ as_, const float* __restrict__ ad_,
        void* __restrict__ hout, float* __restrict__ es, float* __restrict__ ed) {
    constexpr int KC = (DIN < 32) ? DIN : 32;     // K-chunk
    constexpr int NCH = DIN / KC;                 // chunks
    constexpr int CG = (DOUT >= 64) ? (DOUT / 8) : 1;      // col groups
    constexpr int NT = (DOUT >= 64) ? ((256 / CG) * 4) : 256;  // nodes/block
    constexpr int NTP = NT + 4;                   // pad

    __shared__ float sX[KC][NTP];   // transposed x chunk
    __shared__ float sW[KC][DOUT];  // W chunk

    const int t = threadIdx.x;
    const int node0 = blockIdx.x * NT;
    const int nvalid = min(NT, N_NODES - node0);

    const int cg = t & (CG - 1);
    const int ng = t / CG;

    float acc[4][8] = {};

    for (int ch = 0; ch < NCH; ch++) {
        const int k0 = ch * KC;
        if (ch > 0) __syncthreads();
        for (int i = t; i < nvalid * KC; i += 256) {
            int n = i / KC, k = i - n * KC;
            sX[k][n] = in[(size_t)(node0 + n) * DIN + k0 + k];
        }
        for (int i = t; i < KC * DOUT; i += 256) {
            int k = i / DOUT, c = i - k * DOUT;
            sW[k][c] = W[(size_t)(k0 + k) * DOUT + c];
        }
        __syncthreads();

        if constexpr (DOUT >= 64) {
#pragma unroll 4
            for (int k = 0; k < KC; k++) {
                float4 xv = *(const float4*)&sX[k][ng * 4];
                float4 w0 = *(const float4*)&sW[k][cg * 8];
                float4 w1 = *(const float4*)&sW[k][cg * 8 + 4];
                float xs[4] = {xv.x, xv.y, xv.z, xv.w};
                float ws[8] = {w0.x, w0.y, w0.z, w0.w, w1.x, w1.y, w1.z, w1.w};
#pragma unroll
                for (int j = 0; j < 4; j++)
#pragma unroll
                    for (int c = 0; c < 8; c++)
                        acc[j][c] = fmaf(xs[j], ws[c], acc[j][c]);
            }
        } else {
#pragma unroll 4
            for (int k = 0; k < KC; k++) {
                float xv = sX[k][t];
#pragma unroll
                for (int c = 0; c < DOUT; c++)
                    acc[0][c] = fmaf(xv, sW[k][c], acc[0][c]);
            }
        }
    }

    if constexpr (DOUT >= 64) {
        float asv[8], adv[8];
#pragma unroll
        for (int c = 0; c < 8; c++) {
            asv[c] = as_[cg * 8 + c];
            adv[c] = ad_[cg * 8 + c];
        }
#pragma unroll
        for (int j = 0; j < 4; j++) {
            int n = ng * 4 + j;
            float e_s = 0.f, e_d = 0.f;
#pragma unroll
            for (int c = 0; c < 8; c++) {
                e_s = fmaf(acc[j][c], asv[c], e_s);
                e_d = fmaf(acc[j][c], adv[c], e_d);
            }
#pragma unroll
            for (int m = 1; m < CG; m <<= 1) {
                e_s += __shfl_xor(e_s, m, 64);
                e_d += __shfl_xor(e_d, m, 64);
            }
            if (n < nvalid) {
                if (cg == 0) {
                    es[node0 + n] = e_s;
                    ed[node0 + n] = e_d;
                }
                if constexpr (HB16) {
                    unsigned short* hb = (unsigned short*)hout;
                    uint4 u;
                    u.x = pk2(acc[j][0], acc[j][1]);
                    u.y = pk2(acc[j][2], acc[j][3]);
                    u.z = pk2(acc[j][4], acc[j][5]);
                    u.w = pk2(acc[j][6], acc[j][7]);
                    *(uint4*)&hb[(size_t)(node0 + n) * DOUT + cg * 8] = u;
                } else {
                    float* h = (float*)hout;
                    float4 v0 = {acc[j][0], acc[j][1], acc[j][2], acc[j][3]};
                    float4 v1 = {acc[j][4], acc[j][5], acc[j][6], acc[j][7]};
                    *(float4*)&h[(size_t)(node0 + n) * DOUT + cg * 8] = v0;
                    *(float4*)&h[(size_t)(node0 + n) * DOUT + cg * 8 + 4] = v1;
                }
            }
        }
    } else {
        if (t < nvalid) {
            int node = node0 + t;
            float e_s = 0.f, e_d = 0.f;
#pragma unroll
            for (int c = 0; c < DOUT; c++) {
                e_s = fmaf(acc[0][c], as_[c], e_s);
                e_d = fmaf(acc[0][c], ad_[c], e_d);
            }
            es[node] = e_s;
            ed[node] = e_d;
            float* h = (float*)hout;
            float4 v = {acc[0][0], acc[0][1], acc[0][2], 0.f};  // stride-4 padded
            *(float4*)&h[(size_t)node * 4] = v;
        }
    }
}

// ---------------- one-pass softmax + weighted sum, DOUT=128, bf16 h ------------
// unnormalized p=exp(e); per-lane S accumulation; normalize before bias.
// paired rows: half-wave 0 = even edges, half-wave 1 = odd edges.
template <bool RELU_OUT>
__global__ __launch_bounds__(256) void k_wsum128f(
        const unsigned short* __restrict__ hb, const float* __restrict__ es,
        const float* __restrict__ ed, const float* __restrict__ bias,
        const int* __restrict__ off, const int* __restrict__ csr_send,
        float* __restrict__ out) {
    int wid = threadIdx.x >> 6, lane = threadIdx.x & 63;
    int node = blockIdx.x * 4 + wid;
    if (node >= N_NODES) return;
    int start = off[node], end = off[node + 1];
    float edi = ed[node];

    const int hf = lane >> 5;
    const int hl = lane & 31;
    float4 a0 = {0.f, 0.f, 0.f, 0.f}, a1 = {0.f, 0.f, 0.f, 0.f};
    float sl = 0.f;

    for (int base = start; base < end; base += 64) {
        int j = base + lane;
        bool valid = j < end;
        int src = valid ? csr_send[j] : 0;
        float p = valid ? attn_p(es[src], edi) : 0.f;
        sl += p;
        int cnt = min(64, end - base);
        int npr = (cnt + 1) >> 1;
        int j2 = 0;
        for (; j2 + 2 <= npr; j2 += 2) {
            int qA = 2 * j2 + hf, qB = qA + 2;
            float pA = __shfl(p, qA, 64); int sA = __shfl(src, qA, 64);
            float pB = __shfl(p, qB, 64); int sB = __shfl(src, qB, 64);
            uint2 uA = *((const uint2*)(hb + (size_t)sA * 128) + hl);
            uint2 uB = *((const uint2*)(hb + (size_t)sB * 128) + hl);
            a0.x = fmaf(pA, bf_lo(uA.x), a0.x); a0.y = fmaf(pA, bf_hi(uA.x), a0.y);
            a0.z = fmaf(pA, bf_lo(uA.y), a0.z); a0.w = fmaf(pA, bf_hi(uA.y), a0.w);
            a1.x = fmaf(pB, bf_lo(uB.x), a1.x); a1.y = fmaf(pB, bf_hi(uB.x), a1.y);
            a1.z = fmaf(pB, bf_lo(uB.y), a1.z); a1.w = fmaf(pB, bf_hi(uB.y), a1.w);
        }
        for (; j2 < npr; j2++) {
            int q = 2 * j2 + hf;
            float pq = __shfl(p, q, 64); int sq = __shfl(src, q, 64);
            uint2 u = *((const uint2*)(hb + (size_t)sq * 128) + hl);
            a0.x = fmaf(pq, bf_lo(u.x), a0.x); a0.y = fmaf(pq, bf_hi(u.x), a0.y);
            a0.z = fmaf(pq, bf_lo(u.y), a0.z); a0.w = fmaf(pq, bf_hi(u.y), a0.w);
        }
    }
    float S = wave_sum(sl);
    float inv = 1.f / S;
    float4 r;
    r.x = a0.x + a1.x; r.y = a0.y + a1.y; r.z = a0.z + a1.z; r.w = a0.w + a1.w;
    r.x += __shfl_xor(r.x, 32, 64);
    r.y += __shfl_xor(r.y, 32, 64);
    r.z += __shfl_xor(r.z, 32, 64);
    r.w += __shfl_xor(r.w, 32, 64);
    if (hf == 0) {
        float4 b = ((const float4*)bias)[hl];
        r.x = fmaf(r.x, inv, b.x); r.y = fmaf(r.y, inv, b.y);
        r.z = fmaf(r.z, inv, b.z); r.w = fmaf(r.w, inv, b.w);
        if (RELU_OUT) {
            r.x = fmaxf(r.x, 0.f); r.y = fmaxf(r.y, 0.f);
            r.z = fmaxf(r.z, 0.f); r.w = fmaxf(r.w, 0.f);
        }
        ((float4*)(out + (size_t)node * 128))[hl] = r;
    }
}

// ---------------- one-pass softmax + weighted sum, DOUT=64, bf16 h -------------
// quad rows: quarter-wave q handles edges 4*j2+q.
__global__ __launch_bounds__(256) void k_wsum64f(
        const unsigned short* __restrict__ hb, const float* __restrict__ es,
        const float* __restrict__ ed, const float* __restrict__ bias,
        const int* __restrict__ off, const int* __restrict__ csr_send,
        float* __restrict__ out, void* __restrict__ out_dev, long long out_off,
        const int* __restrict__ flags) {
    int wid = threadIdx.x >> 6, lane = threadIdx.x & 63;
    int node = blockIdx.x * 4 + wid;
    if (node >= N_NODES) return;
    int start = off[node], end = off[node + 1];
    float edi = ed[node];

    const int qd = lane >> 4;
    const int ql = lane & 15;
    float4 a0 = {0.f, 0.f, 0.f, 0.f}, a1 = {0.f, 0.f, 0.f, 0.f};
    float sl = 0.f;

    for (int base = start; base < end; base += 64) {
        int j = base + lane;
        bool valid = j < end;
        int src = valid ? csr_send[j] : 0;
        float p = valid ? attn_p(es[src], edi) : 0.f;
        sl += p;
        int cnt = min(64, end - base);
        int nq = (cnt + 3) >> 2;
        int j2 = 0;
        for (; j2 + 2 <= nq; j2 += 2) {
            int qA = 4 * j2 + qd, qB = qA + 4;
            float pA = __shfl(p, qA, 64); int sA = __shfl(src, qA, 64);
            float pB = __shfl(p, qB, 64); int sB = __shfl(src, qB, 64);
            uint2 uA = *((const uint2*)(hb + (size_t)sA * 64) + ql);
            uint2 uB = *((const uint2*)(hb + (size_t)sB * 64) + ql);
            a0.x = fmaf(pA, bf_lo(uA.x), a0.x); a0.y = fmaf(pA, bf_hi(uA.x), a0.y);
            a0.z = fmaf(pA, bf_lo(uA.y), a0.z); a0.w = fmaf(pA, bf_hi(uA.y), a0.w);
            a1.x = fmaf(pB, bf_lo(uB.x), a1.x); a1.y = fmaf(pB, bf_hi(uB.x), a1.y);
            a1.z = fmaf(pB, bf_lo(uB.y), a1.z); a1.w = fmaf(pB, bf_hi(uB.y), a1.w);
        }
        for (; j2 < nq; j2++) {
            int q = 4 * j2 + qd;
            float pq = __shfl(p, q, 64); int sq = __shfl(src, q, 64);
            uint2 u = *((const uint2*)(hb + (size_t)sq * 64) + ql);
            a0.x = fmaf(pq, bf_lo(u.x), a0.x); a0.y = fmaf(pq, bf_hi(u.x), a0.y);
            a0.z = fmaf(pq, bf_lo(u.y), a0.z); a0.w = fmaf(pq, bf_hi(u.y), a0.w);
        }
    }
    float S = wave_sum(sl);
    float inv = 1.f / S;
    float4 r;
    r.x = a0.x + a1.x; r.y = a0.y + a1.y; r.z = a0.z + a1.z; r.w = a0.w + a1.w;
    r.x += __shfl_xor(r.x, 16, 64); r.y += __shfl_xor(r.y, 16, 64);
    r.z += __shfl_xor(r.z, 16, 64); r.w += __shfl_xor(r.w, 16, 64);
    r.x += __shfl_xor(r.x, 32, 64); r.y += __shfl_xor(r.y, 32, 64);
    r.z += __shfl_xor(r.z, 32, 64); r.w += __shfl_xor(r.w, 32, 64);
    if (qd == 0) {
        float4 b = ((const float4*)bias)[ql];
        r.x = fmaf(r.x, inv, b.x); r.y = fmaf(r.y, inv, b.y);
        r.z = fmaf(r.z, inv, b.z); r.w = fmaf(r.w, inv, b.w);
        ((float4*)(out + (size_t)node * 64))[ql] = r;
        if (out_dev) {
            int isbf = flags[0];
            long long o4 = out_off + (long long)node * 64 + 4 * ql;
            st_out(out_dev, o4 + 0, r.x, isbf);
            st_out(out_dev, o4 + 1, r.y, isbf);
            st_out(out_dev, o4 + 2, r.z, isbf);
            st_out(out_dev, o4 + 3, r.w, isbf);
        }
    }
}

// ---------------- one-pass softmax + weighted sum, DOUT=3 (edge-parallel) ------
__global__ __launch_bounds__(256) void k_wsum3f(
        const float* __restrict__ h, const float* __restrict__ es,
        const float* __restrict__ ed, const float* __restrict__ bias,
        const int* __restrict__ off, const int* __restrict__ csr_send,
        void* __restrict__ out_dev, long long out_off, const int* __restrict__ flags) {
    int wid = threadIdx.x >> 6, lane = threadIdx.x & 63;
    int node = blockIdx.x * 4 + wid;
    if (node >= N_NODES) return;
    int start = off[node], end = off[node + 1];
    float edi = ed[node];

    float a0 = 0.f, a1 = 0.f, a2 = 0.f, sl = 0.f;
    for (int j = start + lane; j < end; j += 64) {
        int s = csr_send[j];
        float p = attn_p(es[s], edi);
        sl += p;
        float4 rv = *(const float4*)(h + (size_t)s * 4);
        a0 = fmaf(p, rv.x, a0);
        a1 = fmaf(p, rv.y, a1);
        a2 = fmaf(p, rv.z, a2);
    }
    float S = wave_sum(sl);
    a0 = wave_sum(a0);
    a1 = wave_sum(a1);
    a2 = wave_sum(a2);
    if (lane < 3) {
        float inv = 1.f / S;
        float v = fmaf((lane == 0 ? a0 : (lane == 1 ? a1 : a2)), inv, bias[lane]);
        st_out(out_dev, out_off + (long long)node * 3 + lane, v, flags[0]);
    }
}

// ---------------- per-graph mean pooling: 1 block/graph, 16 waves ----------------
#define POOL_W 16
__global__ void k_pool(const float* __restrict__ latent, const void* __restrict__ batch,
                       const int* __restrict__ flags, float* __restrict__ pooled) {
    int b = blockIdx.x;
    int lane = threadIdx.x & 63;   // channel
    int wave = threadIdx.x >> 6;   // 0..15
    int is64 = flags[1];
    int lo = 0, hi = N_NODES;
    while (lo < hi) { int mid = (lo + hi) >> 1; if (ld_idx(batch, mid, is64) < b) lo = mid + 1; else hi = mid; }
    int start = lo;
    lo = 0; hi = N_NODES;
    while (lo < hi) { int mid = (lo + hi) >> 1; if (ld_idx(batch, mid, is64) < b + 1) lo = mid + 1; else hi = mid; }
    int end = lo;
    float s = 0.f;
    for (int n = start + wave; n < end; n += POOL_W) s += latent[(size_t)n * 64 + lane];
    __shared__ float red[POOL_W][64];
    red[wave][lane] = s;
    __syncthreads();
    if (wave == 0) {
        float t = s;
#pragma unroll
        for (int w2 = 1; w2 < POOL_W; w2++) t += red[w2][lane];
        float cnt = (float)(end - start);
        pooled[b * 64 + lane] = t / fmaxf(cnt, 1.f);
    }
}

// ---------------- classifier head ----------------
__global__ void k_cls(const float* __restrict__ pooled, const float* __restrict__ pb,
                      void* __restrict__ out_dev, long long out_off,
                      const int* __restrict__ flags) {
    int b = threadIdx.x;  // 64 threads, one per graph
    const float* Wc1 = pb + P_WC1;
    const float* bc1 = pb + P_BC1;
    const float* Wc2 = pb + P_WC2;
    const float* bc2 = pb + P_BC2;
    float z[32];
#pragma unroll
    for (int k = 0; k < 32; k++) z[k] = bc1[k];
    for (int c = 0; c < 64; c++) {
        float pv = pooled[b * 64 + c];
#pragma unroll
        for (int k = 0; k < 32; k++) z[k] = fmaf(pv, Wc1[c * 32 + k], z[k]);
    }
#pragma unroll
    for (int k = 0; k < 32; k++) z[k] = fmaxf(z[k], 0.f);
    float n0 = bc2[0], n1 = bc2[1];
#pragma unroll
    for (int k = 0; k < 32; k++) {
        n0 = fmaf(z[k], Wc2[k * 2 + 0], n0);
        n1 = fmaf(z[k], Wc2[k * 2 + 1], n1);
    }
    int isbf = flags[0];
    st_out(out_dev, out_off + b * 2 + 0, n0, isbf);
    st_out(out_dev, out_off + b * 2 + 1, n1, isbf);
}

extern "C" void kernel_launch(void* const* d_in, const int* in_sizes, int n_in,
                              void* d_out, int out_size, void* d_ws, size_t ws_size,
                              hipStream_t stream) {
    const void* x    = d_in[0];
    const void* eidx = d_in[1];
    const void* batch= d_in[2];

    // workspace carve-up (256B aligned)
    char* w = (char*)d_ws;
    size_t o = 0;
    auto carve = [&](size_t bytes) { void* p = w + o; o = (o + bytes + 255) & ~(size_t)255; return p; };
    int* flags    = (int*)carve(8 * sizeof(int));
    int* off      = (int*)carve((N_NODES + 1) * sizeof(int));
    int* counts   = (int*)carve(N_NODES * sizeof(int));
    int* cursor   = (int*)carve(N_NODES * sizeof(int));
    int* bsum     = (int*)carve(SCAN_NBLK * sizeof(int));
    int* bbase    = (int*)carve(SCAN_NBLK * sizeof(int));
    int* csr_send = (int*)carve((size_t)(N_EDGES + N_NODES) * sizeof(int));
    float* pblock = (float*)carve(P_TOTAL * sizeof(float));
    float* buf0   = (float*)carve((size_t)N_NODES * 128 * sizeof(float));
    unsigned short* hb = (unsigned short*)carve((size_t)N_NODES * 128 * sizeof(unsigned short));
    float* h3     = (float*)carve((size_t)N_NODES * 4 * sizeof(float));
    float* es     = (float*)carve(N_NODES * sizeof(float));
    float* ed     = (float*)carve(N_NODES * sizeof(float));
    float* pooled = (float*)carve(NB * 64 * sizeof(float));

    int gN = (N_NODES + 255) / 256;
    int gE = (N_EDGES + 255) / 256;
    int gW = N_NODES / 4;                 // wave-per-node kernels

    // counts init + dtype detect (merged)
    k_init_detect<<<gN, 256, 0, stream>>>(counts, (const unsigned short*)x,
                                          (const unsigned int*)eidx, flags);

    // params -> f32 block
    PTab tab;
    const int pn[20]  = {384,128,128,128, 8192,64,64,64, 8192,128,128,128, 384,3,3,3, 2048,32,64,2};
    const int pof[20] = {P_W1,P_A1S,P_A1D,P_B1, P_W2,P_A2S,P_A2D,P_B2, P_W3,P_A3S,P_A3D,P_B3,
                         P_W4,P_A4S,P_A4D,P_B4, P_WC1,P_BC1,P_WC2,P_BC2};
    for (int i = 0; i < 20; i++) { tab.src[i] = d_in[3 + i]; tab.off[i] = pof[i]; tab.n[i] = pn[i]; }
    k_cvt_params<<<20, 256, 0, stream>>>(tab, flags, pblock);

    // CSR build
    k_count<<<gE, 256, 0, stream>>>(eidx, flags, counts);
    k_scan_a<<<SCAN_NBLK, SCAN_BLK, 0, stream>>>(counts, off, bsum);
    k_scan_b<<<1, SCAN_BLK, 0, stream>>>(bsum, bbase);
    k_scan_c<<<SCAN_NBLK, SCAN_BLK, 0, stream>>>(off, bbase);
    k_selfloop<<<gN, 256, 0, stream>>>(off, csr_send, cursor);
    k_fill<<<FILL_PASSES * FILL_BPP, 256, 0, stream>>>(eidx, flags, off, cursor, csr_send);

    // x -> f32
    k_cvt_x<<<(N_NODES * 3 + 255) / 256, 256, 0, stream>>>(x, flags, buf0);

    // output element offsets
    const long long OFF_RECON = 0, OFF_LATENT = 150000, OFF_NOISE = 3350000;

    // gemm grids: nodes/block = 64 (DOUT=128), 128 (DOUT=64), 256 (DOUT=3)
    int g64  = (N_NODES + 63) / 64;
    int g128 = (N_NODES + 127) / 128;
    int g256 = (N_NODES + 255) / 256;

    // conv1: [N,3] -> [N,128], relu
    k_gemm<3, 128, true><<<g64, 256, 0, stream>>>(buf0, pblock + P_W1, pblock + P_A1S, pblock + P_A1D, hb, es, ed);
    k_wsum128f<true><<<gW, 256, 0, stream>>>(hb, es, ed, pblock + P_B1, off, csr_send, buf0);

    // conv2: [N,128] -> [N,64] (latent)
    k_gemm<128, 64, true><<<g128, 256, 0, stream>>>(buf0, pblock + P_W2, pblock + P_A2S, pblock + P_A2D, hb, es, ed);
    k_wsum64f<<<gW, 256, 0, stream>>>(hb, es, ed, pblock + P_B2, off, csr_send, buf0, d_out, OFF_LATENT, flags);

    // pooling + classifier from f32 latent (buf0)
    k_pool<<<NB, POOL_W * 64, 0, stream>>>(buf0, batch, flags, pooled);
    k_cls<<<1, 64, 0, stream>>>(pooled, pblock, d_out, OFF_NOISE, flags);

    // conv3: [N,64] -> [N,128], relu
    k_gemm<64, 128, true><<<g64, 256, 0, stream>>>(buf0, pblock + P_W3, pblock + P_A3S, pblock + P_A3D, hb, es, ed);
    k_wsum128f<true><<<gW, 256, 0, stream>>>(hb, es, ed, pblock + P_B3, off, csr_send, buf0);

    // conv4: [N,128] -> [N,3] (reconstructed)
    k_gemm<128, 3, false><<<g256, 256, 0, stream>>>(buf0, pblock + P_W4, pblock + P_A4S, pblock + P_A4D, h3, es, ed);
    k_wsum3f<<<gW, 256, 0, stream>>>(h3, es, ed, pblock + P_B4, off, csr_send, d_out, OFF_RECON, flags);
}

// Round 12
// 342.655 us; speedup vs baseline: 2.5278x; 1.0069x over previous
//
#include <hip/hip_runtime.h>
#include <hip/hip_bf16.h>

typedef __hip_bfloat16 bf16;

#define N_NODES 50000
#define N_EDGES 800000
#define NB 64
#define SCAN_BLK 256
#define SCAN_NBLK ((N_NODES + SCAN_BLK - 1) / SCAN_BLK)   // 196

// bucketed CSR fill
#define NBUCK 256
#define BUCK_R ((N_NODES + NBUCK - 1) / NBUCK)            // 196 nodes/bucket
#define BUCK_CAP 4096                                     // mean 3125, +17 sigma
#define NBLK1 256
#define CHUNK1 ((N_EDGES + NBLK1 - 1) / NBLK1)            // 3125 edges/block

// param block offsets (floats)
#define P_W1 0
#define P_A1S 384
#define P_A1D 512
#define P_B1 640
#define P_W2 768
#define P_A2S 8960
#define P_A2D 9024
#define P_B2 9088
#define P_W3 9152
#define P_A3S 17344
#define P_A3D 17472
#define P_B3 17600
#define P_W4 17728
#define P_A4S 18112
#define P_A4D 18115
#define P_B4 18118
#define P_WC1 18121
#define P_BC1 20169
#define P_WC2 20201
#define P_BC2 20265
#define P_TOTAL 20267

__device__ __forceinline__ float wave_sum(float v) {
#pragma unroll
    for (int o = 32; o >= 1; o >>= 1) v += __shfl_xor(v, o, 64);
    return v;
}

// bf16 pack/unpack (bit tricks, no cvt on unpack)
__device__ __forceinline__ unsigned int pk2(float a, float b) {
    bf16 x = __float2bfloat16(a);
    bf16 y = __float2bfloat16(b);
    unsigned short ux = *reinterpret_cast<unsigned short*>(&x);
    unsigned short uy = *reinterpret_cast<unsigned short*>(&y);
    return ((unsigned int)uy << 16) | ux;
}
__device__ __forceinline__ float bf_lo(unsigned int u) {
    unsigned int v = u << 16;
    return *reinterpret_cast<float*>(&v);
}
__device__ __forceinline__ float bf_hi(unsigned int u) {
    unsigned int v = u & 0xffff0000u;
    return *reinterpret_cast<float*>(&v);
}

// runtime dtype helpers: flags[0]=float-inputs-are-bf16, flags[1]=ints-are-int64
__device__ __forceinline__ int ld_idx(const void* p, long long i, int is64) {
    return is64 ? (int)((const long long*)p)[i] : ((const int*)p)[i];
}
__device__ __forceinline__ void st_out(void* p, long long i, float v, int isbf) {
    if (isbf) ((bf16*)p)[i] = __float2bfloat16(v);
    else ((float*)p)[i] = v;
}

// unnormalized attention weight: p = exp(leaky(es+ed)), clamped (clamp inactive
// for sane inputs; guards f32 overflow only)
__device__ __forceinline__ float attn_p(float esv, float edi) {
    float v = esv + edi;
    float e = (v >= 0.f) ? v : 0.2f * v;
    return __expf(fminf(e, 60.f));
}

// ---------------- counts init + gcur zero + dtype detection (merged) -----------
__global__ void k_init_detect(int* __restrict__ counts, int* __restrict__ gcur,
                              const unsigned short* __restrict__ xraw,
                              const unsigned int* __restrict__ eraw,
                              int* __restrict__ flags) {
    int i = blockIdx.x * blockDim.x + threadIdx.x;
    if (i < N_NODES) counts[i] = 1;  // self loop
    if (i < NBUCK) gcur[i] = 0;
    if (i == 0) {
        int cnt = 0;
        for (int k = 0; k < 256; k++) {
            unsigned int hb = (xraw[2 * k] >> 8) & 0x7F;
            if (hb >= 58 && hb <= 65) cnt++;
        }
        flags[0] = (cnt >= 200) ? 1 : 0;
        int z = 0;
        for (int k = 0; k < 64; k++)
            if (eraw[2 * k + 1] == 0u) z++;
        flags[1] = (z >= 60) ? 1 : 0;
    }
}

// ---------------- input/param convert to f32 ----------------
struct PTab {
    const void* src[20];
    int off[20];
    int n[20];
};

__global__ void k_cvt_params(PTab tab, const int* __restrict__ flags,
                             float* __restrict__ pblock) {
    int t = blockIdx.x;
    const void* s = tab.src[t];
    float* d = pblock + tab.off[t];
    int n = tab.n[t];
    int isbf = flags[0];
    for (int i = threadIdx.x; i < n; i += blockDim.x)
        d[i] = isbf ? __bfloat162float(((const bf16*)s)[i]) : ((const float*)s)[i];
}

__global__ void k_cvt_x(const void* __restrict__ x, const int* __restrict__ flags,
                        float* __restrict__ buf) {
    int i = blockIdx.x * blockDim.x + threadIdx.x;
    if (i < N_NODES * 3)
        buf[i] = flags[0] ? __bfloat162float(((const bf16*)x)[i]) : ((const float*)x)[i];
}

// ---------------- CSR build ----------------
__global__ void k_count(const void* __restrict__ eidx, const int* __restrict__ flags,
                        int* __restrict__ counts) {
    int e = blockIdx.x * blockDim.x + threadIdx.x;
    if (e < N_EDGES) {
        int r = ld_idx(eidx, (long long)N_EDGES + e, flags[1]);
        atomicAdd(&counts[r], 1);
    }
}

__global__ void k_scan_a(const int* __restrict__ counts, int* __restrict__ off,
                         int* __restrict__ bsum) {
    __shared__ int s[SCAN_BLK];
    int t = threadIdx.x;
    int i = blockIdx.x * SCAN_BLK + t;
    int v = (i < N_NODES) ? counts[i] : 0;
    s[t] = v;
    __syncthreads();
#pragma unroll
    for (int o = 1; o < SCAN_BLK; o <<= 1) {
        int add = (t >= o) ? s[t - o] : 0;
        __syncthreads();
        s[t] += add;
        __syncthreads();
    }
    if (i < N_NODES) off[i + 1] = s[t];
    if (t == SCAN_BLK - 1) bsum[blockIdx.x] = s[t];
}

__global__ void k_scan_b(int* __restrict__ bsum, int* __restrict__ bbase) {
    __shared__ int s[SCAN_BLK];
    int t = threadIdx.x;
    s[t] = (t < SCAN_NBLK) ? bsum[t] : 0;
    __syncthreads();
#pragma unroll
    for (int o = 1; o < SCAN_BLK; o <<= 1) {
        int add = (t >= o) ? s[t - o] : 0;
        __syncthreads();
        s[t] += add;
        __syncthreads();
    }
    if (t < SCAN_NBLK) bbase[t] = s[t] - bsum[t];  // exclusive
}

__global__ void k_scan_c(int* __restrict__ off, const int* __restrict__ bbase) {
    int t = threadIdx.x;
    int i = blockIdx.x * SCAN_BLK + t;
    if (i < N_NODES) off[i + 1] += bbase[blockIdx.x];
    if (i == 0) off[0] = 0;
}

__global__ void k_selfloop(const int* __restrict__ off, int* __restrict__ csr_send,
                           int* __restrict__ cursor) {
    int i = blockIdx.x * blockDim.x + threadIdx.x;
    if (i < N_NODES) { csr_send[off[i]] = i; cursor[i] = 1; }
}

// ---------------- bucketed CSR fill, phase 1: edges -> per-bucket staging ------
// per-block LDS histogram -> one global cursor reservation per (block,bucket)
// -> contiguous runs in staging (same-XCD writes, no line bounce).
__global__ __launch_bounds__(256) void k_bucket(
        const void* __restrict__ eidx, const int* __restrict__ flags,
        const int* __restrict__ off, int* __restrict__ cursor,
        int* __restrict__ csr_send, int* __restrict__ gcur,
        uint2* __restrict__ stage) {
    __shared__ int hist[NBUCK];
    __shared__ int base[NBUCK];
    const int t = threadIdx.x;
    const int is64 = flags[1];
    const int e0 = blockIdx.x * CHUNK1;
    const int e1 = min(e0 + CHUNK1, N_EDGES);

    hist[t] = 0;
    __syncthreads();
    for (int e = e0 + t; e < e1; e += 256) {
        int r = ld_idx(eidx, (long long)N_EDGES + e, is64);
        atomicAdd(&hist[r / BUCK_R], 1);
    }
    __syncthreads();
    int cnt = hist[t];
    base[t] = (cnt > 0) ? atomicAdd(&gcur[t], cnt) : 0;
    __syncthreads();
    hist[t] = 0;  // reuse as within-block running index
    __syncthreads();
    for (int e = e0 + t; e < e1; e += 256) {
        int r = ld_idx(eidx, (long long)N_EDGES + e, is64);
        int s = ld_idx(eidx, e, is64);
        int b = r / BUCK_R;
        int l = atomicAdd(&hist[b], 1);
        int slot = base[b] + l;
        if (slot < BUCK_CAP) {
            stage[(size_t)b * BUCK_CAP + slot] = make_uint2((unsigned)s, (unsigned)r);
        } else {
            // overflow fallback (statistically never): direct scatter
            int p = atomicAdd(&cursor[r], 1);
            csr_send[off[r] + p] = s;
        }
    }
}

// ---------------- bucketed CSR fill, phase 2: one block per bucket -------------
// bucket's csr region (~13KB) written by ONE CU -> L2-coalesced, write-amp ~1.
__global__ __launch_bounds__(256) void k_fill2(
        const int* __restrict__ gcur, const uint2* __restrict__ stage,
        const int* __restrict__ off, int* __restrict__ cursor,
        int* __restrict__ csr_send) {
    const int b = blockIdx.x;
    const int cnt = min(gcur[b], BUCK_CAP);
    const uint2* sb = stage + (size_t)b * BUCK_CAP;
    for (int i = threadIdx.x; i < cnt; i += 256) {
        uint2 pr = sb[i];
        int r = (int)pr.y;
        int p = atomicAdd(&cursor[r], 1);
        csr_send[off[r] + p] = (int)pr.x;
    }
}

// ---------------- register-tiled linear + attention coefficients ----------------
template <int DIN, int DOUT, bool HB16>
__global__ __launch_bounds__(256) void k_gemm(
        const float* __restrict__ in, const float* __restrict__ W,
        const float* __restrict__ as_, const float* __restrict__ ad_,
        void* __restrict__ hout, float* __restrict__ es, float* __restrict__ ed) {
    constexpr int KC = (DIN < 32) ? DIN : 32;     // K-chunk
    constexpr int NCH = DIN / KC;                 // chunks
    constexpr int CG = (DOUT >= 64) ? (DOUT / 8) : 1;      // col groups
    constexpr int NT = (DOUT >= 64) ? ((256 / CG) * 4) : 256;  // nodes/block
    constexpr int NTP = NT + 4;                   // pad

    __shared__ float sX[KC][NTP];   // transposed x chunk
    __shared__ float sW[KC][DOUT];  // W chunk

    const int t = threadIdx.x;
    const int node0 = blockIdx.x * NT;
    const int nvalid = min(NT, N_NODES - node0);

    const int cg = t & (CG - 1);
    const int ng = t / CG;

    float acc[4][8] = {};

    for (int ch = 0; ch < NCH; ch++) {
        const int k0 = ch * KC;
        if (ch > 0) __syncthreads();
        for (int i = t; i < nvalid * KC; i += 256) {
            int n = i / KC, k = i - n * KC;
            sX[k][n] = in[(size_t)(node0 + n) * DIN + k0 + k];
        }
        for (int i = t; i < KC * DOUT; i += 256) {
            int k = i / DOUT, c = i - k * DOUT;
            sW[k][c] = W[(size_t)(k0 + k) * DOUT + c];
        }
        __syncthreads();

        if constexpr (DOUT >= 64) {
#pragma unroll 4
            for (int k = 0; k < KC; k++) {
                float4 xv = *(const float4*)&sX[k][ng * 4];
                float4 w0 = *(const float4*)&sW[k][cg * 8];
                float4 w1 = *(const float4*)&sW[k][cg * 8 + 4];
                float xs[4] = {xv.x, xv.y, xv.z, xv.w};
                float ws[8] = {w0.x, w0.y, w0.z, w0.w, w1.x, w1.y, w1.z, w1.w};
#pragma unroll
                for (int j = 0; j < 4; j++)
#pragma unroll
                    for (int c = 0; c < 8; c++)
                        acc[j][c] = fmaf(xs[j], ws[c], acc[j][c]);
            }
        } else {
#pragma unroll 4
            for (int k = 0; k < KC; k++) {
                float xv = sX[k][t];
#pragma unroll
                for (int c = 0; c < DOUT; c++)
                    acc[0][c] = fmaf(xv, sW[k][c], acc[0][c]);
            }
        }
    }

    if constexpr (DOUT >= 64) {
        float asv[8], adv[8];
#pragma unroll
        for (int c = 0; c < 8; c++) {
            asv[c] = as_[cg * 8 + c];
            adv[c] = ad_[cg * 8 + c];
        }
#pragma unroll
        for (int j = 0; j < 4; j++) {
            int n = ng * 4 + j;
            float e_s = 0.f, e_d = 0.f;
#pragma unroll
            for (int c = 0; c < 8; c++) {
                e_s = fmaf(acc[j][c], asv[c], e_s);
                e_d = fmaf(acc[j][c], adv[c], e_d);
            }
#pragma unroll
            for (int m = 1; m < CG; m <<= 1) {
                e_s += __shfl_xor(e_s, m, 64);
                e_d += __shfl_xor(e_d, m, 64);
            }
            if (n < nvalid) {
                if (cg == 0) {
                    es[node0 + n] = e_s;
                    ed[node0 + n] = e_d;
                }
                if constexpr (HB16) {
                    unsigned short* hb = (unsigned short*)hout;
                    uint4 u;
                    u.x = pk2(acc[j][0], acc[j][1]);
                    u.y = pk2(acc[j][2], acc[j][3]);
                    u.z = pk2(acc[j][4], acc[j][5]);
                    u.w = pk2(acc[j][6], acc[j][7]);
                    *(uint4*)&hb[(size_t)(node0 + n) * DOUT + cg * 8] = u;
                } else {
                    float* h = (float*)hout;
                    float4 v0 = {acc[j][0], acc[j][1], acc[j][2], acc[j][3]};
                    float4 v1 = {acc[j][4], acc[j][5], acc[j][6], acc[j][7]};
                    *(float4*)&h[(size_t)(node0 + n) * DOUT + cg * 8] = v0;
                    *(float4*)&h[(size_t)(node0 + n) * DOUT + cg * 8 + 4] = v1;
                }
            }
        }
    } else {
        if (t < nvalid) {
            int node = node0 + t;
            float e_s = 0.f, e_d = 0.f;
#pragma unroll
            for (int c = 0; c < DOUT; c++) {
                e_s = fmaf(acc[0][c], as_[c], e_s);
                e_d = fmaf(acc[0][c], ad_[c], e_d);
            }
            es[node] = e_s;
            ed[node] = e_d;
            float* h = (float*)hout;
            float4 v = {acc[0][0], acc[0][1], acc[0][2], 0.f};  // stride-4 padded
            *(float4*)&h[(size_t)node * 4] = v;
        }
    }
}

// ---------------- one-pass softmax + weighted sum, DOUT=128, bf16 h ------------
template <bool RELU_OUT>
__global__ __launch_bounds__(256) void k_wsum128f(
        const unsigned short* __restrict__ hb, const float* __restrict__ es,
        const float* __restrict__ ed, const float* __restrict__ bias,
        const int* __restrict__ off, const int* __restrict__ csr_send,
        float* __restrict__ out) {
    int wid = threadIdx.x >> 6, lane = threadIdx.x & 63;
    int node = blockIdx.x * 4 + wid;
    if (node >= N_NODES) return;
    int start = off[node], end = off[node + 1];
    float edi = ed[node];

    const int hf = lane >> 5;
    const int hl = lane & 31;
    float4 a0 = {0.f, 0.f, 0.f, 0.f}, a1 = {0.f, 0.f, 0.f, 0.f};
    float sl = 0.f;

    for (int base = start; base < end; base += 64) {
        int j = base + lane;
        bool valid = j < end;
        int src = valid ? csr_send[j] : 0;
        float p = valid ? attn_p(es[src], edi) : 0.f;
        sl += p;
        int cnt = min(64, end - base);
        int npr = (cnt + 1) >> 1;
        int j2 = 0;
        for (; j2 + 2 <= npr; j2 += 2) {
            int qA = 2 * j2 + hf, qB = qA + 2;
            float pA = __shfl(p, qA, 64); int sA = __shfl(src, qA, 64);
            float pB = __shfl(p, qB, 64); int sB = __shfl(src, qB, 64);
            uint2 uA = *((const uint2*)(hb + (size_t)sA * 128) + hl);
            uint2 uB = *((const uint2*)(hb + (size_t)sB * 128) + hl);
            a0.x = fmaf(pA, bf_lo(uA.x), a0.x); a0.y = fmaf(pA, bf_hi(uA.x), a0.y);
            a0.z = fmaf(pA, bf_lo(uA.y), a0.z); a0.w = fmaf(pA, bf_hi(uA.y), a0.w);
            a1.x = fmaf(pB, bf_lo(uB.x), a1.x); a1.y = fmaf(pB, bf_hi(uB.x), a1.y);
            a1.z = fmaf(pB, bf_lo(uB.y), a1.z); a1.w = fmaf(pB, bf_hi(uB.y), a1.w);
        }
        for (; j2 < npr; j2++) {
            int q = 2 * j2 + hf;
            float pq = __shfl(p, q, 64); int sq = __shfl(src, q, 64);
            uint2 u = *((const uint2*)(hb + (size_t)sq * 128) + hl);
            a0.x = fmaf(pq, bf_lo(u.x), a0.x); a0.y = fmaf(pq, bf_hi(u.x), a0.y);
            a0.z = fmaf(pq, bf_lo(u.y), a0.z); a0.w = fmaf(pq, bf_hi(u.y), a0.w);
        }
    }
    float S = wave_sum(sl);
    float inv = 1.f / S;
    float4 r;
    r.x = a0.x + a1.x; r.y = a0.y + a1.y; r.z = a0.z + a1.z; r.w = a0.w + a1.w;
    r.x += __shfl_xor(r.x, 32, 64);
    r.y += __shfl_xor(r.y, 32, 64);
    r.z += __shfl_xor(r.z, 32, 64);
    r.w += __shfl_xor(r.w, 32, 64);
    if (hf == 0) {
        float4 b = ((const float4*)bias)[hl];
        r.x = fmaf(r.x, inv, b.x); r.y = fmaf(r.y, inv, b.y);
        r.z = fmaf(r.z, inv, b.z); r.w = fmaf(r.w, inv, b.w);
        if (RELU_OUT) {
            r.x = fmaxf(r.x, 0.f); r.y = fmaxf(r.y, 0.f);
            r.z = fmaxf(r.z, 0.f); r.w = fmaxf(r.w, 0.f);
        }
        ((float4*)(out + (size_t)node * 128))[hl] = r;
    }
}

// ---------------- one-pass softmax + weighted sum, DOUT=64, bf16 h -------------
__global__ __launch_bounds__(256) void k_wsum64f(
        const unsigned short* __restrict__ hb, const float* __restrict__ es,
        const float* __restrict__ ed, const float* __restrict__ bias,
        const int* __restrict__ off, const int* __restrict__ csr_send,
        float* __restrict__ out, void* __restrict__ out_dev, long long out_off,
        const int* __restrict__ flags) {
    int wid = threadIdx.x >> 6, lane = threadIdx.x & 63;
    int node = blockIdx.x * 4 + wid;
    if (node >= N_NODES) return;
    int start = off[node], end = off[node + 1];
    float edi = ed[node];

    const int qd = lane >> 4;
    const int ql = lane & 15;
    float4 a0 = {0.f, 0.f, 0.f, 0.f}, a1 = {0.f, 0.f, 0.f, 0.f};
    float sl = 0.f;

    for (int base = start; base < end; base += 64) {
        int j = base + lane;
        bool valid = j < end;
        int src = valid ? csr_send[j] : 0;
        float p = valid ? attn_p(es[src], edi) : 0.f;
        sl += p;
        int cnt = min(64, end - base);
        int nq = (cnt + 3) >> 2;
        int j2 = 0;
        for (; j2 + 2 <= nq; j2 += 2) {
            int qA = 4 * j2 + qd, qB = qA + 4;
            float pA = __shfl(p, qA, 64); int sA = __shfl(src, qA, 64);
            float pB = __shfl(p, qB, 64); int sB = __shfl(src, qB, 64);
            uint2 uA = *((const uint2*)(hb + (size_t)sA * 64) + ql);
            uint2 uB = *((const uint2*)(hb + (size_t)sB * 64) + ql);
            a0.x = fmaf(pA, bf_lo(uA.x), a0.x); a0.y = fmaf(pA, bf_hi(uA.x), a0.y);
            a0.z = fmaf(pA, bf_lo(uA.y), a0.z); a0.w = fmaf(pA, bf_hi(uA.y), a0.w);
            a1.x = fmaf(pB, bf_lo(uB.x), a1.x); a1.y = fmaf(pB, bf_hi(uB.x), a1.y);
            a1.z = fmaf(pB, bf_lo(uB.y), a1.z); a1.w = fmaf(pB, bf_hi(uB.y), a1.w);
        }
        for (; j2 < nq; j2++) {
            int q = 4 * j2 + qd;
            float pq = __shfl(p, q, 64); int sq = __shfl(src, q, 64);
            uint2 u = *((const uint2*)(hb + (size_t)sq * 64) + ql);
            a0.x = fmaf(pq, bf_lo(u.x), a0.x); a0.y = fmaf(pq, bf_hi(u.x), a0.y);
            a0.z = fmaf(pq, bf_lo(u.y), a0.z); a0.w = fmaf(pq, bf_hi(u.y), a0.w);
        }
    }
    float S = wave_sum(sl);
    float inv = 1.f / S;
    float4 r;
    r.x = a0.x + a1.x; r.y = a0.y + a1.y; r.z = a0.z + a1.z; r.w = a0.w + a1.w;
    r.x += __shfl_xor(r.x, 16, 64); r.y += __shfl_xor(r.y, 16, 64);
    r.z += __shfl_xor(r.z, 16, 64); r.w += __shfl_xor(r.w, 16, 64);
    r.x += __shfl_xor(r.x, 32, 64); r.y += __shfl_xor(r.y, 32, 64);
    r.z += __shfl_xor(r.z, 32, 64); r.w += __shfl_xor(r.w, 32, 64);
    if (qd == 0) {
        float4 b = ((const float4*)bias)[ql];
        r.x = fmaf(r.x, inv, b.x); r.y = fmaf(r.y, inv, b.y);
        r.z = fmaf(r.z, inv, b.z); r.w = fmaf(r.w, inv, b.w);
        ((float4*)(out + (size_t)node * 64))[ql] = r;
        if (out_dev) {
            int isbf = flags[0];
            long long o4 = out_off + (long long)node * 64 + 4 * ql;
            st_out(out_dev, o4 + 0, r.x, isbf);
            st_out(out_dev, o4 + 1, r.y, isbf);
            st_out(out_dev, o4 + 2, r.z, isbf);
            st_out(out_dev, o4 + 3, r.w, isbf);
        }
    }
}

// ---------------- one-pass softmax + weighted sum, DOUT=3 (edge-parallel) ------
__global__ __launch_bounds__(256) void k_wsum3f(
        const float* __restrict__ h, const float* __restrict__ es,
        const float* __restrict__ ed, const float* __restrict__ bias,
        const int* __restrict__ off, const int* __restrict__ csr_send,
        void* __restrict__ out_dev, long long out_off, const int* __restrict__ flags) {
    int wid = threadIdx.x >> 6, lane = threadIdx.x & 63;
    int node = blockIdx.x * 4 + wid;
    if (node >= N_NODES) return;
    int start = off[node], end = off[node + 1];
    float edi = ed[node];

    float a0 = 0.f, a1 = 0.f, a2 = 0.f, sl = 0.f;
    for (int j = start + lane; j < end; j += 64) {
        int s = csr_send[j];
        float p = attn_p(es[s], edi);
        sl += p;
        float4 rv = *(const float4*)(h + (size_t)s * 4);
        a0 = fmaf(p, rv.x, a0);
        a1 = fmaf(p, rv.y, a1);
        a2 = fmaf(p, rv.z, a2);
    }
    float S = wave_sum(sl);
    a0 = wave_sum(a0);
    a1 = wave_sum(a1);
    a2 = wave_sum(a2);
    if (lane < 3) {
        float inv = 1.f / S;
        float v = fmaf((lane == 0 ? a0 : (lane == 1 ? a1 : a2)), inv, bias[lane]);
        st_out(out_dev, out_off + (long long)node * 3 + lane, v, flags[0]);
    }
}

// ---------------- per-graph mean pooling: 1 block/graph, 16 waves ----------------
#define POOL_W 16
__global__ void k_pool(const float* __restrict__ latent, const void* __restrict__ batch,
                       const int* __restrict__ flags, float* __restrict__ pooled) {
    int b = blockIdx.x;
    int lane = threadIdx.x & 63;   // channel
    int wave = threadIdx.x >> 6;   // 0..15
    int is64 = flags[1];
    int lo = 0, hi = N_NODES;
    while (lo < hi) { int mid = (lo + hi) >> 1; if (ld_idx(batch, mid, is64) < b) lo = mid + 1; else hi = mid; }
    int start = lo;
    lo = 0; hi = N_NODES;
    while (lo < hi) { int mid = (lo + hi) >> 1; if (ld_idx(batch, mid, is64) < b + 1) lo = mid + 1; else hi = mid; }
    int end = lo;
    float s = 0.f;
    for (int n = start + wave; n < end; n += POOL_W) s += latent[(size_t)n * 64 + lane];
    __shared__ float red[POOL_W][64];
    red[wave][lane] = s;
    __syncthreads();
    if (wave == 0) {
        float t = s;
#pragma unroll
        for (int w2 = 1; w2 < POOL_W; w2++) t += red[w2][lane];
        float cnt = (float)(end - start);
        pooled[b * 64 + lane] = t / fmaxf(cnt, 1.f);
    }
}

// ---------------- classifier head ----------------
__global__ void k_cls(const float* __restrict__ pooled, const float* __restrict__ pb,
                      void* __restrict__ out_dev, long long out_off,
                      const int* __restrict__ flags) {
    int b = threadIdx.x;  // 64 threads, one per graph
    const float* Wc1 = pb + P_WC1;
    const float* bc1 = pb + P_BC1;
    const float* Wc2 = pb + P_WC2;
    const float* bc2 = pb + P_BC2;
    float z[32];
#pragma unroll
    for (int k = 0; k < 32; k++) z[k] = bc1[k];
    for (int c = 0; c < 64; c++) {
        float pv = pooled[b * 64 + c];
#pragma unroll
        for (int k = 0; k < 32; k++) z[k] = fmaf(pv, Wc1[c * 32 + k], z[k]);
    }
#pragma unroll
    for (int k = 0; k < 32; k++) z[k] = fmaxf(z[k], 0.f);
    float n0 = bc2[0], n1 = bc2[1];
#pragma unroll
    for (int k = 0; k < 32; k++) {
        n0 = fmaf(z[k], Wc2[k * 2 + 0], n0);
        n1 = fmaf(z[k], Wc2[k * 2 + 1], n1);
    }
    int isbf = flags[0];
    st_out(out_dev, out_off + b * 2 + 0, n0, isbf);
    st_out(out_dev, out_off + b * 2 + 1, n1, isbf);
}

extern "C" void kernel_launch(void* const* d_in, const int* in_sizes, int n_in,
                              void* d_out, int out_size, void* d_ws, size_t ws_size,
                              hipStream_t stream) {
    const void* x    = d_in[0];
    const void* eidx = d_in[1];
    const void* batch= d_in[2];

    // workspace carve-up (256B aligned)
    char* w = (char*)d_ws;
    size_t o = 0;
    auto carve = [&](size_t bytes) { void* p = w + o; o = (o + bytes + 255) & ~(size_t)255; return p; };
    int* flags    = (int*)carve(8 * sizeof(int));
    int* off      = (int*)carve((N_NODES + 1) * sizeof(int));
    int* counts   = (int*)carve(N_NODES * sizeof(int));
    int* cursor   = (int*)carve(N_NODES * sizeof(int));
    int* bsum     = (int*)carve(SCAN_NBLK * sizeof(int));
    int* bbase    = (int*)carve(SCAN_NBLK * sizeof(int));
    int* gcur     = (int*)carve(NBUCK * sizeof(int));
    int* csr_send = (int*)carve((size_t)(N_EDGES + N_NODES) * sizeof(int));
    uint2* stage  = (uint2*)carve((size_t)NBUCK * BUCK_CAP * sizeof(uint2));
    float* pblock = (float*)carve(P_TOTAL * sizeof(float));
    float* buf0   = (float*)carve((size_t)N_NODES * 128 * sizeof(float));
    unsigned short* hb = (unsigned short*)carve((size_t)N_NODES * 128 * sizeof(unsigned short));
    float* h3     = (float*)carve((size_t)N_NODES * 4 * sizeof(float));
    float* es     = (float*)carve(N_NODES * sizeof(float));
    float* ed     = (float*)carve(N_NODES * sizeof(float));
    float* pooled = (float*)carve(NB * 64 * sizeof(float));

    int gN = (N_NODES + 255) / 256;
    int gE = (N_EDGES + 255) / 256;
    int gW = N_NODES / 4;                 // wave-per-node kernels

    // counts init + gcur zero + dtype detect (merged)
    k_init_detect<<<gN, 256, 0, stream>>>(counts, gcur, (const unsigned short*)x,
                                          (const unsigned int*)eidx, flags);

    // params -> f32 block
    PTab tab;
    const int pn[20]  = {384,128,128,128, 8192,64,64,64, 8192,128,128,128, 384,3,3,3, 2048,32,64,2};
    const int pof[20] = {P_W1,P_A1S,P_A1D,P_B1, P_W2,P_A2S,P_A2D,P_B2, P_W3,P_A3S,P_A3D,P_B3,
                         P_W4,P_A4S,P_A4D,P_B4, P_WC1,P_BC1,P_WC2,P_BC2};
    for (int i = 0; i < 20; i++) { tab.src[i] = d_in[3 + i]; tab.off[i] = pof[i]; tab.n[i] = pn[i]; }
    k_cvt_params<<<20, 256, 0, stream>>>(tab, flags, pblock);

    // CSR build
    k_count<<<gE, 256, 0, stream>>>(eidx, flags, counts);
    k_scan_a<<<SCAN_NBLK, SCAN_BLK, 0, stream>>>(counts, off, bsum);
    k_scan_b<<<1, SCAN_BLK, 0, stream>>>(bsum, bbase);
    k_scan_c<<<SCAN_NBLK, SCAN_BLK, 0, stream>>>(off, bbase);
    k_selfloop<<<gN, 256, 0, stream>>>(off, csr_send, cursor);
    k_bucket<<<NBLK1, 256, 0, stream>>>(eidx, flags, off, cursor, csr_send, gcur, stage);
    k_fill2<<<NBUCK, 256, 0, stream>>>(gcur, stage, off, cursor, csr_send);

    // x -> f32
    k_cvt_x<<<(N_NODES * 3 + 255) / 256, 256, 0, stream>>>(x, flags, buf0);

    // output element offsets
    const long long OFF_RECON = 0, OFF_LATENT = 150000, OFF_NOISE = 3350000;

    // gemm grids: nodes/block = 64 (DOUT=128), 128 (DOUT=64), 256 (DOUT=3)
    int g64  = (N_NODES + 63) / 64;
    int g128 = (N_NODES + 127) / 128;
    int g256 = (N_NODES + 255) / 256;

    // conv1: [N,3] -> [N,128], relu
    k_gemm<3, 128, true><<<g64, 256, 0, stream>>>(buf0, pblock + P_W1, pblock + P_A1S, pblock + P_A1D, hb, es, ed);
    k_wsum128f<true><<<gW, 256, 0, stream>>>(hb, es, ed, pblock + P_B1, off, csr_send, buf0);

    // conv2: [N,128] -> [N,64] (latent)
    k_gemm<128, 64, true><<<g128, 256, 0, stream>>>(buf0, pblock + P_W2, pblock + P_A2S, pblock + P_A2D, hb, es, ed);
    k_wsum64f<<<gW, 256, 0, stream>>>(hb, es, ed, pblock + P_B2, off, csr_send, buf0, d_out, OFF_LATENT, flags);

    // pooling + classifier from f32 latent (buf0)
    k_pool<<<NB, POOL_W * 64, 0, stream>>>(buf0, batch, flags, pooled);
    k_cls<<<1, 64, 0, stream>>>(pooled, pblock, d_out, OFF_NOISE, flags);

    // conv3: [N,64] -> [N,128], relu
    k_gemm<64, 128, true><<<g64, 256, 0, stream>>>(buf0, pblock + P_W3, pblock + P_A3S, pblock + P_A3D, hb, es, ed);
    k_wsum128f<true><<<gW, 256, 0, stream>>>(hb, es, ed, pblock + P_B3, off, csr_send, buf0);

    // conv4: [N,128] -> [N,3] (reconstructed)
    k_gemm<128, 3, false><<<g256, 256, 0, stream>>>(buf0, pblock + P_W4, pblock + P_A4S, pblock + P_A4D, h3, es, ed);
    k_wsum3f<<<gW, 256, 0, stream>>>(h3, es, ed, pblock + P_B4, off, csr_send, d_out, OFF_RECON, flags);
}

// Round 13
// 288.624 us; speedup vs baseline: 3.0010x; 1.1872x over previous
//
#include <hip/hip_runtime.h>
#include <hip/hip_bf16.h>

typedef __hip_bfloat16 bf16;

#define N_NODES 50000
#define N_EDGES 800000
#define NB 64
#define SCAN_BLK 256
#define SCAN_NBLK ((N_NODES + SCAN_BLK - 1) / SCAN_BLK)   // 196

// bucketed CSR build
#define NBUCK 256
#define BUCK_R ((N_NODES + NBUCK - 1) / NBUCK)            // 196 nodes/bucket
#define BUCK_CAP 4352                                     // mean 3136, +21 sigma
#define OVF_CAP 65536
#define NBLK1 256
#define CHUNK1 ((N_EDGES + NBLK1 - 1) / NBLK1)            // 3125 edges/block
#define NIT ((CHUNK1 + 255) / 256)                        // 13 iters/thread

// param block offsets (floats)
#define P_W1 0
#define P_A1S 384
#define P_A1D 512
#define P_B1 640
#define P_W2 768
#define P_A2S 8960
#define P_A2D 9024
#define P_B2 9088
#define P_W3 9152
#define P_A3S 17344
#define P_A3D 17472
#define P_B3 17600
#define P_W4 17728
#define P_A4S 18112
#define P_A4D 18115
#define P_B4 18118
#define P_WC1 18121
#define P_BC1 20169
#define P_WC2 20201
#define P_BC2 20265
#define P_TOTAL 20267

__device__ __forceinline__ float wave_sum(float v) {
#pragma unroll
    for (int o = 32; o >= 1; o >>= 1) v += __shfl_xor(v, o, 64);
    return v;
}

// bf16 pack/unpack (bit tricks, no cvt on unpack)
__device__ __forceinline__ unsigned int pk2(float a, float b) {
    bf16 x = __float2bfloat16(a);
    bf16 y = __float2bfloat16(b);
    unsigned short ux = *reinterpret_cast<unsigned short*>(&x);
    unsigned short uy = *reinterpret_cast<unsigned short*>(&y);
    return ((unsigned int)uy << 16) | ux;
}
__device__ __forceinline__ float bf_lo(unsigned int u) {
    unsigned int v = u << 16;
    return *reinterpret_cast<float*>(&v);
}
__device__ __forceinline__ float bf_hi(unsigned int u) {
    unsigned int v = u & 0xffff0000u;
    return *reinterpret_cast<float*>(&v);
}

// runtime dtype helpers: flags[0]=float-inputs-are-bf16, flags[1]=ints-are-int64
__device__ __forceinline__ int ld_idx(const void* p, long long i, int is64) {
    return is64 ? (int)((const long long*)p)[i] : ((const int*)p)[i];
}
__device__ __forceinline__ void st_out(void* p, long long i, float v, int isbf) {
    if (isbf) ((bf16*)p)[i] = __float2bfloat16(v);
    else ((float*)p)[i] = v;
}

// unnormalized attention weight: p = exp(leaky(es+ed)), clamped (clamp inactive
// for sane inputs; guards f32 overflow only)
__device__ __forceinline__ float attn_p(float esv, float edi) {
    float v = esv + edi;
    float e = (v >= 0.f) ? v : 0.2f * v;
    return __expf(fminf(e, 60.f));
}

// ---------------- init (gcur/ovf zero) + dtype detection ----------------
__global__ void k_init_detect(int* __restrict__ gcur, int* __restrict__ ovf_cnt,
                              const unsigned short* __restrict__ xraw,
                              const unsigned int* __restrict__ eraw,
                              int* __restrict__ flags) {
    int t = threadIdx.x;
    if (t < NBUCK) gcur[t] = 0;
    if (t == 0) {
        *ovf_cnt = 0;
        int cnt = 0;
        for (int k = 0; k < 256; k++) {
            unsigned int hb = (xraw[2 * k] >> 8) & 0x7F;
            if (hb >= 58 && hb <= 65) cnt++;
        }
        flags[0] = (cnt >= 200) ? 1 : 0;
        int z = 0;
        for (int k = 0; k < 64; k++)
            if (eraw[2 * k + 1] == 0u) z++;
        flags[1] = (z >= 60) ? 1 : 0;
    }
}

// ---------------- input/param convert to f32 ----------------
struct PTab {
    const void* src[20];
    int off[20];
    int n[20];
};

__global__ void k_cvt_params(PTab tab, const int* __restrict__ flags,
                             float* __restrict__ pblock) {
    int t = blockIdx.x;
    const void* s = tab.src[t];
    float* d = pblock + tab.off[t];
    int n = tab.n[t];
    int isbf = flags[0];
    for (int i = threadIdx.x; i < n; i += blockDim.x)
        d[i] = isbf ? __bfloat162float(((const bf16*)s)[i]) : ((const float*)s)[i];
}

__global__ void k_cvt_x(const void* __restrict__ x, const int* __restrict__ flags,
                        float* __restrict__ buf) {
    int i = blockIdx.x * blockDim.x + threadIdx.x;
    if (i < N_NODES * 3)
        buf[i] = flags[0] ? __bfloat162float(((const bf16*)x)[i]) : ((const float*)x)[i];
}

// ---------------- bucket phase: edges -> per-bucket staging --------------------
// per-block LDS histogram -> one gcur reservation per (block,bucket) ->
// contiguous staging runs. Edge list cached in registers across the 2 passes.
__global__ __launch_bounds__(256) void k_bucket(
        const void* __restrict__ eidx, const int* __restrict__ flags,
        int* __restrict__ gcur, uint2* __restrict__ stage,
        int* __restrict__ ovf_cnt, uint2* __restrict__ ovf) {
    __shared__ int hist[NBUCK];
    __shared__ int base[NBUCK];
    const int t = threadIdx.x;
    const int is64 = flags[1];
    const int e0 = blockIdx.x * CHUNK1;
    const int e1 = min(e0 + CHUNK1, N_EDGES);

    int rs[NIT], ss[NIT];
    hist[t] = 0;
    __syncthreads();
#pragma unroll
    for (int it = 0; it < NIT; it++) {
        int e = e0 + t + it * 256;
        int r = -1, s = 0;
        if (e < e1) {
            r = ld_idx(eidx, (long long)N_EDGES + e, is64);
            s = ld_idx(eidx, e, is64);
            atomicAdd(&hist[r / BUCK_R], 1);
        }
        rs[it] = r;
        ss[it] = s;
    }
    __syncthreads();
    int cnt = hist[t];
    base[t] = (cnt > 0) ? atomicAdd(&gcur[t], cnt) : 0;
    __syncthreads();
    hist[t] = 0;  // reuse as within-block running index
    __syncthreads();
#pragma unroll
    for (int it = 0; it < NIT; it++) {
        int r = rs[it];
        if (r >= 0) {
            int b = r / BUCK_R;
            int l = atomicAdd(&hist[b], 1);
            int slot = base[b] + l;
            if (slot < BUCK_CAP) {
                stage[(size_t)b * BUCK_CAP + slot] = make_uint2((unsigned)ss[it], (unsigned)r);
            } else {
                int oi = atomicAdd(ovf_cnt, 1);
                if (oi < OVF_CAP) ovf[oi] = make_uint2((unsigned)ss[it], (unsigned)r);
            }
        }
    }
}

// ---------------- counts from staging (LDS histogram, zero global atomics) -----
__global__ __launch_bounds__(256) void k_count2(
        const int* __restrict__ gcur, const uint2* __restrict__ stage,
        const int* __restrict__ ovf_cnt, const uint2* __restrict__ ovf,
        int* __restrict__ counts) {
    __shared__ int hist[BUCK_R];
    const int b = blockIdx.x;
    const int r0 = b * BUCK_R;
    const int nr = min(BUCK_R, N_NODES - r0);
    for (int i = threadIdx.x; i < nr; i += 256) hist[i] = 0;
    __syncthreads();
    const int cnt = min(gcur[b], BUCK_CAP);
    const uint2* sb = stage + (size_t)b * BUCK_CAP;
    for (int i = threadIdx.x; i < cnt; i += 256)
        atomicAdd(&hist[(int)sb[i].y - r0], 1);
    int oc = min(*ovf_cnt, OVF_CAP);
    for (int i = threadIdx.x; i < oc; i += 256) {
        int r = (int)ovf[i].y;
        if (r >= r0 && r < r0 + nr) atomicAdd(&hist[r - r0], 1);
    }
    __syncthreads();
    for (int i = threadIdx.x; i < nr; i += 256) counts[r0 + i] = hist[i] + 1;
}

// ---------------- 3-phase parallel scan ----------------
__global__ void k_scan_a(const int* __restrict__ counts, int* __restrict__ off,
                         int* __restrict__ bsum) {
    __shared__ int s[SCAN_BLK];
    int t = threadIdx.x;
    int i = blockIdx.x * SCAN_BLK + t;
    int v = (i < N_NODES) ? counts[i] : 0;
    s[t] = v;
    __syncthreads();
#pragma unroll
    for (int o = 1; o < SCAN_BLK; o <<= 1) {
        int add = (t >= o) ? s[t - o] : 0;
        __syncthreads();
        s[t] += add;
        __syncthreads();
    }
    if (i < N_NODES) off[i + 1] = s[t];
    if (t == SCAN_BLK - 1) bsum[blockIdx.x] = s[t];
}

__global__ void k_scan_b(int* __restrict__ bsum, int* __restrict__ bbase) {
    __shared__ int s[SCAN_BLK];
    int t = threadIdx.x;
    s[t] = (t < SCAN_NBLK) ? bsum[t] : 0;
    __syncthreads();
#pragma unroll
    for (int o = 1; o < SCAN_BLK; o <<= 1) {
        int add = (t >= o) ? s[t - o] : 0;
        __syncthreads();
        s[t] += add;
        __syncthreads();
    }
    if (t < SCAN_NBLK) bbase[t] = s[t] - bsum[t];  // exclusive
}

__global__ void k_scan_c(int* __restrict__ off, const int* __restrict__ bbase) {
    int t = threadIdx.x;
    int i = blockIdx.x * SCAN_BLK + t;
    if (i < N_NODES) off[i + 1] += bbase[blockIdx.x];
    if (i == 0) off[0] = 0;
}

// ---------------- fill from staging (LDS cursors, self-loop merged) ------------
__global__ __launch_bounds__(256) void k_fill3(
        const int* __restrict__ gcur, const uint2* __restrict__ stage,
        const int* __restrict__ ovf_cnt, const uint2* __restrict__ ovf,
        const int* __restrict__ off, int* __restrict__ csr_send) {
    __shared__ int lcur[BUCK_R];
    const int b = blockIdx.x;
    const int r0 = b * BUCK_R;
    const int nr = min(BUCK_R, N_NODES - r0);
    for (int i = threadIdx.x; i < nr; i += 256) {
        lcur[i] = 1;
        csr_send[off[r0 + i]] = r0 + i;   // self loop in slot 0
    }
    __syncthreads();
    const int cnt = min(gcur[b], BUCK_CAP);
    const uint2* sb = stage + (size_t)b * BUCK_CAP;
    for (int i = threadIdx.x; i < cnt; i += 256) {
        uint2 pr = sb[i];
        int r = (int)pr.y;
        int l = atomicAdd(&lcur[r - r0], 1);
        csr_send[off[r] + l] = (int)pr.x;
    }
    int oc = min(*ovf_cnt, OVF_CAP);
    for (int i = threadIdx.x; i < oc; i += 256) {
        uint2 pr = ovf[i];
        int r = (int)pr.y;
        if (r >= r0 && r < r0 + nr) {
            int l = atomicAdd(&lcur[r - r0], 1);
            csr_send[off[r] + l] = (int)pr.x;
        }
    }
}

// ---------------- register-tiled linear + attention coefficients ----------------
template <int DIN, int DOUT, bool HB16>
__global__ __launch_bounds__(256) void k_gemm(
        const float* __restrict__ in, const float* __restrict__ W,
        const float* __restrict__ as_, const float* __restrict__ ad_,
        void* __restrict__ hout, float* __restrict__ es, float* __restrict__ ed) {
    constexpr int KC = (DIN < 32) ? DIN : 32;     // K-chunk
    constexpr int NCH = DIN / KC;                 // chunks
    constexpr int CG = (DOUT >= 64) ? (DOUT / 8) : 1;      // col groups
    constexpr int NT = (DOUT >= 64) ? ((256 / CG) * 4) : 256;  // nodes/block
    constexpr int NTP = NT + 4;                   // pad

    __shared__ float sX[KC][NTP];   // transposed x chunk
    __shared__ float sW[KC][DOUT];  // W chunk

    const int t = threadIdx.x;
    const int node0 = blockIdx.x * NT;
    const int nvalid = min(NT, N_NODES - node0);

    const int cg = t & (CG - 1);
    const int ng = t / CG;

    float acc[4][8] = {};

    for (int ch = 0; ch < NCH; ch++) {
        const int k0 = ch * KC;
        if (ch > 0) __syncthreads();
        for (int i = t; i < nvalid * KC; i += 256) {
            int n = i / KC, k = i - n * KC;
            sX[k][n] = in[(size_t)(node0 + n) * DIN + k0 + k];
        }
        for (int i = t; i < KC * DOUT; i += 256) {
            int k = i / DOUT, c = i - k * DOUT;
            sW[k][c] = W[(size_t)(k0 + k) * DOUT + c];
        }
        __syncthreads();

        if constexpr (DOUT >= 64) {
#pragma unroll 4
            for (int k = 0; k < KC; k++) {
                float4 xv = *(const float4*)&sX[k][ng * 4];
                float4 w0 = *(const float4*)&sW[k][cg * 8];
                float4 w1 = *(const float4*)&sW[k][cg * 8 + 4];
                float xs[4] = {xv.x, xv.y, xv.z, xv.w};
                float ws[8] = {w0.x, w0.y, w0.z, w0.w, w1.x, w1.y, w1.z, w1.w};
#pragma unroll
                for (int j = 0; j < 4; j++)
#pragma unroll
                    for (int c = 0; c < 8; c++)
                        acc[j][c] = fmaf(xs[j], ws[c], acc[j][c]);
            }
        } else {
#pragma unroll 4
            for (int k = 0; k < KC; k++) {
                float xv = sX[k][t];
#pragma unroll
                for (int c = 0; c < DOUT; c++)
                    acc[0][c] = fmaf(xv, sW[k][c], acc[0][c]);
            }
        }
    }

    if constexpr (DOUT >= 64) {
        float asv[8], adv[8];
#pragma unroll
        for (int c = 0; c < 8; c++) {
            asv[c] = as_[cg * 8 + c];
            adv[c] = ad_[cg * 8 + c];
        }
#pragma unroll
        for (int j = 0; j < 4; j++) {
            int n = ng * 4 + j;
            float e_s = 0.f, e_d = 0.f;
#pragma unroll
            for (int c = 0; c < 8; c++) {
                e_s = fmaf(acc[j][c], asv[c], e_s);
                e_d = fmaf(acc[j][c], adv[c], e_d);
            }
#pragma unroll
            for (int m = 1; m < CG; m <<= 1) {
                e_s += __shfl_xor(e_s, m, 64);
                e_d += __shfl_xor(e_d, m, 64);
            }
            if (n < nvalid) {
                if (cg == 0) {
                    es[node0 + n] = e_s;
                    ed[node0 + n] = e_d;
                }
                if constexpr (HB16) {
                    unsigned short* hb = (unsigned short*)hout;
                    uint4 u;
                    u.x = pk2(acc[j][0], acc[j][1]);
                    u.y = pk2(acc[j][2], acc[j][3]);
                    u.z = pk2(acc[j][4], acc[j][5]);
                    u.w = pk2(acc[j][6], acc[j][7]);
                    *(uint4*)&hb[(size_t)(node0 + n) * DOUT + cg * 8] = u;
                } else {
                    float* h = (float*)hout;
                    float4 v0 = {acc[j][0], acc[j][1], acc[j][2], acc[j][3]};
                    float4 v1 = {acc[j][4], acc[j][5], acc[j][6], acc[j][7]};
                    *(float4*)&h[(size_t)(node0 + n) * DOUT + cg * 8] = v0;
                    *(float4*)&h[(size_t)(node0 + n) * DOUT + cg * 8 + 4] = v1;
                }
            }
        }
    } else {
        if (t < nvalid) {
            int node = node0 + t;
            float e_s = 0.f, e_d = 0.f;
#pragma unroll
            for (int c = 0; c < DOUT; c++) {
                e_s = fmaf(acc[0][c], as_[c], e_s);
                e_d = fmaf(acc[0][c], ad_[c], e_d);
            }
            es[node] = e_s;
            ed[node] = e_d;
            float* h = (float*)hout;
            float4 v = {acc[0][0], acc[0][1], acc[0][2], 0.f};  // stride-4 padded
            *(float4*)&h[(size_t)node * 4] = v;
        }
    }
}

// ---------------- one-pass softmax + weighted sum, DOUT=128, bf16 h ------------
// paired rows + unroll-4: 4 uint2 gathers in flight per lane.
template <bool RELU_OUT>
__global__ __launch_bounds__(256) void k_wsum128f(
        const unsigned short* __restrict__ hb, const float* __restrict__ es,
        const float* __restrict__ ed, const float* __restrict__ bias,
        const int* __restrict__ off, const int* __restrict__ csr_send,
        float* __restrict__ out) {
    int wid = threadIdx.x >> 6, lane = threadIdx.x & 63;
    int node = blockIdx.x * 4 + wid;
    if (node >= N_NODES) return;
    int start = off[node], end = off[node + 1];
    float edi = ed[node];

    const int hf = lane >> 5;
    const int hl = lane & 31;
    float4 a0 = {0.f, 0.f, 0.f, 0.f}, a1 = {0.f, 0.f, 0.f, 0.f};
    float4 a2 = {0.f, 0.f, 0.f, 0.f}, a3 = {0.f, 0.f, 0.f, 0.f};
    float sl = 0.f;

    for (int base = start; base < end; base += 64) {
        int j = base + lane;
        bool valid = j < end;
        int src = valid ? csr_send[j] : 0;
        float p = valid ? attn_p(es[src], edi) : 0.f;
        sl += p;
        int cnt = min(64, end - base);
        int npr = (cnt + 1) >> 1;
        int j2 = 0;
        for (; j2 + 4 <= npr; j2 += 4) {
            int qA = 2 * j2 + hf;
            float pA = __shfl(p, qA, 64);     int sA = __shfl(src, qA, 64);
            float pB = __shfl(p, qA + 2, 64); int sB = __shfl(src, qA + 2, 64);
            float pC = __shfl(p, qA + 4, 64); int sC = __shfl(src, qA + 4, 64);
            float pD = __shfl(p, qA + 6, 64); int sD = __shfl(src, qA + 6, 64);
            uint2 uA = *((const uint2*)(hb + (size_t)sA * 128) + hl);
            uint2 uB = *((const uint2*)(hb + (size_t)sB * 128) + hl);
            uint2 uC = *((const uint2*)(hb + (size_t)sC * 128) + hl);
            uint2 uD = *((const uint2*)(hb + (size_t)sD * 128) + hl);
            a0.x = fmaf(pA, bf_lo(uA.x), a0.x); a0.y = fmaf(pA, bf_hi(uA.x), a0.y);
            a0.z = fmaf(pA, bf_lo(uA.y), a0.z); a0.w = fmaf(pA, bf_hi(uA.y), a0.w);
            a1.x = fmaf(pB, bf_lo(uB.x), a1.x); a1.y = fmaf(pB, bf_hi(uB.x), a1.y);
            a1.z = fmaf(pB, bf_lo(uB.y), a1.z); a1.w = fmaf(pB, bf_hi(uB.y), a1.w);
            a2.x = fmaf(pC, bf_lo(uC.x), a2.x); a2.y = fmaf(pC, bf_hi(uC.x), a2.y);
            a2.z = fmaf(pC, bf_lo(uC.y), a2.z); a2.w = fmaf(pC, bf_hi(uC.y), a2.w);
            a3.x = fmaf(pD, bf_lo(uD.x), a3.x); a3.y = fmaf(pD, bf_hi(uD.x), a3.y);
            a3.z = fmaf(pD, bf_lo(uD.y), a3.z); a3.w = fmaf(pD, bf_hi(uD.y), a3.w);
        }
        for (; j2 < npr; j2++) {
            int q = 2 * j2 + hf;
            float pq = __shfl(p, q, 64); int sq = __shfl(src, q, 64);
            uint2 u = *((const uint2*)(hb + (size_t)sq * 128) + hl);
            a0.x = fmaf(pq, bf_lo(u.x), a0.x); a0.y = fmaf(pq, bf_hi(u.x), a0.y);
            a0.z = fmaf(pq, bf_lo(u.y), a0.z); a0.w = fmaf(pq, bf_hi(u.y), a0.w);
        }
    }
    float S = wave_sum(sl);
    float inv = 1.f / S;
    float4 r;
    r.x = (a0.x + a1.x) + (a2.x + a3.x);
    r.y = (a0.y + a1.y) + (a2.y + a3.y);
    r.z = (a0.z + a1.z) + (a2.z + a3.z);
    r.w = (a0.w + a1.w) + (a2.w + a3.w);
    r.x += __shfl_xor(r.x, 32, 64);
    r.y += __shfl_xor(r.y, 32, 64);
    r.z += __shfl_xor(r.z, 32, 64);
    r.w += __shfl_xor(r.w, 32, 64);
    if (hf == 0) {
        float4 b = ((const float4*)bias)[hl];
        r.x = fmaf(r.x, inv, b.x); r.y = fmaf(r.y, inv, b.y);
        r.z = fmaf(r.z, inv, b.z); r.w = fmaf(r.w, inv, b.w);
        if (RELU_OUT) {
            r.x = fmaxf(r.x, 0.f); r.y = fmaxf(r.y, 0.f);
            r.z = fmaxf(r.z, 0.f); r.w = fmaxf(r.w, 0.f);
        }
        ((float4*)(out + (size_t)node * 128))[hl] = r;
    }
}

// ---------------- one-pass softmax + weighted sum, DOUT=64, bf16 h -------------
// quad rows + unroll-4: 4 uint2 gathers in flight per lane.
__global__ __launch_bounds__(256) void k_wsum64f(
        const unsigned short* __restrict__ hb, const float* __restrict__ es,
        const float* __restrict__ ed, const float* __restrict__ bias,
        const int* __restrict__ off, const int* __restrict__ csr_send,
        float* __restrict__ out, void* __restrict__ out_dev, long long out_off,
        const int* __restrict__ flags) {
    int wid = threadIdx.x >> 6, lane = threadIdx.x & 63;
    int node = blockIdx.x * 4 + wid;
    if (node >= N_NODES) return;
    int start = off[node], end = off[node + 1];
    float edi = ed[node];

    const int qd = lane >> 4;
    const int ql = lane & 15;
    float4 a0 = {0.f, 0.f, 0.f, 0.f}, a1 = {0.f, 0.f, 0.f, 0.f};
    float4 a2 = {0.f, 0.f, 0.f, 0.f}, a3 = {0.f, 0.f, 0.f, 0.f};
    float sl = 0.f;

    for (int base = start; base < end; base += 64) {
        int j = base + lane;
        bool valid = j < end;
        int src = valid ? csr_send[j] : 0;
        float p = valid ? attn_p(es[src], edi) : 0.f;
        sl += p;
        int cnt = min(64, end - base);
        int nq = (cnt + 3) >> 2;
        int j2 = 0;
        for (; j2 + 4 <= nq; j2 += 4) {
            int qA = 4 * j2 + qd;
            float pA = __shfl(p, qA, 64);      int sA = __shfl(src, qA, 64);
            float pB = __shfl(p, qA + 4, 64);  int sB = __shfl(src, qA + 4, 64);
            float pC = __shfl(p, qA + 8, 64);  int sC = __shfl(src, qA + 8, 64);
            float pD = __shfl(p, qA + 12, 64); int sD = __shfl(src, qA + 12, 64);
            uint2 uA = *((const uint2*)(hb + (size_t)sA * 64) + ql);
            uint2 uB = *((const uint2*)(hb + (size_t)sB * 64) + ql);
            uint2 uC = *((const uint2*)(hb + (size_t)sC * 64) + ql);
            uint2 uD = *((const uint2*)(hb + (size_t)sD * 64) + ql);
            a0.x = fmaf(pA, bf_lo(uA.x), a0.x); a0.y = fmaf(pA, bf_hi(uA.x), a0.y);
            a0.z = fmaf(pA, bf_lo(uA.y), a0.z); a0.w = fmaf(pA, bf_hi(uA.y), a0.w);
            a1.x = fmaf(pB, bf_lo(uB.x), a1.x); a1.y = fmaf(pB, bf_hi(uB.x), a1.y);
            a1.z = fmaf(pB, bf_lo(uB.y), a1.z); a1.w = fmaf(pB, bf_hi(uB.y), a1.w);
            a2.x = fmaf(pC, bf_lo(uC.x), a2.x); a2.y = fmaf(pC, bf_hi(uC.x), a2.y);
            a2.z = fmaf(pC, bf_lo(uC.y), a2.z); a2.w = fmaf(pC, bf_hi(uC.y), a2.w);
            a3.x = fmaf(pD, bf_lo(uD.x), a3.x); a3.y = fmaf(pD, bf_hi(uD.x), a3.y);
            a3.z = fmaf(pD, bf_lo(uD.y), a3.z); a3.w = fmaf(pD, bf_hi(uD.y), a3.w);
        }
        for (; j2 < nq; j2++) {
            int q = 4 * j2 + qd;
            float pq = __shfl(p, q, 64); int sq = __shfl(src, q, 64);
            uint2 u = *((const uint2*)(hb + (size_t)sq * 64) + ql);
            a0.x = fmaf(pq, bf_lo(u.x), a0.x); a0.y = fmaf(pq, bf_hi(u.x), a0.y);
            a0.z = fmaf(pq, bf_lo(u.y), a0.z); a0.w = fmaf(pq, bf_hi(u.y), a0.w);
        }
    }
    float S = wave_sum(sl);
    float inv = 1.f / S;
    float4 r;
    r.x = (a0.x + a1.x) + (a2.x + a3.x);
    r.y = (a0.y + a1.y) + (a2.y + a3.y);
    r.z = (a0.z + a1.z) + (a2.z + a3.z);
    r.w = (a0.w + a1.w) + (a2.w + a3.w);
    r.x += __shfl_xor(r.x, 16, 64); r.y += __shfl_xor(r.y, 16, 64);
    r.z += __shfl_xor(r.z, 16, 64); r.w += __shfl_xor(r.w, 16, 64);
    r.x += __shfl_xor(r.x, 32, 64); r.y += __shfl_xor(r.y, 32, 64);
    r.z += __shfl_xor(r.z, 32, 64); r.w += __shfl_xor(r.w, 32, 64);
    if (qd == 0) {
        float4 b = ((const float4*)bias)[ql];
        r.x = fmaf(r.x, inv, b.x); r.y = fmaf(r.y, inv, b.y);
        r.z = fmaf(r.z, inv, b.z); r.w = fmaf(r.w, inv, b.w);
        ((float4*)(out + (size_t)node * 64))[ql] = r;
        if (out_dev) {
            int isbf = flags[0];
            long long o4 = out_off + (long long)node * 64 + 4 * ql;
            st_out(out_dev, o4 + 0, r.x, isbf);
            st_out(out_dev, o4 + 1, r.y, isbf);
            st_out(out_dev, o4 + 2, r.z, isbf);
            st_out(out_dev, o4 + 3, r.w, isbf);
        }
    }
}

// ---------------- one-pass softmax + weighted sum, DOUT=3 (edge-parallel) ------
__global__ __launch_bounds__(256) void k_wsum3f(
        const float* __restrict__ h, const float* __restrict__ es,
        const float* __restrict__ ed, const float* __restrict__ bias,
        const int* __restrict__ off, const int* __restrict__ csr_send,
        void* __restrict__ out_dev, long long out_off, const int* __restrict__ flags) {
    int wid = threadIdx.x >> 6, lane = threadIdx.x & 63;
    int node = blockIdx.x * 4 + wid;
    if (node >= N_NODES) return;
    int start = off[node], end = off[node + 1];
    float edi = ed[node];

    float a0 = 0.f, a1 = 0.f, a2 = 0.f, sl = 0.f;
    for (int j = start + lane; j < end; j += 64) {
        int s = csr_send[j];
        float p = attn_p(es[s], edi);
        sl += p;
        float4 rv = *(const float4*)(h + (size_t)s * 4);
        a0 = fmaf(p, rv.x, a0);
        a1 = fmaf(p, rv.y, a1);
        a2 = fmaf(p, rv.z, a2);
    }
    float S = wave_sum(sl);
    a0 = wave_sum(a0);
    a1 = wave_sum(a1);
    a2 = wave_sum(a2);
    if (lane < 3) {
        float inv = 1.f / S;
        float v = fmaf((lane == 0 ? a0 : (lane == 1 ? a1 : a2)), inv, bias[lane]);
        st_out(out_dev, out_off + (long long)node * 3 + lane, v, flags[0]);
    }
}

// ---------------- per-graph mean pooling: 1 block/graph, 16 waves ----------------
#define POOL_W 16
__global__ void k_pool(const float* __restrict__ latent, const void* __restrict__ batch,
                       const int* __restrict__ flags, float* __restrict__ pooled) {
    int b = blockIdx.x;
    int lane = threadIdx.x & 63;   // channel
    int wave = threadIdx.x >> 6;   // 0..15
    int is64 = flags[1];
    int lo = 0, hi = N_NODES;
    while (lo < hi) { int mid = (lo + hi) >> 1; if (ld_idx(batch, mid, is64) < b) lo = mid + 1; else hi = mid; }
    int start = lo;
    lo = 0; hi = N_NODES;
    while (lo < hi) { int mid = (lo + hi) >> 1; if (ld_idx(batch, mid, is64) < b + 1) lo = mid + 1; else hi = mid; }
    int end = lo;
    float s = 0.f;
    for (int n = start + wave; n < end; n += POOL_W) s += latent[(size_t)n * 64 + lane];
    __shared__ float red[POOL_W][64];
    red[wave][lane] = s;
    __syncthreads();
    if (wave == 0) {
        float t = s;
#pragma unroll
        for (int w2 = 1; w2 < POOL_W; w2++) t += red[w2][lane];
        float cnt = (float)(end - start);
        pooled[b * 64 + lane] = t / fmaxf(cnt, 1.f);
    }
}

// ---------------- classifier head ----------------
__global__ void k_cls(const float* __restrict__ pooled, const float* __restrict__ pb,
                      void* __restrict__ out_dev, long long out_off,
                      const int* __restrict__ flags) {
    int b = threadIdx.x;  // 64 threads, one per graph
    const float* Wc1 = pb + P_WC1;
    const float* bc1 = pb + P_BC1;
    const float* Wc2 = pb + P_WC2;
    const float* bc2 = pb + P_BC2;
    float z[32];
#pragma unroll
    for (int k = 0; k < 32; k++) z[k] = bc1[k];
    for (int c = 0; c < 64; c++) {
        float pv = pooled[b * 64 + c];
#pragma unroll
        for (int k = 0; k < 32; k++) z[k] = fmaf(pv, Wc1[c * 32 + k], z[k]);
    }
#pragma unroll
    for (int k = 0; k < 32; k++) z[k] = fmaxf(z[k], 0.f);
    float n0 = bc2[0], n1 = bc2[1];
#pragma unroll
    for (int k = 0; k < 32; k++) {
        n0 = fmaf(z[k], Wc2[k * 2 + 0], n0);
        n1 = fmaf(z[k], Wc2[k * 2 + 1], n1);
    }
    int isbf = flags[0];
    st_out(out_dev, out_off + b * 2 + 0, n0, isbf);
    st_out(out_dev, out_off + b * 2 + 1, n1, isbf);
}

extern "C" void kernel_launch(void* const* d_in, const int* in_sizes, int n_in,
                              void* d_out, int out_size, void* d_ws, size_t ws_size,
                              hipStream_t stream) {
    const void* x    = d_in[0];
    const void* eidx = d_in[1];
    const void* batch= d_in[2];

    // workspace carve-up (256B aligned)
    char* w = (char*)d_ws;
    size_t o = 0;
    auto carve = [&](size_t bytes) { void* p = w + o; o = (o + bytes + 255) & ~(size_t)255; return p; };
    int* flags    = (int*)carve(8 * sizeof(int));
    int* off      = (int*)carve((N_NODES + 1) * sizeof(int));
    int* counts   = (int*)carve(N_NODES * sizeof(int));
    int* bsum     = (int*)carve(SCAN_NBLK * sizeof(int));
    int* bbase    = (int*)carve(SCAN_NBLK * sizeof(int));
    int* gcur     = (int*)carve(NBUCK * sizeof(int));
    int* ovf_cnt  = (int*)carve(sizeof(int));
    int* csr_send = (int*)carve((size_t)(N_EDGES + N_NODES) * sizeof(int));
    uint2* stage  = (uint2*)carve((size_t)NBUCK * BUCK_CAP * sizeof(uint2));
    uint2* ovf    = (uint2*)carve((size_t)OVF_CAP * sizeof(uint2));
    float* pblock = (float*)carve(P_TOTAL * sizeof(float));
    float* buf0   = (float*)carve((size_t)N_NODES * 128 * sizeof(float));
    unsigned short* hb = (unsigned short*)carve((size_t)N_NODES * 128 * sizeof(unsigned short));
    float* h3     = (float*)carve((size_t)N_NODES * 4 * sizeof(float));
    float* es     = (float*)carve(N_NODES * sizeof(float));
    float* ed     = (float*)carve(N_NODES * sizeof(float));
    float* pooled = (float*)carve(NB * 64 * sizeof(float));

    int gW = N_NODES / 4;                 // wave-per-node kernels

    // init + dtype detect
    k_init_detect<<<1, 256, 0, stream>>>(gcur, ovf_cnt, (const unsigned short*)x,
                                         (const unsigned int*)eidx, flags);

    // params -> f32 block
    PTab tab;
    const int pn[20]  = {384,128,128,128, 8192,64,64,64, 8192,128,128,128, 384,3,3,3, 2048,32,64,2};
    const int pof[20] = {P_W1,P_A1S,P_A1D,P_B1, P_W2,P_A2S,P_A2D,P_B2, P_W3,P_A3S,P_A3D,P_B3,
                         P_W4,P_A4S,P_A4D,P_B4, P_WC1,P_BC1,P_WC2,P_BC2};
    for (int i = 0; i < 20; i++) { tab.src[i] = d_in[3 + i]; tab.off[i] = pof[i]; tab.n[i] = pn[i]; }
    k_cvt_params<<<20, 256, 0, stream>>>(tab, flags, pblock);

    // CSR build (bucketed, zero global atomics after k_bucket)
    k_bucket<<<NBLK1, 256, 0, stream>>>(eidx, flags, gcur, stage, ovf_cnt, ovf);
    k_count2<<<NBUCK, 256, 0, stream>>>(gcur, stage, ovf_cnt, ovf, counts);
    k_scan_a<<<SCAN_NBLK, SCAN_BLK, 0, stream>>>(counts, off, bsum);
    k_scan_b<<<1, SCAN_BLK, 0, stream>>>(bsum, bbase);
    k_scan_c<<<SCAN_NBLK, SCAN_BLK, 0, stream>>>(off, bbase);
    k_fill3<<<NBUCK, 256, 0, stream>>>(gcur, stage, ovf_cnt, ovf, off, csr_send);

    // x -> f32
    k_cvt_x<<<(N_NODES * 3 + 255) / 256, 256, 0, stream>>>(x, flags, buf0);

    // output element offsets
    const long long OFF_RECON = 0, OFF_LATENT = 150000, OFF_NOISE = 3350000;

    // gemm grids: nodes/block = 64 (DOUT=128), 128 (DOUT=64), 256 (DOUT=3)
    int g64  = (N_NODES + 63) / 64;
    int g128 = (N_NODES + 127) / 128;
    int g256 = (N_NODES + 255) / 256;

    // conv1: [N,3] -> [N,128], relu
    k_gemm<3, 128, true><<<g64, 256, 0, stream>>>(buf0, pblock + P_W1, pblock + P_A1S, pblock + P_A1D, hb, es, ed);
    k_wsum128f<true><<<gW, 256, 0, stream>>>(hb, es, ed, pblock + P_B1, off, csr_send, buf0);

    // conv2: [N,128] -> [N,64] (latent)
    k_gemm<128, 64, true><<<g128, 256, 0, stream>>>(buf0, pblock + P_W2, pblock + P_A2S, pblock + P_A2D, hb, es, ed);
    k_wsum64f<<<gW, 256, 0, stream>>>(hb, es, ed, pblock + P_B2, off, csr_send, buf0, d_out, OFF_LATENT, flags);

    // pooling + classifier from f32 latent (buf0)
    k_pool<<<NB, POOL_W * 64, 0, stream>>>(buf0, batch, flags, pooled);
    k_cls<<<1, 64, 0, stream>>>(pooled, pblock, d_out, OFF_NOISE, flags);

    // conv3: [N,64] -> [N,128], relu
    k_gemm<64, 128, true><<<g64, 256, 0, stream>>>(buf0, pblock + P_W3, pblock + P_A3S, pblock + P_A3D, hb, es, ed);
    k_wsum128f<true><<<gW, 256, 0, stream>>>(hb, es, ed, pblock + P_B3, off, csr_send, buf0);

    // conv4: [N,128] -> [N,3] (reconstructed)
    k_gemm<128, 3, false><<<g256, 256, 0, stream>>>(buf0, pblock + P_W4, pblock + P_A4S, pblock + P_A4D, h3, es, ed);
    k_wsum3f<<<gW, 256, 0, stream>>>(h3, es, ed, pblock + P_B4, off, csr_send, d_out, OFF_RECON, flags);
}

// Round 14
// 270.478 us; speedup vs baseline: 3.2023x; 1.0671x over previous
//
#include <hip/hip_runtime.h>
#include <hip/hip_bf16.h>

typedef __hip_bfloat16 bf16;

#define N_NODES 50000
#define N_EDGES 800000
#define NB 64

// bucketed CSR build
#define NBUCK 256
#define BUCK_R ((N_NODES + NBUCK - 1) / NBUCK)            // 196 nodes/bucket
#define BUCK_CAP 4352                                     // mean 3136, +21 sigma
#define OVF_CAP 65536
#define NBLK1 256
#define CHUNK1 ((N_EDGES + NBLK1 - 1) / NBLK1)            // 3125 edges/block
#define NIT ((CHUNK1 + 255) / 256)                        // 13 iters/thread

// k_prep block partition
#define XCVT_BLKS ((N_NODES * 3 + 255) / 256)             // 586
#define PREP_BLKS (XCVT_BLKS + 20 + 1)

// param block offsets (floats)
#define P_W1 0
#define P_A1S 384
#define P_A1D 512
#define P_B1 640
#define P_W2 768
#define P_A2S 8960
#define P_A2D 9024
#define P_B2 9088
#define P_W3 9152
#define P_A3S 17344
#define P_A3D 17472
#define P_B3 17600
#define P_W4 17728
#define P_A4S 18112
#define P_A4D 18115
#define P_B4 18118
#define P_WC1 18121
#define P_BC1 20169
#define P_WC2 20201
#define P_BC2 20265
#define P_TOTAL 20267

__device__ __forceinline__ float wave_sum(float v) {
#pragma unroll
    for (int o = 32; o >= 1; o >>= 1) v += __shfl_xor(v, o, 64);
    return v;
}

// bf16 pack/unpack (bit tricks, no cvt on unpack)
__device__ __forceinline__ unsigned int pk2(float a, float b) {
    bf16 x = __float2bfloat16(a);
    bf16 y = __float2bfloat16(b);
    unsigned short ux = *reinterpret_cast<unsigned short*>(&x);
    unsigned short uy = *reinterpret_cast<unsigned short*>(&y);
    return ((unsigned int)uy << 16) | ux;
}
__device__ __forceinline__ float bf_lo(unsigned int u) {
    unsigned int v = u << 16;
    return *reinterpret_cast<float*>(&v);
}
__device__ __forceinline__ float bf_hi(unsigned int u) {
    unsigned int v = u & 0xffff0000u;
    return *reinterpret_cast<float*>(&v);
}

// runtime dtype helpers: flags[0]=float-inputs-are-bf16, flags[1]=ints-are-int64
__device__ __forceinline__ int ld_idx(const void* p, long long i, int is64) {
    return is64 ? (int)((const long long*)p)[i] : ((const int*)p)[i];
}
__device__ __forceinline__ void st_out(void* p, long long i, float v, int isbf) {
    if (isbf) ((bf16*)p)[i] = __float2bfloat16(v);
    else ((float*)p)[i] = v;
}

// unnormalized attention weight: p = exp(leaky(es+ed)), clamped (clamp inactive
// for sane inputs; guards f32 overflow only)
__device__ __forceinline__ float attn_p(float esv, float edi) {
    float v = esv + edi;
    float e = (v >= 0.f) ? v : 0.2f * v;
    return __expf(fminf(e, 60.f));
}

// ---------------- fused prep: dtype detect (per-block) + param/x cvt + init ----
struct PTab {
    const void* src[20];
    int off[20];
    int n[20];
};

__global__ __launch_bounds__(256) void k_prep(
        const void* __restrict__ x, const void* __restrict__ eidx, PTab tab,
        float* __restrict__ pblock, float* __restrict__ xbuf,
        int* __restrict__ gcur, int* __restrict__ ovf_cnt, int* __restrict__ flags) {
    __shared__ int scnt[2];
    const int t = threadIdx.x;
    if (t < 2) scnt[t] = 0;
    __syncthreads();
    // parallel dtype detection (same addresses every block -> L2 broadcast)
    {
        const unsigned short* xr = (const unsigned short*)x;
        unsigned int hb = (xr[2 * t] >> 8) & 0x7F;
        if (hb >= 58 && hb <= 65) atomicAdd(&scnt[0], 1);
        if (t < 64) {
            const unsigned int* er = (const unsigned int*)eidx;
            if (er[2 * t + 1] == 0u) atomicAdd(&scnt[1], 1);
        }
    }
    __syncthreads();
    const int isbf = (scnt[0] >= 200) ? 1 : 0;
    const int is64 = (scnt[1] >= 60) ? 1 : 0;

    const int b = blockIdx.x;
    if (b < XCVT_BLKS) {
        int i = b * 256 + t;
        if (i < N_NODES * 3)
            xbuf[i] = isbf ? __bfloat162float(((const bf16*)x)[i]) : ((const float*)x)[i];
    } else if (b < XCVT_BLKS + 20) {
        int p = b - XCVT_BLKS;
        const void* s = tab.src[p];
        float* d = pblock + tab.off[p];
        int n = tab.n[p];
        for (int i = t; i < n; i += 256)
            d[i] = isbf ? __bfloat162float(((const bf16*)s)[i]) : ((const float*)s)[i];
    } else {
        if (t < NBUCK) gcur[t] = 0;
        if (t == 0) { *ovf_cnt = 0; flags[0] = isbf; flags[1] = is64; }
    }
}

// ---------------- bucket phase: edges -> per-bucket staging (packed uint) ------
__global__ __launch_bounds__(256) void k_bucket(
        const void* __restrict__ eidx, const int* __restrict__ flags,
        int* __restrict__ gcur, unsigned int* __restrict__ stage,
        int* __restrict__ ovf_cnt, uint2* __restrict__ ovf) {
    __shared__ int hist[NBUCK];
    __shared__ int base[NBUCK];
    const int t = threadIdx.x;
    const int is64 = flags[1];
    const int e0 = blockIdx.x * CHUNK1;
    const int e1 = min(e0 + CHUNK1, N_EDGES);

    unsigned int ent[NIT];
    int bk[NIT];
    hist[t] = 0;
    __syncthreads();
#pragma unroll
    for (int it = 0; it < NIT; it++) {
        int e = e0 + t + it * 256;
        int b = -1;
        unsigned int en = 0;
        if (e < e1) {
            int r = ld_idx(eidx, (long long)N_EDGES + e, is64);
            int s = ld_idx(eidx, e, is64);
            b = r / BUCK_R;
            en = ((unsigned)(r - b * BUCK_R) << 16) | (unsigned)s;
            atomicAdd(&hist[b], 1);
        }
        ent[it] = en;
        bk[it] = b;
    }
    __syncthreads();
    int cnt = hist[t];
    base[t] = (cnt > 0) ? atomicAdd(&gcur[t], cnt) : 0;
    __syncthreads();
    hist[t] = 0;  // reuse as within-block running index
    __syncthreads();
#pragma unroll
    for (int it = 0; it < NIT; it++) {
        int b = bk[it];
        if (b >= 0) {
            int l = atomicAdd(&hist[b], 1);
            int slot = base[b] + l;
            if (slot < BUCK_CAP) {
                stage[(size_t)b * BUCK_CAP + slot] = ent[it];
            } else {
                int oi = atomicAdd(ovf_cnt, 1);
                int r = b * BUCK_R + (int)(ent[it] >> 16);
                if (oi < OVF_CAP) ovf[oi] = make_uint2(ent[it] & 0xffffu, (unsigned)r);
            }
        }
    }
}

// ---------------- counts + bucket-local exclusive scan (LDS) -------------------
__global__ __launch_bounds__(256) void k_count2(
        const int* __restrict__ gcur, const unsigned int* __restrict__ stage,
        const int* __restrict__ ovf_cnt, const uint2* __restrict__ ovf,
        int* __restrict__ loff, int* __restrict__ bsum) {
    __shared__ int hist[256];
    __shared__ int ss[256];
    const int b = blockIdx.x;
    const int r0 = b * BUCK_R;
    const int nr = min(BUCK_R, N_NODES - r0);
    const int t = threadIdx.x;
    hist[t] = 0;
    __syncthreads();
    const int cnt = min(gcur[b], BUCK_CAP);
    const unsigned int* sb = stage + (size_t)b * BUCK_CAP;
    for (int i = t; i < cnt; i += 256) atomicAdd(&hist[sb[i] >> 16], 1);
    int oc = min(*ovf_cnt, OVF_CAP);
    for (int i = t; i < oc; i += 256) {
        int r = (int)ovf[i].y;
        if (r >= r0 && r < r0 + nr) atomicAdd(&hist[r - r0], 1);
    }
    __syncthreads();
    int v = (t < nr) ? hist[t] + 1 : 0;  // +1 self loop
    ss[t] = v;
    __syncthreads();
#pragma unroll
    for (int o = 1; o < 256; o <<= 1) {
        int add = (t >= o) ? ss[t - o] : 0;
        __syncthreads();
        ss[t] += add;
        __syncthreads();
    }
    if (t < nr) loff[r0 + t] = ss[t] - v;  // exclusive local start
    if (t == 255) bsum[b] = ss[255];
}

// ---------------- scan bucket totals (1 block) ----------------
__global__ void k_scan_b(const int* __restrict__ bsum, int* __restrict__ bbase,
                         int* __restrict__ off) {
    __shared__ int s[NBUCK];
    int t = threadIdx.x;
    int v = bsum[t];
    s[t] = v;
    __syncthreads();
#pragma unroll
    for (int o = 1; o < NBUCK; o <<= 1) {
        int add = (t >= o) ? s[t - o] : 0;
        __syncthreads();
        s[t] += add;
        __syncthreads();
    }
    bbase[t] = s[t] - v;  // exclusive
    if (t == NBUCK - 1) off[N_NODES] = s[t];
}

// ---------------- fill: final off + self-loops + staged scatter (LDS cursors) ---
__global__ __launch_bounds__(256) void k_fill3(
        const int* __restrict__ gcur, const unsigned int* __restrict__ stage,
        const int* __restrict__ ovf_cnt, const uint2* __restrict__ ovf,
        const int* __restrict__ loff, const int* __restrict__ bbase,
        int* __restrict__ off, int* __restrict__ csr_send) {
    __shared__ int sstart[BUCK_R];
    __shared__ int lcur[BUCK_R];
    const int b = blockIdx.x;
    const int r0 = b * BUCK_R;
    const int nr = min(BUCK_R, N_NODES - r0);
    const int bb = bbase[b];
    for (int i = threadIdx.x; i < nr; i += 256) {
        int st = bb + loff[r0 + i];
        sstart[i] = st;
        off[r0 + i] = st;           // finalized global off
        lcur[i] = 1;
        csr_send[st] = r0 + i;      // self loop in slot 0
    }
    __syncthreads();
    const int cnt = min(gcur[b], BUCK_CAP);
    const unsigned int* sb = stage + (size_t)b * BUCK_CAP;
    for (int i = threadIdx.x; i < cnt; i += 256) {
        unsigned int e = sb[i];
        int rl = (int)(e >> 16);
        int l = atomicAdd(&lcur[rl], 1);
        csr_send[sstart[rl] + l] = (int)(e & 0xffffu);
    }
    int oc = min(*ovf_cnt, OVF_CAP);
    for (int i = threadIdx.x; i < oc; i += 256) {
        uint2 pr = ovf[i];
        int r = (int)pr.y;
        if (r >= r0 && r < r0 + nr) {
            int rl = r - r0;
            int l = atomicAdd(&lcur[rl], 1);
            csr_send[sstart[rl] + l] = (int)pr.x;
        }
    }
}

// ---------------- register-tiled linear + attention coefficients ----------------
template <int DIN, int DOUT, bool HB16>
__global__ __launch_bounds__(256) void k_gemm(
        const float* __restrict__ in, const float* __restrict__ W,
        const float* __restrict__ as_, const float* __restrict__ ad_,
        void* __restrict__ hout, float* __restrict__ es, float* __restrict__ ed) {
    constexpr int KC = (DIN < 32) ? DIN : 32;     // K-chunk
    constexpr int NCH = DIN / KC;                 // chunks
    constexpr int CG = (DOUT >= 64) ? (DOUT / 8) : 1;      // col groups
    constexpr int NT = (DOUT >= 64) ? ((256 / CG) * 4) : 256;  // nodes/block
    constexpr int NTP = NT + 4;                   // pad

    __shared__ float sX[KC][NTP];   // transposed x chunk
    __shared__ float sW[KC][DOUT];  // W chunk

    const int t = threadIdx.x;
    const int node0 = blockIdx.x * NT;
    const int nvalid = min(NT, N_NODES - node0);

    const int cg = t & (CG - 1);
    const int ng = t / CG;

    float acc[4][8] = {};

    for (int ch = 0; ch < NCH; ch++) {
        const int k0 = ch * KC;
        if (ch > 0) __syncthreads();
        for (int i = t; i < nvalid * KC; i += 256) {
            int n = i / KC, k = i - n * KC;
            sX[k][n] = in[(size_t)(node0 + n) * DIN + k0 + k];
        }
        for (int i = t; i < KC * DOUT; i += 256) {
            int k = i / DOUT, c = i - k * DOUT;
            sW[k][c] = W[(size_t)(k0 + k) * DOUT + c];
        }
        __syncthreads();

        if constexpr (DOUT >= 64) {
#pragma unroll 4
            for (int k = 0; k < KC; k++) {
                float4 xv = *(const float4*)&sX[k][ng * 4];
                float4 w0 = *(const float4*)&sW[k][cg * 8];
                float4 w1 = *(const float4*)&sW[k][cg * 8 + 4];
                float xs[4] = {xv.x, xv.y, xv.z, xv.w};
                float ws[8] = {w0.x, w0.y, w0.z, w0.w, w1.x, w1.y, w1.z, w1.w};
#pragma unroll
                for (int j = 0; j < 4; j++)
#pragma unroll
                    for (int c = 0; c < 8; c++)
                        acc[j][c] = fmaf(xs[j], ws[c], acc[j][c]);
            }
        } else {
#pragma unroll 4
            for (int k = 0; k < KC; k++) {
                float xv = sX[k][t];
#pragma unroll
                for (int c = 0; c < DOUT; c++)
                    acc[0][c] = fmaf(xv, sW[k][c], acc[0][c]);
            }
        }
    }

    if constexpr (DOUT >= 64) {
        float asv[8], adv[8];
#pragma unroll
        for (int c = 0; c < 8; c++) {
            asv[c] = as_[cg * 8 + c];
            adv[c] = ad_[cg * 8 + c];
        }
#pragma unroll
        for (int j = 0; j < 4; j++) {
            int n = ng * 4 + j;
            float e_s = 0.f, e_d = 0.f;
#pragma unroll
            for (int c = 0; c < 8; c++) {
                e_s = fmaf(acc[j][c], asv[c], e_s);
                e_d = fmaf(acc[j][c], adv[c], e_d);
            }
#pragma unroll
            for (int m = 1; m < CG; m <<= 1) {
                e_s += __shfl_xor(e_s, m, 64);
                e_d += __shfl_xor(e_d, m, 64);
            }
            if (n < nvalid) {
                if (cg == 0) {
                    es[node0 + n] = e_s;
                    ed[node0 + n] = e_d;
                }
                if constexpr (HB16) {
                    unsigned short* hb = (unsigned short*)hout;
                    uint4 u;
                    u.x = pk2(acc[j][0], acc[j][1]);
                    u.y = pk2(acc[j][2], acc[j][3]);
                    u.z = pk2(acc[j][4], acc[j][5]);
                    u.w = pk2(acc[j][6], acc[j][7]);
                    *(uint4*)&hb[(size_t)(node0 + n) * DOUT + cg * 8] = u;
                } else {
                    float* h = (float*)hout;
                    float4 v0 = {acc[j][0], acc[j][1], acc[j][2], acc[j][3]};
                    float4 v1 = {acc[j][4], acc[j][5], acc[j][6], acc[j][7]};
                    *(float4*)&h[(size_t)(node0 + n) * DOUT + cg * 8] = v0;
                    *(float4*)&h[(size_t)(node0 + n) * DOUT + cg * 8 + 4] = v1;
                }
            }
        }
    } else {
        if (t < nvalid) {
            int node = node0 + t;
            float e_s = 0.f, e_d = 0.f;
#pragma unroll
            for (int c = 0; c < DOUT; c++) {
                e_s = fmaf(acc[0][c], as_[c], e_s);
                e_d = fmaf(acc[0][c], ad_[c], e_d);
            }
            es[node] = e_s;
            ed[node] = e_d;
            float* h = (float*)hout;
            float4 v = {acc[0][0], acc[0][1], acc[0][2], 0.f};  // stride-4 padded
            *(float4*)&h[(size_t)node * 4] = v;
        }
    }
}

// ---------------- one-pass softmax + weighted sum, DOUT=128, bf16 h ------------
// paired rows + unroll-4: 4 uint2 gathers in flight per lane.
template <bool RELU_OUT>
__global__ __launch_bounds__(256) void k_wsum128f(
        const unsigned short* __restrict__ hb, const float* __restrict__ es,
        const float* __restrict__ ed, const float* __restrict__ bias,
        const int* __restrict__ off, const int* __restrict__ csr_send,
        float* __restrict__ out) {
    int wid = threadIdx.x >> 6, lane = threadIdx.x & 63;
    int node = blockIdx.x * 4 + wid;
    if (node >= N_NODES) return;
    int start = off[node], end = off[node + 1];
    float edi = ed[node];

    const int hf = lane >> 5;
    const int hl = lane & 31;
    float4 a0 = {0.f, 0.f, 0.f, 0.f}, a1 = {0.f, 0.f, 0.f, 0.f};
    float4 a2 = {0.f, 0.f, 0.f, 0.f}, a3 = {0.f, 0.f, 0.f, 0.f};
    float sl = 0.f;

    for (int base = start; base < end; base += 64) {
        int j = base + lane;
        bool valid = j < end;
        int src = valid ? csr_send[j] : 0;
        float p = valid ? attn_p(es[src], edi) : 0.f;
        sl += p;
        int cnt = min(64, end - base);
        int npr = (cnt + 1) >> 1;
        int j2 = 0;
        for (; j2 + 4 <= npr; j2 += 4) {
            int qA = 2 * j2 + hf;
            float pA = __shfl(p, qA, 64);     int sA = __shfl(src, qA, 64);
            float pB = __shfl(p, qA + 2, 64); int sB = __shfl(src, qA + 2, 64);
            float pC = __shfl(p, qA + 4, 64); int sC = __shfl(src, qA + 4, 64);
            float pD = __shfl(p, qA + 6, 64); int sD = __shfl(src, qA + 6, 64);
            uint2 uA = *((const uint2*)(hb + (size_t)sA * 128) + hl);
            uint2 uB = *((const uint2*)(hb + (size_t)sB * 128) + hl);
            uint2 uC = *((const uint2*)(hb + (size_t)sC * 128) + hl);
            uint2 uD = *((const uint2*)(hb + (size_t)sD * 128) + hl);
            a0.x = fmaf(pA, bf_lo(uA.x), a0.x); a0.y = fmaf(pA, bf_hi(uA.x), a0.y);
            a0.z = fmaf(pA, bf_lo(uA.y), a0.z); a0.w = fmaf(pA, bf_hi(uA.y), a0.w);
            a1.x = fmaf(pB, bf_lo(uB.x), a1.x); a1.y = fmaf(pB, bf_hi(uB.x), a1.y);
            a1.z = fmaf(pB, bf_lo(uB.y), a1.z); a1.w = fmaf(pB, bf_hi(uB.y), a1.w);
            a2.x = fmaf(pC, bf_lo(uC.x), a2.x); a2.y = fmaf(pC, bf_hi(uC.x), a2.y);
            a2.z = fmaf(pC, bf_lo(uC.y), a2.z); a2.w = fmaf(pC, bf_hi(uC.y), a2.w);
            a3.x = fmaf(pD, bf_lo(uD.x), a3.x); a3.y = fmaf(pD, bf_hi(uD.x), a3.y);
            a3.z = fmaf(pD, bf_lo(uD.y), a3.z); a3.w = fmaf(pD, bf_hi(uD.y), a3.w);
        }
        for (; j2 < npr; j2++) {
            int q = 2 * j2 + hf;
            float pq = __shfl(p, q, 64); int sq = __shfl(src, q, 64);
            uint2 u = *((const uint2*)(hb + (size_t)sq * 128) + hl);
            a0.x = fmaf(pq, bf_lo(u.x), a0.x); a0.y = fmaf(pq, bf_hi(u.x), a0.y);
            a0.z = fmaf(pq, bf_lo(u.y), a0.z); a0.w = fmaf(pq, bf_hi(u.y), a0.w);
        }
    }
    float S = wave_sum(sl);
    float inv = 1.f / S;
    float4 r;
    r.x = (a0.x + a1.x) + (a2.x + a3.x);
    r.y = (a0.y + a1.y) + (a2.y + a3.y);
    r.z = (a0.z + a1.z) + (a2.z + a3.z);
    r.w = (a0.w + a1.w) + (a2.w + a3.w);
    r.x += __shfl_xor(r.x, 32, 64);
    r.y += __shfl_xor(r.y, 32, 64);
    r.z += __shfl_xor(r.z, 32, 64);
    r.w += __shfl_xor(r.w, 32, 64);
    if (hf == 0) {
        float4 b = ((const float4*)bias)[hl];
        r.x = fmaf(r.x, inv, b.x); r.y = fmaf(r.y, inv, b.y);
        r.z = fmaf(r.z, inv, b.z); r.w = fmaf(r.w, inv, b.w);
        if (RELU_OUT) {
            r.x = fmaxf(r.x, 0.f); r.y = fmaxf(r.y, 0.f);
            r.z = fmaxf(r.z, 0.f); r.w = fmaxf(r.w, 0.f);
        }
        ((float4*)(out + (size_t)node * 128))[hl] = r;
    }
}

// ---------------- one-pass softmax + weighted sum, DOUT=64, bf16 h -------------
__global__ __launch_bounds__(256) void k_wsum64f(
        const unsigned short* __restrict__ hb, const float* __restrict__ es,
        const float* __restrict__ ed, const float* __restrict__ bias,
        const int* __restrict__ off, const int* __restrict__ csr_send,
        float* __restrict__ out, void* __restrict__ out_dev, long long out_off,
        const int* __restrict__ flags) {
    int wid = threadIdx.x >> 6, lane = threadIdx.x & 63;
    int node = blockIdx.x * 4 + wid;
    if (node >= N_NODES) return;
    int start = off[node], end = off[node + 1];
    float edi = ed[node];

    const int qd = lane >> 4;
    const int ql = lane & 15;
    float4 a0 = {0.f, 0.f, 0.f, 0.f}, a1 = {0.f, 0.f, 0.f, 0.f};
    float4 a2 = {0.f, 0.f, 0.f, 0.f}, a3 = {0.f, 0.f, 0.f, 0.f};
    float sl = 0.f;

    for (int base = start; base < end; base += 64) {
        int j = base + lane;
        bool valid = j < end;
        int src = valid ? csr_send[j] : 0;
        float p = valid ? attn_p(es[src], edi) : 0.f;
        sl += p;
        int cnt = min(64, end - base);
        int nq = (cnt + 3) >> 2;
        int j2 = 0;
        for (; j2 + 4 <= nq; j2 += 4) {
            int qA = 4 * j2 + qd;
            float pA = __shfl(p, qA, 64);      int sA = __shfl(src, qA, 64);
            float pB = __shfl(p, qA + 4, 64);  int sB = __shfl(src, qA + 4, 64);
            float pC = __shfl(p, qA + 8, 64);  int sC = __shfl(src, qA + 8, 64);
            float pD = __shfl(p, qA + 12, 64); int sD = __shfl(src, qA + 12, 64);
            uint2 uA = *((const uint2*)(hb + (size_t)sA * 64) + ql);
            uint2 uB = *((const uint2*)(hb + (size_t)sB * 64) + ql);
            uint2 uC = *((const uint2*)(hb + (size_t)sC * 64) + ql);
            uint2 uD = *((const uint2*)(hb + (size_t)sD * 64) + ql);
            a0.x = fmaf(pA, bf_lo(uA.x), a0.x); a0.y = fmaf(pA, bf_hi(uA.x), a0.y);
            a0.z = fmaf(pA, bf_lo(uA.y), a0.z); a0.w = fmaf(pA, bf_hi(uA.y), a0.w);
            a1.x = fmaf(pB, bf_lo(uB.x), a1.x); a1.y = fmaf(pB, bf_hi(uB.x), a1.y);
            a1.z = fmaf(pB, bf_lo(uB.y), a1.z); a1.w = fmaf(pB, bf_hi(uB.y), a1.w);
            a2.x = fmaf(pC, bf_lo(uC.x), a2.x); a2.y = fmaf(pC, bf_hi(uC.x), a2.y);
            a2.z = fmaf(pC, bf_lo(uC.y), a2.z); a2.w = fmaf(pC, bf_hi(uC.y), a2.w);
            a3.x = fmaf(pD, bf_lo(uD.x), a3.x); a3.y = fmaf(pD, bf_hi(uD.x), a3.y);
            a3.z = fmaf(pD, bf_lo(uD.y), a3.z); a3.w = fmaf(pD, bf_hi(uD.y), a3.w);
        }
        for (; j2 < nq; j2++) {
            int q = 4 * j2 + qd;
            float pq = __shfl(p, q, 64); int sq = __shfl(src, q, 64);
            uint2 u = *((const uint2*)(hb + (size_t)sq * 64) + ql);
            a0.x = fmaf(pq, bf_lo(u.x), a0.x); a0.y = fmaf(pq, bf_hi(u.x), a0.y);
            a0.z = fmaf(pq, bf_lo(u.y), a0.z); a0.w = fmaf(pq, bf_hi(u.y), a0.w);
        }
    }
    float S = wave_sum(sl);
    float inv = 1.f / S;
    float4 r;
    r.x = (a0.x + a1.x) + (a2.x + a3.x);
    r.y = (a0.y + a1.y) + (a2.y + a3.y);
    r.z = (a0.z + a1.z) + (a2.z + a3.z);
    r.w = (a0.w + a1.w) + (a2.w + a3.w);
    r.x += __shfl_xor(r.x, 16, 64); r.y += __shfl_xor(r.y, 16, 64);
    r.z += __shfl_xor(r.z, 16, 64); r.w += __shfl_xor(r.w, 16, 64);
    r.x += __shfl_xor(r.x, 32, 64); r.y += __shfl_xor(r.y, 32, 64);
    r.z += __shfl_xor(r.z, 32, 64); r.w += __shfl_xor(r.w, 32, 64);
    if (qd == 0) {
        float4 b = ((const float4*)bias)[ql];
        r.x = fmaf(r.x, inv, b.x); r.y = fmaf(r.y, inv, b.y);
        r.z = fmaf(r.z, inv, b.z); r.w = fmaf(r.w, inv, b.w);
        ((float4*)(out + (size_t)node * 64))[ql] = r;
        if (out_dev) {
            int isbf = flags[0];
            long long o4 = out_off + (long long)node * 64 + 4 * ql;
            st_out(out_dev, o4 + 0, r.x, isbf);
            st_out(out_dev, o4 + 1, r.y, isbf);
            st_out(out_dev, o4 + 2, r.z, isbf);
            st_out(out_dev, o4 + 3, r.w, isbf);
        }
    }
}

// ---------------- one-pass softmax + weighted sum, DOUT=3 (edge-parallel) ------
__global__ __launch_bounds__(256) void k_wsum3f(
        const float* __restrict__ h, const float* __restrict__ es,
        const float* __restrict__ ed, const float* __restrict__ bias,
        const int* __restrict__ off, const int* __restrict__ csr_send,
        void* __restrict__ out_dev, long long out_off, const int* __restrict__ flags) {
    int wid = threadIdx.x >> 6, lane = threadIdx.x & 63;
    int node = blockIdx.x * 4 + wid;
    if (node >= N_NODES) return;
    int start = off[node], end = off[node + 1];
    float edi = ed[node];

    float a0 = 0.f, a1 = 0.f, a2 = 0.f, sl = 0.f;
    for (int j = start + lane; j < end; j += 64) {
        int s = csr_send[j];
        float p = attn_p(es[s], edi);
        sl += p;
        float4 rv = *(const float4*)(h + (size_t)s * 4);
        a0 = fmaf(p, rv.x, a0);
        a1 = fmaf(p, rv.y, a1);
        a2 = fmaf(p, rv.z, a2);
    }
    float S = wave_sum(sl);
    a0 = wave_sum(a0);
    a1 = wave_sum(a1);
    a2 = wave_sum(a2);
    if (lane < 3) {
        float inv = 1.f / S;
        float v = fmaf((lane == 0 ? a0 : (lane == 1 ? a1 : a2)), inv, bias[lane]);
        st_out(out_dev, out_off + (long long)node * 3 + lane, v, flags[0]);
    }
}

// ---------------- per-graph mean pooling: 1 block/graph, 16 waves ----------------
#define POOL_W 16
__global__ void k_pool(const float* __restrict__ latent, const void* __restrict__ batch,
                       const int* __restrict__ flags, float* __restrict__ pooled) {
    int b = blockIdx.x;
    int lane = threadIdx.x & 63;   // channel
    int wave = threadIdx.x >> 6;   // 0..15
    int is64 = flags[1];
    int lo = 0, hi = N_NODES;
    while (lo < hi) { int mid = (lo + hi) >> 1; if (ld_idx(batch, mid, is64) < b) lo = mid + 1; else hi = mid; }
    int start = lo;
    lo = 0; hi = N_NODES;
    while (lo < hi) { int mid = (lo + hi) >> 1; if (ld_idx(batch, mid, is64) < b + 1) lo = mid + 1; else hi = mid; }
    int end = lo;
    float s = 0.f;
    for (int n = start + wave; n < end; n += POOL_W) s += latent[(size_t)n * 64 + lane];
    __shared__ float red[POOL_W][64];
    red[wave][lane] = s;
    __syncthreads();
    if (wave == 0) {
        float t = s;
#pragma unroll
        for (int w2 = 1; w2 < POOL_W; w2++) t += red[w2][lane];
        float cnt = (float)(end - start);
        pooled[b * 64 + lane] = t / fmaxf(cnt, 1.f);
    }
}

// ---------------- classifier head ----------------
__global__ void k_cls(const float* __restrict__ pooled, const float* __restrict__ pb,
                      void* __restrict__ out_dev, long long out_off,
                      const int* __restrict__ flags) {
    int b = threadIdx.x;  // 64 threads, one per graph
    const float* Wc1 = pb + P_WC1;
    const float* bc1 = pb + P_BC1;
    const float* Wc2 = pb + P_WC2;
    const float* bc2 = pb + P_BC2;
    float z[32];
#pragma unroll
    for (int k = 0; k < 32; k++) z[k] = bc1[k];
    for (int c = 0; c < 64; c++) {
        float pv = pooled[b * 64 + c];
#pragma unroll
        for (int k = 0; k < 32; k++) z[k] = fmaf(pv, Wc1[c * 32 + k], z[k]);
    }
#pragma unroll
    for (int k = 0; k < 32; k++) z[k] = fmaxf(z[k], 0.f);
    float n0 = bc2[0], n1 = bc2[1];
#pragma unroll
    for (int k = 0; k < 32; k++) {
        n0 = fmaf(z[k], Wc2[k * 2 + 0], n0);
        n1 = fmaf(z[k], Wc2[k * 2 + 1], n1);
    }
    int isbf = flags[0];
    st_out(out_dev, out_off + b * 2 + 0, n0, isbf);
    st_out(out_dev, out_off + b * 2 + 1, n1, isbf);
}

extern "C" void kernel_launch(void* const* d_in, const int* in_sizes, int n_in,
                              void* d_out, int out_size, void* d_ws, size_t ws_size,
                              hipStream_t stream) {
    const void* x    = d_in[0];
    const void* eidx = d_in[1];
    const void* batch= d_in[2];

    // workspace carve-up (256B aligned)
    char* w = (char*)d_ws;
    size_t o = 0;
    auto carve = [&](size_t bytes) { void* p = w + o; o = (o + bytes + 255) & ~(size_t)255; return p; };
    int* flags    = (int*)carve(8 * sizeof(int));
    int* off      = (int*)carve((N_NODES + 1) * sizeof(int));
    int* loff     = (int*)carve(N_NODES * sizeof(int));
    int* bsum     = (int*)carve(NBUCK * sizeof(int));
    int* bbase    = (int*)carve(NBUCK * sizeof(int));
    int* gcur     = (int*)carve(NBUCK * sizeof(int));
    int* ovf_cnt  = (int*)carve(sizeof(int));
    int* csr_send = (int*)carve((size_t)(N_EDGES + N_NODES) * sizeof(int));
    unsigned int* stage = (unsigned int*)carve((size_t)NBUCK * BUCK_CAP * sizeof(unsigned int));
    uint2* ovf    = (uint2*)carve((size_t)OVF_CAP * sizeof(uint2));
    float* pblock = (float*)carve(P_TOTAL * sizeof(float));
    float* buf0   = (float*)carve((size_t)N_NODES * 128 * sizeof(float));
    unsigned short* hb = (unsigned short*)carve((size_t)N_NODES * 128 * sizeof(unsigned short));
    float* h3     = (float*)carve((size_t)N_NODES * 4 * sizeof(float));
    float* es     = (float*)carve(N_NODES * sizeof(float));
    float* ed     = (float*)carve(N_NODES * sizeof(float));
    float* pooled = (float*)carve(NB * 64 * sizeof(float));

    int gW = N_NODES / 4;                 // wave-per-node kernels

    // fused prep: detect + param cvt + x cvt + init
    PTab tab;
    const int pn[20]  = {384,128,128,128, 8192,64,64,64, 8192,128,128,128, 384,3,3,3, 2048,32,64,2};
    const int pof[20] = {P_W1,P_A1S,P_A1D,P_B1, P_W2,P_A2S,P_A2D,P_B2, P_W3,P_A3S,P_A3D,P_B3,
                         P_W4,P_A4S,P_A4D,P_B4, P_WC1,P_BC1,P_WC2,P_BC2};
    for (int i = 0; i < 20; i++) { tab.src[i] = d_in[3 + i]; tab.off[i] = pof[i]; tab.n[i] = pn[i]; }
    k_prep<<<PREP_BLKS, 256, 0, stream>>>(x, eidx, tab, pblock, buf0, gcur, ovf_cnt, flags);

    // CSR build (bucketed; scan fused into count2/fill3)
    k_bucket<<<NBLK1, 256, 0, stream>>>(eidx, flags, gcur, stage, ovf_cnt, ovf);
    k_count2<<<NBUCK, 256, 0, stream>>>(gcur, stage, ovf_cnt, ovf, loff, bsum);
    k_scan_b<<<1, NBUCK, 0, stream>>>(bsum, bbase, off);
    k_fill3<<<NBUCK, 256, 0, stream>>>(gcur, stage, ovf_cnt, ovf, loff, bbase, off, csr_send);

    // output element offsets
    const long long OFF_RECON = 0, OFF_LATENT = 150000, OFF_NOISE = 3350000;

    // gemm grids: nodes/block = 64 (DOUT=128), 128 (DOUT=64), 256 (DOUT=3)
    int g64  = (N_NODES + 63) / 64;
    int g128 = (N_NODES + 127) / 128;
    int g256 = (N_NODES + 255) / 256;

    // conv1: [N,3] -> [N,128], relu
    k_gemm<3, 128, true><<<g64, 256, 0, stream>>>(buf0, pblock + P_W1, pblock + P_A1S, pblock + P_A1D, hb, es, ed);
    k_wsum128f<true><<<gW, 256, 0, stream>>>(hb, es, ed, pblock + P_B1, off, csr_send, buf0);

    // conv2: [N,128] -> [N,64] (latent)
    k_gemm<128, 64, true><<<g128, 256, 0, stream>>>(buf0, pblock + P_W2, pblock + P_A2S, pblock + P_A2D, hb, es, ed);
    k_wsum64f<<<gW, 256, 0, stream>>>(hb, es, ed, pblock + P_B2, off, csr_send, buf0, d_out, OFF_LATENT, flags);

    // pooling + classifier from f32 latent (buf0)
    k_pool<<<NB, POOL_W * 64, 0, stream>>>(buf0, batch, flags, pooled);
    k_cls<<<1, 64, 0, stream>>>(pooled, pblock, d_out, OFF_NOISE, flags);

    // conv3: [N,64] -> [N,128], relu
    k_gemm<64, 128, true><<<g64, 256, 0, stream>>>(buf0, pblock + P_W3, pblock + P_A3S, pblock + P_A3D, hb, es, ed);
    k_wsum128f<true><<<gW, 256, 0, stream>>>(hb, es, ed, pblock + P_B3, off, csr_send, buf0);

    // conv4: [N,128] -> [N,3] (reconstructed)
    k_gemm<128, 3, false><<<g256, 256, 0, stream>>>(buf0, pblock + P_W4, pblock + P_A4S, pblock + P_A4D, h3, es, ed);
    k_wsum3f<<<gW, 256, 0, stream>>>(h3, es, ed, pblock + P_B4, off, csr_send, d_out, OFF_RECON, flags);
}

// Round 15
// 251.318 us; speedup vs baseline: 3.4464x; 1.0762x over previous
//
#include <hip/hip_runtime.h>
#include <hip/hip_bf16.h>

typedef __hip_bfloat16 bf16;

#define N_NODES 50000
#define N_EDGES 800000
#define NB 64

// bucketed CSR build
#define NBUCK 256
#define BUCK_R ((N_NODES + NBUCK - 1) / NBUCK)            // 196 nodes/bucket
#define BUCK_CAP 4352                                     // mean 3136, +21 sigma
#define OVF_CAP 65536
#define NBLK1 256
#define CHUNK1 ((N_EDGES + NBLK1 - 1) / NBLK1)            // 3125 edges/block
#define NIT ((CHUNK1 + 255) / 256)                        // 13 iters/thread

// k_prep block partition (x-phase is node-based now)
#define XN_BLKS ((N_NODES + 255) / 256)                   // 196
#define PREP_BLKS (XN_BLKS + 20 + 1)

// param block offsets (floats)
#define P_W1 0
#define P_A1S 384
#define P_A1D 512
#define P_B1 640
#define P_W2 768
#define P_A2S 8960
#define P_A2D 9024
#define P_B2 9088
#define P_W3 9152
#define P_A3S 17344
#define P_A3D 17472
#define P_B3 17600
#define P_W4 17728
#define P_A4S 18112
#define P_A4D 18115
#define P_B4 18118
#define P_WC1 18121
#define P_BC1 20169
#define P_WC2 20201
#define P_BC2 20265
// extension: factored attention vectors
#define P_W1S 20272
#define P_W1D 20276
#define P_W3S 20280
#define P_W3D 20344
#define P_TOTAL 20408

__device__ __forceinline__ float wave_sum(float v) {
#pragma unroll
    for (int o = 32; o >= 1; o >>= 1) v += __shfl_xor(v, o, 64);
    return v;
}

__device__ __forceinline__ unsigned int pk2(float a, float b) {
    bf16 x = __float2bfloat16(a);
    bf16 y = __float2bfloat16(b);
    unsigned short ux = *reinterpret_cast<unsigned short*>(&x);
    unsigned short uy = *reinterpret_cast<unsigned short*>(&y);
    return ((unsigned int)uy << 16) | ux;
}
__device__ __forceinline__ float bf_lo(unsigned int u) {
    unsigned int v = u << 16;
    return *reinterpret_cast<float*>(&v);
}
__device__ __forceinline__ float bf_hi(unsigned int u) {
    unsigned int v = u & 0xffff0000u;
    return *reinterpret_cast<float*>(&v);
}

// runtime dtype helpers: flags[0]=float-inputs-are-bf16, flags[1]=ints-are-int64
__device__ __forceinline__ int ld_idx(const void* p, long long i, int is64) {
    return is64 ? (int)((const long long*)p)[i] : ((const int*)p)[i];
}
__device__ __forceinline__ float ldf(const void* p, int i, int isbf) {
    return isbf ? __bfloat162float(((const bf16*)p)[i]) : ((const float*)p)[i];
}
__device__ __forceinline__ void st_out(void* p, long long i, float v, int isbf) {
    if (isbf) ((bf16*)p)[i] = __float2bfloat16(v);
    else ((float*)p)[i] = v;
}

// unnormalized attention weight
__device__ __forceinline__ float attn_p(float esv, float edi) {
    float v = esv + edi;
    float e = (v >= 0.f) ? v : 0.2f * v;
    return __expf(fminf(e, 60.f));
}

// ---------------- fused prep ----------------
struct PTab {
    const void* src[20];
    int off[20];
    int n[20];
};

__global__ __launch_bounds__(256) void k_prep(
        const void* __restrict__ x, const void* __restrict__ eidx,
        const void* __restrict__ rW1, const void* __restrict__ rA1s,
        const void* __restrict__ rA1d, const void* __restrict__ rW3,
        const void* __restrict__ rA3s, const void* __restrict__ rA3d,
        PTab tab, float* __restrict__ pblock, float* __restrict__ x4,
        int* __restrict__ gcur, int* __restrict__ ovf_cnt, int* __restrict__ flags) {
    __shared__ int scnt[2];
    const int t = threadIdx.x;
    if (t < 2) scnt[t] = 0;
    __syncthreads();
    {
        const unsigned short* xr = (const unsigned short*)x;
        unsigned int hb = (xr[2 * t] >> 8) & 0x7F;
        if (hb >= 58 && hb <= 65) atomicAdd(&scnt[0], 1);
        if (t < 64) {
            const unsigned int* er = (const unsigned int*)eidx;
            if (er[2 * t + 1] == 0u) atomicAdd(&scnt[1], 1);
        }
    }
    __syncthreads();
    const int isbf = (scnt[0] >= 200) ? 1 : 0;
    const int is64 = (scnt[1] >= 60) ? 1 : 0;

    const int b = blockIdx.x;
    if (b < XN_BLKS) {
        int node = b * 256 + t;
        if (node < N_NODES) {
            float4 v;
            v.x = ldf(x, node * 3 + 0, isbf);
            v.y = ldf(x, node * 3 + 1, isbf);
            v.z = ldf(x, node * 3 + 2, isbf);
            v.w = 0.f;
            *(float4*)&x4[node * 4] = v;
        }
    } else if (b < XN_BLKS + 20) {
        int p = b - XN_BLKS;
        const void* s = tab.src[p];
        float* d = pblock + tab.off[p];
        int n = tab.n[p];
        for (int i = t; i < n; i += 256) d[i] = ldf(s, i, isbf);
    } else {
        if (t < NBUCK) gcur[t] = 0;
        if (t == 0) { *ovf_cnt = 0; flags[0] = isbf; flags[1] = is64; }
        if (t < 3) {   // w1s/w1d: W1 [3][128] . a1s/a1d
            float s = 0.f, d = 0.f;
            for (int k = 0; k < 128; k++) {
                float wv = ldf(rW1, t * 128 + k, isbf);
                s = fmaf(wv, ldf(rA1s, k, isbf), s);
                d = fmaf(wv, ldf(rA1d, k, isbf), d);
            }
            pblock[P_W1S + t] = s;
            pblock[P_W1D + t] = d;
        }
        if (t >= 64 && t < 128) {  // w3s/w3d: W3 [64][128] . a3s/a3d
            int k = t - 64;
            float s = 0.f, d = 0.f;
            for (int c = 0; c < 128; c++) {
                float wv = ldf(rW3, k * 128 + c, isbf);
                s = fmaf(wv, ldf(rA3s, c, isbf), s);
                d = fmaf(wv, ldf(rA3d, c, isbf), d);
            }
            pblock[P_W3S + k] = s;
            pblock[P_W3D + k] = d;
        }
    }
}

// ---------------- bucket phase ----------------
__global__ __launch_bounds__(256) void k_bucket(
        const void* __restrict__ eidx, const int* __restrict__ flags,
        int* __restrict__ gcur, unsigned int* __restrict__ stage,
        int* __restrict__ ovf_cnt, uint2* __restrict__ ovf) {
    __shared__ int hist[NBUCK];
    __shared__ int base[NBUCK];
    const int t = threadIdx.x;
    const int is64 = flags[1];
    const int e0 = blockIdx.x * CHUNK1;
    const int e1 = min(e0 + CHUNK1, N_EDGES);

    unsigned int ent[NIT];
    int bk[NIT];
    hist[t] = 0;
    __syncthreads();
#pragma unroll
    for (int it = 0; it < NIT; it++) {
        int e = e0 + t + it * 256;
        int b = -1;
        unsigned int en = 0;
        if (e < e1) {
            int r = ld_idx(eidx, (long long)N_EDGES + e, is64);
            int s = ld_idx(eidx, e, is64);
            b = r / BUCK_R;
            en = ((unsigned)(r - b * BUCK_R) << 16) | (unsigned)s;
            atomicAdd(&hist[b], 1);
        }
        ent[it] = en;
        bk[it] = b;
    }
    __syncthreads();
    int cnt = hist[t];
    base[t] = (cnt > 0) ? atomicAdd(&gcur[t], cnt) : 0;
    __syncthreads();
    hist[t] = 0;
    __syncthreads();
#pragma unroll
    for (int it = 0; it < NIT; it++) {
        int b = bk[it];
        if (b >= 0) {
            int l = atomicAdd(&hist[b], 1);
            int slot = base[b] + l;
            if (slot < BUCK_CAP) {
                stage[(size_t)b * BUCK_CAP + slot] = ent[it];
            } else {
                int oi = atomicAdd(ovf_cnt, 1);
                int r = b * BUCK_R + (int)(ent[it] >> 16);
                if (oi < OVF_CAP) ovf[oi] = make_uint2(ent[it] & 0xffffu, (unsigned)r);
            }
        }
    }
}

// ---------------- counts + bucket-local exclusive scan ----------------
__global__ __launch_bounds__(256) void k_count2(
        const int* __restrict__ gcur, const unsigned int* __restrict__ stage,
        const int* __restrict__ ovf_cnt, const uint2* __restrict__ ovf,
        int* __restrict__ loff, int* __restrict__ bsum) {
    __shared__ int hist[256];
    __shared__ int ss[256];
    const int b = blockIdx.x;
    const int r0 = b * BUCK_R;
    const int nr = min(BUCK_R, N_NODES - r0);
    const int t = threadIdx.x;
    hist[t] = 0;
    __syncthreads();
    const int cnt = min(gcur[b], BUCK_CAP);
    const unsigned int* sb = stage + (size_t)b * BUCK_CAP;
    for (int i = t; i < cnt; i += 256) atomicAdd(&hist[sb[i] >> 16], 1);
    int oc = min(*ovf_cnt, OVF_CAP);
    for (int i = t; i < oc; i += 256) {
        int r = (int)ovf[i].y;
        if (r >= r0 && r < r0 + nr) atomicAdd(&hist[r - r0], 1);
    }
    __syncthreads();
    int v = (t < nr) ? hist[t] + 1 : 0;  // +1 self loop
    ss[t] = v;
    __syncthreads();
#pragma unroll
    for (int o = 1; o < 256; o <<= 1) {
        int add = (t >= o) ? ss[t - o] : 0;
        __syncthreads();
        ss[t] += add;
        __syncthreads();
    }
    if (t < nr) loff[r0 + t] = ss[t] - v;
    if (t == 255) bsum[b] = ss[255];
}

// ---------------- fill: self-scans bsum, writes off + csr ----------------
__global__ __launch_bounds__(256) void k_fill3(
        const int* __restrict__ gcur, const unsigned int* __restrict__ stage,
        const int* __restrict__ ovf_cnt, const uint2* __restrict__ ovf,
        const int* __restrict__ loff, const int* __restrict__ bsum,
        int* __restrict__ off, int* __restrict__ csr_send) {
    __shared__ int sbs[NBUCK];
    __shared__ int ss[NBUCK];
    __shared__ int sstart[BUCK_R];
    __shared__ int lcur[BUCK_R];
    const int b = blockIdx.x;
    const int t = threadIdx.x;
    int v = bsum[t];
    sbs[t] = v;
    ss[t] = v;
    __syncthreads();
#pragma unroll
    for (int o = 1; o < NBUCK; o <<= 1) {
        int add = (t >= o) ? ss[t - o] : 0;
        __syncthreads();
        ss[t] += add;
        __syncthreads();
    }
    const int bb = ss[b] - sbs[b];  // exclusive prefix for this bucket
    if (b == NBUCK - 1 && t == 0) off[N_NODES] = ss[NBUCK - 1];

    const int r0 = b * BUCK_R;
    const int nr = min(BUCK_R, N_NODES - r0);
    for (int i = t; i < nr; i += 256) {
        int st = bb + loff[r0 + i];
        sstart[i] = st;
        off[r0 + i] = st;
        lcur[i] = 1;
        csr_send[st] = r0 + i;      // self loop in slot 0
    }
    __syncthreads();
    const int cnt = min(gcur[b], BUCK_CAP);
    const unsigned int* sb = stage + (size_t)b * BUCK_CAP;
    for (int i = t; i < cnt; i += 256) {
        unsigned int e = sb[i];
        int rl = (int)(e >> 16);
        int l = atomicAdd(&lcur[rl], 1);
        csr_send[sstart[rl] + l] = (int)(e & 0xffffu);
    }
    int oc = min(*ovf_cnt, OVF_CAP);
    for (int i = t; i < oc; i += 256) {
        uint2 pr = ovf[i];
        int r = (int)pr.y;
        if (r >= r0 && r < r0 + nr) {
            int rl = r - r0;
            int l = atomicAdd(&lcur[rl], 1);
            csr_send[sstart[rl] + l] = (int)pr.x;
        }
    }
}

// ---------------- es/ed for conv1 (factored: x . (W1 a)) ----------------
__global__ __launch_bounds__(256) void k_esed1(
        const float* __restrict__ x4, const float* __restrict__ pb,
        float* __restrict__ es, float* __restrict__ ed) {
    int node = blockIdx.x * 256 + threadIdx.x;
    if (node >= N_NODES) return;
    float4 v = *(const float4*)&x4[node * 4];
    es[node] = v.x * pb[P_W1S] + v.y * pb[P_W1S + 1] + v.z * pb[P_W1S + 2];
    ed[node] = v.x * pb[P_W1D] + v.y * pb[P_W1D + 1] + v.z * pb[P_W1D + 2];
}

// ---------------- es/ed for conv3 (latent . (W3 a)), wave/node ----------------
__global__ __launch_bounds__(256) void k_esed3(
        const float* __restrict__ latent, const float* __restrict__ pb,
        float* __restrict__ es, float* __restrict__ ed) {
    int wid = threadIdx.x >> 6, lane = threadIdx.x & 63;
    int node = blockIdx.x * 4 + wid;
    if (node >= N_NODES) return;
    float lv = latent[(size_t)node * 64 + lane];
    float s = lv * pb[P_W3S + lane];
    float d = lv * pb[P_W3D + lane];
    s = wave_sum(s);
    d = wave_sum(d);
    if (lane == 0) { es[node] = s; ed[node] = d; }
}

// ---------------- conv1 aggregation: gather x4 (L2-resident), 3-dim ------------
__global__ __launch_bounds__(256) void k_wsumx3(
        const float* __restrict__ x4, const float* __restrict__ es,
        const float* __restrict__ ed, const int* __restrict__ off,
        const int* __restrict__ csr_send, float* __restrict__ xagg) {
    int wid = threadIdx.x >> 6, lane = threadIdx.x & 63;
    int node = blockIdx.x * 4 + wid;
    if (node >= N_NODES) return;
    int start = off[node], end = off[node + 1];
    float edi = ed[node];
    float a0 = 0.f, a1 = 0.f, a2 = 0.f, sl = 0.f;
    for (int j = start + lane; j < end; j += 64) {
        int s = csr_send[j];
        float p = attn_p(es[s], edi);
        sl += p;
        float4 xv = *(const float4*)&x4[s * 4];
        a0 = fmaf(p, xv.x, a0);
        a1 = fmaf(p, xv.y, a1);
        a2 = fmaf(p, xv.z, a2);
    }
    float S = wave_sum(sl);
    a0 = wave_sum(a0);
    a1 = wave_sum(a1);
    a2 = wave_sum(a2);
    if (lane == 0) {
        float inv = 1.f / S;
        float4 r = {a0 * inv, a1 * inv, a2 * inv, 0.f};
        *(float4*)&xagg[node * 4] = r;
    }
}

// ---------------- register-tiled GEMM ----------------
// MODE 0: pre (es/ed + bf16 h out); MODE 1: pre (es/ed + f32 pad4 out, DOUT=3);
// MODE 2: post (bias + relu, f32 out).
template <int DIN, int DINS, int DOUT, int MODE>
__global__ __launch_bounds__(256) void k_gemm(
        const float* __restrict__ in, const float* __restrict__ W,
        const float* __restrict__ as_, const float* __restrict__ ad_,
        const float* __restrict__ bias, void* __restrict__ hout,
        float* __restrict__ es, float* __restrict__ ed) {
    constexpr int KC = (DIN < 32) ? DIN : 32;
    constexpr int NCH = DIN / KC;
    constexpr int CG = (DOUT >= 64) ? (DOUT / 8) : 1;
    constexpr int NT = (DOUT >= 64) ? ((256 / CG) * 4) : 256;
    constexpr int NTP = NT + 4;

    __shared__ float sX[KC][NTP];
    __shared__ float sW[KC][DOUT];

    const int t = threadIdx.x;
    const int node0 = blockIdx.x * NT;
    const int nvalid = min(NT, N_NODES - node0);

    const int cg = t & (CG - 1);
    const int ng = t / CG;

    float acc[4][8] = {};

    for (int ch = 0; ch < NCH; ch++) {
        const int k0 = ch * KC;
        if (ch > 0) __syncthreads();
        for (int i = t; i < nvalid * KC; i += 256) {
            int n = i / KC, k = i - n * KC;
            sX[k][n] = in[(size_t)(node0 + n) * DINS + k0 + k];
        }
        for (int i = t; i < KC * DOUT; i += 256) {
            int k = i / DOUT, c = i - k * DOUT;
            sW[k][c] = W[(size_t)(k0 + k) * DOUT + c];
        }
        __syncthreads();

        if constexpr (DOUT >= 64) {
#pragma unroll 4
            for (int k = 0; k < KC; k++) {
                float4 xv = *(const float4*)&sX[k][ng * 4];
                float4 w0 = *(const float4*)&sW[k][cg * 8];
                float4 w1 = *(const float4*)&sW[k][cg * 8 + 4];
                float xs[4] = {xv.x, xv.y, xv.z, xv.w};
                float ws[8] = {w0.x, w0.y, w0.z, w0.w, w1.x, w1.y, w1.z, w1.w};
#pragma unroll
                for (int j = 0; j < 4; j++)
#pragma unroll
                    for (int c = 0; c < 8; c++)
                        acc[j][c] = fmaf(xs[j], ws[c], acc[j][c]);
            }
        } else {
#pragma unroll 4
            for (int k = 0; k < KC; k++) {
                float xv = sX[k][t];
#pragma unroll
                for (int c = 0; c < DOUT; c++)
                    acc[0][c] = fmaf(xv, sW[k][c], acc[0][c]);
            }
        }
    }

    if constexpr (DOUT >= 64) {
        if constexpr (MODE == 2) {
            float bv[8];
#pragma unroll
            for (int c = 0; c < 8; c++) bv[c] = bias[cg * 8 + c];
            float* out = (float*)hout;
#pragma unroll
            for (int j = 0; j < 4; j++) {
                int n = ng * 4 + j;
                if (n < nvalid) {
                    float4 v0, v1;
                    v0.x = fmaxf(acc[j][0] + bv[0], 0.f);
                    v0.y = fmaxf(acc[j][1] + bv[1], 0.f);
                    v0.z = fmaxf(acc[j][2] + bv[2], 0.f);
                    v0.w = fmaxf(acc[j][3] + bv[3], 0.f);
                    v1.x = fmaxf(acc[j][4] + bv[4], 0.f);
                    v1.y = fmaxf(acc[j][5] + bv[5], 0.f);
                    v1.z = fmaxf(acc[j][6] + bv[6], 0.f);
                    v1.w = fmaxf(acc[j][7] + bv[7], 0.f);
                    *(float4*)&out[(size_t)(node0 + n) * DOUT + cg * 8] = v0;
                    *(float4*)&out[(size_t)(node0 + n) * DOUT + cg * 8 + 4] = v1;
                }
            }
        } else {
            float asv[8], adv[8];
#pragma unroll
            for (int c = 0; c < 8; c++) {
                asv[c] = as_[cg * 8 + c];
                adv[c] = ad_[cg * 8 + c];
            }
#pragma unroll
            for (int j = 0; j < 4; j++) {
                int n = ng * 4 + j;
                float e_s = 0.f, e_d = 0.f;
#pragma unroll
                for (int c = 0; c < 8; c++) {
                    e_s = fmaf(acc[j][c], asv[c], e_s);
                    e_d = fmaf(acc[j][c], adv[c], e_d);
                }
#pragma unroll
                for (int m = 1; m < CG; m <<= 1) {
                    e_s += __shfl_xor(e_s, m, 64);
                    e_d += __shfl_xor(e_d, m, 64);
                }
                if (n < nvalid) {
                    if (cg == 0) {
                        es[node0 + n] = e_s;
                        ed[node0 + n] = e_d;
                    }
                    unsigned short* hb = (unsigned short*)hout;
                    uint4 u;
                    u.x = pk2(acc[j][0], acc[j][1]);
                    u.y = pk2(acc[j][2], acc[j][3]);
                    u.z = pk2(acc[j][4], acc[j][5]);
                    u.w = pk2(acc[j][6], acc[j][7]);
                    *(uint4*)&hb[(size_t)(node0 + n) * DOUT + cg * 8] = u;
                }
            }
        }
    } else {
        if (t < nvalid) {
            int node = node0 + t;
            float e_s = 0.f, e_d = 0.f;
#pragma unroll
            for (int c = 0; c < DOUT; c++) {
                e_s = fmaf(acc[0][c], as_[c], e_s);
                e_d = fmaf(acc[0][c], ad_[c], e_d);
            }
            es[node] = e_s;
            ed[node] = e_d;
            float* h = (float*)hout;
            float4 v = {acc[0][0], acc[0][1], acc[0][2], 0.f};
            *(float4*)&h[(size_t)node * 4] = v;
        }
    }
}

// ---------------- conv2: one-pass softmax + weighted sum, 64-dim bf16 h --------
// also emits bf16 latent copy (lat16) for conv3's gather.
__global__ __launch_bounds__(256) void k_wsum64f(
        const unsigned short* __restrict__ hb, const float* __restrict__ es,
        const float* __restrict__ ed, const float* __restrict__ bias,
        const int* __restrict__ off, const int* __restrict__ csr_send,
        float* __restrict__ out, unsigned short* __restrict__ lat16,
        void* __restrict__ out_dev, long long out_off, const int* __restrict__ flags) {
    int wid = threadIdx.x >> 6, lane = threadIdx.x & 63;
    int node = blockIdx.x * 4 + wid;
    if (node >= N_NODES) return;
    int start = off[node], end = off[node + 1];
    float edi = ed[node];

    const int qd = lane >> 4;
    const int ql = lane & 15;
    float4 a0 = {0.f, 0.f, 0.f, 0.f}, a1 = {0.f, 0.f, 0.f, 0.f};
    float4 a2 = {0.f, 0.f, 0.f, 0.f}, a3 = {0.f, 0.f, 0.f, 0.f};
    float sl = 0.f;

    for (int base = start; base < end; base += 64) {
        int j = base + lane;
        bool valid = j < end;
        int src = valid ? csr_send[j] : 0;
        float p = valid ? attn_p(es[src], edi) : 0.f;
        sl += p;
        int cnt = min(64, end - base);
        int nq = (cnt + 3) >> 2;
        int j2 = 0;
        for (; j2 + 4 <= nq; j2 += 4) {
            int qA = 4 * j2 + qd;
            float pA = __shfl(p, qA, 64);      int sA = __shfl(src, qA, 64);
            float pB = __shfl(p, qA + 4, 64);  int sB = __shfl(src, qA + 4, 64);
            float pC = __shfl(p, qA + 8, 64);  int sC = __shfl(src, qA + 8, 64);
            float pD = __shfl(p, qA + 12, 64); int sD = __shfl(src, qA + 12, 64);
            uint2 uA = *((const uint2*)(hb + (size_t)sA * 64) + ql);
            uint2 uB = *((const uint2*)(hb + (size_t)sB * 64) + ql);
            uint2 uC = *((const uint2*)(hb + (size_t)sC * 64) + ql);
            uint2 uD = *((const uint2*)(hb + (size_t)sD * 64) + ql);
            a0.x = fmaf(pA, bf_lo(uA.x), a0.x); a0.y = fmaf(pA, bf_hi(uA.x), a0.y);
            a0.z = fmaf(pA, bf_lo(uA.y), a0.z); a0.w = fmaf(pA, bf_hi(uA.y), a0.w);
            a1.x = fmaf(pB, bf_lo(uB.x), a1.x); a1.y = fmaf(pB, bf_hi(uB.x), a1.y);
            a1.z = fmaf(pB, bf_lo(uB.y), a1.z); a1.w = fmaf(pB, bf_hi(uB.y), a1.w);
            a2.x = fmaf(pC, bf_lo(uC.x), a2.x); a2.y = fmaf(pC, bf_hi(uC.x), a2.y);
            a2.z = fmaf(pC, bf_lo(uC.y), a2.z); a2.w = fmaf(pC, bf_hi(uC.y), a2.w);
            a3.x = fmaf(pD, bf_lo(uD.x), a3.x); a3.y = fmaf(pD, bf_hi(uD.x), a3.y);
            a3.z = fmaf(pD, bf_lo(uD.y), a3.z); a3.w = fmaf(pD, bf_hi(uD.y), a3.w);
        }
        for (; j2 < nq; j2++) {
            int q = 4 * j2 + qd;
            float pq = __shfl(p, q, 64); int sq = __shfl(src, q, 64);
            uint2 u = *((const uint2*)(hb + (size_t)sq * 64) + ql);
            a0.x = fmaf(pq, bf_lo(u.x), a0.x); a0.y = fmaf(pq, bf_hi(u.x), a0.y);
            a0.z = fmaf(pq, bf_lo(u.y), a0.z); a0.w = fmaf(pq, bf_hi(u.y), a0.w);
        }
    }
    float S = wave_sum(sl);
    float inv = 1.f / S;
    float4 r;
    r.x = (a0.x + a1.x) + (a2.x + a3.x);
    r.y = (a0.y + a1.y) + (a2.y + a3.y);
    r.z = (a0.z + a1.z) + (a2.z + a3.z);
    r.w = (a0.w + a1.w) + (a2.w + a3.w);
    r.x += __shfl_xor(r.x, 16, 64); r.y += __shfl_xor(r.y, 16, 64);
    r.z += __shfl_xor(r.z, 16, 64); r.w += __shfl_xor(r.w, 16, 64);
    r.x += __shfl_xor(r.x, 32, 64); r.y += __shfl_xor(r.y, 32, 64);
    r.z += __shfl_xor(r.z, 32, 64); r.w += __shfl_xor(r.w, 32, 64);
    if (qd == 0) {
        float4 b = ((const float4*)bias)[ql];
        r.x = fmaf(r.x, inv, b.x); r.y = fmaf(r.y, inv, b.y);
        r.z = fmaf(r.z, inv, b.z); r.w = fmaf(r.w, inv, b.w);
        ((float4*)(out + (size_t)node * 64))[ql] = r;
        uint2 u = {pk2(r.x, r.y), pk2(r.z, r.w)};
        ((uint2*)(lat16 + (size_t)node * 64))[ql] = u;
        int isbf = flags[0];
        long long o4 = out_off + (long long)node * 64 + 4 * ql;
        st_out(out_dev, o4 + 0, r.x, isbf);
        st_out(out_dev, o4 + 1, r.y, isbf);
        st_out(out_dev, o4 + 2, r.z, isbf);
        st_out(out_dev, o4 + 3, r.w, isbf);
    }
}

// ---------------- conv3 aggregation: gather lat16 (64-dim bf16) ----------------
__global__ __launch_bounds__(256) void k_wsumx64(
        const unsigned short* __restrict__ lat16, const float* __restrict__ es,
        const float* __restrict__ ed, const int* __restrict__ off,
        const int* __restrict__ csr_send, float* __restrict__ lagg) {
    int wid = threadIdx.x >> 6, lane = threadIdx.x & 63;
    int node = blockIdx.x * 4 + wid;
    if (node >= N_NODES) return;
    int start = off[node], end = off[node + 1];
    float edi = ed[node];

    const int qd = lane >> 4;
    const int ql = lane & 15;
    float4 a0 = {0.f, 0.f, 0.f, 0.f}, a1 = {0.f, 0.f, 0.f, 0.f};
    float4 a2 = {0.f, 0.f, 0.f, 0.f}, a3 = {0.f, 0.f, 0.f, 0.f};
    float sl = 0.f;

    for (int base = start; base < end; base += 64) {
        int j = base + lane;
        bool valid = j < end;
        int src = valid ? csr_send[j] : 0;
        float p = valid ? attn_p(es[src], edi) : 0.f;
        sl += p;
        int cnt = min(64, end - base);
        int nq = (cnt + 3) >> 2;
        int j2 = 0;
        for (; j2 + 4 <= nq; j2 += 4) {
            int qA = 4 * j2 + qd;
            float pA = __shfl(p, qA, 64);      int sA = __shfl(src, qA, 64);
            float pB = __shfl(p, qA + 4, 64);  int sB = __shfl(src, qA + 4, 64);
            float pC = __shfl(p, qA + 8, 64);  int sC = __shfl(src, qA + 8, 64);
            float pD = __shfl(p, qA + 12, 64); int sD = __shfl(src, qA + 12, 64);
            uint2 uA = *((const uint2*)(lat16 + (size_t)sA * 64) + ql);
            uint2 uB = *((const uint2*)(lat16 + (size_t)sB * 64) + ql);
            uint2 uC = *((const uint2*)(lat16 + (size_t)sC * 64) + ql);
            uint2 uD = *((const uint2*)(lat16 + (size_t)sD * 64) + ql);
            a0.x = fmaf(pA, bf_lo(uA.x), a0.x); a0.y = fmaf(pA, bf_hi(uA.x), a0.y);
            a0.z = fmaf(pA, bf_lo(uA.y), a0.z); a0.w = fmaf(pA, bf_hi(uA.y), a0.w);
            a1.x = fmaf(pB, bf_lo(uB.x), a1.x); a1.y = fmaf(pB, bf_hi(uB.x), a1.y);
            a1.z = fmaf(pB, bf_lo(uB.y), a1.z); a1.w = fmaf(pB, bf_hi(uB.y), a1.w);
            a2.x = fmaf(pC, bf_lo(uC.x), a2.x); a2.y = fmaf(pC, bf_hi(uC.x), a2.y);
            a2.z = fmaf(pC, bf_lo(uC.y), a2.z); a2.w = fmaf(pC, bf_hi(uC.y), a2.w);
            a3.x = fmaf(pD, bf_lo(uD.x), a3.x); a3.y = fmaf(pD, bf_hi(uD.x), a3.y);
            a3.z = fmaf(pD, bf_lo(uD.y), a3.z); a3.w = fmaf(pD, bf_hi(uD.y), a3.w);
        }
        for (; j2 < nq; j2++) {
            int q = 4 * j2 + qd;
            float pq = __shfl(p, q, 64); int sq = __shfl(src, q, 64);
            uint2 u = *((const uint2*)(lat16 + (size_t)sq * 64) + ql);
            a0.x = fmaf(pq, bf_lo(u.x), a0.x); a0.y = fmaf(pq, bf_hi(u.x), a0.y);
            a0.z = fmaf(pq, bf_lo(u.y), a0.z); a0.w = fmaf(pq, bf_hi(u.y), a0.w);
        }
    }
    float S = wave_sum(sl);
    float inv = 1.f / S;
    float4 r;
    r.x = (a0.x + a1.x) + (a2.x + a3.x);
    r.y = (a0.y + a1.y) + (a2.y + a3.y);
    r.z = (a0.z + a1.z) + (a2.z + a3.z);
    r.w = (a0.w + a1.w) + (a2.w + a3.w);
    r.x += __shfl_xor(r.x, 16, 64); r.y += __shfl_xor(r.y, 16, 64);
    r.z += __shfl_xor(r.z, 16, 64); r.w += __shfl_xor(r.w, 16, 64);
    r.x += __shfl_xor(r.x, 32, 64); r.y += __shfl_xor(r.y, 32, 64);
    r.z += __shfl_xor(r.z, 32, 64); r.w += __shfl_xor(r.w, 32, 64);
    if (qd == 0) {
        r.x *= inv; r.y *= inv; r.z *= inv; r.w *= inv;
        ((float4*)(lagg + (size_t)node * 64))[ql] = r;
    }
}

// ---------------- conv4 aggregation (h3 padded f32) ----------------
__global__ __launch_bounds__(256) void k_wsum3f(
        const float* __restrict__ h, const float* __restrict__ es,
        const float* __restrict__ ed, const float* __restrict__ bias,
        const int* __restrict__ off, const int* __restrict__ csr_send,
        void* __restrict__ out_dev, long long out_off, const int* __restrict__ flags) {
    int wid = threadIdx.x >> 6, lane = threadIdx.x & 63;
    int node = blockIdx.x * 4 + wid;
    if (node >= N_NODES) return;
    int start = off[node], end = off[node + 1];
    float edi = ed[node];

    float a0 = 0.f, a1 = 0.f, a2 = 0.f, sl = 0.f;
    for (int j = start + lane; j < end; j += 64) {
        int s = csr_send[j];
        float p = attn_p(es[s], edi);
        sl += p;
        float4 rv = *(const float4*)(h + (size_t)s * 4);
        a0 = fmaf(p, rv.x, a0);
        a1 = fmaf(p, rv.y, a1);
        a2 = fmaf(p, rv.z, a2);
    }
    float S = wave_sum(sl);
    a0 = wave_sum(a0);
    a1 = wave_sum(a1);
    a2 = wave_sum(a2);
    if (lane < 3) {
        float inv = 1.f / S;
        float v = fmaf((lane == 0 ? a0 : (lane == 1 ? a1 : a2)), inv, bias[lane]);
        st_out(out_dev, out_off + (long long)node * 3 + lane, v, flags[0]);
    }
}

// ---------------- pooling + classifier (fused; per-graph independent) ----------
#define POOL_W 16
__global__ void k_poolcls(const float* __restrict__ latent, const void* __restrict__ batch,
                          const int* __restrict__ flags, const float* __restrict__ pb,
                          void* __restrict__ out_dev, long long out_off) {
    int b = blockIdx.x;
    int lane = threadIdx.x & 63;
    int wave = threadIdx.x >> 6;
    int is64 = flags[1];
    int lo = 0, hi = N_NODES;
    while (lo < hi) { int mid = (lo + hi) >> 1; if (ld_idx(batch, mid, is64) < b) lo = mid + 1; else hi = mid; }
    int start = lo;
    lo = 0; hi = N_NODES;
    while (lo < hi) { int mid = (lo + hi) >> 1; if (ld_idx(batch, mid, is64) < b + 1) lo = mid + 1; else hi = mid; }
    int end = lo;
    float s = 0.f;
    for (int n = start + wave; n < end; n += POOL_W) s += latent[(size_t)n * 64 + lane];
    __shared__ float red[POOL_W][64];
    __shared__ float ps[64];
    red[wave][lane] = s;
    __syncthreads();
    if (wave == 0) {
        float t = s;
#pragma unroll
        for (int w2 = 1; w2 < POOL_W; w2++) t += red[w2][lane];
        float cnt = (float)(end - start);
        ps[lane] = t / fmaxf(cnt, 1.f);
    }
    __syncthreads();
    if (wave == 0 && lane < 32) {
        float z = pb[P_BC1 + lane];
        for (int c = 0; c < 64; c++) z = fmaf(ps[c], pb[P_WC1 + c * 32 + lane], z);
        z = fmaxf(z, 0.f);
        float p0 = z * pb[P_WC2 + lane * 2];
        float p1 = z * pb[P_WC2 + lane * 2 + 1];
#pragma unroll
        for (int o = 16; o >= 1; o >>= 1) {
            p0 += __shfl_xor(p0, o, 64);
            p1 += __shfl_xor(p1, o, 64);
        }
        if (lane == 0) {
            int isbf = flags[0];
            st_out(out_dev, out_off + b * 2 + 0, p0 + pb[P_BC2], isbf);
            st_out(out_dev, out_off + b * 2 + 1, p1 + pb[P_BC2 + 1], isbf);
        }
    }
}

extern "C" void kernel_launch(void* const* d_in, const int* in_sizes, int n_in,
                              void* d_out, int out_size, void* d_ws, size_t ws_size,
                              hipStream_t stream) {
    const void* x    = d_in[0];
    const void* eidx = d_in[1];
    const void* batch= d_in[2];

    // workspace carve-up (256B aligned)
    char* w = (char*)d_ws;
    size_t o = 0;
    auto carve = [&](size_t bytes) { void* p = w + o; o = (o + bytes + 255) & ~(size_t)255; return p; };
    int* flags    = (int*)carve(8 * sizeof(int));
    int* off      = (int*)carve((N_NODES + 1) * sizeof(int));
    int* loff     = (int*)carve(N_NODES * sizeof(int));
    int* bsum     = (int*)carve(NBUCK * sizeof(int));
    int* gcur     = (int*)carve(NBUCK * sizeof(int));
    int* ovf_cnt  = (int*)carve(sizeof(int));
    int* csr_send = (int*)carve((size_t)(N_EDGES + N_NODES) * sizeof(int));
    unsigned int* stage = (unsigned int*)carve((size_t)NBUCK * BUCK_CAP * sizeof(unsigned int));
    uint2* ovf    = (uint2*)carve((size_t)OVF_CAP * sizeof(uint2));
    float* pblock = (float*)carve(P_TOTAL * sizeof(float));
    float* x4     = (float*)carve((size_t)N_NODES * 4 * sizeof(float));
    float* xagg   = (float*)carve((size_t)N_NODES * 4 * sizeof(float));
    float* buf0   = (float*)carve((size_t)N_NODES * 128 * sizeof(float));
    unsigned short* hb = (unsigned short*)carve((size_t)N_NODES * 64 * sizeof(unsigned short));
    unsigned short* lat16 = (unsigned short*)carve((size_t)N_NODES * 64 * sizeof(unsigned short));
    float* lagg   = (float*)carve((size_t)N_NODES * 64 * sizeof(float));
    float* h3     = (float*)carve((size_t)N_NODES * 4 * sizeof(float));
    float* es     = (float*)carve(N_NODES * sizeof(float));
    float* ed     = (float*)carve(N_NODES * sizeof(float));

    int gW = N_NODES / 4;

    // fused prep
    PTab tab;
    const int pn[20]  = {384,128,128,128, 8192,64,64,64, 8192,128,128,128, 384,3,3,3, 2048,32,64,2};
    const int pof[20] = {P_W1,P_A1S,P_A1D,P_B1, P_W2,P_A2S,P_A2D,P_B2, P_W3,P_A3S,P_A3D,P_B3,
                         P_W4,P_A4S,P_A4D,P_B4, P_WC1,P_BC1,P_WC2,P_BC2};
    for (int i = 0; i < 20; i++) { tab.src[i] = d_in[3 + i]; tab.off[i] = pof[i]; tab.n[i] = pn[i]; }
    k_prep<<<PREP_BLKS, 256, 0, stream>>>(x, eidx, d_in[3], d_in[4], d_in[5],
                                          d_in[11], d_in[12], d_in[13],
                                          tab, pblock, x4, gcur, ovf_cnt, flags);

    // CSR build
    k_bucket<<<NBLK1, 256, 0, stream>>>(eidx, flags, gcur, stage, ovf_cnt, ovf);
    k_count2<<<NBUCK, 256, 0, stream>>>(gcur, stage, ovf_cnt, ovf, loff, bsum);
    k_fill3<<<NBUCK, 256, 0, stream>>>(gcur, stage, ovf_cnt, ovf, loff, bsum, off, csr_send);

    const long long OFF_RECON = 0, OFF_LATENT = 150000, OFF_NOISE = 3350000;

    int g64  = (N_NODES + 63) / 64;
    int g128 = (N_NODES + 127) / 128;
    int g196 = (N_NODES + 255) / 256;
    int g256 = (N_NODES + 255) / 256;

    // conv1 (aggregate-then-transform): es/ed from x, gather x, post-GEMM+relu
    k_esed1<<<g196, 256, 0, stream>>>(x4, pblock, es, ed);
    k_wsumx3<<<gW, 256, 0, stream>>>(x4, es, ed, off, csr_send, xagg);
    k_gemm<3, 4, 128, 2><<<g64, 256, 0, stream>>>(xagg, pblock + P_W1, pblock, pblock,
                                                  pblock + P_B1, buf0, es, ed);

    // conv2 (transform-then-aggregate): GEMM -> bf16 h + es/ed, gather h
    k_gemm<128, 128, 64, 0><<<g128, 256, 0, stream>>>(buf0, pblock + P_W2, pblock + P_A2S,
                                                      pblock + P_A2D, pblock, hb, es, ed);
    k_wsum64f<<<gW, 256, 0, stream>>>(hb, es, ed, pblock + P_B2, off, csr_send,
                                      buf0, lat16, d_out, OFF_LATENT, flags);

    // pooling + classifier (reads f32 latent in buf0)
    k_poolcls<<<NB, POOL_W * 64, 0, stream>>>(buf0, batch, flags, pblock, d_out, OFF_NOISE);

    // conv3 (aggregate-then-transform): es/ed from latent, gather lat16, post-GEMM
    k_esed3<<<gW, 256, 0, stream>>>(buf0, pblock, es, ed);
    k_wsumx64<<<gW, 256, 0, stream>>>(lat16, es, ed, off, csr_send, lagg);
    k_gemm<64, 64, 128, 2><<<g64, 256, 0, stream>>>(lagg, pblock + P_W3, pblock, pblock,
                                                    pblock + P_B3, buf0, es, ed);

    // conv4 (transform-then-aggregate, 3-dim h): GEMM -> h3 pad4 + es/ed, gather
    k_gemm<128, 128, 3, 1><<<g256, 256, 0, stream>>>(buf0, pblock + P_W4, pblock + P_A4S,
                                                     pblock + P_A4D, pblock, h3, es, ed);
    k_wsum3f<<<gW, 256, 0, stream>>>(h3, es, ed, pblock + P_B4, off, csr_send,
                                     d_out, OFF_RECON, flags);
}

// Round 16
// 232.473 us; speedup vs baseline: 3.7258x; 1.0811x over previous
//
#include <hip/hip_runtime.h>
#include <hip/hip_bf16.h>

typedef __hip_bfloat16 bf16;

#define N_NODES 50000
#define N_EDGES 800000
#define NB 64

// bucketed CSR build
#define NBUCK 256
#define BUCK_R ((N_NODES + NBUCK - 1) / NBUCK)            // 196 nodes/bucket
#define BUCK_CAP 4352                                     // mean 3136, +21 sigma
#define OVF_CAP 65536
#define NBLK1 256
#define CHUNK1 ((N_EDGES + NBLK1 - 1) / NBLK1)            // 3125 edges/block
#define NIT ((CHUNK1 + 255) / 256)                        // 13 iters/thread

// k_prep block partition
#define XN_BLKS ((N_NODES + 255) / 256)                   // 196
#define PREP_BLKS (XN_BLKS + 20 + 1)

// param block offsets (floats)
#define P_W1 0
#define P_A1S 384
#define P_A1D 512
#define P_B1 640
#define P_W2 768
#define P_A2S 8960
#define P_A2D 9024
#define P_B2 9088
#define P_W3 9152
#define P_A3S 17344
#define P_A3D 17472
#define P_B3 17600
#define P_W4 17728
#define P_A4S 18112
#define P_A4D 18115
#define P_B4 18118
#define P_WC1 18121
#define P_BC1 20169
#define P_WC2 20201
#define P_BC2 20265
// factored attention vectors for conv3
#define P_W3S 20280
#define P_W3D 20344
#define P_TOTAL 20408

__device__ __forceinline__ float wave_sum(float v) {
#pragma unroll
    for (int o = 32; o >= 1; o >>= 1) v += __shfl_xor(v, o, 64);
    return v;
}

__device__ __forceinline__ unsigned int pk2(float a, float b) {
    bf16 x = __float2bfloat16(a);
    bf16 y = __float2bfloat16(b);
    unsigned short ux = *reinterpret_cast<unsigned short*>(&x);
    unsigned short uy = *reinterpret_cast<unsigned short*>(&y);
    return ((unsigned int)uy << 16) | ux;
}
__device__ __forceinline__ float bf_lo(unsigned int u) {
    unsigned int v = u << 16;
    return *reinterpret_cast<float*>(&v);
}
__device__ __forceinline__ float bf_hi(unsigned int u) {
    unsigned int v = u & 0xffff0000u;
    return *reinterpret_cast<float*>(&v);
}

// runtime dtype helpers: flags[0]=float-inputs-are-bf16, flags[1]=ints-are-int64
__device__ __forceinline__ int ld_idx(const void* p, long long i, int is64) {
    return is64 ? (int)((const long long*)p)[i] : ((const int*)p)[i];
}
__device__ __forceinline__ float ldf(const void* p, int i, int isbf) {
    return isbf ? __bfloat162float(((const bf16*)p)[i]) : ((const float*)p)[i];
}
__device__ __forceinline__ void st_out(void* p, long long i, float v, int isbf) {
    if (isbf) ((bf16*)p)[i] = __float2bfloat16(v);
    else ((float*)p)[i] = v;
}

// unnormalized attention weight
__device__ __forceinline__ float attn_p(float esv, float edi) {
    float v = esv + edi;
    float e = (v >= 0.f) ? v : 0.2f * v;
    return __expf(fminf(e, 60.f));
}

// ---------------- fused prep (+ conv1 es/ed) ----------------
struct PTab {
    const void* src[20];
    int off[20];
    int n[20];
};

__global__ __launch_bounds__(256) void k_prep(
        const void* __restrict__ x, const void* __restrict__ eidx,
        const void* __restrict__ rW1, const void* __restrict__ rA1s,
        const void* __restrict__ rA1d, const void* __restrict__ rW3,
        const void* __restrict__ rA3s, const void* __restrict__ rA3d,
        PTab tab, float* __restrict__ pblock, float* __restrict__ x4,
        float* __restrict__ es, float* __restrict__ ed,
        int* __restrict__ gcur, int* __restrict__ ovf_cnt, int* __restrict__ flags) {
    __shared__ int scnt[2];
    __shared__ float sw[6];
    const int t = threadIdx.x;
    if (t < 2) scnt[t] = 0;
    __syncthreads();
    {
        const unsigned short* xr = (const unsigned short*)x;
        unsigned int hb = (xr[2 * t] >> 8) & 0x7F;
        if (hb >= 58 && hb <= 65) atomicAdd(&scnt[0], 1);
        if (t < 64) {
            const unsigned int* er = (const unsigned int*)eidx;
            if (er[2 * t + 1] == 0u) atomicAdd(&scnt[1], 1);
        }
    }
    __syncthreads();
    const int isbf = (scnt[0] >= 200) ? 1 : 0;
    const int is64 = (scnt[1] >= 60) ? 1 : 0;

    const int b = blockIdx.x;
    if (b < XN_BLKS) {
        // per-block factored vectors w1s/w1d (L2-hot, trivial)
        if (t < 6) {
            int row = (t < 3) ? t : t - 3;
            const void* av = (t < 3) ? rA1s : rA1d;
            float s = 0.f;
            for (int k = 0; k < 128; k++)
                s = fmaf(ldf(rW1, row * 128 + k, isbf), ldf(av, k, isbf), s);
            sw[t] = s;
        }
        __syncthreads();
        int node = b * 256 + t;
        if (node < N_NODES) {
            float x0 = ldf(x, node * 3 + 0, isbf);
            float x1 = ldf(x, node * 3 + 1, isbf);
            float x2 = ldf(x, node * 3 + 2, isbf);
            float4 v = {x0, x1, x2, 0.f};
            *(float4*)&x4[node * 4] = v;
            es[node] = x0 * sw[0] + x1 * sw[1] + x2 * sw[2];
            ed[node] = x0 * sw[3] + x1 * sw[4] + x2 * sw[5];
        }
    } else if (b < XN_BLKS + 20) {
        int p = b - XN_BLKS;
        const void* s = tab.src[p];
        float* d = pblock + tab.off[p];
        int n = tab.n[p];
        for (int i = t; i < n; i += 256) d[i] = ldf(s, i, isbf);
    } else {
        if (t < NBUCK) gcur[t] = 0;
        if (t == 0) { *ovf_cnt = 0; flags[0] = isbf; flags[1] = is64; }
        if (t >= 64 && t < 128) {  // w3s/w3d: W3 [64][128] . a3s/a3d
            int k = t - 64;
            float s = 0.f, d = 0.f;
            for (int c = 0; c < 128; c++) {
                float wv = ldf(rW3, k * 128 + c, isbf);
                s = fmaf(wv, ldf(rA3s, c, isbf), s);
                d = fmaf(wv, ldf(rA3d, c, isbf), d);
            }
            pblock[P_W3S + k] = s;
            pblock[P_W3D + k] = d;
        }
    }
}

// ---------------- bucket phase ----------------
__global__ __launch_bounds__(256) void k_bucket(
        const void* __restrict__ eidx, const int* __restrict__ flags,
        int* __restrict__ gcur, unsigned int* __restrict__ stage,
        int* __restrict__ ovf_cnt, uint2* __restrict__ ovf) {
    __shared__ int hist[NBUCK];
    __shared__ int base[NBUCK];
    const int t = threadIdx.x;
    const int is64 = flags[1];
    const int e0 = blockIdx.x * CHUNK1;
    const int e1 = min(e0 + CHUNK1, N_EDGES);

    unsigned int ent[NIT];
    int bk[NIT];
    hist[t] = 0;
    __syncthreads();
#pragma unroll
    for (int it = 0; it < NIT; it++) {
        int e = e0 + t + it * 256;
        int b = -1;
        unsigned int en = 0;
        if (e < e1) {
            int r = ld_idx(eidx, (long long)N_EDGES + e, is64);
            int s = ld_idx(eidx, e, is64);
            b = r / BUCK_R;
            en = ((unsigned)(r - b * BUCK_R) << 16) | (unsigned)s;
            atomicAdd(&hist[b], 1);
        }
        ent[it] = en;
        bk[it] = b;
    }
    __syncthreads();
    int cnt = hist[t];
    base[t] = (cnt > 0) ? atomicAdd(&gcur[t], cnt) : 0;
    __syncthreads();
    hist[t] = 0;
    __syncthreads();
#pragma unroll
    for (int it = 0; it < NIT; it++) {
        int b = bk[it];
        if (b >= 0) {
            int l = atomicAdd(&hist[b], 1);
            int slot = base[b] + l;
            if (slot < BUCK_CAP) {
                stage[(size_t)b * BUCK_CAP + slot] = ent[it];
            } else {
                int oi = atomicAdd(ovf_cnt, 1);
                int r = b * BUCK_R + (int)(ent[it] >> 16);
                if (oi < OVF_CAP) ovf[oi] = make_uint2(ent[it] & 0xffffu, (unsigned)r);
            }
        }
    }
}

// ---------------- counts + bucket-local exclusive scan ----------------
__global__ __launch_bounds__(256) void k_count2(
        const int* __restrict__ gcur, const unsigned int* __restrict__ stage,
        const int* __restrict__ ovf_cnt, const uint2* __restrict__ ovf,
        int* __restrict__ loff, int* __restrict__ bsum) {
    __shared__ int hist[256];
    __shared__ int ss[256];
    const int b = blockIdx.x;
    const int r0 = b * BUCK_R;
    const int nr = min(BUCK_R, N_NODES - r0);
    const int t = threadIdx.x;
    hist[t] = 0;
    __syncthreads();
    const int cnt = min(gcur[b], BUCK_CAP);
    const unsigned int* sb = stage + (size_t)b * BUCK_CAP;
    for (int i = t; i < cnt; i += 256) atomicAdd(&hist[sb[i] >> 16], 1);
    int oc = min(*ovf_cnt, OVF_CAP);
    for (int i = t; i < oc; i += 256) {
        int r = (int)ovf[i].y;
        if (r >= r0 && r < r0 + nr) atomicAdd(&hist[r - r0], 1);
    }
    __syncthreads();
    int v = (t < nr) ? hist[t] + 1 : 0;  // +1 self loop
    ss[t] = v;
    __syncthreads();
#pragma unroll
    for (int o = 1; o < 256; o <<= 1) {
        int add = (t >= o) ? ss[t - o] : 0;
        __syncthreads();
        ss[t] += add;
        __syncthreads();
    }
    if (t < nr) loff[r0 + t] = ss[t] - v;
    if (t == 255) bsum[b] = ss[255];
}

// ---------------- fill: self-scans bsum, writes off + csr ----------------
__global__ __launch_bounds__(256) void k_fill3(
        const int* __restrict__ gcur, const unsigned int* __restrict__ stage,
        const int* __restrict__ ovf_cnt, const uint2* __restrict__ ovf,
        const int* __restrict__ loff, const int* __restrict__ bsum,
        int* __restrict__ off, int* __restrict__ csr_send) {
    __shared__ int sbs[NBUCK];
    __shared__ int ss[NBUCK];
    __shared__ int sstart[BUCK_R];
    __shared__ int lcur[BUCK_R];
    const int b = blockIdx.x;
    const int t = threadIdx.x;
    int v = bsum[t];
    sbs[t] = v;
    ss[t] = v;
    __syncthreads();
#pragma unroll
    for (int o = 1; o < NBUCK; o <<= 1) {
        int add = (t >= o) ? ss[t - o] : 0;
        __syncthreads();
        ss[t] += add;
        __syncthreads();
    }
    const int bb = ss[b] - sbs[b];
    if (b == NBUCK - 1 && t == 0) off[N_NODES] = ss[NBUCK - 1];

    const int r0 = b * BUCK_R;
    const int nr = min(BUCK_R, N_NODES - r0);
    for (int i = t; i < nr; i += 256) {
        int st = bb + loff[r0 + i];
        sstart[i] = st;
        off[r0 + i] = st;
        lcur[i] = 1;
        csr_send[st] = r0 + i;      // self loop in slot 0
    }
    __syncthreads();
    const int cnt = min(gcur[b], BUCK_CAP);
    const unsigned int* sb = stage + (size_t)b * BUCK_CAP;
    for (int i = t; i < cnt; i += 256) {
        unsigned int e = sb[i];
        int rl = (int)(e >> 16);
        int l = atomicAdd(&lcur[rl], 1);
        csr_send[sstart[rl] + l] = (int)(e & 0xffffu);
    }
    int oc = min(*ovf_cnt, OVF_CAP);
    for (int i = t; i < oc; i += 256) {
        uint2 pr = ovf[i];
        int r = (int)pr.y;
        if (r >= r0 && r < r0 + nr) {
            int rl = r - r0;
            int l = atomicAdd(&lcur[rl], 1);
            csr_send[sstart[rl] + l] = (int)pr.x;
        }
    }
}

// ---------------- conv1: gather x4 + fused post-GEMM (+bias+relu) --------------
__global__ __launch_bounds__(256) void k_wsumx3(
        const float* __restrict__ x4, const float* __restrict__ es,
        const float* __restrict__ ed, const float* __restrict__ pb,
        const int* __restrict__ off, const int* __restrict__ csr_send,
        float* __restrict__ out) {
    int wid = threadIdx.x >> 6, lane = threadIdx.x & 63;
    int node = blockIdx.x * 4 + wid;
    if (node >= N_NODES) return;
    int start = off[node], end = off[node + 1];
    float edi = ed[node];
    float a0 = 0.f, a1 = 0.f, a2 = 0.f, sl = 0.f;
    for (int j = start + lane; j < end; j += 64) {
        int s = csr_send[j];
        float p = attn_p(es[s], edi);
        sl += p;
        float4 xv = *(const float4*)&x4[s * 4];
        a0 = fmaf(p, xv.x, a0);
        a1 = fmaf(p, xv.y, a1);
        a2 = fmaf(p, xv.z, a2);
    }
    float S = wave_sum(sl);
    a0 = wave_sum(a0);
    a1 = wave_sum(a1);
    a2 = wave_sum(a2);
    float inv = 1.f / S;
    a0 *= inv; a1 *= inv; a2 *= inv;
    // fused [3]->[128] GEMM: lane computes cols lane, lane+64 (W1 L2-hot)
    const float* W1 = pb + P_W1;
    const float* b1 = pb + P_B1;
    int c0 = lane, c1 = lane + 64;
    float v0 = fmaf(a0, W1[c0], fmaf(a1, W1[128 + c0], fmaf(a2, W1[256 + c0], b1[c0])));
    float v1 = fmaf(a0, W1[c1], fmaf(a1, W1[128 + c1], fmaf(a2, W1[256 + c1], b1[c1])));
    out[(size_t)node * 128 + c0] = fmaxf(v0, 0.f);
    out[(size_t)node * 128 + c1] = fmaxf(v1, 0.f);
}

// ---------------- register-tiled GEMM ----------------
// MODE 0: pre (es/ed + bf16 h out); MODE 1: pre (es/ed + f32 pad4 out, DOUT=3);
// MODE 2: post (bias + relu, f32 out).
template <int DIN, int DINS, int DOUT, int MODE>
__global__ __launch_bounds__(256) void k_gemm(
        const float* __restrict__ in, const float* __restrict__ W,
        const float* __restrict__ as_, const float* __restrict__ ad_,
        const float* __restrict__ bias, void* __restrict__ hout,
        float* __restrict__ es, float* __restrict__ ed) {
    constexpr int KC = (DIN < 32) ? DIN : 32;
    constexpr int NCH = DIN / KC;
    constexpr int CG = (DOUT >= 64) ? (DOUT / 8) : 1;
    constexpr int NT = (DOUT >= 64) ? ((256 / CG) * 4) : 256;
    constexpr int NTP = NT + 4;

    __shared__ float sX[KC][NTP];
    __shared__ float sW[KC][DOUT];

    const int t = threadIdx.x;
    const int node0 = blockIdx.x * NT;
    const int nvalid = min(NT, N_NODES - node0);

    const int cg = t & (CG - 1);
    const int ng = t / CG;

    float acc[4][8] = {};

    for (int ch = 0; ch < NCH; ch++) {
        const int k0 = ch * KC;
        if (ch > 0) __syncthreads();
        for (int i = t; i < nvalid * KC; i += 256) {
            int n = i / KC, k = i - n * KC;
            sX[k][n] = in[(size_t)(node0 + n) * DINS + k0 + k];
        }
        for (int i = t; i < KC * DOUT; i += 256) {
            int k = i / DOUT, c = i - k * DOUT;
            sW[k][c] = W[(size_t)(k0 + k) * DOUT + c];
        }
        __syncthreads();

        if constexpr (DOUT >= 64) {
#pragma unroll 4
            for (int k = 0; k < KC; k++) {
                float4 xv = *(const float4*)&sX[k][ng * 4];
                float4 w0 = *(const float4*)&sW[k][cg * 8];
                float4 w1 = *(const float4*)&sW[k][cg * 8 + 4];
                float xs[4] = {xv.x, xv.y, xv.z, xv.w};
                float ws[8] = {w0.x, w0.y, w0.z, w0.w, w1.x, w1.y, w1.z, w1.w};
#pragma unroll
                for (int j = 0; j < 4; j++)
#pragma unroll
                    for (int c = 0; c < 8; c++)
                        acc[j][c] = fmaf(xs[j], ws[c], acc[j][c]);
            }
        } else {
#pragma unroll 4
            for (int k = 0; k < KC; k++) {
                float xv = sX[k][t];
#pragma unroll
                for (int c = 0; c < DOUT; c++)
                    acc[0][c] = fmaf(xv, sW[k][c], acc[0][c]);
            }
        }
    }

    if constexpr (DOUT >= 64) {
        if constexpr (MODE == 2) {
            float bv[8];
#pragma unroll
            for (int c = 0; c < 8; c++) bv[c] = bias[cg * 8 + c];
            float* out = (float*)hout;
#pragma unroll
            for (int j = 0; j < 4; j++) {
                int n = ng * 4 + j;
                if (n < nvalid) {
                    float4 v0, v1;
                    v0.x = fmaxf(acc[j][0] + bv[0], 0.f);
                    v0.y = fmaxf(acc[j][1] + bv[1], 0.f);
                    v0.z = fmaxf(acc[j][2] + bv[2], 0.f);
                    v0.w = fmaxf(acc[j][3] + bv[3], 0.f);
                    v1.x = fmaxf(acc[j][4] + bv[4], 0.f);
                    v1.y = fmaxf(acc[j][5] + bv[5], 0.f);
                    v1.z = fmaxf(acc[j][6] + bv[6], 0.f);
                    v1.w = fmaxf(acc[j][7] + bv[7], 0.f);
                    *(float4*)&out[(size_t)(node0 + n) * DOUT + cg * 8] = v0;
                    *(float4*)&out[(size_t)(node0 + n) * DOUT + cg * 8 + 4] = v1;
                }
            }
        } else {
            float asv[8], adv[8];
#pragma unroll
            for (int c = 0; c < 8; c++) {
                asv[c] = as_[cg * 8 + c];
                adv[c] = ad_[cg * 8 + c];
            }
#pragma unroll
            for (int j = 0; j < 4; j++) {
                int n = ng * 4 + j;
                float e_s = 0.f, e_d = 0.f;
#pragma unroll
                for (int c = 0; c < 8; c++) {
                    e_s = fmaf(acc[j][c], asv[c], e_s);
                    e_d = fmaf(acc[j][c], adv[c], e_d);
                }
#pragma unroll
                for (int m = 1; m < CG; m <<= 1) {
                    e_s += __shfl_xor(e_s, m, 64);
                    e_d += __shfl_xor(e_d, m, 64);
                }
                if (n < nvalid) {
                    if (cg == 0) {
                        es[node0 + n] = e_s;
                        ed[node0 + n] = e_d;
                    }
                    unsigned short* hb = (unsigned short*)hout;
                    uint4 u;
                    u.x = pk2(acc[j][0], acc[j][1]);
                    u.y = pk2(acc[j][2], acc[j][3]);
                    u.z = pk2(acc[j][4], acc[j][5]);
                    u.w = pk2(acc[j][6], acc[j][7]);
                    *(uint4*)&hb[(size_t)(node0 + n) * DOUT + cg * 8] = u;
                }
            }
        }
    } else {
        if (t < nvalid) {
            int node = node0 + t;
            float e_s = 0.f, e_d = 0.f;
#pragma unroll
            for (int c = 0; c < DOUT; c++) {
                e_s = fmaf(acc[0][c], as_[c], e_s);
                e_d = fmaf(acc[0][c], ad_[c], e_d);
            }
            es[node] = e_s;
            ed[node] = e_d;
            float* h = (float*)hout;
            float4 v = {acc[0][0], acc[0][1], acc[0][2], 0.f};
            *(float4*)&h[(size_t)node * 4] = v;
        }
    }
}

// ---------------- conv2: softmax+wsum, bf16 h; fused conv3 es/ed epilogue ------
__global__ __launch_bounds__(256) void k_wsum64f(
        const unsigned short* __restrict__ hb, const float* __restrict__ es,
        const float* __restrict__ ed, const float* __restrict__ pb,
        const int* __restrict__ off, const int* __restrict__ csr_send,
        float* __restrict__ out, unsigned short* __restrict__ lat16,
        float* __restrict__ es2, float* __restrict__ ed2,
        void* __restrict__ out_dev, long long out_off, const int* __restrict__ flags) {
    int wid = threadIdx.x >> 6, lane = threadIdx.x & 63;
    int node = blockIdx.x * 4 + wid;
    if (node >= N_NODES) return;
    int start = off[node], end = off[node + 1];
    float edi = ed[node];

    const int qd = lane >> 4;
    const int ql = lane & 15;
    float4 a0 = {0.f, 0.f, 0.f, 0.f}, a1 = {0.f, 0.f, 0.f, 0.f};
    float4 a2 = {0.f, 0.f, 0.f, 0.f}, a3 = {0.f, 0.f, 0.f, 0.f};
    float sl = 0.f;

    for (int base = start; base < end; base += 64) {
        int j = base + lane;
        bool valid = j < end;
        int src = valid ? csr_send[j] : 0;
        float p = valid ? attn_p(es[src], edi) : 0.f;
        sl += p;
        int cnt = min(64, end - base);
        int nq = (cnt + 3) >> 2;
        int j2 = 0;
        for (; j2 + 4 <= nq; j2 += 4) {
            int qA = 4 * j2 + qd;
            float pA = __shfl(p, qA, 64);      int sA = __shfl(src, qA, 64);
            float pB = __shfl(p, qA + 4, 64);  int sB = __shfl(src, qA + 4, 64);
            float pC = __shfl(p, qA + 8, 64);  int sC = __shfl(src, qA + 8, 64);
            float pD = __shfl(p, qA + 12, 64); int sD = __shfl(src, qA + 12, 64);
            uint2 uA = *((const uint2*)(hb + (size_t)sA * 64) + ql);
            uint2 uB = *((const uint2*)(hb + (size_t)sB * 64) + ql);
            uint2 uC = *((const uint2*)(hb + (size_t)sC * 64) + ql);
            uint2 uD = *((const uint2*)(hb + (size_t)sD * 64) + ql);
            a0.x = fmaf(pA, bf_lo(uA.x), a0.x); a0.y = fmaf(pA, bf_hi(uA.x), a0.y);
            a0.z = fmaf(pA, bf_lo(uA.y), a0.z); a0.w = fmaf(pA, bf_hi(uA.y), a0.w);
            a1.x = fmaf(pB, bf_lo(uB.x), a1.x); a1.y = fmaf(pB, bf_hi(uB.x), a1.y);
            a1.z = fmaf(pB, bf_lo(uB.y), a1.z); a1.w = fmaf(pB, bf_hi(uB.y), a1.w);
            a2.x = fmaf(pC, bf_lo(uC.x), a2.x); a2.y = fmaf(pC, bf_hi(uC.x), a2.y);
            a2.z = fmaf(pC, bf_lo(uC.y), a2.z); a2.w = fmaf(pC, bf_hi(uC.y), a2.w);
            a3.x = fmaf(pD, bf_lo(uD.x), a3.x); a3.y = fmaf(pD, bf_hi(uD.x), a3.y);
            a3.z = fmaf(pD, bf_lo(uD.y), a3.z); a3.w = fmaf(pD, bf_hi(uD.y), a3.w);
        }
        for (; j2 < nq; j2++) {
            int q = 4 * j2 + qd;
            float pq = __shfl(p, q, 64); int sq = __shfl(src, q, 64);
            uint2 u = *((const uint2*)(hb + (size_t)sq * 64) + ql);
            a0.x = fmaf(pq, bf_lo(u.x), a0.x); a0.y = fmaf(pq, bf_hi(u.x), a0.y);
            a0.z = fmaf(pq, bf_lo(u.y), a0.z); a0.w = fmaf(pq, bf_hi(u.y), a0.w);
        }
    }
    float S = wave_sum(sl);
    float inv = 1.f / S;
    float4 r;
    r.x = (a0.x + a1.x) + (a2.x + a3.x);
    r.y = (a0.y + a1.y) + (a2.y + a3.y);
    r.z = (a0.z + a1.z) + (a2.z + a3.z);
    r.w = (a0.w + a1.w) + (a2.w + a3.w);
    r.x += __shfl_xor(r.x, 16, 64); r.y += __shfl_xor(r.y, 16, 64);
    r.z += __shfl_xor(r.z, 16, 64); r.w += __shfl_xor(r.w, 16, 64);
    r.x += __shfl_xor(r.x, 32, 64); r.y += __shfl_xor(r.y, 32, 64);
    r.z += __shfl_xor(r.z, 32, 64); r.w += __shfl_xor(r.w, 32, 64);
    if (qd == 0) {
        float4 b = ((const float4*)(pb + P_B2))[ql];
        r.x = fmaf(r.x, inv, b.x); r.y = fmaf(r.y, inv, b.y);
        r.z = fmaf(r.z, inv, b.z); r.w = fmaf(r.w, inv, b.w);
        ((float4*)(out + (size_t)node * 64))[ql] = r;
        uint2 u = {pk2(r.x, r.y), pk2(r.z, r.w)};
        ((uint2*)(lat16 + (size_t)node * 64))[ql] = u;
        int isbf = flags[0];
        long long o4 = out_off + (long long)node * 64 + 4 * ql;
        st_out(out_dev, o4 + 0, r.x, isbf);
        st_out(out_dev, o4 + 1, r.y, isbf);
        st_out(out_dev, o4 + 2, r.z, isbf);
        st_out(out_dev, o4 + 3, r.w, isbf);
        // fused conv3 es/ed: latent . (W3 a3s/d); lanes 0-15 all active -> shfl safe
        const float* w3s = pb + P_W3S;
        const float* w3d = pb + P_W3D;
        float s3 = r.x * w3s[4 * ql] + r.y * w3s[4 * ql + 1] +
                   r.z * w3s[4 * ql + 2] + r.w * w3s[4 * ql + 3];
        float d3 = r.x * w3d[4 * ql] + r.y * w3d[4 * ql + 1] +
                   r.z * w3d[4 * ql + 2] + r.w * w3d[4 * ql + 3];
#pragma unroll
        for (int o = 8; o >= 1; o >>= 1) {
            s3 += __shfl_xor(s3, o, 64);
            d3 += __shfl_xor(d3, o, 64);
        }
        if (ql == 0) { es2[node] = s3; ed2[node] = d3; }
    }
}

// ---------------- conv3 aggregation: gather lat16 (64-dim bf16) ----------------
__global__ __launch_bounds__(256) void k_wsumx64(
        const unsigned short* __restrict__ lat16, const float* __restrict__ es,
        const float* __restrict__ ed, const int* __restrict__ off,
        const int* __restrict__ csr_send, float* __restrict__ lagg) {
    int wid = threadIdx.x >> 6, lane = threadIdx.x & 63;
    int node = blockIdx.x * 4 + wid;
    if (node >= N_NODES) return;
    int start = off[node], end = off[node + 1];
    float edi = ed[node];

    const int qd = lane >> 4;
    const int ql = lane & 15;
    float4 a0 = {0.f, 0.f, 0.f, 0.f}, a1 = {0.f, 0.f, 0.f, 0.f};
    float4 a2 = {0.f, 0.f, 0.f, 0.f}, a3 = {0.f, 0.f, 0.f, 0.f};
    float sl = 0.f;

    for (int base = start; base < end; base += 64) {
        int j = base + lane;
        bool valid = j < end;
        int src = valid ? csr_send[j] : 0;
        float p = valid ? attn_p(es[src], edi) : 0.f;
        sl += p;
        int cnt = min(64, end - base);
        int nq = (cnt + 3) >> 2;
        int j2 = 0;
        for (; j2 + 4 <= nq; j2 += 4) {
            int qA = 4 * j2 + qd;
            float pA = __shfl(p, qA, 64);      int sA = __shfl(src, qA, 64);
            float pB = __shfl(p, qA + 4, 64);  int sB = __shfl(src, qA + 4, 64);
            float pC = __shfl(p, qA + 8, 64);  int sC = __shfl(src, qA + 8, 64);
            float pD = __shfl(p, qA + 12, 64); int sD = __shfl(src, qA + 12, 64);
            uint2 uA = *((const uint2*)(lat16 + (size_t)sA * 64) + ql);
            uint2 uB = *((const uint2*)(lat16 + (size_t)sB * 64) + ql);
            uint2 uC = *((const uint2*)(lat16 + (size_t)sC * 64) + ql);
            uint2 uD = *((const uint2*)(lat16 + (size_t)sD * 64) + ql);
            a0.x = fmaf(pA, bf_lo(uA.x), a0.x); a0.y = fmaf(pA, bf_hi(uA.x), a0.y);
            a0.z = fmaf(pA, bf_lo(uA.y), a0.z); a0.w = fmaf(pA, bf_hi(uA.y), a0.w);
            a1.x = fmaf(pB, bf_lo(uB.x), a1.x); a1.y = fmaf(pB, bf_hi(uB.x), a1.y);
            a1.z = fmaf(pB, bf_lo(uB.y), a1.z); a1.w = fmaf(pB, bf_hi(uB.y), a1.w);
            a2.x = fmaf(pC, bf_lo(uC.x), a2.x); a2.y = fmaf(pC, bf_hi(uC.x), a2.y);
            a2.z = fmaf(pC, bf_lo(uC.y), a2.z); a2.w = fmaf(pC, bf_hi(uC.y), a2.w);
            a3.x = fmaf(pD, bf_lo(uD.x), a3.x); a3.y = fmaf(pD, bf_hi(uD.x), a3.y);
            a3.z = fmaf(pD, bf_lo(uD.y), a3.z); a3.w = fmaf(pD, bf_hi(uD.y), a3.w);
        }
        for (; j2 < nq; j2++) {
            int q = 4 * j2 + qd;
            float pq = __shfl(p, q, 64); int sq = __shfl(src, q, 64);
            uint2 u = *((const uint2*)(lat16 + (size_t)sq * 64) + ql);
            a0.x = fmaf(pq, bf_lo(u.x), a0.x); a0.y = fmaf(pq, bf_hi(u.x), a0.y);
            a0.z = fmaf(pq, bf_lo(u.y), a0.z); a0.w = fmaf(pq, bf_hi(u.y), a0.w);
        }
    }
    float S = wave_sum(sl);
    float inv = 1.f / S;
    float4 r;
    r.x = (a0.x + a1.x) + (a2.x + a3.x);
    r.y = (a0.y + a1.y) + (a2.y + a3.y);
    r.z = (a0.z + a1.z) + (a2.z + a3.z);
    r.w = (a0.w + a1.w) + (a2.w + a3.w);
    r.x += __shfl_xor(r.x, 16, 64); r.y += __shfl_xor(r.y, 16, 64);
    r.z += __shfl_xor(r.z, 16, 64); r.w += __shfl_xor(r.w, 16, 64);
    r.x += __shfl_xor(r.x, 32, 64); r.y += __shfl_xor(r.y, 32, 64);
    r.z += __shfl_xor(r.z, 32, 64); r.w += __shfl_xor(r.w, 32, 64);
    if (qd == 0) {
        r.x *= inv; r.y *= inv; r.z *= inv; r.w *= inv;
        ((float4*)(lagg + (size_t)node * 64))[ql] = r;
    }
}

// ---------------- conv4 aggregation (h3 padded f32) ----------------
__global__ __launch_bounds__(256) void k_wsum3f(
        const float* __restrict__ h, const float* __restrict__ es,
        const float* __restrict__ ed, const float* __restrict__ bias,
        const int* __restrict__ off, const int* __restrict__ csr_send,
        void* __restrict__ out_dev, long long out_off, const int* __restrict__ flags) {
    int wid = threadIdx.x >> 6, lane = threadIdx.x & 63;
    int node = blockIdx.x * 4 + wid;
    if (node >= N_NODES) return;
    int start = off[node], end = off[node + 1];
    float edi = ed[node];

    float a0 = 0.f, a1 = 0.f, a2 = 0.f, sl = 0.f;
    for (int j = start + lane; j < end; j += 64) {
        int s = csr_send[j];
        float p = attn_p(es[s], edi);
        sl += p;
        float4 rv = *(const float4*)(h + (size_t)s * 4);
        a0 = fmaf(p, rv.x, a0);
        a1 = fmaf(p, rv.y, a1);
        a2 = fmaf(p, rv.z, a2);
    }
    float S = wave_sum(sl);
    a0 = wave_sum(a0);
    a1 = wave_sum(a1);
    a2 = wave_sum(a2);
    if (lane < 3) {
        float inv = 1.f / S;
        float v = fmaf((lane == 0 ? a0 : (lane == 1 ? a1 : a2)), inv, bias[lane]);
        st_out(out_dev, out_off + (long long)node * 3 + lane, v, flags[0]);
    }
}

// ---------------- pooling + classifier (fused) ----------------
#define POOL_W 16
__global__ void k_poolcls(const float* __restrict__ latent, const void* __restrict__ batch,
                          const int* __restrict__ flags, const float* __restrict__ pb,
                          void* __restrict__ out_dev, long long out_off) {
    int b = blockIdx.x;
    int lane = threadIdx.x & 63;
    int wave = threadIdx.x >> 6;
    int is64 = flags[1];
    int lo = 0, hi = N_NODES;
    while (lo < hi) { int mid = (lo + hi) >> 1; if (ld_idx(batch, mid, is64) < b) lo = mid + 1; else hi = mid; }
    int start = lo;
    lo = 0; hi = N_NODES;
    while (lo < hi) { int mid = (lo + hi) >> 1; if (ld_idx(batch, mid, is64) < b + 1) lo = mid + 1; else hi = mid; }
    int end = lo;
    float s = 0.f;
    for (int n = start + wave; n < end; n += POOL_W) s += latent[(size_t)n * 64 + lane];
    __shared__ float red[POOL_W][64];
    __shared__ float ps[64];
    red[wave][lane] = s;
    __syncthreads();
    if (wave == 0) {
        float t = s;
#pragma unroll
        for (int w2 = 1; w2 < POOL_W; w2++) t += red[w2][lane];
        float cnt = (float)(end - start);
        ps[lane] = t / fmaxf(cnt, 1.f);
    }
    __syncthreads();
    if (wave == 0 && lane < 32) {
        float z = pb[P_BC1 + lane];
        for (int c = 0; c < 64; c++) z = fmaf(ps[c], pb[P_WC1 + c * 32 + lane], z);
        z = fmaxf(z, 0.f);
        float p0 = z * pb[P_WC2 + lane * 2];
        float p1 = z * pb[P_WC2 + lane * 2 + 1];
#pragma unroll
        for (int o = 16; o >= 1; o >>= 1) {
            p0 += __shfl_xor(p0, o, 64);
            p1 += __shfl_xor(p1, o, 64);
        }
        if (lane == 0) {
            int isbf = flags[0];
            st_out(out_dev, out_off + b * 2 + 0, p0 + pb[P_BC2], isbf);
            st_out(out_dev, out_off + b * 2 + 1, p1 + pb[P_BC2 + 1], isbf);
        }
    }
}

extern "C" void kernel_launch(void* const* d_in, const int* in_sizes, int n_in,
                              void* d_out, int out_size, void* d_ws, size_t ws_size,
                              hipStream_t stream) {
    const void* x    = d_in[0];
    const void* eidx = d_in[1];
    const void* batch= d_in[2];

    // workspace carve-up (256B aligned)
    char* w = (char*)d_ws;
    size_t o = 0;
    auto carve = [&](size_t bytes) { void* p = w + o; o = (o + bytes + 255) & ~(size_t)255; return p; };
    int* flags    = (int*)carve(8 * sizeof(int));
    int* off      = (int*)carve((N_NODES + 1) * sizeof(int));
    int* loff     = (int*)carve(N_NODES * sizeof(int));
    int* bsum     = (int*)carve(NBUCK * sizeof(int));
    int* gcur     = (int*)carve(NBUCK * sizeof(int));
    int* ovf_cnt  = (int*)carve(sizeof(int));
    int* csr_send = (int*)carve((size_t)(N_EDGES + N_NODES) * sizeof(int));
    unsigned int* stage = (unsigned int*)carve((size_t)NBUCK * BUCK_CAP * sizeof(unsigned int));
    uint2* ovf    = (uint2*)carve((size_t)OVF_CAP * sizeof(uint2));
    float* pblock = (float*)carve(P_TOTAL * sizeof(float));
    float* x4     = (float*)carve((size_t)N_NODES * 4 * sizeof(float));
    float* buf0   = (float*)carve((size_t)N_NODES * 128 * sizeof(float));
    unsigned short* hb = (unsigned short*)carve((size_t)N_NODES * 64 * sizeof(unsigned short));
    unsigned short* lat16 = (unsigned short*)carve((size_t)N_NODES * 64 * sizeof(unsigned short));
    float* lagg   = (float*)carve((size_t)N_NODES * 64 * sizeof(float));
    float* h3     = (float*)carve((size_t)N_NODES * 4 * sizeof(float));
    float* es     = (float*)carve(N_NODES * sizeof(float));
    float* ed     = (float*)carve(N_NODES * sizeof(float));
    float* es2    = (float*)carve(N_NODES * sizeof(float));
    float* ed2    = (float*)carve(N_NODES * sizeof(float));

    int gW = N_NODES / 4;

    // fused prep (+conv1 es/ed)
    PTab tab;
    const int pn[20]  = {384,128,128,128, 8192,64,64,64, 8192,128,128,128, 384,3,3,3, 2048,32,64,2};
    const int pof[20] = {P_W1,P_A1S,P_A1D,P_B1, P_W2,P_A2S,P_A2D,P_B2, P_W3,P_A3S,P_A3D,P_B3,
                         P_W4,P_A4S,P_A4D,P_B4, P_WC1,P_BC1,P_WC2,P_BC2};
    for (int i = 0; i < 20; i++) { tab.src[i] = d_in[3 + i]; tab.off[i] = pof[i]; tab.n[i] = pn[i]; }
    k_prep<<<PREP_BLKS, 256, 0, stream>>>(x, eidx, d_in[3], d_in[4], d_in[5],
                                          d_in[11], d_in[12], d_in[13],
                                          tab, pblock, x4, es, ed, gcur, ovf_cnt, flags);

    // CSR build
    k_bucket<<<NBLK1, 256, 0, stream>>>(eidx, flags, gcur, stage, ovf_cnt, ovf);
    k_count2<<<NBUCK, 256, 0, stream>>>(gcur, stage, ovf_cnt, ovf, loff, bsum);
    k_fill3<<<NBUCK, 256, 0, stream>>>(gcur, stage, ovf_cnt, ovf, loff, bsum, off, csr_send);

    const long long OFF_RECON = 0, OFF_LATENT = 150000, OFF_NOISE = 3350000;

    int g128 = (N_NODES + 127) / 128;
    int g64  = (N_NODES + 63) / 64;
    int g256 = (N_NODES + 255) / 256;

    // conv1: gather x + fused post-GEMM -> buf0 (relu'd h1)
    k_wsumx3<<<gW, 256, 0, stream>>>(x4, es, ed, pblock, off, csr_send, buf0);

    // conv2: GEMM -> bf16 h + es/ed; gather -> latent (+ fused conv3 es2/ed2)
    k_gemm<128, 128, 64, 0><<<g128, 256, 0, stream>>>(buf0, pblock + P_W2, pblock + P_A2S,
                                                      pblock + P_A2D, pblock, hb, es, ed);
    k_wsum64f<<<gW, 256, 0, stream>>>(hb, es, ed, pblock, off, csr_send,
                                      buf0, lat16, es2, ed2, d_out, OFF_LATENT, flags);

    // pooling + classifier
    k_poolcls<<<NB, POOL_W * 64, 0, stream>>>(buf0, batch, flags, pblock, d_out, OFF_NOISE);

    // conv3: gather lat16 -> lagg; post-GEMM -> buf0
    k_wsumx64<<<gW, 256, 0, stream>>>(lat16, es2, ed2, off, csr_send, lagg);
    k_gemm<64, 64, 128, 2><<<g64, 256, 0, stream>>>(lagg, pblock + P_W3, pblock, pblock,
                                                    pblock + P_B3, buf0, es, ed);

    // conv4: GEMM -> h3 pad4 + es/ed; gather -> reconstructed
    k_gemm<128, 128, 3, 1><<<g256, 256, 0, stream>>>(buf0, pblock + P_W4, pblock + P_A4S,
                                                     pblock + P_A4D, pblock, h3, es, ed);
    k_wsum3f<<<gW, 256, 0, stream>>>(h3, es, ed, pblock + P_B4, off, csr_send,
                                     d_out, OFF_RECON, flags);
}

// Round 17
// 216.534 us; speedup vs baseline: 4.0001x; 1.0736x over previous
//
#include <hip/hip_runtime.h>
#include <hip/hip_bf16.h>

typedef __hip_bfloat16 bf16;

#define N_NODES 50000
#define N_EDGES 800000
#define NB 64

// bucketed CSR build
#define NBUCK 256
#define BUCK_R ((N_NODES + NBUCK - 1) / NBUCK)            // 196 nodes/bucket
#define BUCK_CAP 4352                                     // mean 3136, +21 sigma
#define OVF_CAP 65536
#define NBLK1 256
#define CHUNK1 ((N_EDGES + NBLK1 - 1) / NBLK1)            // 3125 edges/block
#define NIT ((CHUNK1 + 255) / 256)                        // 13 iters/thread

// k_prep block partition
#define XN_BLKS ((N_NODES + 255) / 256)                   // 196
#define PREP_BLKS (XN_BLKS + 20 + 1)

// param block offsets (floats)
#define P_W1 0
#define P_A1S 384
#define P_A1D 512
#define P_B1 640
#define P_W2 768
#define P_A2S 8960
#define P_A2D 9024
#define P_B2 9088
#define P_W3 9152
#define P_A3S 17344
#define P_A3D 17472
#define P_B3 17600
#define P_W4 17728
#define P_A4S 18112
#define P_A4D 18115
#define P_B4 18118
#define P_WC1 18121
#define P_BC1 20169
#define P_WC2 20201
#define P_BC2 20265
// factored attention vectors for conv3
#define P_W3S 20280
#define P_W3D 20344
#define P_TOTAL 20408

__device__ __forceinline__ float wave_sum(float v) {
#pragma unroll
    for (int o = 32; o >= 1; o >>= 1) v += __shfl_xor(v, o, 64);
    return v;
}

__device__ __forceinline__ unsigned int pk2(float a, float b) {
    bf16 x = __float2bfloat16(a);
    bf16 y = __float2bfloat16(b);
    unsigned short ux = *reinterpret_cast<unsigned short*>(&x);
    unsigned short uy = *reinterpret_cast<unsigned short*>(&y);
    return ((unsigned int)uy << 16) | ux;
}
__device__ __forceinline__ float bf_lo(unsigned int u) {
    unsigned int v = u << 16;
    return *reinterpret_cast<float*>(&v);
}
__device__ __forceinline__ float bf_hi(unsigned int u) {
    unsigned int v = u & 0xffff0000u;
    return *reinterpret_cast<float*>(&v);
}

// runtime dtype helpers: flags[0]=float-inputs-are-bf16, flags[1]=ints-are-int64
__device__ __forceinline__ int ld_idx(const void* p, long long i, int is64) {
    return is64 ? (int)((const long long*)p)[i] : ((const int*)p)[i];
}
__device__ __forceinline__ float ldf(const void* p, int i, int isbf) {
    return isbf ? __bfloat162float(((const bf16*)p)[i]) : ((const float*)p)[i];
}
__device__ __forceinline__ void st_out(void* p, long long i, float v, int isbf) {
    if (isbf) ((bf16*)p)[i] = __float2bfloat16(v);
    else ((float*)p)[i] = v;
}

// unnormalized attention weight
__device__ __forceinline__ float attn_p(float esv, float edi) {
    float v = esv + edi;
    float e = (v >= 0.f) ? v : 0.2f * v;
    return __expf(fminf(e, 60.f));
}

// ---------------- fused prep (+ conv1 es/ed) ----------------
struct PTab {
    const void* src[20];
    int off[20];
    int n[20];
};

__global__ __launch_bounds__(256) void k_prep(
        const void* __restrict__ x, const void* __restrict__ eidx,
        const void* __restrict__ rW1, const void* __restrict__ rA1s,
        const void* __restrict__ rA1d, const void* __restrict__ rW3,
        const void* __restrict__ rA3s, const void* __restrict__ rA3d,
        PTab tab, float* __restrict__ pblock, float* __restrict__ x4,
        float* __restrict__ es, float* __restrict__ ed,
        int* __restrict__ gcur, int* __restrict__ ovf_cnt, int* __restrict__ flags) {
    __shared__ int scnt[2];
    __shared__ float sw[6];
    const int t = threadIdx.x;
    if (t < 2) scnt[t] = 0;
    __syncthreads();
    {
        const unsigned short* xr = (const unsigned short*)x;
        unsigned int hb = (xr[2 * t] >> 8) & 0x7F;
        if (hb >= 58 && hb <= 65) atomicAdd(&scnt[0], 1);
        if (t < 64) {
            const unsigned int* er = (const unsigned int*)eidx;
            if (er[2 * t + 1] == 0u) atomicAdd(&scnt[1], 1);
        }
    }
    __syncthreads();
    const int isbf = (scnt[0] >= 200) ? 1 : 0;
    const int is64 = (scnt[1] >= 60) ? 1 : 0;

    const int b = blockIdx.x;
    if (b < XN_BLKS) {
        if (t < 6) {
            int row = (t < 3) ? t : t - 3;
            const void* av = (t < 3) ? rA1s : rA1d;
            float s = 0.f;
            for (int k = 0; k < 128; k++)
                s = fmaf(ldf(rW1, row * 128 + k, isbf), ldf(av, k, isbf), s);
            sw[t] = s;
        }
        __syncthreads();
        int node = b * 256 + t;
        if (node < N_NODES) {
            float x0 = ldf(x, node * 3 + 0, isbf);
            float x1 = ldf(x, node * 3 + 1, isbf);
            float x2 = ldf(x, node * 3 + 2, isbf);
            float4 v = {x0, x1, x2, 0.f};
            *(float4*)&x4[node * 4] = v;
            es[node] = x0 * sw[0] + x1 * sw[1] + x2 * sw[2];
            ed[node] = x0 * sw[3] + x1 * sw[4] + x2 * sw[5];
        }
    } else if (b < XN_BLKS + 20) {
        int p = b - XN_BLKS;
        const void* s = tab.src[p];
        float* d = pblock + tab.off[p];
        int n = tab.n[p];
        for (int i = t; i < n; i += 256) d[i] = ldf(s, i, isbf);
    } else {
        if (t < NBUCK) gcur[t] = 0;
        if (t == 0) { *ovf_cnt = 0; flags[0] = isbf; flags[1] = is64; }
        if (t >= 64 && t < 128) {  // w3s/w3d: W3 [64][128] . a3s/a3d
            int k = t - 64;
            float s = 0.f, d = 0.f;
            for (int c = 0; c < 128; c++) {
                float wv = ldf(rW3, k * 128 + c, isbf);
                s = fmaf(wv, ldf(rA3s, c, isbf), s);
                d = fmaf(wv, ldf(rA3d, c, isbf), d);
            }
            pblock[P_W3S + k] = s;
            pblock[P_W3D + k] = d;
        }
    }
}

// ---------------- bucket phase ----------------
__global__ __launch_bounds__(256) void k_bucket(
        const void* __restrict__ eidx, const int* __restrict__ flags,
        int* __restrict__ gcur, unsigned int* __restrict__ stage,
        int* __restrict__ ovf_cnt, uint2* __restrict__ ovf) {
    __shared__ int hist[NBUCK];
    __shared__ int base[NBUCK];
    const int t = threadIdx.x;
    const int is64 = flags[1];
    const int e0 = blockIdx.x * CHUNK1;
    const int e1 = min(e0 + CHUNK1, N_EDGES);

    unsigned int ent[NIT];
    int bk[NIT];
    hist[t] = 0;
    __syncthreads();
#pragma unroll
    for (int it = 0; it < NIT; it++) {
        int e = e0 + t + it * 256;
        int b = -1;
        unsigned int en = 0;
        if (e < e1) {
            int r = ld_idx(eidx, (long long)N_EDGES + e, is64);
            int s = ld_idx(eidx, e, is64);
            b = r / BUCK_R;
            en = ((unsigned)(r - b * BUCK_R) << 16) | (unsigned)s;
            atomicAdd(&hist[b], 1);
        }
        ent[it] = en;
        bk[it] = b;
    }
    __syncthreads();
    int cnt = hist[t];
    base[t] = (cnt > 0) ? atomicAdd(&gcur[t], cnt) : 0;
    __syncthreads();
    hist[t] = 0;
    __syncthreads();
#pragma unroll
    for (int it = 0; it < NIT; it++) {
        int b = bk[it];
        if (b >= 0) {
            int l = atomicAdd(&hist[b], 1);
            int slot = base[b] + l;
            if (slot < BUCK_CAP) {
                stage[(size_t)b * BUCK_CAP + slot] = ent[it];
            } else {
                int oi = atomicAdd(ovf_cnt, 1);
                int r = b * BUCK_R + (int)(ent[it] >> 16);
                if (oi < OVF_CAP) ovf[oi] = make_uint2(ent[it] & 0xffffu, (unsigned)r);
            }
        }
    }
}

// ---------------- counts + bucket-local exclusive scan ----------------
__global__ __launch_bounds__(256) void k_count2(
        const int* __restrict__ gcur, const unsigned int* __restrict__ stage,
        const int* __restrict__ ovf_cnt, const uint2* __restrict__ ovf,
        int* __restrict__ loff, int* __restrict__ bsum) {
    __shared__ int hist[256];
    __shared__ int ss[256];
    const int b = blockIdx.x;
    const int r0 = b * BUCK_R;
    const int nr = min(BUCK_R, N_NODES - r0);
    const int t = threadIdx.x;
    hist[t] = 0;
    __syncthreads();
    const int cnt = min(gcur[b], BUCK_CAP);
    const unsigned int* sb = stage + (size_t)b * BUCK_CAP;
    for (int i = t; i < cnt; i += 256) atomicAdd(&hist[sb[i] >> 16], 1);
    int oc = min(*ovf_cnt, OVF_CAP);
    for (int i = t; i < oc; i += 256) {
        int r = (int)ovf[i].y;
        if (r >= r0 && r < r0 + nr) atomicAdd(&hist[r - r0], 1);
    }
    __syncthreads();
    int v = (t < nr) ? hist[t] + 1 : 0;  // +1 self loop
    ss[t] = v;
    __syncthreads();
#pragma unroll
    for (int o = 1; o < 256; o <<= 1) {
        int add = (t >= o) ? ss[t - o] : 0;
        __syncthreads();
        ss[t] += add;
        __syncthreads();
    }
    if (t < nr) loff[r0 + t] = ss[t] - v;
    if (t == 255) bsum[b] = ss[255];
}

// ---------------- fill: self-scans bsum, writes off + csr ----------------
__global__ __launch_bounds__(256) void k_fill3(
        const int* __restrict__ gcur, const unsigned int* __restrict__ stage,
        const int* __restrict__ ovf_cnt, const uint2* __restrict__ ovf,
        const int* __restrict__ loff, const int* __restrict__ bsum,
        int* __restrict__ off, int* __restrict__ csr_send) {
    __shared__ int sbs[NBUCK];
    __shared__ int ss[NBUCK];
    __shared__ int sstart[BUCK_R];
    __shared__ int lcur[BUCK_R];
    const int b = blockIdx.x;
    const int t = threadIdx.x;
    int v = bsum[t];
    sbs[t] = v;
    ss[t] = v;
    __syncthreads();
#pragma unroll
    for (int o = 1; o < NBUCK; o <<= 1) {
        int add = (t >= o) ? ss[t - o] : 0;
        __syncthreads();
        ss[t] += add;
        __syncthreads();
    }
    const int bb = ss[b] - sbs[b];
    if (b == NBUCK - 1 && t == 0) off[N_NODES] = ss[NBUCK - 1];

    const int r0 = b * BUCK_R;
    const int nr = min(BUCK_R, N_NODES - r0);
    for (int i = t; i < nr; i += 256) {
        int st = bb + loff[r0 + i];
        sstart[i] = st;
        off[r0 + i] = st;
        lcur[i] = 1;
        csr_send[st] = r0 + i;      // self loop in slot 0
    }
    __syncthreads();
    const int cnt = min(gcur[b], BUCK_CAP);
    const unsigned int* sb = stage + (size_t)b * BUCK_CAP;
    for (int i = t; i < cnt; i += 256) {
        unsigned int e = sb[i];
        int rl = (int)(e >> 16);
        int l = atomicAdd(&lcur[rl], 1);
        csr_send[sstart[rl] + l] = (int)(e & 0xffffu);
    }
    int oc = min(*ovf_cnt, OVF_CAP);
    for (int i = t; i < oc; i += 256) {
        uint2 pr = ovf[i];
        int r = (int)pr.y;
        if (r >= r0 && r < r0 + nr) {
            int rl = r - r0;
            int l = atomicAdd(&lcur[rl], 1);
            csr_send[sstart[rl] + l] = (int)pr.x;
        }
    }
}

// ---------------- conv1: gather x4 + fused post-GEMM (+bias+relu) --------------
__global__ __launch_bounds__(256) void k_wsumx3(
        const float* __restrict__ x4, const float* __restrict__ es,
        const float* __restrict__ ed, const float* __restrict__ pb,
        const int* __restrict__ off, const int* __restrict__ csr_send,
        float* __restrict__ out) {
    int wid = threadIdx.x >> 6, lane = threadIdx.x & 63;
    int node = blockIdx.x * 4 + wid;
    if (node >= N_NODES) return;
    int start = off[node], end = off[node + 1];
    float edi = ed[node];
    float a0 = 0.f, a1 = 0.f, a2 = 0.f, sl = 0.f;
    for (int j = start + lane; j < end; j += 64) {
        int s = csr_send[j];
        float p = attn_p(es[s], edi);
        sl += p;
        float4 xv = *(const float4*)&x4[s * 4];
        a0 = fmaf(p, xv.x, a0);
        a1 = fmaf(p, xv.y, a1);
        a2 = fmaf(p, xv.z, a2);
    }
    float S = wave_sum(sl);
    a0 = wave_sum(a0);
    a1 = wave_sum(a1);
    a2 = wave_sum(a2);
    float inv = 1.f / S;
    a0 *= inv; a1 *= inv; a2 *= inv;
    const float* W1 = pb + P_W1;
    const float* b1 = pb + P_B1;
    int c0 = lane, c1 = lane + 64;
    float v0 = fmaf(a0, W1[c0], fmaf(a1, W1[128 + c0], fmaf(a2, W1[256 + c0], b1[c0])));
    float v1 = fmaf(a0, W1[c1], fmaf(a1, W1[128 + c1], fmaf(a2, W1[256 + c1], b1[c1])));
    out[(size_t)node * 128 + c0] = fmaxf(v0, 0.f);
    out[(size_t)node * 128 + c1] = fmaxf(v1, 0.f);
}

// ---------------- register-tiled GEMM ----------------
// MODE 0: pre (es/ed + bf16 h out), used for conv2.
// MODE 3: conv3-post (bias+relu in reg) fused with conv4-pre (128->3 proj +
//         es/ed via cg-lane shfl tree), writes h3 pad4 + es/ed. as_ = pblock.
template <int DIN, int DINS, int DOUT, int MODE>
__global__ __launch_bounds__(256) void k_gemm(
        const float* __restrict__ in, const float* __restrict__ W,
        const float* __restrict__ as_, const float* __restrict__ ad_,
        const float* __restrict__ bias, void* __restrict__ hout,
        float* __restrict__ es, float* __restrict__ ed) {
    constexpr int KC = (DIN < 32) ? DIN : 32;
    constexpr int NCH = DIN / KC;
    constexpr int CG = DOUT / 8;
    constexpr int NT = (256 / CG) * 4;
    constexpr int NTP = NT + 4;

    __shared__ float sX[KC][NTP];
    __shared__ float sW[KC][DOUT];

    const int t = threadIdx.x;
    const int node0 = blockIdx.x * NT;
    const int nvalid = min(NT, N_NODES - node0);

    const int cg = t & (CG - 1);
    const int ng = t / CG;

    float acc[4][8] = {};

    for (int ch = 0; ch < NCH; ch++) {
        const int k0 = ch * KC;
        if (ch > 0) __syncthreads();
        for (int i = t; i < nvalid * KC; i += 256) {
            int n = i / KC, k = i - n * KC;
            sX[k][n] = in[(size_t)(node0 + n) * DINS + k0 + k];
        }
        for (int i = t; i < KC * DOUT; i += 256) {
            int k = i / DOUT, c = i - k * DOUT;
            sW[k][c] = W[(size_t)(k0 + k) * DOUT + c];
        }
        __syncthreads();

#pragma unroll 4
        for (int k = 0; k < KC; k++) {
            float4 xv = *(const float4*)&sX[k][ng * 4];
            float4 w0 = *(const float4*)&sW[k][cg * 8];
            float4 w1 = *(const float4*)&sW[k][cg * 8 + 4];
            float xs[4] = {xv.x, xv.y, xv.z, xv.w};
            float ws[8] = {w0.x, w0.y, w0.z, w0.w, w1.x, w1.y, w1.z, w1.w};
#pragma unroll
            for (int j = 0; j < 4; j++)
#pragma unroll
                for (int c = 0; c < 8; c++)
                    acc[j][c] = fmaf(xs[j], ws[c], acc[j][c]);
        }
    }

    if constexpr (MODE == 0) {
        float asv[8], adv[8];
#pragma unroll
        for (int c = 0; c < 8; c++) {
            asv[c] = as_[cg * 8 + c];
            adv[c] = ad_[cg * 8 + c];
        }
#pragma unroll
        for (int j = 0; j < 4; j++) {
            int n = ng * 4 + j;
            float e_s = 0.f, e_d = 0.f;
#pragma unroll
            for (int c = 0; c < 8; c++) {
                e_s = fmaf(acc[j][c], asv[c], e_s);
                e_d = fmaf(acc[j][c], adv[c], e_d);
            }
#pragma unroll
            for (int m = 1; m < CG; m <<= 1) {
                e_s += __shfl_xor(e_s, m, 64);
                e_d += __shfl_xor(e_d, m, 64);
            }
            if (n < nvalid) {
                if (cg == 0) {
                    es[node0 + n] = e_s;
                    ed[node0 + n] = e_d;
                }
                unsigned short* hb = (unsigned short*)hout;
                uint4 u;
                u.x = pk2(acc[j][0], acc[j][1]);
                u.y = pk2(acc[j][2], acc[j][3]);
                u.z = pk2(acc[j][4], acc[j][5]);
                u.w = pk2(acc[j][6], acc[j][7]);
                *(uint4*)&hb[(size_t)(node0 + n) * DOUT + cg * 8] = u;
            }
        }
    } else {  // MODE 3
        const float* pbase = as_;
        const float* W4 = pbase + P_W4;
        float bv[8], w40[8], w41[8], w42[8];
#pragma unroll
        for (int c = 0; c < 8; c++) {
            bv[c] = bias[cg * 8 + c];
            int row = cg * 8 + c;
            w40[c] = W4[row * 3 + 0];
            w41[c] = W4[row * 3 + 1];
            w42[c] = W4[row * 3 + 2];
        }
        float a4s0 = pbase[P_A4S], a4s1 = pbase[P_A4S + 1], a4s2 = pbase[P_A4S + 2];
        float a4d0 = pbase[P_A4D], a4d1 = pbase[P_A4D + 1], a4d2 = pbase[P_A4D + 2];
        float* h3o = (float*)hout;
#pragma unroll
        for (int j = 0; j < 4; j++) {
            int n = ng * 4 + j;
            float h40 = 0.f, h41 = 0.f, h42 = 0.f;
#pragma unroll
            for (int c = 0; c < 8; c++) {
                float v = fmaxf(acc[j][c] + bv[c], 0.f);
                h40 = fmaf(v, w40[c], h40);
                h41 = fmaf(v, w41[c], h41);
                h42 = fmaf(v, w42[c], h42);
            }
#pragma unroll
            for (int m = 1; m < CG; m <<= 1) {
                h40 += __shfl_xor(h40, m, 64);
                h41 += __shfl_xor(h41, m, 64);
                h42 += __shfl_xor(h42, m, 64);
            }
            if (n < nvalid && cg == 0) {
                es[node0 + n] = h40 * a4s0 + h41 * a4s1 + h42 * a4s2;
                ed[node0 + n] = h40 * a4d0 + h41 * a4d1 + h42 * a4d2;
                float4 vv = {h40, h41, h42, 0.f};
                *(float4*)&h3o[(size_t)(node0 + n) * 4] = vv;
            }
        }
    }
}

// ---------------- conv2: softmax+wsum, bf16 h; fused conv3 es/ed epilogue ------
__global__ __launch_bounds__(256) void k_wsum64f(
        const unsigned short* __restrict__ hb, const float* __restrict__ es,
        const float* __restrict__ ed, const float* __restrict__ pb,
        const int* __restrict__ off, const int* __restrict__ csr_send,
        float* __restrict__ out, unsigned short* __restrict__ lat16,
        float* __restrict__ es2, float* __restrict__ ed2,
        void* __restrict__ out_dev, long long out_off, const int* __restrict__ flags) {
    int wid = threadIdx.x >> 6, lane = threadIdx.x & 63;
    int node = blockIdx.x * 4 + wid;
    if (node >= N_NODES) return;
    int start = off[node], end = off[node + 1];
    float edi = ed[node];

    const int qd = lane >> 4;
    const int ql = lane & 15;
    float4 a0 = {0.f, 0.f, 0.f, 0.f}, a1 = {0.f, 0.f, 0.f, 0.f};
    float4 a2 = {0.f, 0.f, 0.f, 0.f}, a3 = {0.f, 0.f, 0.f, 0.f};
    float sl = 0.f;

    for (int base = start; base < end; base += 64) {
        int j = base + lane;
        bool valid = j < end;
        int src = valid ? csr_send[j] : 0;
        float p = valid ? attn_p(es[src], edi) : 0.f;
        sl += p;
        int cnt = min(64, end - base);
        int nq = (cnt + 3) >> 2;
        int j2 = 0;
        for (; j2 + 4 <= nq; j2 += 4) {
            int qA = 4 * j2 + qd;
            float pA = __shfl(p, qA, 64);      int sA = __shfl(src, qA, 64);
            float pB = __shfl(p, qA + 4, 64);  int sB = __shfl(src, qA + 4, 64);
            float pC = __shfl(p, qA + 8, 64);  int sC = __shfl(src, qA + 8, 64);
            float pD = __shfl(p, qA + 12, 64); int sD = __shfl(src, qA + 12, 64);
            uint2 uA = *((const uint2*)(hb + (size_t)sA * 64) + ql);
            uint2 uB = *((const uint2*)(hb + (size_t)sB * 64) + ql);
            uint2 uC = *((const uint2*)(hb + (size_t)sC * 64) + ql);
            uint2 uD = *((const uint2*)(hb + (size_t)sD * 64) + ql);
            a0.x = fmaf(pA, bf_lo(uA.x), a0.x); a0.y = fmaf(pA, bf_hi(uA.x), a0.y);
            a0.z = fmaf(pA, bf_lo(uA.y), a0.z); a0.w = fmaf(pA, bf_hi(uA.y), a0.w);
            a1.x = fmaf(pB, bf_lo(uB.x), a1.x); a1.y = fmaf(pB, bf_hi(uB.x), a1.y);
            a1.z = fmaf(pB, bf_lo(uB.y), a1.z); a1.w = fmaf(pB, bf_hi(uB.y), a1.w);
            a2.x = fmaf(pC, bf_lo(uC.x), a2.x); a2.y = fmaf(pC, bf_hi(uC.x), a2.y);
            a2.z = fmaf(pC, bf_lo(uC.y), a2.z); a2.w = fmaf(pC, bf_hi(uC.y), a2.w);
            a3.x = fmaf(pD, bf_lo(uD.x), a3.x); a3.y = fmaf(pD, bf_hi(uD.x), a3.y);
            a3.z = fmaf(pD, bf_lo(uD.y), a3.z); a3.w = fmaf(pD, bf_hi(uD.y), a3.w);
        }
        for (; j2 < nq; j2++) {
            int q = 4 * j2 + qd;
            float pq = __shfl(p, q, 64); int sq = __shfl(src, q, 64);
            uint2 u = *((const uint2*)(hb + (size_t)sq * 64) + ql);
            a0.x = fmaf(pq, bf_lo(u.x), a0.x); a0.y = fmaf(pq, bf_hi(u.x), a0.y);
            a0.z = fmaf(pq, bf_lo(u.y), a0.z); a0.w = fmaf(pq, bf_hi(u.y), a0.w);
        }
    }
    float S = wave_sum(sl);
    float inv = 1.f / S;
    float4 r;
    r.x = (a0.x + a1.x) + (a2.x + a3.x);
    r.y = (a0.y + a1.y) + (a2.y + a3.y);
    r.z = (a0.z + a1.z) + (a2.z + a3.z);
    r.w = (a0.w + a1.w) + (a2.w + a3.w);
    r.x += __shfl_xor(r.x, 16, 64); r.y += __shfl_xor(r.y, 16, 64);
    r.z += __shfl_xor(r.z, 16, 64); r.w += __shfl_xor(r.w, 16, 64);
    r.x += __shfl_xor(r.x, 32, 64); r.y += __shfl_xor(r.y, 32, 64);
    r.z += __shfl_xor(r.z, 32, 64); r.w += __shfl_xor(r.w, 32, 64);
    if (qd == 0) {
        float4 b = ((const float4*)(pb + P_B2))[ql];
        r.x = fmaf(r.x, inv, b.x); r.y = fmaf(r.y, inv, b.y);
        r.z = fmaf(r.z, inv, b.z); r.w = fmaf(r.w, inv, b.w);
        ((float4*)(out + (size_t)node * 64))[ql] = r;
        uint2 u = {pk2(r.x, r.y), pk2(r.z, r.w)};
        ((uint2*)(lat16 + (size_t)node * 64))[ql] = u;
        int isbf = flags[0];
        long long o4 = out_off + (long long)node * 64 + 4 * ql;
        st_out(out_dev, o4 + 0, r.x, isbf);
        st_out(out_dev, o4 + 1, r.y, isbf);
        st_out(out_dev, o4 + 2, r.z, isbf);
        st_out(out_dev, o4 + 3, r.w, isbf);
        const float* w3s = pb + P_W3S;
        const float* w3d = pb + P_W3D;
        float s3 = r.x * w3s[4 * ql] + r.y * w3s[4 * ql + 1] +
                   r.z * w3s[4 * ql + 2] + r.w * w3s[4 * ql + 3];
        float d3 = r.x * w3d[4 * ql] + r.y * w3d[4 * ql + 1] +
                   r.z * w3d[4 * ql + 2] + r.w * w3d[4 * ql + 3];
#pragma unroll
        for (int o = 8; o >= 1; o >>= 1) {
            s3 += __shfl_xor(s3, o, 64);
            d3 += __shfl_xor(d3, o, 64);
        }
        if (ql == 0) { es2[node] = s3; ed2[node] = d3; }
    }
}

// ---------------- conv3 aggregation: gather lat16 (64-dim bf16) ----------------
__global__ __launch_bounds__(256) void k_wsumx64(
        const unsigned short* __restrict__ lat16, const float* __restrict__ es,
        const float* __restrict__ ed, const int* __restrict__ off,
        const int* __restrict__ csr_send, float* __restrict__ lagg) {
    int wid = threadIdx.x >> 6, lane = threadIdx.x & 63;
    int node = blockIdx.x * 4 + wid;
    if (node >= N_NODES) return;
    int start = off[node], end = off[node + 1];
    float edi = ed[node];

    const int qd = lane >> 4;
    const int ql = lane & 15;
    float4 a0 = {0.f, 0.f, 0.f, 0.f}, a1 = {0.f, 0.f, 0.f, 0.f};
    float4 a2 = {0.f, 0.f, 0.f, 0.f}, a3 = {0.f, 0.f, 0.f, 0.f};
    float sl = 0.f;

    for (int base = start; base < end; base += 64) {
        int j = base + lane;
        bool valid = j < end;
        int src = valid ? csr_send[j] : 0;
        float p = valid ? attn_p(es[src], edi) : 0.f;
        sl += p;
        int cnt = min(64, end - base);
        int nq = (cnt + 3) >> 2;
        int j2 = 0;
        for (; j2 + 4 <= nq; j2 += 4) {
            int qA = 4 * j2 + qd;
            float pA = __shfl(p, qA, 64);      int sA = __shfl(src, qA, 64);
            float pB = __shfl(p, qA + 4, 64);  int sB = __shfl(src, qA + 4, 64);
            float pC = __shfl(p, qA + 8, 64);  int sC = __shfl(src, qA + 8, 64);
            float pD = __shfl(p, qA + 12, 64); int sD = __shfl(src, qA + 12, 64);
            uint2 uA = *((const uint2*)(lat16 + (size_t)sA * 64) + ql);
            uint2 uB = *((const uint2*)(lat16 + (size_t)sB * 64) + ql);
            uint2 uC = *((const uint2*)(lat16 + (size_t)sC * 64) + ql);
            uint2 uD = *((const uint2*)(lat16 + (size_t)sD * 64) + ql);
            a0.x = fmaf(pA, bf_lo(uA.x), a0.x); a0.y = fmaf(pA, bf_hi(uA.x), a0.y);
            a0.z = fmaf(pA, bf_lo(uA.y), a0.z); a0.w = fmaf(pA, bf_hi(uA.y), a0.w);
            a1.x = fmaf(pB, bf_lo(uB.x), a1.x); a1.y = fmaf(pB, bf_hi(uB.x), a1.y);
            a1.z = fmaf(pB, bf_lo(uB.y), a1.z); a1.w = fmaf(pB, bf_hi(uB.y), a1.w);
            a2.x = fmaf(pC, bf_lo(uC.x), a2.x); a2.y = fmaf(pC, bf_hi(uC.x), a2.y);
            a2.z = fmaf(pC, bf_lo(uC.y), a2.z); a2.w = fmaf(pC, bf_hi(uC.y), a2.w);
            a3.x = fmaf(pD, bf_lo(uD.x), a3.x); a3.y = fmaf(pD, bf_hi(uD.x), a3.y);
            a3.z = fmaf(pD, bf_lo(uD.y), a3.z); a3.w = fmaf(pD, bf_hi(uD.y), a3.w);
        }
        for (; j2 < nq; j2++) {
            int q = 4 * j2 + qd;
            float pq = __shfl(p, q, 64); int sq = __shfl(src, q, 64);
            uint2 u = *((const uint2*)(lat16 + (size_t)sq * 64) + ql);
            a0.x = fmaf(pq, bf_lo(u.x), a0.x); a0.y = fmaf(pq, bf_hi(u.x), a0.y);
            a0.z = fmaf(pq, bf_lo(u.y), a0.z); a0.w = fmaf(pq, bf_hi(u.y), a0.w);
        }
    }
    float S = wave_sum(sl);
    float inv = 1.f / S;
    float4 r;
    r.x = (a0.x + a1.x) + (a2.x + a3.x);
    r.y = (a0.y + a1.y) + (a2.y + a3.y);
    r.z = (a0.z + a1.z) + (a2.z + a3.z);
    r.w = (a0.w + a1.w) + (a2.w + a3.w);
    r.x += __shfl_xor(r.x, 16, 64); r.y += __shfl_xor(r.y, 16, 64);
    r.z += __shfl_xor(r.z, 16, 64); r.w += __shfl_xor(r.w, 16, 64);
    r.x += __shfl_xor(r.x, 32, 64); r.y += __shfl_xor(r.y, 32, 64);
    r.z += __shfl_xor(r.z, 32, 64); r.w += __shfl_xor(r.w, 32, 64);
    if (qd == 0) {
        r.x *= inv; r.y *= inv; r.z *= inv; r.w *= inv;
        ((float4*)(lagg + (size_t)node * 64))[ql] = r;
    }
}

// ---------------- conv4 aggregation (h3 padded f32) ----------------
__global__ __launch_bounds__(256) void k_wsum3f(
        const float* __restrict__ h, const float* __restrict__ es,
        const float* __restrict__ ed, const float* __restrict__ bias,
        const int* __restrict__ off, const int* __restrict__ csr_send,
        void* __restrict__ out_dev, long long out_off, const int* __restrict__ flags) {
    int wid = threadIdx.x >> 6, lane = threadIdx.x & 63;
    int node = blockIdx.x * 4 + wid;
    if (node >= N_NODES) return;
    int start = off[node], end = off[node + 1];
    float edi = ed[node];

    float a0 = 0.f, a1 = 0.f, a2 = 0.f, sl = 0.f;
    for (int j = start + lane; j < end; j += 64) {
        int s = csr_send[j];
        float p = attn_p(es[s], edi);
        sl += p;
        float4 rv = *(const float4*)(h + (size_t)s * 4);
        a0 = fmaf(p, rv.x, a0);
        a1 = fmaf(p, rv.y, a1);
        a2 = fmaf(p, rv.z, a2);
    }
    float S = wave_sum(sl);
    a0 = wave_sum(a0);
    a1 = wave_sum(a1);
    a2 = wave_sum(a2);
    if (lane < 3) {
        float inv = 1.f / S;
        float v = fmaf((lane == 0 ? a0 : (lane == 1 ? a1 : a2)), inv, bias[lane]);
        st_out(out_dev, out_off + (long long)node * 3 + lane, v, flags[0]);
    }
}

// ---------------- pooling + classifier (fused) ----------------
#define POOL_W 16
__global__ void k_poolcls(const float* __restrict__ latent, const void* __restrict__ batch,
                          const int* __restrict__ flags, const float* __restrict__ pb,
                          void* __restrict__ out_dev, long long out_off) {
    int b = blockIdx.x;
    int lane = threadIdx.x & 63;
    int wave = threadIdx.x >> 6;
    int is64 = flags[1];
    int lo = 0, hi = N_NODES;
    while (lo < hi) { int mid = (lo + hi) >> 1; if (ld_idx(batch, mid, is64) < b) lo = mid + 1; else hi = mid; }
    int start = lo;
    lo = 0; hi = N_NODES;
    while (lo < hi) { int mid = (lo + hi) >> 1; if (ld_idx(batch, mid, is64) < b + 1) lo = mid + 1; else hi = mid; }
    int end = lo;
    float s = 0.f;
    for (int n = start + wave; n < end; n += POOL_W) s += latent[(size_t)n * 64 + lane];
    __shared__ float red[POOL_W][64];
    __shared__ float ps[64];
    red[wave][lane] = s;
    __syncthreads();
    if (wave == 0) {
        float t = s;
#pragma unroll
        for (int w2 = 1; w2 < POOL_W; w2++) t += red[w2][lane];
        float cnt = (float)(end - start);
        ps[lane] = t / fmaxf(cnt, 1.f);
    }
    __syncthreads();
    if (wave == 0 && lane < 32) {
        float z = pb[P_BC1 + lane];
        for (int c = 0; c < 64; c++) z = fmaf(ps[c], pb[P_WC1 + c * 32 + lane], z);
        z = fmaxf(z, 0.f);
        float p0 = z * pb[P_WC2 + lane * 2];
        float p1 = z * pb[P_WC2 + lane * 2 + 1];
#pragma unroll
        for (int o = 16; o >= 1; o >>= 1) {
            p0 += __shfl_xor(p0, o, 64);
            p1 += __shfl_xor(p1, o, 64);
        }
        if (lane == 0) {
            int isbf = flags[0];
            st_out(out_dev, out_off + b * 2 + 0, p0 + pb[P_BC2], isbf);
            st_out(out_dev, out_off + b * 2 + 1, p1 + pb[P_BC2 + 1], isbf);
        }
    }
}

extern "C" void kernel_launch(void* const* d_in, const int* in_sizes, int n_in,
                              void* d_out, int out_size, void* d_ws, size_t ws_size,
                              hipStream_t stream) {
    const void* x    = d_in[0];
    const void* eidx = d_in[1];
    const void* batch= d_in[2];

    // workspace carve-up (256B aligned)
    char* w = (char*)d_ws;
    size_t o = 0;
    auto carve = [&](size_t bytes) { void* p = w + o; o = (o + bytes + 255) & ~(size_t)255; return p; };
    int* flags    = (int*)carve(8 * sizeof(int));
    int* off      = (int*)carve((N_NODES + 1) * sizeof(int));
    int* loff     = (int*)carve(N_NODES * sizeof(int));
    int* bsum     = (int*)carve(NBUCK * sizeof(int));
    int* gcur     = (int*)carve(NBUCK * sizeof(int));
    int* ovf_cnt  = (int*)carve(sizeof(int));
    int* csr_send = (int*)carve((size_t)(N_EDGES + N_NODES) * sizeof(int));
    unsigned int* stage = (unsigned int*)carve((size_t)NBUCK * BUCK_CAP * sizeof(unsigned int));
    uint2* ovf    = (uint2*)carve((size_t)OVF_CAP * sizeof(uint2));
    float* pblock = (float*)carve(P_TOTAL * sizeof(float));
    float* x4     = (float*)carve((size_t)N_NODES * 4 * sizeof(float));
    float* buf0   = (float*)carve((size_t)N_NODES * 128 * sizeof(float));
    unsigned short* hb = (unsigned short*)carve((size_t)N_NODES * 64 * sizeof(unsigned short));
    unsigned short* lat16 = (unsigned short*)carve((size_t)N_NODES * 64 * sizeof(unsigned short));
    float* lagg   = (float*)carve((size_t)N_NODES * 64 * sizeof(float));
    float* h3     = (float*)carve((size_t)N_NODES * 4 * sizeof(float));
    float* es     = (float*)carve(N_NODES * sizeof(float));
    float* ed     = (float*)carve(N_NODES * sizeof(float));
    float* es2    = (float*)carve(N_NODES * sizeof(float));
    float* ed2    = (float*)carve(N_NODES * sizeof(float));

    int gW = N_NODES / 4;

    // fused prep (+conv1 es/ed)
    PTab tab;
    const int pn[20]  = {384,128,128,128, 8192,64,64,64, 8192,128,128,128, 384,3,3,3, 2048,32,64,2};
    const int pof[20] = {P_W1,P_A1S,P_A1D,P_B1, P_W2,P_A2S,P_A2D,P_B2, P_W3,P_A3S,P_A3D,P_B3,
                         P_W4,P_A4S,P_A4D,P_B4, P_WC1,P_BC1,P_WC2,P_BC2};
    for (int i = 0; i < 20; i++) { tab.src[i] = d_in[3 + i]; tab.off[i] = pof[i]; tab.n[i] = pn[i]; }
    k_prep<<<PREP_BLKS, 256, 0, stream>>>(x, eidx, d_in[3], d_in[4], d_in[5],
                                          d_in[11], d_in[12], d_in[13],
                                          tab, pblock, x4, es, ed, gcur, ovf_cnt, flags);

    // CSR build
    k_bucket<<<NBLK1, 256, 0, stream>>>(eidx, flags, gcur, stage, ovf_cnt, ovf);
    k_count2<<<NBUCK, 256, 0, stream>>>(gcur, stage, ovf_cnt, ovf, loff, bsum);
    k_fill3<<<NBUCK, 256, 0, stream>>>(gcur, stage, ovf_cnt, ovf, loff, bsum, off, csr_send);

    const long long OFF_RECON = 0, OFF_LATENT = 150000, OFF_NOISE = 3350000;

    int g128 = (N_NODES + 127) / 128;
    int g64  = (N_NODES + 63) / 64;

    // conv1: gather x + fused post-GEMM -> buf0 (relu'd h1)
    k_wsumx3<<<gW, 256, 0, stream>>>(x4, es, ed, pblock, off, csr_send, buf0);

    // conv2: GEMM -> bf16 h + es/ed; gather -> latent (+ fused conv3 es2/ed2)
    k_gemm<128, 128, 64, 0><<<g128, 256, 0, stream>>>(buf0, pblock + P_W2, pblock + P_A2S,
                                                      pblock + P_A2D, pblock, hb, es, ed);
    k_wsum64f<<<gW, 256, 0, stream>>>(hb, es, ed, pblock, off, csr_send,
                                      buf0, lat16, es2, ed2, d_out, OFF_LATENT, flags);

    // pooling + classifier
    k_poolcls<<<NB, POOL_W * 64, 0, stream>>>(buf0, batch, flags, pblock, d_out, OFF_NOISE);

    // conv3 gather -> lagg; fused conv3-post+conv4-pre GEMM -> h3 + es/ed
    k_wsumx64<<<gW, 256, 0, stream>>>(lat16, es2, ed2, off, csr_send, lagg);
    k_gemm<64, 64, 128, 3><<<g64, 256, 0, stream>>>(lagg, pblock + P_W3, pblock, pblock,
                                                    pblock + P_B3, h3, es, ed);

    // conv4 gather -> reconstructed
    k_wsum3f<<<gW, 256, 0, stream>>>(h3, es, ed, pblock + P_B4, off, csr_send,
                                     d_out, OFF_RECON, flags);
}